// Round 1
// 30928.961 us; speedup vs baseline: 1.0227x; 1.0227x over previous
//
#include <hip/hip_runtime.h>

typedef unsigned short u16;
typedef unsigned int u32;

#define DEVI __device__ __forceinline__

constexpr float SCALE_ATT = 0.04419417382415922f;  // 1/sqrt(512)

// ---------------- workspace layout (bytes) ----------------
constexpr size_t OFF_GI    = 0;                                  // f32 [2][32][128][1536] per-chunk x@Wih
constexpr size_t OFF_ENC   = OFF_GI    + 4ull*2*32*128*1536;
constexpr size_t OFF_EATT  = OFF_ENC   + 2ull*256*128*512;       // bf16 enc, bf16 enc_att
constexpr size_t OFF_AM    = OFF_EATT  + 2ull*256*128*512;       // f32 [2][256][128][8]
constexpr size_t OFF_HF    = OFF_AM    + 4ull*2*256*128*8;       // ---- zero region start
constexpr size_t OFF_HB    = OFF_HF    + 4ull*2*128*512;
constexpr size_t OFF_HFB   = OFF_HB    + 4ull*2*128*512;
constexpr size_t OFF_HBB   = OFF_HFB   + 2ull*2*128*512;
constexpr size_t OFF_HIDA  = OFF_HBB   + 2ull*2*128*512;
constexpr size_t OFF_HIDAB = OFF_HIDA  + 4ull*2*2*128*512;
constexpr size_t OFF_BAR   = OFF_HIDAB + 2ull*2*2*128*512;       // u32 barrier counters
constexpr size_t OFF_ZEND  = OFF_BAR   + 4096;                   // ---- zero region end
constexpr size_t OFF_DECH  = OFF_ZEND;
constexpr size_t OFF_DECHB = OFF_DECH  + 4ull*2*128*512;
constexpr size_t OFF_PTRS  = OFF_DECHB + 2ull*2*128*512;         // f32 [2][128][8]
constexpr size_t OFF_VPRE  = OFF_PTRS  + 4ull*2*128*8;           // f32 [128][1024]  (b-major!)
constexpr size_t OFF_CTX   = OFF_VPRE  + 4ull*128*1024;
constexpr size_t OFF_DPART = OFF_CTX   + 4ull*128*512;
constexpr size_t OFF_QCK   = OFF_DPART + 4ull*128*512;           // f32 [128][520] (513 used)
constexpr size_t OFF_CV2P  = OFF_QCK   + 4ull*128*520;
constexpr size_t OFF_GIDEC = OFF_CV2P  + 4ull*128*512;           // f32 4 K-slabs [128][1536]
constexpr size_t OFF_OUTT  = OFF_GIDEC + 4ull*4*128*1536;        // f32 4 K-slabs [128][512]
constexpr size_t OFF_WOVF  = OFF_OUTT  + 4ull*4*128*512;         // f32 [2][512][512]
constexpr size_t OFF_WOVCF = OFF_WOVF  + 4ull*2*512*512;         // f32 [512][512]
constexpr size_t OFF_MKTF  = OFF_WOVCF + 4ull*512*512;           // f32 [513 rows][1024]
constexpr size_t OFF_DWF   = OFF_MKTF  + 4ull*513*1024;          // bf16 [1536][2048] folded dec Wih
constexpr size_t OFF_MKTW  = OFF_DWF   + 2ull*1536*2048;         // bf16 [513][1024] folded qck W
constexpr size_t OFF_OWF   = OFF_MKTW  + 2ull*513*1024;          // bf16 [512][2560] folded out W
constexpr size_t OFF_BOV   = OFF_OWF   + 2ull*512*2560;          // f32 [2][512]  (contiguous w/ BOVC!)
constexpr size_t OFF_BOVC  = OFF_BOV   + 4ull*2*512;             // f32 [512]
constexpr size_t OFF_KA    = OFF_BOVC  + 4ull*512;               // f32 [2][512][16] (9 used)
constexpr size_t OFF_CAE   = OFF_KA    + 4ull*2*512*16;          // f32 [2][16]
constexpr size_t OFF_RT    = OFF_CAE   + 4ull*2*16;              // f32 [2][512][16]
constexpr size_t OFF_BQC   = OFF_RT    + 4ull*2*512*16;          // f32 [2][512]
constexpr size_t OFF_PMAT  = OFF_BQC   + 4ull*2*512;             // f32 [512][516]
constexpr size_t OFF_CQ    = OFF_PMAT  + 4ull*512*516;
constexpr size_t OFF_VKE2  = OFF_CQ    + 4ull*512;               // f32 [520]
constexpr size_t OFF_DBIH2 = OFF_VKE2  + 4ull*520;               // f32 [1536]
constexpr size_t OFF_OUTB2 = OFF_DBIH2 + 4ull*1536;              // f32 [512]
constexpr size_t WS_NEED   = OFF_OUTB2 + 4ull*512;

// ---------------- helpers ----------------
DEVI float b2f(u16 u){ union{u32 i; float f;} x; x.i = ((u32)u) << 16; return x.f; }
DEVI u16 f2b(float f){ union{float f; u32 i;} x; x.f = f; u32 i = x.i; u32 r = i + 0x7FFFu + ((i >> 16) & 1u); return (u16)(r >> 16); }
DEVI float sigmf_(float x){ return 1.f / (1.f + __expf(-x)); }
DEVI float tanhf_(float x){ x = fminf(15.f, fmaxf(-15.f, x)); float e = __expf(2.f*x); return (e - 1.f) / (e + 1.f); }

typedef __attribute__((ext_vector_type(8))) short bfrag;
typedef __attribute__((ext_vector_type(4))) float ffrag;

DEVI uint4 cvt8(float4 a, float4 b){
  union{uint4 u; u16 h[8];} r;
  r.h[0]=f2b(a.x); r.h[1]=f2b(a.y); r.h[2]=f2b(a.z); r.h[3]=f2b(a.w);
  r.h[4]=f2b(b.x); r.h[5]=f2b(b.y); r.h[6]=f2b(b.z); r.h[7]=f2b(b.w);
  return r.u;
}

// ---- manual device-scope grid barrier (monotonic counters, no reset) ----
// arrive: __threadfence + atomicAdd(+1) (use returned count);
// wait: spin on relaxed SYSTEM-scope atomic LOAD (sc0 sc1 -> reads coherence
// point, no same-line RMW serialization). Fallback RMW every 64 polls
// guarantees progress even if a load path were ever stale. Previous RMW-only
// spin serialized 256 blocks x ~200ns on one line => ~60us per barrier.
DEVI void gridbar(u32* bars, int idx, u32 nblk)
{
  __syncthreads();
  if (threadIdx.x == 0){
    __threadfence();
    u32 cnt = atomicAdd(&bars[idx], 1u) + 1u;
    int it = 0;
    while (cnt < nblk){
      __builtin_amdgcn_s_sleep(1);
      if ((++it & 63) == 0)
        cnt = atomicAdd(&bars[idx], 0u);
      else
        cnt = __hip_atomic_load(&bars[idx], __ATOMIC_RELAXED, __HIP_MEMORY_SCOPE_SYSTEM);
    }
    __threadfence();
  }
  __syncthreads();
}

// ================ host-launched 3-seg NT GEMM (GI chunks + EATT) ================
struct Seg { const void* p; int ld; int f32; int K; };
struct NTZ {
  Seg sg[3];
  const void* Bp; int ldb; int bf32;
  const void* bias; int biasf32;
  void* Cp; int ldc; int cf32; int cslab;
  int N; int rev_s0; int K;
};
struct NTA { NTZ z[3]; int tilesN; };

template<int BN>
__global__ __launch_bounds__(256) void k_mfma_nt(NTA a)
{
  NTZ z = a.z[blockIdx.z];
  int tn = blockIdx.x % a.tilesN;
  int tm = blockIdx.x / a.tilesN;
  if (tn * BN >= z.N) return;
  int nks = gridDim.y;
  int kb = blockIdx.y * (z.K / nks);
  int ke = kb + z.K / nks;

  __shared__ short Al[128*32];
  __shared__ short Bl[BN*32];

  int t = threadIdx.x;
  int lane = t & 63, w = t >> 6;
  constexpr int FRS = (BN == 128) ? 4 : 2;
  int wn = (BN == 128) ? (w & 1) : 0;
  int rowbase = (BN == 128) ? (w >> 1) * 64 : w * 32;

  ffrag zz4 = {0.f, 0.f, 0.f, 0.f};
  ffrag acc[FRS][4];
  #pragma unroll
  for (int i = 0; i < FRS; i++)
    #pragma unroll
    for (int j = 0; j < 4; j++) acc[i][j] = zz4;

  for (int k0 = kb; k0 < ke; k0 += 32){
    #pragma unroll
    for (int r2 = 0; r2 < 2; r2++){
      int slot = t + r2 * 256;
      int row = slot >> 2, kq = slot & 3;
      int m = tm * 128 + row;
      int arow = (z.rev_s0 >= 0) ? (((z.rev_s0 - (m >> 7)) << 7) | (m & 127)) : m;
      int k = k0 + kq * 8;
      Seg sg;
      if (k < z.sg[0].K) sg = z.sg[0];
      else { k -= z.sg[0].K; if (k < z.sg[1].K) sg = z.sg[1]; else { k -= z.sg[1].K; sg = z.sg[2]; } }
      uint4 v;
      if (sg.f32){
        const float* ap = (const float*)sg.p + (size_t)arow * sg.ld + k;
        v = cvt8(*(const float4*)ap, *(const float4*)(ap + 4));
      } else {
        v = *(const uint4*)((const u16*)sg.p + (size_t)arow * sg.ld + k);
      }
      *(uint4*)&Al[(((row >> 4) << 6) + (kq << 4) + (row & 15)) * 8] = v;
    }
    #pragma unroll
    for (int r2 = 0; r2 < BN/64; r2++){
      int slot = t + r2 * 256;
      int brow = slot >> 2, kq = slot & 3;
      int n = tn * BN + brow;
      uint4 v = make_uint4(0u, 0u, 0u, 0u);
      if (n < z.N){
        int k = k0 + kq * 8;
        if (z.bf32){
          const float* bp = (const float*)z.Bp + (size_t)n * z.ldb + k;
          v = cvt8(*(const float4*)bp, *(const float4*)(bp + 4));
        } else {
          v = *(const uint4*)((const u16*)z.Bp + (size_t)n * z.ldb + k);
        }
      }
      *(uint4*)&Bl[(kq * BN + brow) * 8] = v;
    }
    __syncthreads();
    bfrag af[FRS], bv[4];
    #pragma unroll
    for (int fr = 0; fr < FRS; fr++) af[fr] = *(bfrag*)&Al[(((rowbase >> 4) + fr) * 64 + lane) * 8];
    #pragma unroll
    for (int fc = 0; fc < 4; fc++) bv[fc] = *(bfrag*)&Bl[(((lane >> 4) * BN) + wn * 64 + fc * 16 + (lane & 15)) * 8];
    #pragma unroll
    for (int fr = 0; fr < FRS; fr++)
      #pragma unroll
      for (int fc = 0; fc < 4; fc++)
        acc[fr][fc] = __builtin_amdgcn_mfma_f32_16x16x32_bf16(af[fr], bv[fc], acc[fr][fc], 0, 0, 0);
    __syncthreads();
  }

  float* Cf = (float*)z.Cp + (size_t)blockIdx.y * z.cslab;
  u16*  Cb = (u16*)z.Cp  + (size_t)blockIdx.y * z.cslab;
  #pragma unroll
  for (int fc = 0; fc < 4; fc++){
    int n = tn * BN + wn * 64 + fc * 16 + (lane & 15);
    if (n >= z.N) continue;
    float bs = 0.f;
    if (z.bias) bs = z.biasf32 ? ((const float*)z.bias)[n] : b2f(((const u16*)z.bias)[n]);
    #pragma unroll
    for (int fr = 0; fr < FRS; fr++){
      #pragma unroll
      for (int i = 0; i < 4; i++){
        int m = tm * 128 + rowbase + fr * 16 + ((lane >> 4) << 2) + i;
        float vv = acc[fr][fc][i] + bs;
        size_t idx = (size_t)m * z.ldc + n;
        if (z.cf32) Cf[idx] = vv; else Cb[idx] = f2b(vv);
      }
    }
  }
}

// ================ device-side 4-seg NT GEMM (M=128 fixed) ================
struct Seg4 { const void* p; int ld; int f32; int K; };
struct Z4 {
  Seg4 sg[4];
  const void* Bp; int ldb; int bf32;
  const float* bias;
  float* Cp; int ldc; int cslab;
  int N; int K;
};

template<int BN>
DEVI void dev_mfma4(const Z4& z, int tn, int ks, int nks, short* Al, short* Bl)
{
  int kseg = z.K / nks;
  int kb = ks * kseg, ke = kb + kseg;
  int t = threadIdx.x, lane = t & 63, w = t >> 6;
  constexpr int FRS = (BN == 128) ? 4 : 2;
  int wn = (BN == 128) ? (w & 1) : 0;
  int rowbase = (BN == 128) ? (w >> 1) * 64 : w * 32;
  ffrag zz4 = {0.f, 0.f, 0.f, 0.f};
  ffrag acc[FRS][4];
  #pragma unroll
  for (int i = 0; i < FRS; i++)
    #pragma unroll
    for (int j = 0; j < 4; j++) acc[i][j] = zz4;

  for (int k0 = kb; k0 < ke; k0 += 32){
    #pragma unroll
    for (int r2 = 0; r2 < 2; r2++){
      int slot = t + r2 * 256;
      int row = slot >> 2, kq = slot & 3;
      int k = k0 + kq * 8;
      Seg4 sg = z.sg[0];
      if (k >= sg.K){ k -= sg.K; sg = z.sg[1];
        if (k >= sg.K){ k -= sg.K; sg = z.sg[2];
          if (k >= sg.K){ k -= sg.K; sg = z.sg[3]; } } }
      uint4 v;
      if (sg.f32){
        const float* ap = (const float*)sg.p + (size_t)row * sg.ld + k;
        v = cvt8(*(const float4*)ap, *(const float4*)(ap + 4));
      } else {
        v = *(const uint4*)((const u16*)sg.p + (size_t)row * sg.ld + k);
      }
      *(uint4*)&Al[(((row >> 4) << 6) + (kq << 4) + (row & 15)) * 8] = v;
    }
    #pragma unroll
    for (int r2 = 0; r2 < BN/64; r2++){
      int slot = t + r2 * 256;
      int brow = slot >> 2, kq = slot & 3;
      int n = tn * BN + brow;
      uint4 v = make_uint4(0u, 0u, 0u, 0u);
      if (n < z.N){
        int k = k0 + kq * 8;
        if (z.bf32){
          const float* bp = (const float*)z.Bp + (size_t)n * z.ldb + k;
          v = cvt8(*(const float4*)bp, *(const float4*)(bp + 4));
        } else {
          v = *(const uint4*)((const u16*)z.Bp + (size_t)n * z.ldb + k);
        }
      }
      *(uint4*)&Bl[(kq * BN + brow) * 8] = v;
    }
    __syncthreads();
    bfrag af[FRS], bv[4];
    #pragma unroll
    for (int fr = 0; fr < FRS; fr++) af[fr] = *(bfrag*)&Al[(((rowbase >> 4) + fr) * 64 + lane) * 8];
    #pragma unroll
    for (int fc = 0; fc < 4; fc++) bv[fc] = *(bfrag*)&Bl[(((lane >> 4) * BN) + wn * 64 + fc * 16 + (lane & 15)) * 8];
    #pragma unroll
    for (int fr = 0; fr < FRS; fr++)
      #pragma unroll
      for (int fc = 0; fc < 4; fc++)
        acc[fr][fc] = __builtin_amdgcn_mfma_f32_16x16x32_bf16(af[fr], bv[fc], acc[fr][fc], 0, 0, 0);
    __syncthreads();
  }

  float* Cf = z.Cp + (size_t)ks * z.cslab;
  #pragma unroll
  for (int fc = 0; fc < 4; fc++){
    int n = tn * BN + wn * 64 + fc * 16 + (lane & 15);
    if (n >= z.N) continue;
    float bs = z.bias ? z.bias[n] : 0.f;
    #pragma unroll
    for (int fr = 0; fr < FRS; fr++){
      #pragma unroll
      for (int i = 0; i < 4; i++){
        int m = rowbase + fr * 16 + ((lane >> 4) << 2) + i;
        Cf[(size_t)m * z.ldc + n] = acc[fr][fc][i] + bs;
      }
    }
  }
}

// ================ device-side fused GRU step (h@Whh MFMA + epilogue) ================
// MODE 1 = pointer unit (gi from ptr(B,8)@Wih); MODE 2 = decoder (gi = 4 K-split slabs)
template<int MODE>
DEVI void dev_gru3(int g0, const u16* hb, const float* hf, const float* Whh,
                   const float* gi_f, const float* xp, const float* Wih,
                   const float* bih, const float* bhh,
                   float* hnf, u16* hnb, short* Al, short* Bl)
{
  int t = threadIdx.x, lane = t & 63, w = t >> 6;
  int wm = w >> 1, wn = w & 1;
  ffrag zz4 = {0.f, 0.f, 0.f, 0.f};
  ffrag acc[4][3];
  #pragma unroll
  for (int i = 0; i < 4; i++)
    #pragma unroll
    for (int j = 0; j < 3; j++) acc[i][j] = zz4;

  for (int k0 = 0; k0 < 512; k0 += 32){
    #pragma unroll
    for (int r2 = 0; r2 < 2; r2++){
      int slot = t + r2 * 256;
      int row = slot >> 2, kq = slot & 3;
      uint4 v = *(const uint4*)(hb + (size_t)row * 512 + k0 + kq * 8);
      *(uint4*)&Al[(((row >> 4) << 6) + (kq << 4) + (row & 15)) * 8] = v;
    }
    {
      int lb = t >> 2, kq = t & 3;
      int wn2 = lb / 48, rem = lb - wn2 * 48, fc = rem >> 4, i16 = rem & 15;
      int grow = fc * 512 + g0 + wn2 * 16 + i16;
      const float* wp = Whh + (size_t)grow * 512 + k0 + kq * 8;
      uint4 v = cvt8(*(const float4*)wp, *(const float4*)(wp + 4));
      *(uint4*)&Bl[(kq * 96 + lb) * 8] = v;
      if (t < 128){
        int slot = t + 256;
        lb = slot >> 2; kq = slot & 3;
        wn2 = lb / 48; rem = lb - wn2 * 48; fc = rem >> 4; i16 = rem & 15;
        grow = fc * 512 + g0 + wn2 * 16 + i16;
        wp = Whh + (size_t)grow * 512 + k0 + kq * 8;
        v = cvt8(*(const float4*)wp, *(const float4*)(wp + 4));
        *(uint4*)&Bl[(kq * 96 + lb) * 8] = v;
      }
    }
    __syncthreads();
    bfrag af[4], bv[3];
    #pragma unroll
    for (int fr = 0; fr < 4; fr++) af[fr] = *(bfrag*)&Al[((wm * 4 + fr) * 64 + lane) * 8];
    #pragma unroll
    for (int fc = 0; fc < 3; fc++) bv[fc] = *(bfrag*)&Bl[((lane >> 4) * 96 + (wn * 3 + fc) * 16 + (lane & 15)) * 8];
    #pragma unroll
    for (int fr = 0; fr < 4; fr++)
      #pragma unroll
      for (int fc = 0; fc < 3; fc++)
        acc[fr][fc] = __builtin_amdgcn_mfma_f32_16x16x32_bf16(af[fr], bv[fc], acc[fr][fc], 0, 0, 0);
    __syncthreads();
  }

  int gcol = g0 + wn * 16 + (lane & 15);
  float bir = bih[gcol],        bhr = bhh[gcol];
  float biz = bih[512 + gcol],  bhz = bhh[512 + gcol];
  float bin = bih[1024 + gcol], bhn = bhh[1024 + gcol];
  float wxr[8], wxz[8], wxn[8];
  if (MODE == 1){
    #pragma unroll
    for (int a2 = 0; a2 < 8; a2++){
      wxr[a2] = Wih[(size_t)gcol * 8 + a2];
      wxz[a2] = Wih[(size_t)(512 + gcol) * 8 + a2];
      wxn[a2] = Wih[(size_t)(1024 + gcol) * 8 + a2];
    }
  }
  #pragma unroll
  for (int fr = 0; fr < 4; fr++){
    #pragma unroll
    for (int i = 0; i < 4; i++){
      int brow = wm * 64 + fr * 16 + ((lane >> 4) << 2) + i;
      float gr_, gz_, gn_;
      if (MODE == 2){
        gr_ = gz_ = gn_ = 0.f;
        #pragma unroll
        for (int sl = 0; sl < 4; sl++){
          const float* gp = gi_f + (size_t)sl * 196608 + (size_t)brow * 1536;
          gr_ += gp[gcol]; gz_ += gp[512 + gcol]; gn_ += gp[1024 + gcol];
        }
      } else {
        float4 x0 = *(const float4*)(xp + brow * 8);
        float4 x1 = *(const float4*)(xp + brow * 8 + 4);
        float xa[8] = {x0.x, x0.y, x0.z, x0.w, x1.x, x1.y, x1.z, x1.w};
        gr_ = gz_ = gn_ = 0.f;
        #pragma unroll
        for (int a2 = 0; a2 < 8; a2++){ gr_ += xa[a2]*wxr[a2]; gz_ += xa[a2]*wxz[a2]; gn_ += xa[a2]*wxn[a2]; }
      }
      float hold = hf[(size_t)brow * 512 + gcol];
      float r  = sigmf_(gr_ + acc[fr][0][i] + bir + bhr);
      float zg = sigmf_(gz_ + acc[fr][1][i] + biz + bhz);
      float n  = tanhf_(gn_ + bin + r * (acc[fr][2][i] + bhn));
      float hn = (1.f - zg) * n + zg * hold;
      hnf[(size_t)brow * 512 + gcol] = hn;
      hnb[(size_t)brow * 512 + gcol] = f2b(hn);
    }
  }
}

// ================ device-side attention pieces ================
DEVI void dev_puattn(int b, const float* hida2, const float* Ka, const float* cae,
                     const float* Am, const float* Ain, const u16* enc,
                     float* vpre, float* ptrs, float* fs)
{
  int t = threadIdx.x, lane = t & 63, w = t >> 6;
  float* sc0 = fs; float* sc1 = fs + 256; float* smx = fs + 512;
  float* wred = fs + 768; float* qa = fs + 840; float* cd = fs + 860;

  if (t < 16) cd[t] = 0.f;
  for (int u = 0; u < 2; u++){
    const float* hp = hida2 + ((size_t)u * 128 + b) * 512;
    float hv0 = hp[t], hv1 = hp[t + 256];
    const float* k0p = Ka + u * 8192 + t * 16;
    const float* k1p = Ka + u * 8192 + (t + 256) * 16;
    float p[9];
    #pragma unroll
    for (int j = 0; j < 9; j++) p[j] = hv0 * k0p[j] + hv1 * k1p[j];
    #pragma unroll
    for (int j = 0; j < 9; j++){
      #pragma unroll
      for (int off = 32; off > 0; off >>= 1) p[j] += __shfl_xor(p[j], off);
    }
    if (lane == 0){
      #pragma unroll
      for (int j = 0; j < 9; j++) wred[w * 9 + j] = p[j];
    }
    __syncthreads();
    if (t < 9) qa[u * 10 + t] = wred[t] + wred[9 + t] + wred[18 + t] + wred[27 + t] + cae[u * 16 + t];
    __syncthreads();
  }

  float su[2];
  #pragma unroll
  for (int u = 0; u < 2; u++){
    const float* amp = Am + (((size_t)u * 256 + t) * 128 + b) * 8;
    float4 a0 = *(const float4*)amp;
    float4 a1 = *(const float4*)(amp + 4);
    const float* q = qa + u * 10;
    su[u] = (q[8] + q[0]*a0.x + q[1]*a0.y + q[2]*a0.z + q[3]*a0.w
                  + q[4]*a1.x + q[5]*a1.y + q[6]*a1.z + q[7]*a1.w) * SCALE_ATT;
  }

  const float* ap = Ain + ((size_t)b * 256 + t) * 8;
  float av[8];
  {
    float4 v0 = *(const float4*)ap;
    float4 v1 = *(const float4*)(ap + 4);
    av[0]=v0.x; av[1]=v0.y; av[2]=v0.z; av[3]=v0.w;
    av[4]=v1.x; av[5]=v1.y; av[6]=v1.z; av[7]=v1.w;
  }

  float inv[2];
  for (int u = 0; u < 2; u++){
    float s_ = su[u];
    float* sc = u ? sc1 : sc0;
    smx[t] = s_; __syncthreads();
    for (int o = 128; o > 0; o >>= 1){ if (t < o) smx[t] = fmaxf(smx[t], smx[t + o]); __syncthreads(); }
    float mx = smx[0]; __syncthreads();
    float e = __expf(s_ - mx); sc[t] = e;
    #pragma unroll
    for (int a2 = 0; a2 < 8; a2++) atomicAdd(&cd[u * 8 + a2], e * av[a2]);
    smx[t] = e; __syncthreads();
    for (int o = 128; o > 0; o >>= 1){ if (t < o) smx[t] += smx[t + o]; __syncthreads(); }
    inv[u] = 1.f / smx[0]; __syncthreads();
  }
  if (t < 8){
    ptrs[((size_t)0 * 128 + b) * 8 + t] = cd[t] * inv[0];
    ptrs[((size_t)128 + b) * 8 + t]     = cd[8 + t] * inv[1];
  }

  // value pass over ENC: thread t owns cols 2t,2t+1 (one u32 = 2 bf16 per s2)
  float a00 = 0.f, a01 = 0.f, a10 = 0.f, a11 = 0.f;
  const u16* ep = enc + (size_t)b * 512;
  #pragma unroll 8
  for (int s2 = 0; s2 < 256; s2++){
    float w0 = sc0[s2], w1 = sc1[s2];
    u32 pv = *(const u32*)(ep + (size_t)s2 * 65536 + 2 * t);
    float v0 = b2f((u16)pv);
    float v1 = b2f((u16)(pv >> 16));
    a00 += w0 * v0; a01 += w0 * v1; a10 += w1 * v0; a11 += w1 * v1;
  }
  float* vp = vpre + (size_t)b * 1024;
  vp[2 * t] = a00 * inv[0];           vp[2 * t + 1] = a01 * inv[0];
  vp[512 + 2 * t] = a10 * inv[1];     vp[512 + 2 * t + 1] = a11 * inv[1];
}

DEVI void dev_bahd(int b, const u16* eatt, const float* dpart, const float* vvec,
                   const u16* enc, float* ctx, float* fs)
{
  int t = threadIdx.x, lane = t & 63, w = t >> 6;
  float* dp = fs; float* vv = fs + 512; float* sc = fs + 1024; float* smx = fs + 1280;
  dp[t] = dpart[(size_t)b * 512 + t]; dp[t + 256] = dpart[(size_t)b * 512 + t + 256];
  vv[t] = vvec[t]; vv[t + 256] = vvec[t + 256];
  __syncthreads();
  for (int s = w; s < 256; s += 4){
    uint4 v = *(const uint4*)(eatt + ((size_t)s * 128 + b) * 512 + lane * 8);
    const u16* h = (const u16*)&v;
    float4 d0 = *(float4*)&dp[lane * 8], d1 = *(float4*)&dp[lane * 8 + 4];
    float4 v0 = *(float4*)&vv[lane * 8], v1 = *(float4*)&vv[lane * 8 + 4];
    float r = fmaxf(0.f, b2f(h[0]) + d0.x) * v0.x + fmaxf(0.f, b2f(h[1]) + d0.y) * v0.y
            + fmaxf(0.f, b2f(h[2]) + d0.z) * v0.z + fmaxf(0.f, b2f(h[3]) + d0.w) * v0.w
            + fmaxf(0.f, b2f(h[4]) + d1.x) * v1.x + fmaxf(0.f, b2f(h[5]) + d1.y) * v1.y
            + fmaxf(0.f, b2f(h[6]) + d1.z) * v1.z + fmaxf(0.f, b2f(h[7]) + d1.w) * v1.w;
    #pragma unroll
    for (int off = 32; off > 0; off >>= 1) r += __shfl_xor(r, off);
    if (lane == 0) sc[s] = r;
  }
  __syncthreads();
  float s0 = sc[t];
  smx[t] = s0; __syncthreads();
  for (int o = 128; o > 0; o >>= 1){ if (t < o) smx[t] = fmaxf(smx[t], smx[t + o]); __syncthreads(); }
  float mx = smx[0]; __syncthreads();
  float e = __expf(s0 - mx); sc[t] = e; smx[t] = e; __syncthreads();
  for (int o = 128; o > 0; o >>= 1){ if (t < o) smx[t] += smx[t + o]; __syncthreads(); }
  float inv = 1.f / smx[0];
  float a0 = 0.f, a1 = 0.f;
  const u16* ep = enc + (size_t)b * 512;
  #pragma unroll 8
  for (int s2 = 0; s2 < 256; s2++){
    float wgt = sc[s2];
    u32 pv = *(const u32*)(ep + (size_t)s2 * 65536 + 2 * t);
    a0 += wgt * b2f((u16)pv);
    a1 += wgt * b2f((u16)(pv >> 16));
  }
  ctx[(size_t)b * 512 + 2 * t] = a0 * inv;
  ctx[(size_t)b * 512 + 2 * t + 1] = a1 * inv;
}

DEVI void dev_cattn(int b, const float* qck, const u16* enc, float* cv2p, float* fs)
{
  int t = threadIdx.x, lane = t & 63, w = t >> 6;
  float* qv = fs; float* sc = fs + 1024; float* smx = fs + 1280;
  qv[t] = qck[(size_t)b * 520 + t]; qv[t + 256] = qck[(size_t)b * 520 + t + 256];
  __syncthreads();
  float qc0 = qck[(size_t)b * 520 + 512];
  for (int s = w; s < 256; s += 4){
    uint4 v = *(const uint4*)(enc + ((size_t)s * 128 + b) * 512 + lane * 8);
    const u16* h = (const u16*)&v;
    float4 q0 = *(float4*)&qv[lane * 8], q1 = *(float4*)&qv[lane * 8 + 4];
    float r = b2f(h[0])*q0.x + b2f(h[1])*q0.y + b2f(h[2])*q0.z + b2f(h[3])*q0.w
            + b2f(h[4])*q1.x + b2f(h[5])*q1.y + b2f(h[6])*q1.z + b2f(h[7])*q1.w;
    #pragma unroll
    for (int off = 32; off > 0; off >>= 1) r += __shfl_xor(r, off);
    if (lane == 0) sc[s] = (r + qc0) * SCALE_ATT;
  }
  __syncthreads();
  float s0 = sc[t];
  smx[t] = s0; __syncthreads();
  for (int o = 128; o > 0; o >>= 1){ if (t < o) smx[t] = fmaxf(smx[t], smx[t + o]); __syncthreads(); }
  float mx = smx[0]; __syncthreads();
  float e = __expf(s0 - mx); sc[t] = e; smx[t] = e; __syncthreads();
  for (int o = 128; o > 0; o >>= 1){ if (t < o) smx[t] += smx[t + o]; __syncthreads(); }
  float inv = 1.f / smx[0];
  float a0 = 0.f, a1 = 0.f;
  const u16* ep = enc + (size_t)b * 512;
  #pragma unroll 8
  for (int s2 = 0; s2 < 256; s2++){
    float wgt = sc[s2];
    u32 pv = *(const u32*)(ep + (size_t)s2 * 65536 + 2 * t);
    a0 += wgt * b2f((u16)pv);
    a1 += wgt * b2f((u16)(pv >> 16));
  }
  cv2p[(size_t)b * 512 + 2 * t] = a0 * inv;
  cv2p[(size_t)b * 512 + 2 * t + 1] = a1 * inv;
}

DEVI void dev_outcvt(int b, const float* outt, const float* outb2, float* dst)
{
  int t = threadIdx.x;
  #pragma unroll
  for (int rep = 0; rep < 2; rep++){
    int o = t + rep * 256;
    float s = outt[(size_t)b * 512 + o] + outt[65536 + (size_t)b * 512 + o]
            + outt[131072 + (size_t)b * 512 + o] + outt[196608 + (size_t)b * 512 + o];
    dst[(size_t)b * 512 + o] = s + outb2[o];
  }
}

// ================ persistent encoder (32 steps per launch, manual barrier) ================
struct EncArgs {
  const float *WhhF, *WhhB, *giF, *giB;
  const float *bihF, *bhhF, *bihB, *bhhB;
  float *HF, *HB; u16 *HFB, *HBB, *ENC;
  u32 *BAR; int bar0;
  int s0;
};

__global__ __launch_bounds__(256) void k_enc(EncArgs a)
{
  __shared__ short Bw[24576];   // 48 rows (3 gates x 16 cols) x 512 K, bf16, MFMA layout
  __shared__ short Al[4096];
  int blk = blockIdx.x;
  int d = blk >> 5, gt = blk & 31;
  int t = threadIdx.x, lane = t & 63, w = t >> 6;

  const float* Whh = d ? a.WhhB : a.WhhF;
  for (int c = t; c < 3072; c += 256){
    int brow = c >> 6, kc = c & 63;
    int grow = (brow >> 4) * 512 + gt * 16 + (brow & 15);
    const float* wp = Whh + (size_t)grow * 512 + kc * 8;
    *(uint4*)&Bw[((kc * 48) + brow) * 8] = cvt8(*(const float4*)wp, *(const float4*)(wp + 4));
  }
  const float* bih = d ? a.bihB : a.bihF;
  const float* bhh = d ? a.bhhB : a.bhhF;
  int gcol = gt * 16 + (lane & 15);
  float bir = bih[gcol],        bhr = bhh[gcol];
  float biz = bih[512 + gcol],  bhz = bhh[512 + gcol];
  float bin = bih[1024 + gcol], bhn = bhh[1024 + gcol];
  float* hf_base = d ? a.HB : a.HF;
  u16*   hb_base = d ? a.HBB : a.HFB;
  const float* gi_base = d ? a.giB : a.giF;
  __syncthreads();

  for (int si = 0; si < 32; si++){
    int s = a.s0 + si;
    const u16* hb = hb_base + (size_t)(s & 1) * 65536;
    const float* hf = hf_base + (size_t)(s & 1) * 65536;
    float* hnf = hf_base + (size_t)((s + 1) & 1) * 65536;
    u16* hnb = hb_base + (size_t)((s + 1) & 1) * 65536;
    u16* eacc = a.ENC + (size_t)(d ? 255 - s : s) * 65536;

    ffrag zz4 = {0.f, 0.f, 0.f, 0.f};
    ffrag acc[2][3];
    #pragma unroll
    for (int i = 0; i < 2; i++)
      #pragma unroll
      for (int j = 0; j < 3; j++) acc[i][j] = zz4;

    for (int ki = 0; ki < 16; ki++){
      int k0 = ki * 32;
      #pragma unroll
      for (int r2 = 0; r2 < 2; r2++){
        int slot = t + r2 * 256;
        int row = slot >> 2, kq = slot & 3;
        uint4 v = *(const uint4*)(hb + (size_t)row * 512 + k0 + kq * 8);
        *(uint4*)&Al[(((row >> 4) << 6) + (kq << 4) + (row & 15)) * 8] = v;
      }
      __syncthreads();
      bfrag af[2], bv[3];
      #pragma unroll
      for (int fr = 0; fr < 2; fr++) af[fr] = *(bfrag*)&Al[(((w * 2 + fr) * 64) + lane) * 8];
      #pragma unroll
      for (int fc = 0; fc < 3; fc++) bv[fc] = *(bfrag*)&Bw[(((ki * 4 + (lane >> 4)) * 48) + fc * 16 + (lane & 15)) * 8];
      #pragma unroll
      for (int fr = 0; fr < 2; fr++)
        #pragma unroll
        for (int fc = 0; fc < 3; fc++)
          acc[fr][fc] = __builtin_amdgcn_mfma_f32_16x16x32_bf16(af[fr], bv[fc], acc[fr][fc], 0, 0, 0);
      __syncthreads();
    }

    const float* gp0 = gi_base + (size_t)si * 196608;
    #pragma unroll
    for (int fr = 0; fr < 2; fr++){
      #pragma unroll
      for (int i = 0; i < 4; i++){
        int brow = w * 32 + fr * 16 + ((lane >> 4) << 2) + i;
        const float* gp = gp0 + (size_t)brow * 1536;
        float gr_ = gp[gcol], gz_ = gp[512 + gcol], gn_ = gp[1024 + gcol];
        float hold = hf[(size_t)brow * 512 + gcol];
        float r  = sigmf_(gr_ + acc[fr][0][i] + bir + bhr);
        float zg = sigmf_(gz_ + acc[fr][1][i] + biz + bhz);
        float n  = tanhf_(gn_ + bin + r * (acc[fr][2][i] + bhn));
        float hn = (1.f - zg) * n + zg * hold;
        hnf[(size_t)brow * 512 + gcol] = hn;
        hnb[(size_t)brow * 512 + gcol] = f2b(hn);
        size_t idx = (size_t)brow * 512 + gcol;
        eacc[idx] = f2b(b2f(eacc[idx]) + hn);
      }
    }
    gridbar(a.BAR, a.bar0 + si, 64);
  }
}

// ================ persistent decoder (all 64 steps, manual barrier) ================
struct DecArgs {
  const float *tgt, *Ag, *AM, *KA, *CAE, *dattW, *dattv;
  const float *puWhh, *puWih, *pubih, *pubhh;
  const float *dWhh, *DBIH2, *dbhh, *VKE2, *OUTB2;
  const u16 *ENC, *EATT, *DWF, *MKTW, *OWF;
  float *HIDA; u16 *HIDAB;
  float *DECH; u16 *DECHB;
  float *HF0; u16 *HFB0;
  float *PTRS, *VPRE, *CTX, *DPART, *QCK, *CV2P, *GIDEC, *OUTT, *out;
  u32 *BAR;
};

__global__ __launch_bounds__(256) void k_dec(DecArgs a)
{
  __shared__ short Al[4096];
  __shared__ short Bl[4096];
  __shared__ float fs[1600];
  const int blk = blockIdx.x;
  const Seg4 S4SENT = {nullptr, 0, 0, 1 << 30};

  for (int st = 0; st < 64; st++){
    const float* hida_c  = a.HIDA  + (size_t)(st & 1) * 131072;
    float*       hida_n  = a.HIDA  + (size_t)((st + 1) & 1) * 131072;
    const u16*   hidab_c = a.HIDAB + (size_t)(st & 1) * 131072;
    u16*         hidab_n = a.HIDAB + (size_t)((st + 1) & 1) * 131072;
    const float* dech_c  = (st == 0) ? a.HF0  : a.DECH  + (size_t)((st + 1) & 1) * 65536;
    const u16*   dechb_c = (st == 0) ? a.HFB0 : a.DECHB + (size_t)((st + 1) & 1) * 65536;
    float*       dech_n  = a.DECH  + (size_t)(st & 1) * 65536;
    u16*         dechb_n = a.DECHB + (size_t)(st & 1) * 65536;
    int bar0 = 256 + st * 5;

    // ---- phase A: pu GRUs | dpart GEMM | outcvt(st-1)
    if (blk < 32){
      int u = blk >> 4, g0 = (blk & 15) * 32;
      dev_gru3<1>(g0, hidab_c + (size_t)u * 65536, hida_c + (size_t)u * 65536,
                  a.puWhh + (size_t)u * 786432, nullptr,
                  a.PTRS + u * 1024, a.puWih + (size_t)u * 12288,
                  a.pubih + u * 1536, a.pubhh + u * 1536,
                  hida_n + (size_t)u * 65536, hidab_n + (size_t)u * 65536, Al, Bl);
    } else if (blk < 40){
      Z4 z;
      z.sg[0] = {dechb_c, 512, 0, 512}; z.sg[1] = S4SENT; z.sg[2] = S4SENT; z.sg[3] = S4SENT;
      z.Bp = a.dattW; z.ldb = 1024; z.bf32 = 1; z.bias = nullptr;
      z.Cp = a.DPART; z.ldc = 512; z.cslab = 0; z.N = 512; z.K = 512;
      dev_mfma4<64>(z, blk - 32, 0, 1, Al, Bl);
    } else if (blk < 168 && st > 0){
      dev_outcvt(blk - 40, a.OUTT, a.OUTB2, a.out + (size_t)(st - 1) * 65536);
    }
    gridbar(a.BAR, bar0 + 0, 256);

    // ---- phase B: pointer attention (both units) | Bahdanau
    if (blk < 128){
      dev_puattn(blk, hida_n, a.KA, a.CAE, a.AM, a.Ag, a.ENC, a.VPRE, a.PTRS, fs);
    } else {
      dev_bahd(blk - 128, a.EATT, a.DPART, a.dattv, a.ENC, a.CTX, fs);
    }
    gridbar(a.BAR, bar0 + 1, 256);

    // ---- phase C: decoder gi GEMM (folded Wih) | qck GEMM (folded)
    if (blk < 48){
      Z4 z;
      z.sg[0] = {a.tgt + (size_t)(st ? st - 1 : 0) * 65536, 512, 1, 512};
      z.sg[1] = {a.VPRE, 1024, 1, 1024};
      z.sg[2] = {a.CTX, 512, 1, 512};
      z.sg[3] = S4SENT;
      z.Bp = a.DWF; z.ldb = 2048; z.bf32 = 0; z.bias = nullptr;
      z.Cp = a.GIDEC; z.ldc = 1536; z.cslab = 196608; z.N = 1536; z.K = 2048;
      dev_mfma4<128>(z, blk % 12, blk / 12, 4, Al, Bl);
    } else if (blk < 57){
      Z4 z;
      z.sg[0] = {a.VPRE, 1024, 1, 1024}; z.sg[1] = S4SENT; z.sg[2] = S4SENT; z.sg[3] = S4SENT;
      z.Bp = a.MKTW; z.ldb = 1024; z.bf32 = 0; z.bias = a.VKE2;
      z.Cp = a.QCK; z.ldc = 520; z.cslab = 0; z.N = 513; z.K = 1024;
      dev_mfma4<64>(z, blk - 48, 0, 1, Al, Bl);
    }
    gridbar(a.BAR, bar0 + 2, 256);

    // ---- phase D: decoder GRU combine | content attention
    if (blk < 16){
      dev_gru3<2>(blk * 32, dechb_c, dech_c, a.dWhh, a.GIDEC, nullptr, nullptr,
                  a.DBIH2, a.dbhh, dech_n, dechb_n, Al, Bl);
    } else if (blk < 144){
      dev_cattn(blk - 16, a.QCK, a.ENC, a.CV2P, fs);
    }
    gridbar(a.BAR, bar0 + 3, 256);

    // ---- phase E: folded output head GEMM (K=2560, split-K 4)
    if (blk < 32){
      Z4 z;
      z.sg[0] = {dechb_n, 512, 0, 512};
      z.sg[1] = {a.CTX, 512, 1, 512};
      z.sg[2] = {a.VPRE, 1024, 1, 1024};
      z.sg[3] = {a.CV2P, 512, 1, 512};
      z.Bp = a.OWF; z.ldb = 2560; z.bf32 = 0; z.bias = nullptr;
      z.Cp = a.OUTT; z.ldc = 512; z.cslab = 65536; z.N = 512; z.K = 2560;
      dev_mfma4<64>(z, blk & 7, blk >> 3, 4, Al, Bl);
    }
    gridbar(a.BAR, bar0 + 4, 256);
  }
  if (blk < 128) dev_outcvt(blk, a.OUTT, a.OUTB2, a.out + 63ull * 65536);
}

// ================ setup: batched fold jobs ================
struct Job {
  const float* A; const float* B; const float* D; void* C;
  int Asm, Ask, Bsk, Bsn, Dsm, Dsn, Csm, Csn;
  int cbf, M, N, K, kind;
};
struct Jobs { Job j[24]; int nj; long long off[25]; };

__global__ __launch_bounds__(256) void k_setup(Jobs J)
{
  long long total = J.off[J.nj];
  for (long long tid = (long long)blockIdx.x * 256 + threadIdx.x; tid < total; tid += (long long)gridDim.x * 256){
    int ji = 0;
    while (tid >= J.off[ji + 1]) ji++;
    Job jb = J.j[ji];
    long long l = tid - J.off[ji];
    if (jb.kind == 0){
      int m = (int)(l / jb.N), n = (int)(l - (long long)m * jb.N);
      float acc = 0.f;
      const float* ap = jb.A + (size_t)m * jb.Asm;
      const float* bp = jb.B + (size_t)n * jb.Bsn;
      for (int k = 0; k < jb.K; k++)
        acc += ap[(size_t)k * jb.Ask] * bp[(size_t)k * jb.Bsk];
      if (jb.D) acc += jb.D[(size_t)m * jb.Dsm + (size_t)n * jb.Dsn];
      if (jb.cbf) ((u16*)jb.C)[(size_t)m * jb.Csm + (size_t)n * jb.Csn] = f2b(acc);
      else ((float*)jb.C)[(size_t)m * jb.Csm + (size_t)n * jb.Csn] = acc;
    } else if (jb.kind == 1){
      int m = (int)(l / jb.N), n = (int)(l - (long long)m * jb.N);
      ((u16*)jb.C)[(size_t)m * jb.Csm + (size_t)n * jb.Csn] = f2b(jb.A[(size_t)m * jb.Asm + (size_t)n * jb.Ask]);
    } else if (jb.kind == 2){
      int u = (int)(l >> 15), sb = (int)(l & 32767);
      float x[8];
      #pragma unroll
      for (int a2 = 0; a2 < 8; a2++) x[a2] = jb.A[(size_t)sb * 8 + a2];
      float* op = (float*)jb.C + ((size_t)u * 32768 + sb) * 8;
      #pragma unroll
      for (int c = 0; c < 8; c++){
        float acc = jb.D[u * 8 + c];
        #pragma unroll
        for (int a2 = 0; a2 < 8; a2++) acc += x[a2] * jb.B[(u * 8 + c) * 8 + a2];
        op[c] = acc;
      }
    } else {
      int u = (int)(l >> 10), r = (int)(l & 1023);
      int bb = r >> 3, aa = r & 7;
      int su = u ? 255 : 0;
      ((float*)jb.C)[l] = jb.A[((size_t)su * 128 + bb) * 8 + aa];
    }
  }
}

// ================ host ================
static inline Seg mkseg(const void* p, int ld, int f32, int K){ Seg s; s.p = p; s.ld = ld; s.f32 = f32; s.K = K; return s; }
static const Seg SENT = {nullptr, 0, 0, 1 << 30};

static inline void addJ(Jobs& JS, Job jb, long long cnt){
  JS.j[JS.nj] = jb;
  JS.off[JS.nj + 1] = JS.off[JS.nj] + cnt;
  JS.nj++;
}
static inline Job JG(const float* A, int Asm, int Ask, const float* B, int Bsk, int Bsn,
                     const float* D, int Dsm, int Dsn, void* C, int Csm, int Csn,
                     int cbf, int M, int N, int K, int kind = 0){
  Job j; j.A=A; j.B=B; j.D=D; j.C=C; j.Asm=Asm; j.Ask=Ask; j.Bsk=Bsk; j.Bsn=Bsn;
  j.Dsm=Dsm; j.Dsn=Dsn; j.Csm=Csm; j.Csn=Csn; j.cbf=cbf; j.M=M; j.N=N; j.K=K; j.kind=kind;
  return j;
}

extern "C" void kernel_launch(void* const* d_in, const int* in_sizes, int n_in,
                              void* d_out, int out_size, void* d_ws, size_t ws_size,
                              hipStream_t stream)
{
  (void)in_sizes; (void)out_size;
  if (n_in < 44 || ws_size < WS_NEED) return;

  const float* src   = (const float*)d_in[0];
  const float* tgt   = (const float*)d_in[1];
  const float* Ag    = (const float*)d_in[2];
  const float* eWihF = (const float*)d_in[3];
  const float* eWhhF = (const float*)d_in[4];
  const float* ebihF = (const float*)d_in[5];
  const float* ebhhF = (const float*)d_in[6];
  const float* eWihB = (const float*)d_in[7];
  const float* eWhhB = (const float*)d_in[8];
  const float* ebihB = (const float*)d_in[9];
  const float* ebhhB = (const float*)d_in[10];
  const float* dattW = (const float*)d_in[11];
  const float* dattb = (const float*)d_in[12];
  const float* dattv = (const float*)d_in[13];
  const float* dWih  = (const float*)d_in[14];
  const float* dWhh  = (const float*)d_in[15];
  const float* dbih  = (const float*)d_in[16];
  const float* dbhh  = (const float*)d_in[17];
  const float* doW   = (const float*)d_in[18];
  const float* dob   = (const float*)d_in[19];
  const float* puWih = (const float*)d_in[20];
  const float* puWhh = (const float*)d_in[21];
  const float* pubih = (const float*)d_in[22];
  const float* pubhh = (const float*)d_in[23];
  const float* puqW  = (const float*)d_in[24];
  const float* puqb  = (const float*)d_in[25];
  const float* puAW  = (const float*)d_in[26];
  const float* puAb  = (const float*)d_in[27];
  const float* puqp  = (const float*)d_in[28];
  const float* pukp  = (const float*)d_in[29];
  const float* puvp  = (const float*)d_in[30];
  const float* puinb = (const float*)d_in[31];
  const float* puop  = (const float*)d_in[32];
  const float* puob  = (const float*)d_in[33];
  const float* aaq   = (const float*)d_in[34];
  const float* aak   = (const float*)d_in[35];
  const float* aav   = (const float*)d_in[36];
  const float* aainb = (const float*)d_in[37];
  const float* aao   = (const float*)d_in[38];
  const float* aaob  = (const float*)d_in[39];
  const float* tohW  = (const float*)d_in[40];
  const float* tohb  = (const float*)d_in[41];
  const float* outW  = (const float*)d_in[42];
  const float* outb  = (const float*)d_in[43];

  char* ws = (char*)d_ws;
  float* GI    = (float*)(ws + OFF_GI);
  u16*   ENC   = (u16*)(ws + OFF_ENC);
  u16*   EATT  = (u16*)(ws + OFF_EATT);
  float* AM    = (float*)(ws + OFF_AM);
  float* HF    = (float*)(ws + OFF_HF);
  float* HB    = (float*)(ws + OFF_HB);
  u16*   HFB   = (u16*)(ws + OFF_HFB);
  u16*   HBB   = (u16*)(ws + OFF_HBB);
  float* HIDA  = (float*)(ws + OFF_HIDA);
  u16*   HIDAB = (u16*)(ws + OFF_HIDAB);
  u32*   BAR   = (u32*)(ws + OFF_BAR);
  float* DECH  = (float*)(ws + OFF_DECH);
  u16*   DECHB = (u16*)(ws + OFF_DECHB);
  float* PTRS  = (float*)(ws + OFF_PTRS);
  float* VPRE  = (float*)(ws + OFF_VPRE);
  float* CTX   = (float*)(ws + OFF_CTX);
  float* DPART = (float*)(ws + OFF_DPART);
  float* QCK   = (float*)(ws + OFF_QCK);
  float* CV2P  = (float*)(ws + OFF_CV2P);
  float* GIDEC = (float*)(ws + OFF_GIDEC);
  float* OUTT  = (float*)(ws + OFF_OUTT);
  float* WOVF  = (float*)(ws + OFF_WOVF);
  float* WOVCF = (float*)(ws + OFF_WOVCF);
  float* MKTF  = (float*)(ws + OFF_MKTF);
  u16*   DWF   = (u16*)(ws + OFF_DWF);
  u16*   MKTW  = (u16*)(ws + OFF_MKTW);
  u16*   OWF   = (u16*)(ws + OFF_OWF);
  float* BOV   = (float*)(ws + OFF_BOV);
  float* BOVC  = (float*)(ws + OFF_BOVC);
  float* KAx   = (float*)(ws + OFF_KA);
  float* CAE   = (float*)(ws + OFF_CAE);
  float* RT    = (float*)(ws + OFF_RT);
  float* BQC   = (float*)(ws + OFF_BQC);
  float* PMAT  = (float*)(ws + OFF_PMAT);
  float* CQ    = (float*)(ws + OFF_CQ);
  float* VKE2  = (float*)(ws + OFF_VKE2);
  float* DBIH2 = (float*)(ws + OFF_DBIH2);
  float* OUTB2 = (float*)(ws + OFF_OUTB2);

  hipMemsetAsync(ENC, 0, 2ull*256*128*512, stream);
  hipMemsetAsync(ws + OFF_HF, 0, OFF_ZEND - OFF_HF, stream);  // states + barrier counters

  // -------- stage 1: independent folds --------
  {
    Jobs S{}; S.nj = 0; S.off[0] = 0;
    for (int u = 0; u < 2; u++){
      const float* qp  = puqp + (size_t)u * 262144;
      const float* kp  = pukp + (size_t)u * 4096;
      float* RTu = RT + u * 8192;
      addJ(S, JG(qp, 1, 512, kp, 8, 1, nullptr, 0, 0, RTu, 16, 1, 0, 512, 8, 512), 4096);
      addJ(S, JG(qp, 1, 512, puinb + u*1536 + 512, 1, 0, nullptr, 0, 0, RTu + 8, 16, 1, 0, 512, 1, 512), 512);
      addJ(S, JG(qp, 512, 1, puqb + u*512, 1, 0, puinb + u*1536, 1, 0, BQC + u*512, 1, 1, 0, 512, 1, 512), 512);
      addJ(S, JG(puop + (size_t)u*262144, 512, 1, puvp + (size_t)u*262144, 512, 1, nullptr, 0, 0, WOVF + (size_t)u*262144, 512, 1, 0, 512, 512, 512), 262144);
      addJ(S, JG(puop + (size_t)u*262144, 512, 1, puinb + u*1536 + 1024, 1, 0, puob + u*512, 1, 0, BOV + u*512, 1, 1, 0, 512, 1, 512), 512);
    }
    addJ(S, JG(aao, 512, 1, aav, 512, 1, nullptr, 0, 0, WOVCF, 512, 1, 0, 512, 512, 512), 262144);
    addJ(S, JG(aao, 512, 1, aainb + 1024, 1, 0, aaob, 1, 0, BOVC, 1, 1, 0, 512, 1, 512), 512);
    addJ(S, JG(aaq, 1, 512, aak, 512, 1, nullptr, 0, 0, PMAT, 516, 1, 0, 512, 512, 512), 262144);
    addJ(S, JG(aaq, 1, 512, aainb + 512, 1, 0, nullptr, 0, 0, PMAT + 512, 516, 1, 0, 512, 1, 512), 512);
    addJ(S, JG(aaq, 512, 1, tohb, 1, 0, aainb, 1, 0, CQ, 1, 1, 0, 512, 1, 512), 512);
    addJ(S, JG(dWih, 2048, 1, nullptr, 0, 0, nullptr, 0, 0, DWF, 2048, 1, 1, 1536, 512, 0, 1), 786432);
    addJ(S, JG(dWih + 1536, 2048, 1, nullptr, 0, 0, nullptr, 0, 0, DWF + 1536, 2048, 1, 1, 1536, 512, 0, 1), 786432);
    addJ(S, JG(outW, 2048, 1, doW, 1024, 1, nullptr, 0, 0, OWF, 2560, 1, 1, 512, 1024, 512), 524288);
    addJ(S, JG(outW, 2048, 1, dob, 1, 0, outb, 1, 0, OUTB2, 1, 1, 0, 512, 1, 512), 512);
    addJ(S, JG(Ag, 0, 0, puAW, 0, 0, puAb, 0, 0, AM, 0, 0, 0, 0, 0, 0, 2), 65536);
    addJ(S, JG(Ag, 0, 0, nullptr, 0, 0, nullptr, 0, 0, PTRS, 0, 0, 0, 0, 0, 0, 3), 2048);
    k_setup<<<2048, 256, 0, stream>>>(S);
  }
  // -------- stage 2 --------
  {
    Jobs S{}; S.nj = 0; S.off[0] = 0;
    for (int u = 0; u < 2; u++){
      const float* kp = pukp + (size_t)u * 4096;
      addJ(S, JG(puqW + (size_t)u*262144, 1, 512, RT + u*8192, 16, 1, nullptr, 0, 0, KAx + u*8192, 16, 1, 0, 512, 9, 512), 4608);
      addJ(S, JG(BQC + u*512, 0, 1, kp, 8, 1, nullptr, 0, 0, CAE + u*16, 0, 1, 0, 1, 8, 512), 8);
      addJ(S, JG(BQC + u*512, 0, 1, puinb + u*1536 + 512, 1, 0, nullptr, 0, 0, CAE + u*16 + 8, 0, 1, 0, 1, 1, 512), 1);
      addJ(S, JG(dWih + 512 + u*512, 2048, 1, WOVF + (size_t)u*262144, 512, 1, nullptr, 0, 0, DWF + 512 + u*512, 2048, 1, 1, 1536, 512, 512), 786432);
      addJ(S, JG(outW + 512 + u*512, 2048, 1, WOVF + (size_t)u*262144, 512, 1, nullptr, 0, 0, OWF + 1024 + u*512, 2560, 1, 1, 512, 512, 512), 262144);
    }
    addJ(S, JG(tohW, 1, 1024, PMAT, 516, 1, nullptr, 0, 0, MKTF, 1, 1024, 0, 1024, 513, 512), 525312);
    addJ(S, JG(CQ, 0, 1, aak, 512, 1, nullptr, 0, 0, VKE2, 0, 1, 0, 1, 512, 512), 512);
    addJ(S, JG(CQ, 0, 1, aainb + 512, 1, 0, nullptr, 0, 0, VKE2 + 512, 0, 1, 0, 1, 1, 512), 1);
    addJ(S, JG(dWih + 512, 2048, 1, BOV, 1, 0, dbih, 1, 0, DBIH2, 1, 1, 0, 1536, 1, 1024), 1536);
    addJ(S, JG(outW + 1536, 2048, 1, WOVCF, 512, 1, nullptr, 0, 0, OWF + 2048, 2560, 1, 1, 512, 512, 512), 262144);
    addJ(S, JG(outW + 512, 2048, 1, BOV, 1, 0, OUTB2, 1, 0, OUTB2, 1, 1, 0, 512, 1, 1536), 512);
    k_setup<<<2048, 256, 0, stream>>>(S);
  }
  // -------- stage 3 --------
  {
    Jobs S{}; S.nj = 0; S.off[0] = 0;
    for (int u = 0; u < 2; u++)
      addJ(S, JG(MKTF + u*512, 1024, 1, WOVF + (size_t)u*262144, 512, 1, nullptr, 0, 0, MKTW + u*512, 1024, 1, 1, 513, 512, 512), 262656);
    addJ(S, JG(MKTF, 1024, 1, BOV, 1, 0, VKE2, 1, 0, VKE2, 1, 1, 0, 513, 1, 1024), 513);
    k_setup<<<1024, 256, 0, stream>>>(S);
  }

  // -------- encoder: 8 chunks of (gi GEMM + persistent 32-step scan) --------
  for (int c = 0; c < 8; c++){
    int c0 = c * 32;
    NTA nt{};
    nt.tilesN = 12;
    for (int d = 0; d < 2; d++){
      NTZ& zz = nt.z[d];
      zz.sg[0] = mkseg(d == 0 ? (const void*)(src + (size_t)c0 * 65536) : (const void*)src, 512, 1, 512);
      zz.sg[1] = SENT; zz.sg[2] = SENT;
      zz.Bp = d ? eWihB : eWihF; zz.ldb = 512; zz.bf32 = 1;
      zz.bias = nullptr; zz.biasf32 = 0;
      zz.Cp = GI + (size_t)d * 6291456; zz.ldc = 1536; zz.cf32 = 1; zz.cslab = 0;
      zz.N = 1536; zz.rev_s0 = (d == 0) ? -1 : (255 - c0); zz.K = 512;
    }
    k_mfma_nt<128><<<dim3(32*12, 1, 2), 256, 0, stream>>>(nt);

    EncArgs ea;
    ea.WhhF = eWhhF; ea.WhhB = eWhhB;
    ea.giF = GI; ea.giB = GI + 6291456;
    ea.bihF = ebihF; ea.bhhF = ebhhF; ea.bihB = ebihB; ea.bhhB = ebhhB;
    ea.HF = HF; ea.HB = HB; ea.HFB = HFB; ea.HBB = HBB; ea.ENC = ENC;
    ea.BAR = BAR; ea.bar0 = c * 32;
    ea.s0 = c0;
    k_enc<<<dim3(64), dim3(256), 0, stream>>>(ea);
  }

  // -------- enc_att = enc @ W2.T + b --------
  {
    NTA nt{};
    nt.tilesN = 4;
    NTZ& zz = nt.z[0];
    zz.sg[0] = mkseg(ENC, 512, 0, 512); zz.sg[1] = SENT; zz.sg[2] = SENT;
    zz.Bp = dattW + 512; zz.ldb = 1024; zz.bf32 = 1;
    zz.bias = dattb; zz.biasf32 = 1;
    zz.Cp = EATT; zz.ldc = 512; zz.cf32 = 0; zz.cslab = 0;
    zz.N = 512; zz.rev_s0 = -1; zz.K = 512;
    k_mfma_nt<128><<<dim3(256*4, 1, 1), 256, 0, stream>>>(nt);
  }

  // -------- decoder: one persistent kernel, all 64 steps --------
  {
    DecArgs da;
    da.tgt = tgt; da.Ag = Ag; da.AM = AM; da.KA = KAx; da.CAE = CAE;
    da.dattW = dattW; da.dattv = dattv;
    da.puWhh = puWhh; da.puWih = puWih; da.pubih = pubih; da.pubhh = pubhh;
    da.dWhh = dWhh; da.DBIH2 = DBIH2; da.dbhh = dbhh; da.VKE2 = VKE2; da.OUTB2 = OUTB2;
    da.ENC = ENC; da.EATT = EATT; da.DWF = DWF; da.MKTW = MKTW; da.OWF = OWF;
    da.HIDA = HIDA; da.HIDAB = HIDAB; da.DECH = DECH; da.DECHB = DECHB;
    da.HF0 = HF; da.HFB0 = HFB;
    da.PTRS = PTRS; da.VPRE = VPRE; da.CTX = CTX; da.DPART = DPART;
    da.QCK = QCK; da.CV2P = CV2P; da.GIDEC = GIDEC; da.OUTT = OUTT;
    da.out = (float*)d_out;
    da.BAR = BAR;
    k_dec<<<dim3(256), dim3(256), 0, stream>>>(da);
  }
}

// Round 2
// 28873.373 us; speedup vs baseline: 1.0955x; 1.0712x over previous
//
#include <hip/hip_runtime.h>

typedef unsigned short u16;
typedef unsigned int u32;

#define DEVI __device__ __forceinline__

constexpr float SCALE_ATT = 0.04419417382415922f;  // 1/sqrt(512)

// ---------------- workspace layout (bytes) ----------------
constexpr size_t OFF_GI    = 0;                                  // f32 [2][32][128][1536] per-chunk x@Wih
constexpr size_t OFF_ENC   = OFF_GI    + 4ull*2*32*128*1536;
constexpr size_t OFF_EATT  = OFF_ENC   + 2ull*256*128*512;       // bf16 enc, bf16 enc_att
constexpr size_t OFF_AM    = OFF_EATT  + 2ull*256*128*512;       // f32 [2][256][128][8]
constexpr size_t OFF_HF    = OFF_AM    + 4ull*2*256*128*8;       // ---- zero region start
constexpr size_t OFF_HB    = OFF_HF    + 4ull*2*128*512;
constexpr size_t OFF_HFB   = OFF_HB    + 4ull*2*128*512;
constexpr size_t OFF_HBB   = OFF_HFB   + 2ull*2*128*512;
constexpr size_t OFF_HIDA  = OFF_HBB   + 2ull*2*128*512;
constexpr size_t OFF_HIDAB = OFF_HIDA  + 4ull*2*2*128*512;
constexpr size_t OFF_BAR   = OFF_HIDAB + 2ull*2*2*128*512;       // u32 flag lines (see BAR_* below)
constexpr size_t OFF_ZEND  = OFF_BAR   + 49152;                  // ---- zero region end
constexpr size_t OFF_DECH  = OFF_ZEND;
constexpr size_t OFF_DECHB = OFF_DECH  + 4ull*2*128*512;
constexpr size_t OFF_PTRS  = OFF_DECHB + 2ull*2*128*512;         // f32 [2][128][8]
constexpr size_t OFF_VPRE  = OFF_PTRS  + 4ull*2*128*8;           // f32 [128][1024]  (b-major!)
constexpr size_t OFF_CTX   = OFF_VPRE  + 4ull*128*1024;
constexpr size_t OFF_DPART = OFF_CTX   + 4ull*128*512;
constexpr size_t OFF_QCK   = OFF_DPART + 4ull*128*512;           // f32 [128][520] (513 used)
constexpr size_t OFF_CV2P  = OFF_QCK   + 4ull*128*520;
constexpr size_t OFF_GIDEC = OFF_CV2P  + 4ull*128*512;           // f32 4 K-slabs [128][1536]
constexpr size_t OFF_OUTT  = OFF_GIDEC + 4ull*4*128*1536;        // f32 4 K-slabs [128][512]
constexpr size_t OFF_WOVF  = OFF_OUTT  + 4ull*4*128*512;         // f32 [2][512][512]
constexpr size_t OFF_WOVCF = OFF_WOVF  + 4ull*2*512*512;         // f32 [512][512]
constexpr size_t OFF_MKTF  = OFF_WOVCF + 4ull*512*512;           // f32 [513 rows][1024]
constexpr size_t OFF_DWF   = OFF_MKTF  + 4ull*513*1024;          // bf16 [1536][2048] folded dec Wih
constexpr size_t OFF_MKTW  = OFF_DWF   + 2ull*1536*2048;         // bf16 [513][1024] folded qck W
constexpr size_t OFF_OWF   = OFF_MKTW  + 2ull*513*1024;          // bf16 [512][2560] folded out W
constexpr size_t OFF_BOV   = OFF_OWF   + 2ull*512*2560;          // f32 [2][512]  (contiguous w/ BOVC!)
constexpr size_t OFF_BOVC  = OFF_BOV   + 4ull*2*512;             // f32 [512]
constexpr size_t OFF_KA    = OFF_BOVC  + 4ull*512;               // f32 [2][512][16] (9 used)
constexpr size_t OFF_CAE   = OFF_KA    + 4ull*2*512*16;          // f32 [2][16]
constexpr size_t OFF_RT    = OFF_CAE   + 4ull*2*16;              // f32 [2][512][16]
constexpr size_t OFF_BQC   = OFF_RT    + 4ull*2*512*16;          // f32 [2][512]
constexpr size_t OFF_PMAT  = OFF_BQC   + 4ull*2*512;             // f32 [512][516]
constexpr size_t OFF_CQ    = OFF_PMAT  + 4ull*512*516;
constexpr size_t OFF_VKE2  = OFF_CQ    + 4ull*512;               // f32 [520]
constexpr size_t OFF_DBIH2 = OFF_VKE2  + 4ull*520;               // f32 [1536]
constexpr size_t OFF_OUTB2 = OFF_DBIH2 + 4ull*1536;              // f32 [512]
constexpr size_t WS_NEED   = OFF_OUTB2 + 4ull*512;

// ---------------- helpers ----------------
DEVI float b2f(u16 u){ union{u32 i; float f;} x; x.i = ((u32)u) << 16; return x.f; }
DEVI u16 f2b(float f){ union{float f; u32 i;} x; x.f = f; u32 i = x.i; u32 r = i + 0x7FFFu + ((i >> 16) & 1u); return (u16)(r >> 16); }
DEVI float sigmf_(float x){ return 1.f / (1.f + __expf(-x)); }
DEVI float tanhf_(float x){ x = fminf(15.f, fmaxf(-15.f, x)); float e = __expf(2.f*x); return (e - 1.f) / (e + 1.f); }

typedef __attribute__((ext_vector_type(8))) short bfrag;
typedef __attribute__((ext_vector_type(4))) float ffrag;

DEVI uint4 cvt8(float4 a, float4 b){
  union{uint4 u; u16 h[8];} r;
  r.h[0]=f2b(a.x); r.h[1]=f2b(a.y); r.h[2]=f2b(a.z); r.h[3]=f2b(a.w);
  r.h[4]=f2b(b.x); r.h[5]=f2b(b.y); r.h[6]=f2b(b.z); r.h[7]=f2b(b.w);
  return r.u;
}

// ---- all-store flag grid barrier (NO RMWs) ----
// Old design: 256 blocks atomicAdd the SAME line -> same-line RMWs serialize at
// the coherence point (~150ns each) -> ~38us/barrier. New design:
//   arrive:  each block release-stores monotonic seq to its OWN 128B line (parallel)
//   gather:  one designated block's threads poll all flags in parallel, then
//            publishes go=seq (one line)
//   wait:    others spin on go with system-scope relaxed LOADS (read-parallel)
// Expected ~2-3us/barrier (two coherence-point round trips).
constexpr int GB_STRIDE  = 32;     // u32 per flag line (128B)
constexpr int BAR_DECF   = 0;      // 256 flags * 32 u32
constexpr int BAR_DECGO  = 8192;   // 1 line
constexpr int BAR_ENCF   = 8224;   // 64 flags * 32 u32
constexpr int BAR_ENCGO  = 10272;  // 1 line

DEVI u32 ld_sys(u32* p){ return __hip_atomic_load(p, __ATOMIC_RELAXED, __HIP_MEMORY_SCOPE_SYSTEM); }
DEVI void st_sys(u32* p, u32 v){ __hip_atomic_store(p, v, __ATOMIC_RELAXED, __HIP_MEMORY_SCOPE_SYSTEM); }

DEVI void gridbar2(u32* flags, u32* go, u32 seq, int nblk, int blk, int gblk)
{
  __syncthreads();
  int t = threadIdx.x;
  if (blk == gblk){
    if (t == 0){ __threadfence(); st_sys(&flags[(u32)blk * GB_STRIDE], seq); }
    if (t < nblk){
      u32* f = &flags[(u32)t * GB_STRIDE];
      while (ld_sys(f) < seq) __builtin_amdgcn_s_sleep(1);
    }
    __syncthreads();
    if (t == 0){ st_sys(go, seq); __threadfence(); }
  } else {
    if (t == 0){
      __threadfence();
      st_sys(&flags[(u32)blk * GB_STRIDE], seq);
      while (ld_sys(go) < seq) __builtin_amdgcn_s_sleep(1);
      __threadfence();
    }
  }
  __syncthreads();
}

// ================ host-launched 3-seg NT GEMM (GI chunks + EATT) ================
struct Seg { const void* p; int ld; int f32; int K; };
struct NTZ {
  Seg sg[3];
  const void* Bp; int ldb; int bf32;
  const void* bias; int biasf32;
  void* Cp; int ldc; int cf32; int cslab;
  int N; int rev_s0; int K;
};
struct NTA { NTZ z[3]; int tilesN; };

template<int BN>
__global__ __launch_bounds__(256) void k_mfma_nt(NTA a)
{
  NTZ z = a.z[blockIdx.z];
  int tn = blockIdx.x % a.tilesN;
  int tm = blockIdx.x / a.tilesN;
  if (tn * BN >= z.N) return;
  int nks = gridDim.y;
  int kb = blockIdx.y * (z.K / nks);
  int ke = kb + z.K / nks;

  __shared__ short Al[128*32];
  __shared__ short Bl[BN*32];

  int t = threadIdx.x;
  int lane = t & 63, w = t >> 6;
  constexpr int FRS = (BN == 128) ? 4 : 2;
  int wn = (BN == 128) ? (w & 1) : 0;
  int rowbase = (BN == 128) ? (w >> 1) * 64 : w * 32;

  ffrag zz4 = {0.f, 0.f, 0.f, 0.f};
  ffrag acc[FRS][4];
  #pragma unroll
  for (int i = 0; i < FRS; i++)
    #pragma unroll
    for (int j = 0; j < 4; j++) acc[i][j] = zz4;

  for (int k0 = kb; k0 < ke; k0 += 32){
    #pragma unroll
    for (int r2 = 0; r2 < 2; r2++){
      int slot = t + r2 * 256;
      int row = slot >> 2, kq = slot & 3;
      int m = tm * 128 + row;
      int arow = (z.rev_s0 >= 0) ? (((z.rev_s0 - (m >> 7)) << 7) | (m & 127)) : m;
      int k = k0 + kq * 8;
      Seg sg;
      if (k < z.sg[0].K) sg = z.sg[0];
      else { k -= z.sg[0].K; if (k < z.sg[1].K) sg = z.sg[1]; else { k -= z.sg[1].K; sg = z.sg[2]; } }
      uint4 v;
      if (sg.f32){
        const float* ap = (const float*)sg.p + (size_t)arow * sg.ld + k;
        v = cvt8(*(const float4*)ap, *(const float4*)(ap + 4));
      } else {
        v = *(const uint4*)((const u16*)sg.p + (size_t)arow * sg.ld + k);
      }
      *(uint4*)&Al[(((row >> 4) << 6) + (kq << 4) + (row & 15)) * 8] = v;
    }
    #pragma unroll
    for (int r2 = 0; r2 < BN/64; r2++){
      int slot = t + r2 * 256;
      int brow = slot >> 2, kq = slot & 3;
      int n = tn * BN + brow;
      uint4 v = make_uint4(0u, 0u, 0u, 0u);
      if (n < z.N){
        int k = k0 + kq * 8;
        if (z.bf32){
          const float* bp = (const float*)z.Bp + (size_t)n * z.ldb + k;
          v = cvt8(*(const float4*)bp, *(const float4*)(bp + 4));
        } else {
          v = *(const uint4*)((const u16*)z.Bp + (size_t)n * z.ldb + k);
        }
      }
      *(uint4*)&Bl[(kq * BN + brow) * 8] = v;
    }
    __syncthreads();
    bfrag af[FRS], bv[4];
    #pragma unroll
    for (int fr = 0; fr < FRS; fr++) af[fr] = *(bfrag*)&Al[(((rowbase >> 4) + fr) * 64 + lane) * 8];
    #pragma unroll
    for (int fc = 0; fc < 4; fc++) bv[fc] = *(bfrag*)&Bl[(((lane >> 4) * BN) + wn * 64 + fc * 16 + (lane & 15)) * 8];
    #pragma unroll
    for (int fr = 0; fr < FRS; fr++)
      #pragma unroll
      for (int fc = 0; fc < 4; fc++)
        acc[fr][fc] = __builtin_amdgcn_mfma_f32_16x16x32_bf16(af[fr], bv[fc], acc[fr][fc], 0, 0, 0);
    __syncthreads();
  }

  float* Cf = (float*)z.Cp + (size_t)blockIdx.y * z.cslab;
  u16*  Cb = (u16*)z.Cp  + (size_t)blockIdx.y * z.cslab;
  #pragma unroll
  for (int fc = 0; fc < 4; fc++){
    int n = tn * BN + wn * 64 + fc * 16 + (lane & 15);
    if (n >= z.N) continue;
    float bs = 0.f;
    if (z.bias) bs = z.biasf32 ? ((const float*)z.bias)[n] : b2f(((const u16*)z.bias)[n]);
    #pragma unroll
    for (int fr = 0; fr < FRS; fr++){
      #pragma unroll
      for (int i = 0; i < 4; i++){
        int m = tm * 128 + rowbase + fr * 16 + ((lane >> 4) << 2) + i;
        float vv = acc[fr][fc][i] + bs;
        size_t idx = (size_t)m * z.ldc + n;
        if (z.cf32) Cf[idx] = vv; else Cb[idx] = f2b(vv);
      }
    }
  }
}

// ================ device-side 4-seg NT GEMM (M=128 fixed) ================
struct Seg4 { const void* p; int ld; int f32; int K; };
struct Z4 {
  Seg4 sg[4];
  const void* Bp; int ldb; int bf32;
  const float* bias;
  float* Cp; int ldc; int cslab;
  int N; int K;
};

template<int BN>
DEVI void dev_mfma4(const Z4& z, int tn, int ks, int nks, short* Al, short* Bl)
{
  int kseg = z.K / nks;
  int kb = ks * kseg, ke = kb + kseg;
  int t = threadIdx.x, lane = t & 63, w = t >> 6;
  constexpr int FRS = (BN == 128) ? 4 : 2;
  int wn = (BN == 128) ? (w & 1) : 0;
  int rowbase = (BN == 128) ? (w >> 1) * 64 : w * 32;
  ffrag zz4 = {0.f, 0.f, 0.f, 0.f};
  ffrag acc[FRS][4];
  #pragma unroll
  for (int i = 0; i < FRS; i++)
    #pragma unroll
    for (int j = 0; j < 4; j++) acc[i][j] = zz4;

  for (int k0 = kb; k0 < ke; k0 += 32){
    #pragma unroll
    for (int r2 = 0; r2 < 2; r2++){
      int slot = t + r2 * 256;
      int row = slot >> 2, kq = slot & 3;
      int k = k0 + kq * 8;
      Seg4 sg = z.sg[0];
      if (k >= sg.K){ k -= sg.K; sg = z.sg[1];
        if (k >= sg.K){ k -= sg.K; sg = z.sg[2];
          if (k >= sg.K){ k -= sg.K; sg = z.sg[3]; } } }
      uint4 v;
      if (sg.f32){
        const float* ap = (const float*)sg.p + (size_t)row * sg.ld + k;
        v = cvt8(*(const float4*)ap, *(const float4*)(ap + 4));
      } else {
        v = *(const uint4*)((const u16*)sg.p + (size_t)row * sg.ld + k);
      }
      *(uint4*)&Al[(((row >> 4) << 6) + (kq << 4) + (row & 15)) * 8] = v;
    }
    #pragma unroll
    for (int r2 = 0; r2 < BN/64; r2++){
      int slot = t + r2 * 256;
      int brow = slot >> 2, kq = slot & 3;
      int n = tn * BN + brow;
      uint4 v = make_uint4(0u, 0u, 0u, 0u);
      if (n < z.N){
        int k = k0 + kq * 8;
        if (z.bf32){
          const float* bp = (const float*)z.Bp + (size_t)n * z.ldb + k;
          v = cvt8(*(const float4*)bp, *(const float4*)(bp + 4));
        } else {
          v = *(const uint4*)((const u16*)z.Bp + (size_t)n * z.ldb + k);
        }
      }
      *(uint4*)&Bl[(kq * BN + brow) * 8] = v;
    }
    __syncthreads();
    bfrag af[FRS], bv[4];
    #pragma unroll
    for (int fr = 0; fr < FRS; fr++) af[fr] = *(bfrag*)&Al[(((rowbase >> 4) + fr) * 64 + lane) * 8];
    #pragma unroll
    for (int fc = 0; fc < 4; fc++) bv[fc] = *(bfrag*)&Bl[(((lane >> 4) * BN) + wn * 64 + fc * 16 + (lane & 15)) * 8];
    #pragma unroll
    for (int fr = 0; fr < FRS; fr++)
      #pragma unroll
      for (int fc = 0; fc < 4; fc++)
        acc[fr][fc] = __builtin_amdgcn_mfma_f32_16x16x32_bf16(af[fr], bv[fc], acc[fr][fc], 0, 0, 0);
    __syncthreads();
  }

  float* Cf = z.Cp + (size_t)ks * z.cslab;
  #pragma unroll
  for (int fc = 0; fc < 4; fc++){
    int n = tn * BN + wn * 64 + fc * 16 + (lane & 15);
    if (n >= z.N) continue;
    float bs = z.bias ? z.bias[n] : 0.f;
    #pragma unroll
    for (int fr = 0; fr < FRS; fr++){
      #pragma unroll
      for (int i = 0; i < 4; i++){
        int m = rowbase + fr * 16 + ((lane >> 4) << 2) + i;
        Cf[(size_t)m * z.ldc + n] = acc[fr][fc][i] + bs;
      }
    }
  }
}

// ================ device-side fused GRU step (h@Whh MFMA + epilogue) ================
// MODE 1 = pointer unit (gi from ptr(B,8)@Wih); MODE 2 = decoder (gi = 4 K-split slabs)
template<int MODE>
DEVI void dev_gru3(int g0, const u16* hb, const float* hf, const float* Whh,
                   const float* gi_f, const float* xp, const float* Wih,
                   const float* bih, const float* bhh,
                   float* hnf, u16* hnb, short* Al, short* Bl)
{
  int t = threadIdx.x, lane = t & 63, w = t >> 6;
  int wm = w >> 1, wn = w & 1;
  ffrag zz4 = {0.f, 0.f, 0.f, 0.f};
  ffrag acc[4][3];
  #pragma unroll
  for (int i = 0; i < 4; i++)
    #pragma unroll
    for (int j = 0; j < 3; j++) acc[i][j] = zz4;

  for (int k0 = 0; k0 < 512; k0 += 32){
    #pragma unroll
    for (int r2 = 0; r2 < 2; r2++){
      int slot = t + r2 * 256;
      int row = slot >> 2, kq = slot & 3;
      uint4 v = *(const uint4*)(hb + (size_t)row * 512 + k0 + kq * 8);
      *(uint4*)&Al[(((row >> 4) << 6) + (kq << 4) + (row & 15)) * 8] = v;
    }
    {
      int lb = t >> 2, kq = t & 3;
      int wn2 = lb / 48, rem = lb - wn2 * 48, fc = rem >> 4, i16 = rem & 15;
      int grow = fc * 512 + g0 + wn2 * 16 + i16;
      const float* wp = Whh + (size_t)grow * 512 + k0 + kq * 8;
      uint4 v = cvt8(*(const float4*)wp, *(const float4*)(wp + 4));
      *(uint4*)&Bl[(kq * 96 + lb) * 8] = v;
      if (t < 128){
        int slot = t + 256;
        lb = slot >> 2; kq = slot & 3;
        wn2 = lb / 48; rem = lb - wn2 * 48; fc = rem >> 4; i16 = rem & 15;
        grow = fc * 512 + g0 + wn2 * 16 + i16;
        wp = Whh + (size_t)grow * 512 + k0 + kq * 8;
        v = cvt8(*(const float4*)wp, *(const float4*)(wp + 4));
        *(uint4*)&Bl[(kq * 96 + lb) * 8] = v;
      }
    }
    __syncthreads();
    bfrag af[4], bv[3];
    #pragma unroll
    for (int fr = 0; fr < 4; fr++) af[fr] = *(bfrag*)&Al[((wm * 4 + fr) * 64 + lane) * 8];
    #pragma unroll
    for (int fc = 0; fc < 3; fc++) bv[fc] = *(bfrag*)&Bl[((lane >> 4) * 96 + (wn * 3 + fc) * 16 + (lane & 15)) * 8];
    #pragma unroll
    for (int fr = 0; fr < 4; fr++)
      #pragma unroll
      for (int fc = 0; fc < 3; fc++)
        acc[fr][fc] = __builtin_amdgcn_mfma_f32_16x16x32_bf16(af[fr], bv[fc], acc[fr][fc], 0, 0, 0);
    __syncthreads();
  }

  int gcol = g0 + wn * 16 + (lane & 15);
  float bir = bih[gcol],        bhr = bhh[gcol];
  float biz = bih[512 + gcol],  bhz = bhh[512 + gcol];
  float bin = bih[1024 + gcol], bhn = bhh[1024 + gcol];
  float wxr[8], wxz[8], wxn[8];
  if (MODE == 1){
    #pragma unroll
    for (int a2 = 0; a2 < 8; a2++){
      wxr[a2] = Wih[(size_t)gcol * 8 + a2];
      wxz[a2] = Wih[(size_t)(512 + gcol) * 8 + a2];
      wxn[a2] = Wih[(size_t)(1024 + gcol) * 8 + a2];
    }
  }
  #pragma unroll
  for (int fr = 0; fr < 4; fr++){
    #pragma unroll
    for (int i = 0; i < 4; i++){
      int brow = wm * 64 + fr * 16 + ((lane >> 4) << 2) + i;
      float gr_, gz_, gn_;
      if (MODE == 2){
        gr_ = gz_ = gn_ = 0.f;
        #pragma unroll
        for (int sl = 0; sl < 4; sl++){
          const float* gp = gi_f + (size_t)sl * 196608 + (size_t)brow * 1536;
          gr_ += gp[gcol]; gz_ += gp[512 + gcol]; gn_ += gp[1024 + gcol];
        }
      } else {
        float4 x0 = *(const float4*)(xp + brow * 8);
        float4 x1 = *(const float4*)(xp + brow * 8 + 4);
        float xa[8] = {x0.x, x0.y, x0.z, x0.w, x1.x, x1.y, x1.z, x1.w};
        gr_ = gz_ = gn_ = 0.f;
        #pragma unroll
        for (int a2 = 0; a2 < 8; a2++){ gr_ += xa[a2]*wxr[a2]; gz_ += xa[a2]*wxz[a2]; gn_ += xa[a2]*wxn[a2]; }
      }
      float hold = hf[(size_t)brow * 512 + gcol];
      float r  = sigmf_(gr_ + acc[fr][0][i] + bir + bhr);
      float zg = sigmf_(gz_ + acc[fr][1][i] + biz + bhz);
      float n  = tanhf_(gn_ + bin + r * (acc[fr][2][i] + bhn));
      float hn = (1.f - zg) * n + zg * hold;
      hnf[(size_t)brow * 512 + gcol] = hn;
      hnb[(size_t)brow * 512 + gcol] = f2b(hn);
    }
  }
}

// ================ device-side attention pieces ================
DEVI void dev_puattn(int b, const float* hida2, const float* Ka, const float* cae,
                     const float* Am, const float* Ain, const u16* enc,
                     float* vpre, float* ptrs, float* fs)
{
  int t = threadIdx.x, lane = t & 63, w = t >> 6;
  float* sc0 = fs; float* sc1 = fs + 256; float* smx = fs + 512;
  float* wred = fs + 768; float* qa = fs + 840; float* cd = fs + 860;

  if (t < 16) cd[t] = 0.f;
  for (int u = 0; u < 2; u++){
    const float* hp = hida2 + ((size_t)u * 128 + b) * 512;
    float hv0 = hp[t], hv1 = hp[t + 256];
    const float* k0p = Ka + u * 8192 + t * 16;
    const float* k1p = Ka + u * 8192 + (t + 256) * 16;
    float p[9];
    #pragma unroll
    for (int j = 0; j < 9; j++) p[j] = hv0 * k0p[j] + hv1 * k1p[j];
    #pragma unroll
    for (int j = 0; j < 9; j++){
      #pragma unroll
      for (int off = 32; off > 0; off >>= 1) p[j] += __shfl_xor(p[j], off);
    }
    if (lane == 0){
      #pragma unroll
      for (int j = 0; j < 9; j++) wred[w * 9 + j] = p[j];
    }
    __syncthreads();
    if (t < 9) qa[u * 10 + t] = wred[t] + wred[9 + t] + wred[18 + t] + wred[27 + t] + cae[u * 16 + t];
    __syncthreads();
  }

  float su[2];
  #pragma unroll
  for (int u = 0; u < 2; u++){
    const float* amp = Am + (((size_t)u * 256 + t) * 128 + b) * 8;
    float4 a0 = *(const float4*)amp;
    float4 a1 = *(const float4*)(amp + 4);
    const float* q = qa + u * 10;
    su[u] = (q[8] + q[0]*a0.x + q[1]*a0.y + q[2]*a0.z + q[3]*a0.w
                  + q[4]*a1.x + q[5]*a1.y + q[6]*a1.z + q[7]*a1.w) * SCALE_ATT;
  }

  const float* ap = Ain + ((size_t)b * 256 + t) * 8;
  float av[8];
  {
    float4 v0 = *(const float4*)ap;
    float4 v1 = *(const float4*)(ap + 4);
    av[0]=v0.x; av[1]=v0.y; av[2]=v0.z; av[3]=v0.w;
    av[4]=v1.x; av[5]=v1.y; av[6]=v1.z; av[7]=v1.w;
  }

  float inv[2];
  for (int u = 0; u < 2; u++){
    float s_ = su[u];
    float* sc = u ? sc1 : sc0;
    smx[t] = s_; __syncthreads();
    for (int o = 128; o > 0; o >>= 1){ if (t < o) smx[t] = fmaxf(smx[t], smx[t + o]); __syncthreads(); }
    float mx = smx[0]; __syncthreads();
    float e = __expf(s_ - mx); sc[t] = e;
    #pragma unroll
    for (int a2 = 0; a2 < 8; a2++) atomicAdd(&cd[u * 8 + a2], e * av[a2]);
    smx[t] = e; __syncthreads();
    for (int o = 128; o > 0; o >>= 1){ if (t < o) smx[t] += smx[t + o]; __syncthreads(); }
    inv[u] = 1.f / smx[0]; __syncthreads();
  }
  if (t < 8){
    ptrs[((size_t)0 * 128 + b) * 8 + t] = cd[t] * inv[0];
    ptrs[((size_t)128 + b) * 8 + t]     = cd[8 + t] * inv[1];
  }

  // value pass over ENC: thread t owns cols 2t,2t+1 (one u32 = 2 bf16 per s2)
  float a00 = 0.f, a01 = 0.f, a10 = 0.f, a11 = 0.f;
  const u16* ep = enc + (size_t)b * 512;
  #pragma unroll 8
  for (int s2 = 0; s2 < 256; s2++){
    float w0 = sc0[s2], w1 = sc1[s2];
    u32 pv = *(const u32*)(ep + (size_t)s2 * 65536 + 2 * t);
    float v0 = b2f((u16)pv);
    float v1 = b2f((u16)(pv >> 16));
    a00 += w0 * v0; a01 += w0 * v1; a10 += w1 * v0; a11 += w1 * v1;
  }
  float* vp = vpre + (size_t)b * 1024;
  vp[2 * t] = a00 * inv[0];           vp[2 * t + 1] = a01 * inv[0];
  vp[512 + 2 * t] = a10 * inv[1];     vp[512 + 2 * t + 1] = a11 * inv[1];
}

DEVI void dev_bahd(int b, const u16* eatt, const float* dpart, const float* vvec,
                   const u16* enc, float* ctx, float* fs)
{
  int t = threadIdx.x, lane = t & 63, w = t >> 6;
  float* dp = fs; float* vv = fs + 512; float* sc = fs + 1024; float* smx = fs + 1280;
  dp[t] = dpart[(size_t)b * 512 + t]; dp[t + 256] = dpart[(size_t)b * 512 + t + 256];
  vv[t] = vvec[t]; vv[t + 256] = vvec[t + 256];
  __syncthreads();
  for (int s = w; s < 256; s += 4){
    uint4 v = *(const uint4*)(eatt + ((size_t)s * 128 + b) * 512 + lane * 8);
    const u16* h = (const u16*)&v;
    float4 d0 = *(float4*)&dp[lane * 8], d1 = *(float4*)&dp[lane * 8 + 4];
    float4 v0 = *(float4*)&vv[lane * 8], v1 = *(float4*)&vv[lane * 8 + 4];
    float r = fmaxf(0.f, b2f(h[0]) + d0.x) * v0.x + fmaxf(0.f, b2f(h[1]) + d0.y) * v0.y
            + fmaxf(0.f, b2f(h[2]) + d0.z) * v0.z + fmaxf(0.f, b2f(h[3]) + d0.w) * v0.w
            + fmaxf(0.f, b2f(h[4]) + d1.x) * v1.x + fmaxf(0.f, b2f(h[5]) + d1.y) * v1.y
            + fmaxf(0.f, b2f(h[6]) + d1.z) * v1.z + fmaxf(0.f, b2f(h[7]) + d1.w) * v1.w;
    #pragma unroll
    for (int off = 32; off > 0; off >>= 1) r += __shfl_xor(r, off);
    if (lane == 0) sc[s] = r;
  }
  __syncthreads();
  float s0 = sc[t];
  smx[t] = s0; __syncthreads();
  for (int o = 128; o > 0; o >>= 1){ if (t < o) smx[t] = fmaxf(smx[t], smx[t + o]); __syncthreads(); }
  float mx = smx[0]; __syncthreads();
  float e = __expf(s0 - mx); sc[t] = e; smx[t] = e; __syncthreads();
  for (int o = 128; o > 0; o >>= 1){ if (t < o) smx[t] += smx[t + o]; __syncthreads(); }
  float inv = 1.f / smx[0];
  float a0 = 0.f, a1 = 0.f;
  const u16* ep = enc + (size_t)b * 512;
  #pragma unroll 8
  for (int s2 = 0; s2 < 256; s2++){
    float wgt = sc[s2];
    u32 pv = *(const u32*)(ep + (size_t)s2 * 65536 + 2 * t);
    a0 += wgt * b2f((u16)pv);
    a1 += wgt * b2f((u16)(pv >> 16));
  }
  ctx[(size_t)b * 512 + 2 * t] = a0 * inv;
  ctx[(size_t)b * 512 + 2 * t + 1] = a1 * inv;
}

DEVI void dev_cattn(int b, const float* qck, const u16* enc, float* cv2p, float* fs)
{
  int t = threadIdx.x, lane = t & 63, w = t >> 6;
  float* qv = fs; float* sc = fs + 1024; float* smx = fs + 1280;
  qv[t] = qck[(size_t)b * 520 + t]; qv[t + 256] = qck[(size_t)b * 520 + t + 256];
  __syncthreads();
  float qc0 = qck[(size_t)b * 520 + 512];
  for (int s = w; s < 256; s += 4){
    uint4 v = *(const uint4*)(enc + ((size_t)s * 128 + b) * 512 + lane * 8);
    const u16* h = (const u16*)&v;
    float4 q0 = *(float4*)&qv[lane * 8], q1 = *(float4*)&qv[lane * 8 + 4];
    float r = b2f(h[0])*q0.x + b2f(h[1])*q0.y + b2f(h[2])*q0.z + b2f(h[3])*q0.w
            + b2f(h[4])*q1.x + b2f(h[5])*q1.y + b2f(h[6])*q1.z + b2f(h[7])*q1.w;
    #pragma unroll
    for (int off = 32; off > 0; off >>= 1) r += __shfl_xor(r, off);
    if (lane == 0) sc[s] = (r + qc0) * SCALE_ATT;
  }
  __syncthreads();
  float s0 = sc[t];
  smx[t] = s0; __syncthreads();
  for (int o = 128; o > 0; o >>= 1){ if (t < o) smx[t] = fmaxf(smx[t], smx[t + o]); __syncthreads(); }
  float mx = smx[0]; __syncthreads();
  float e = __expf(s0 - mx); sc[t] = e; smx[t] = e; __syncthreads();
  for (int o = 128; o > 0; o >>= 1){ if (t < o) smx[t] += smx[t + o]; __syncthreads(); }
  float inv = 1.f / smx[0];
  float a0 = 0.f, a1 = 0.f;
  const u16* ep = enc + (size_t)b * 512;
  #pragma unroll 8
  for (int s2 = 0; s2 < 256; s2++){
    float wgt = sc[s2];
    u32 pv = *(const u32*)(ep + (size_t)s2 * 65536 + 2 * t);
    a0 += wgt * b2f((u16)pv);
    a1 += wgt * b2f((u16)(pv >> 16));
  }
  cv2p[(size_t)b * 512 + 2 * t] = a0 * inv;
  cv2p[(size_t)b * 512 + 2 * t + 1] = a1 * inv;
}

DEVI void dev_outcvt(int b, const float* outt, const float* outb2, float* dst)
{
  int t = threadIdx.x;
  #pragma unroll
  for (int rep = 0; rep < 2; rep++){
    int o = t + rep * 256;
    float s = outt[(size_t)b * 512 + o] + outt[65536 + (size_t)b * 512 + o]
            + outt[131072 + (size_t)b * 512 + o] + outt[196608 + (size_t)b * 512 + o];
    dst[(size_t)b * 512 + o] = s + outb2[o];
  }
}

// ================ persistent encoder (32 steps per launch, manual barrier) ================
struct EncArgs {
  const float *WhhF, *WhhB, *giF, *giB;
  const float *bihF, *bhhF, *bihB, *bhhB;
  float *HF, *HB; u16 *HFB, *HBB, *ENC;
  u32 *BAR; int bar0;
  int s0;
};

__global__ __launch_bounds__(256) void k_enc(EncArgs a)
{
  __shared__ short Bw[24576];   // 48 rows (3 gates x 16 cols) x 512 K, bf16, MFMA layout
  __shared__ short Al[4096];
  int blk = blockIdx.x;
  int d = blk >> 5, gt = blk & 31;
  int t = threadIdx.x, lane = t & 63, w = t >> 6;

  const float* Whh = d ? a.WhhB : a.WhhF;
  for (int c = t; c < 3072; c += 256){
    int brow = c >> 6, kc = c & 63;
    int grow = (brow >> 4) * 512 + gt * 16 + (brow & 15);
    const float* wp = Whh + (size_t)grow * 512 + kc * 8;
    *(uint4*)&Bw[((kc * 48) + brow) * 8] = cvt8(*(const float4*)wp, *(const float4*)(wp + 4));
  }
  const float* bih = d ? a.bihB : a.bihF;
  const float* bhh = d ? a.bhhB : a.bhhF;
  int gcol = gt * 16 + (lane & 15);
  float bir = bih[gcol],        bhr = bhh[gcol];
  float biz = bih[512 + gcol],  bhz = bhh[512 + gcol];
  float bin = bih[1024 + gcol], bhn = bhh[1024 + gcol];
  float* hf_base = d ? a.HB : a.HF;
  u16*   hb_base = d ? a.HBB : a.HFB;
  const float* gi_base = d ? a.giB : a.giF;
  __syncthreads();

  for (int si = 0; si < 32; si++){
    int s = a.s0 + si;
    const u16* hb = hb_base + (size_t)(s & 1) * 65536;
    const float* hf = hf_base + (size_t)(s & 1) * 65536;
    float* hnf = hf_base + (size_t)((s + 1) & 1) * 65536;
    u16* hnb = hb_base + (size_t)((s + 1) & 1) * 65536;
    u16* eacc = a.ENC + (size_t)(d ? 255 - s : s) * 65536;

    ffrag zz4 = {0.f, 0.f, 0.f, 0.f};
    ffrag acc[2][3];
    #pragma unroll
    for (int i = 0; i < 2; i++)
      #pragma unroll
      for (int j = 0; j < 3; j++) acc[i][j] = zz4;

    for (int ki = 0; ki < 16; ki++){
      int k0 = ki * 32;
      #pragma unroll
      for (int r2 = 0; r2 < 2; r2++){
        int slot = t + r2 * 256;
        int row = slot >> 2, kq = slot & 3;
        uint4 v = *(const uint4*)(hb + (size_t)row * 512 + k0 + kq * 8);
        *(uint4*)&Al[(((row >> 4) << 6) + (kq << 4) + (row & 15)) * 8] = v;
      }
      __syncthreads();
      bfrag af[2], bv[3];
      #pragma unroll
      for (int fr = 0; fr < 2; fr++) af[fr] = *(bfrag*)&Al[(((w * 2 + fr) * 64) + lane) * 8];
      #pragma unroll
      for (int fc = 0; fc < 3; fc++) bv[fc] = *(bfrag*)&Bw[(((ki * 4 + (lane >> 4)) * 48) + fc * 16 + (lane & 15)) * 8];
      #pragma unroll
      for (int fr = 0; fr < 2; fr++)
        #pragma unroll
        for (int fc = 0; fc < 3; fc++)
          acc[fr][fc] = __builtin_amdgcn_mfma_f32_16x16x32_bf16(af[fr], bv[fc], acc[fr][fc], 0, 0, 0);
      __syncthreads();
    }

    const float* gp0 = gi_base + (size_t)si * 196608;
    #pragma unroll
    for (int fr = 0; fr < 2; fr++){
      #pragma unroll
      for (int i = 0; i < 4; i++){
        int brow = w * 32 + fr * 16 + ((lane >> 4) << 2) + i;
        const float* gp = gp0 + (size_t)brow * 1536;
        float gr_ = gp[gcol], gz_ = gp[512 + gcol], gn_ = gp[1024 + gcol];
        float hold = hf[(size_t)brow * 512 + gcol];
        float r  = sigmf_(gr_ + acc[fr][0][i] + bir + bhr);
        float zg = sigmf_(gz_ + acc[fr][1][i] + biz + bhz);
        float n  = tanhf_(gn_ + bin + r * (acc[fr][2][i] + bhn));
        float hn = (1.f - zg) * n + zg * hold;
        hnf[(size_t)brow * 512 + gcol] = hn;
        hnb[(size_t)brow * 512 + gcol] = f2b(hn);
        size_t idx = (size_t)brow * 512 + gcol;
        eacc[idx] = f2b(b2f(eacc[idx]) + hn);
      }
    }
    gridbar2(a.BAR + BAR_ENCF, a.BAR + BAR_ENCGO, (u32)(a.s0 + si + 1), 64, blk, 0);
  }
}

// ================ persistent decoder (all 64 steps, manual barrier) ================
struct DecArgs {
  const float *tgt, *Ag, *AM, *KA, *CAE, *dattW, *dattv;
  const float *puWhh, *puWih, *pubih, *pubhh;
  const float *dWhh, *DBIH2, *dbhh, *VKE2, *OUTB2;
  const u16 *ENC, *EATT, *DWF, *MKTW, *OWF;
  float *HIDA; u16 *HIDAB;
  float *DECH; u16 *DECHB;
  float *HF0; u16 *HFB0;
  float *PTRS, *VPRE, *CTX, *DPART, *QCK, *CV2P, *GIDEC, *OUTT, *out;
  u32 *BAR;
};

__global__ __launch_bounds__(256) void k_dec(DecArgs a)
{
  __shared__ short Al[4096];
  __shared__ short Bl[4096];
  __shared__ float fs[1600];
  const int blk = blockIdx.x;
  const Seg4 S4SENT = {nullptr, 0, 0, 1 << 30};
  u32* dF = a.BAR + BAR_DECF;
  u32* dG = a.BAR + BAR_DECGO;
  const int GATHER = 200;   // busy only in phase B -> polls start early in other phases

  for (int st = 0; st < 64; st++){
    const float* hida_c  = a.HIDA  + (size_t)(st & 1) * 131072;
    float*       hida_n  = a.HIDA  + (size_t)((st + 1) & 1) * 131072;
    const u16*   hidab_c = a.HIDAB + (size_t)(st & 1) * 131072;
    u16*         hidab_n = a.HIDAB + (size_t)((st + 1) & 1) * 131072;
    const float* dech_c  = (st == 0) ? a.HF0  : a.DECH  + (size_t)((st + 1) & 1) * 65536;
    const u16*   dechb_c = (st == 0) ? a.HFB0 : a.DECHB + (size_t)((st + 1) & 1) * 65536;
    float*       dech_n  = a.DECH  + (size_t)(st & 1) * 65536;
    u16*         dechb_n = a.DECHB + (size_t)(st & 1) * 65536;
    u32 seq0 = (u32)(st * 5);

    // ---- phase A: pu GRUs | dpart GEMM | outcvt(st-1)
    if (blk < 32){
      int u = blk >> 4, g0 = (blk & 15) * 32;
      dev_gru3<1>(g0, hidab_c + (size_t)u * 65536, hida_c + (size_t)u * 65536,
                  a.puWhh + (size_t)u * 786432, nullptr,
                  a.PTRS + u * 1024, a.puWih + (size_t)u * 12288,
                  a.pubih + u * 1536, a.pubhh + u * 1536,
                  hida_n + (size_t)u * 65536, hidab_n + (size_t)u * 65536, Al, Bl);
    } else if (blk < 40){
      Z4 z;
      z.sg[0] = {dechb_c, 512, 0, 512}; z.sg[1] = S4SENT; z.sg[2] = S4SENT; z.sg[3] = S4SENT;
      z.Bp = a.dattW; z.ldb = 1024; z.bf32 = 1; z.bias = nullptr;
      z.Cp = a.DPART; z.ldc = 512; z.cslab = 0; z.N = 512; z.K = 512;
      dev_mfma4<64>(z, blk - 32, 0, 1, Al, Bl);
    } else if (blk < 168 && st > 0){
      dev_outcvt(blk - 40, a.OUTT, a.OUTB2, a.out + (size_t)(st - 1) * 65536);
    }
    gridbar2(dF, dG, seq0 + 1, 256, blk, GATHER);

    // ---- phase B: pointer attention (both units) | Bahdanau
    if (blk < 128){
      dev_puattn(blk, hida_n, a.KA, a.CAE, a.AM, a.Ag, a.ENC, a.VPRE, a.PTRS, fs);
    } else {
      dev_bahd(blk - 128, a.EATT, a.DPART, a.dattv, a.ENC, a.CTX, fs);
    }
    gridbar2(dF, dG, seq0 + 2, 256, blk, GATHER);

    // ---- phase C: decoder gi GEMM (folded Wih) | qck GEMM (folded)
    if (blk < 48){
      Z4 z;
      z.sg[0] = {a.tgt + (size_t)(st ? st - 1 : 0) * 65536, 512, 1, 512};
      z.sg[1] = {a.VPRE, 1024, 1, 1024};
      z.sg[2] = {a.CTX, 512, 1, 512};
      z.sg[3] = S4SENT;
      z.Bp = a.DWF; z.ldb = 2048; z.bf32 = 0; z.bias = nullptr;
      z.Cp = a.GIDEC; z.ldc = 1536; z.cslab = 196608; z.N = 1536; z.K = 2048;
      dev_mfma4<128>(z, blk % 12, blk / 12, 4, Al, Bl);
    } else if (blk < 57){
      Z4 z;
      z.sg[0] = {a.VPRE, 1024, 1, 1024}; z.sg[1] = S4SENT; z.sg[2] = S4SENT; z.sg[3] = S4SENT;
      z.Bp = a.MKTW; z.ldb = 1024; z.bf32 = 0; z.bias = a.VKE2;
      z.Cp = a.QCK; z.ldc = 520; z.cslab = 0; z.N = 513; z.K = 1024;
      dev_mfma4<64>(z, blk - 48, 0, 1, Al, Bl);
    }
    gridbar2(dF, dG, seq0 + 3, 256, blk, GATHER);

    // ---- phase D: decoder GRU combine | content attention
    if (blk < 16){
      dev_gru3<2>(blk * 32, dechb_c, dech_c, a.dWhh, a.GIDEC, nullptr, nullptr,
                  a.DBIH2, a.dbhh, dech_n, dechb_n, Al, Bl);
    } else if (blk < 144){
      dev_cattn(blk - 16, a.QCK, a.ENC, a.CV2P, fs);
    }
    gridbar2(dF, dG, seq0 + 4, 256, blk, GATHER);

    // ---- phase E: folded output head GEMM (K=2560, split-K 4)
    if (blk < 32){
      Z4 z;
      z.sg[0] = {dechb_n, 512, 0, 512};
      z.sg[1] = {a.CTX, 512, 1, 512};
      z.sg[2] = {a.VPRE, 1024, 1, 1024};
      z.sg[3] = {a.CV2P, 512, 1, 512};
      z.Bp = a.OWF; z.ldb = 2560; z.bf32 = 0; z.bias = nullptr;
      z.Cp = a.OUTT; z.ldc = 512; z.cslab = 65536; z.N = 512; z.K = 2560;
      dev_mfma4<64>(z, blk & 7, blk >> 3, 4, Al, Bl);
    }
    gridbar2(dF, dG, seq0 + 5, 256, blk, GATHER);
  }
  if (blk < 128) dev_outcvt(blk, a.OUTT, a.OUTB2, a.out + 63ull * 65536);
}

// ================ setup: batched fold jobs ================
struct Job {
  const float* A; const float* B; const float* D; void* C;
  int Asm, Ask, Bsk, Bsn, Dsm, Dsn, Csm, Csn;
  int cbf, M, N, K, kind;
};
struct Jobs { Job j[24]; int nj; long long off[25]; };

__global__ __launch_bounds__(256) void k_setup(Jobs J)
{
  long long total = J.off[J.nj];
  for (long long tid = (long long)blockIdx.x * 256 + threadIdx.x; tid < total; tid += (long long)gridDim.x * 256){
    int ji = 0;
    while (tid >= J.off[ji + 1]) ji++;
    Job jb = J.j[ji];
    long long l = tid - J.off[ji];
    if (jb.kind == 0){
      int m = (int)(l / jb.N), n = (int)(l - (long long)m * jb.N);
      float acc = 0.f;
      const float* ap = jb.A + (size_t)m * jb.Asm;
      const float* bp = jb.B + (size_t)n * jb.Bsn;
      for (int k = 0; k < jb.K; k++)
        acc += ap[(size_t)k * jb.Ask] * bp[(size_t)k * jb.Bsk];
      if (jb.D) acc += jb.D[(size_t)m * jb.Dsm + (size_t)n * jb.Dsn];
      if (jb.cbf) ((u16*)jb.C)[(size_t)m * jb.Csm + (size_t)n * jb.Csn] = f2b(acc);
      else ((float*)jb.C)[(size_t)m * jb.Csm + (size_t)n * jb.Csn] = acc;
    } else if (jb.kind == 1){
      int m = (int)(l / jb.N), n = (int)(l - (long long)m * jb.N);
      ((u16*)jb.C)[(size_t)m * jb.Csm + (size_t)n * jb.Csn] = f2b(jb.A[(size_t)m * jb.Asm + (size_t)n * jb.Ask]);
    } else if (jb.kind == 2){
      int u = (int)(l >> 15), sb = (int)(l & 32767);
      float x[8];
      #pragma unroll
      for (int a2 = 0; a2 < 8; a2++) x[a2] = jb.A[(size_t)sb * 8 + a2];
      float* op = (float*)jb.C + ((size_t)u * 32768 + sb) * 8;
      #pragma unroll
      for (int c = 0; c < 8; c++){
        float acc = jb.D[u * 8 + c];
        #pragma unroll
        for (int a2 = 0; a2 < 8; a2++) acc += x[a2] * jb.B[(u * 8 + c) * 8 + a2];
        op[c] = acc;
      }
    } else {
      int u = (int)(l >> 10), r = (int)(l & 1023);
      int bb = r >> 3, aa = r & 7;
      int su = u ? 255 : 0;
      ((float*)jb.C)[l] = jb.A[((size_t)su * 128 + bb) * 8 + aa];
    }
  }
}

// ================ host ================
static inline Seg mkseg(const void* p, int ld, int f32, int K){ Seg s; s.p = p; s.ld = ld; s.f32 = f32; s.K = K; return s; }
static const Seg SENT = {nullptr, 0, 0, 1 << 30};

static inline void addJ(Jobs& JS, Job jb, long long cnt){
  JS.j[JS.nj] = jb;
  JS.off[JS.nj + 1] = JS.off[JS.nj] + cnt;
  JS.nj++;
}
static inline Job JG(const float* A, int Asm, int Ask, const float* B, int Bsk, int Bsn,
                     const float* D, int Dsm, int Dsn, void* C, int Csm, int Csn,
                     int cbf, int M, int N, int K, int kind = 0){
  Job j; j.A=A; j.B=B; j.D=D; j.C=C; j.Asm=Asm; j.Ask=Ask; j.Bsk=Bsk; j.Bsn=Bsn;
  j.Dsm=Dsm; j.Dsn=Dsn; j.Csm=Csm; j.Csn=Csn; j.cbf=cbf; j.M=M; j.N=N; j.K=K; j.kind=kind;
  return j;
}

extern "C" void kernel_launch(void* const* d_in, const int* in_sizes, int n_in,
                              void* d_out, int out_size, void* d_ws, size_t ws_size,
                              hipStream_t stream)
{
  (void)in_sizes; (void)out_size;
  if (n_in < 44 || ws_size < WS_NEED) return;

  const float* src   = (const float*)d_in[0];
  const float* tgt   = (const float*)d_in[1];
  const float* Ag    = (const float*)d_in[2];
  const float* eWihF = (const float*)d_in[3];
  const float* eWhhF = (const float*)d_in[4];
  const float* ebihF = (const float*)d_in[5];
  const float* ebhhF = (const float*)d_in[6];
  const float* eWihB = (const float*)d_in[7];
  const float* eWhhB = (const float*)d_in[8];
  const float* ebihB = (const float*)d_in[9];
  const float* ebhhB = (const float*)d_in[10];
  const float* dattW = (const float*)d_in[11];
  const float* dattb = (const float*)d_in[12];
  const float* dattv = (const float*)d_in[13];
  const float* dWih  = (const float*)d_in[14];
  const float* dWhh  = (const float*)d_in[15];
  const float* dbih  = (const float*)d_in[16];
  const float* dbhh  = (const float*)d_in[17];
  const float* doW   = (const float*)d_in[18];
  const float* dob   = (const float*)d_in[19];
  const float* puWih = (const float*)d_in[20];
  const float* puWhh = (const float*)d_in[21];
  const float* pubih = (const float*)d_in[22];
  const float* pubhh = (const float*)d_in[23];
  const float* puqW  = (const float*)d_in[24];
  const float* puqb  = (const float*)d_in[25];
  const float* puAW  = (const float*)d_in[26];
  const float* puAb  = (const float*)d_in[27];
  const float* puqp  = (const float*)d_in[28];
  const float* pukp  = (const float*)d_in[29];
  const float* puvp  = (const float*)d_in[30];
  const float* puinb = (const float*)d_in[31];
  const float* puop  = (const float*)d_in[32];
  const float* puob  = (const float*)d_in[33];
  const float* aaq   = (const float*)d_in[34];
  const float* aak   = (const float*)d_in[35];
  const float* aav   = (const float*)d_in[36];
  const float* aainb = (const float*)d_in[37];
  const float* aao   = (const float*)d_in[38];
  const float* aaob  = (const float*)d_in[39];
  const float* tohW  = (const float*)d_in[40];
  const float* tohb  = (const float*)d_in[41];
  const float* outW  = (const float*)d_in[42];
  const float* outb  = (const float*)d_in[43];

  char* ws = (char*)d_ws;
  float* GI    = (float*)(ws + OFF_GI);
  u16*   ENC   = (u16*)(ws + OFF_ENC);
  u16*   EATT  = (u16*)(ws + OFF_EATT);
  float* AM    = (float*)(ws + OFF_AM);
  float* HF    = (float*)(ws + OFF_HF);
  float* HB    = (float*)(ws + OFF_HB);
  u16*   HFB   = (u16*)(ws + OFF_HFB);
  u16*   HBB   = (u16*)(ws + OFF_HBB);
  float* HIDA  = (float*)(ws + OFF_HIDA);
  u16*   HIDAB = (u16*)(ws + OFF_HIDAB);
  u32*   BAR   = (u32*)(ws + OFF_BAR);
  float* DECH  = (float*)(ws + OFF_DECH);
  u16*   DECHB = (u16*)(ws + OFF_DECHB);
  float* PTRS  = (float*)(ws + OFF_PTRS);
  float* VPRE  = (float*)(ws + OFF_VPRE);
  float* CTX   = (float*)(ws + OFF_CTX);
  float* DPART = (float*)(ws + OFF_DPART);
  float* QCK   = (float*)(ws + OFF_QCK);
  float* CV2P  = (float*)(ws + OFF_CV2P);
  float* GIDEC = (float*)(ws + OFF_GIDEC);
  float* OUTT  = (float*)(ws + OFF_OUTT);
  float* WOVF  = (float*)(ws + OFF_WOVF);
  float* WOVCF = (float*)(ws + OFF_WOVCF);
  float* MKTF  = (float*)(ws + OFF_MKTF);
  u16*   DWF   = (u16*)(ws + OFF_DWF);
  u16*   MKTW  = (u16*)(ws + OFF_MKTW);
  u16*   OWF   = (u16*)(ws + OFF_OWF);
  float* BOV   = (float*)(ws + OFF_BOV);
  float* BOVC  = (float*)(ws + OFF_BOVC);
  float* KAx   = (float*)(ws + OFF_KA);
  float* CAE   = (float*)(ws + OFF_CAE);
  float* RT    = (float*)(ws + OFF_RT);
  float* BQC   = (float*)(ws + OFF_BQC);
  float* PMAT  = (float*)(ws + OFF_PMAT);
  float* CQ    = (float*)(ws + OFF_CQ);
  float* VKE2  = (float*)(ws + OFF_VKE2);
  float* DBIH2 = (float*)(ws + OFF_DBIH2);
  float* OUTB2 = (float*)(ws + OFF_OUTB2);

  hipMemsetAsync(ENC, 0, 2ull*256*128*512, stream);
  hipMemsetAsync(ws + OFF_HF, 0, OFF_ZEND - OFF_HF, stream);  // states + barrier flags

  // -------- stage 1: independent folds --------
  {
    Jobs S{}; S.nj = 0; S.off[0] = 0;
    for (int u = 0; u < 2; u++){
      const float* qp  = puqp + (size_t)u * 262144;
      const float* kp  = pukp + (size_t)u * 4096;
      float* RTu = RT + u * 8192;
      addJ(S, JG(qp, 1, 512, kp, 8, 1, nullptr, 0, 0, RTu, 16, 1, 0, 512, 8, 512), 4096);
      addJ(S, JG(qp, 1, 512, puinb + u*1536 + 512, 1, 0, nullptr, 0, 0, RTu + 8, 16, 1, 0, 512, 1, 512), 512);
      addJ(S, JG(qp, 512, 1, puqb + u*512, 1, 0, puinb + u*1536, 1, 0, BQC + u*512, 1, 1, 0, 512, 1, 512), 512);
      addJ(S, JG(puop + (size_t)u*262144, 512, 1, puvp + (size_t)u*262144, 512, 1, nullptr, 0, 0, WOVF + (size_t)u*262144, 512, 1, 0, 512, 512, 512), 262144);
      addJ(S, JG(puop + (size_t)u*262144, 512, 1, puinb + u*1536 + 1024, 1, 0, puob + u*512, 1, 0, BOV + u*512, 1, 1, 0, 512, 1, 512), 512);
    }
    addJ(S, JG(aao, 512, 1, aav, 512, 1, nullptr, 0, 0, WOVCF, 512, 1, 0, 512, 512, 512), 262144);
    addJ(S, JG(aao, 512, 1, aainb + 1024, 1, 0, aaob, 1, 0, BOVC, 1, 1, 0, 512, 1, 512), 512);
    addJ(S, JG(aaq, 1, 512, aak, 512, 1, nullptr, 0, 0, PMAT, 516, 1, 0, 512, 512, 512), 262144);
    addJ(S, JG(aaq, 1, 512, aainb + 512, 1, 0, nullptr, 0, 0, PMAT + 512, 516, 1, 0, 512, 1, 512), 512);
    addJ(S, JG(aaq, 512, 1, tohb, 1, 0, aainb, 1, 0, CQ, 1, 1, 0, 512, 1, 512), 512);
    addJ(S, JG(dWih, 2048, 1, nullptr, 0, 0, nullptr, 0, 0, DWF, 2048, 1, 1, 1536, 512, 0, 1), 786432);
    addJ(S, JG(dWih + 1536, 2048, 1, nullptr, 0, 0, nullptr, 0, 0, DWF + 1536, 2048, 1, 1, 1536, 512, 0, 1), 786432);
    addJ(S, JG(outW, 2048, 1, doW, 1024, 1, nullptr, 0, 0, OWF, 2560, 1, 1, 512, 1024, 512), 524288);
    addJ(S, JG(outW, 2048, 1, dob, 1, 0, outb, 1, 0, OUTB2, 1, 1, 0, 512, 1, 512), 512);
    addJ(S, JG(Ag, 0, 0, puAW, 0, 0, puAb, 0, 0, AM, 0, 0, 0, 0, 0, 0, 2), 65536);
    addJ(S, JG(Ag, 0, 0, nullptr, 0, 0, nullptr, 0, 0, PTRS, 0, 0, 0, 0, 0, 0, 3), 2048);
    k_setup<<<2048, 256, 0, stream>>>(S);
  }
  // -------- stage 2 --------
  {
    Jobs S{}; S.nj = 0; S.off[0] = 0;
    for (int u = 0; u < 2; u++){
      const float* kp = pukp + (size_t)u * 4096;
      addJ(S, JG(puqW + (size_t)u*262144, 1, 512, RT + u*8192, 16, 1, nullptr, 0, 0, KAx + u*8192, 16, 1, 0, 512, 9, 512), 4608);
      addJ(S, JG(BQC + u*512, 0, 1, kp, 8, 1, nullptr, 0, 0, CAE + u*16, 0, 1, 0, 1, 8, 512), 8);
      addJ(S, JG(BQC + u*512, 0, 1, puinb + u*1536 + 512, 1, 0, nullptr, 0, 0, CAE + u*16 + 8, 0, 1, 0, 1, 1, 512), 1);
      addJ(S, JG(dWih + 512 + u*512, 2048, 1, WOVF + (size_t)u*262144, 512, 1, nullptr, 0, 0, DWF + 512 + u*512, 2048, 1, 1, 1536, 512, 512), 786432);
      addJ(S, JG(outW + 512 + u*512, 2048, 1, WOVF + (size_t)u*262144, 512, 1, nullptr, 0, 0, OWF + 1024 + u*512, 2560, 1, 1, 512, 512, 512), 262144);
    }
    addJ(S, JG(tohW, 1, 1024, PMAT, 516, 1, nullptr, 0, 0, MKTF, 1, 1024, 0, 1024, 513, 512), 525312);
    addJ(S, JG(CQ, 0, 1, aak, 512, 1, nullptr, 0, 0, VKE2, 0, 1, 0, 1, 512, 512), 512);
    addJ(S, JG(CQ, 0, 1, aainb + 512, 1, 0, nullptr, 0, 0, VKE2 + 512, 0, 1, 0, 1, 1, 512), 1);
    addJ(S, JG(dWih + 512, 2048, 1, BOV, 1, 0, dbih, 1, 0, DBIH2, 1, 1, 0, 1536, 1, 1024), 1536);
    addJ(S, JG(outW + 1536, 2048, 1, WOVCF, 512, 1, nullptr, 0, 0, OWF + 2048, 2560, 1, 1, 512, 512, 512), 262144);
    addJ(S, JG(outW + 512, 2048, 1, BOV, 1, 0, OUTB2, 1, 0, OUTB2, 1, 1, 0, 512, 1, 1536), 512);
    k_setup<<<2048, 256, 0, stream>>>(S);
  }
  // -------- stage 3 --------
  {
    Jobs S{}; S.nj = 0; S.off[0] = 0;
    for (int u = 0; u < 2; u++)
      addJ(S, JG(MKTF + u*512, 1024, 1, WOVF + (size_t)u*262144, 512, 1, nullptr, 0, 0, MKTW + u*512, 1024, 1, 1, 513, 512, 512), 262656);
    addJ(S, JG(MKTF, 1024, 1, BOV, 1, 0, VKE2, 1, 0, VKE2, 1, 1, 0, 513, 1, 1024), 513);
    k_setup<<<1024, 256, 0, stream>>>(S);
  }

  // -------- encoder: 8 chunks of (gi GEMM + persistent 32-step scan) --------
  for (int c = 0; c < 8; c++){
    int c0 = c * 32;
    NTA nt{};
    nt.tilesN = 12;
    for (int d = 0; d < 2; d++){
      NTZ& zz = nt.z[d];
      zz.sg[0] = mkseg(d == 0 ? (const void*)(src + (size_t)c0 * 65536) : (const void*)src, 512, 1, 512);
      zz.sg[1] = SENT; zz.sg[2] = SENT;
      zz.Bp = d ? eWihB : eWihF; zz.ldb = 512; zz.bf32 = 1;
      zz.bias = nullptr; zz.biasf32 = 0;
      zz.Cp = GI + (size_t)d * 6291456; zz.ldc = 1536; zz.cf32 = 1; zz.cslab = 0;
      zz.N = 1536; zz.rev_s0 = (d == 0) ? -1 : (255 - c0); zz.K = 512;
    }
    k_mfma_nt<128><<<dim3(32*12, 1, 2), 256, 0, stream>>>(nt);

    EncArgs ea;
    ea.WhhF = eWhhF; ea.WhhB = eWhhB;
    ea.giF = GI; ea.giB = GI + 6291456;
    ea.bihF = ebihF; ea.bhhF = ebhhF; ea.bihB = ebihB; ea.bhhB = ebhhB;
    ea.HF = HF; ea.HB = HB; ea.HFB = HFB; ea.HBB = HBB; ea.ENC = ENC;
    ea.BAR = BAR; ea.bar0 = c * 32;
    ea.s0 = c0;
    k_enc<<<dim3(64), dim3(256), 0, stream>>>(ea);
  }

  // -------- enc_att = enc @ W2.T + b --------
  {
    NTA nt{};
    nt.tilesN = 4;
    NTZ& zz = nt.z[0];
    zz.sg[0] = mkseg(ENC, 512, 0, 512); zz.sg[1] = SENT; zz.sg[2] = SENT;
    zz.Bp = dattW + 512; zz.ldb = 1024; zz.bf32 = 1;
    zz.bias = dattb; zz.biasf32 = 1;
    zz.Cp = EATT; zz.ldc = 512; zz.cf32 = 0; zz.cslab = 0;
    zz.N = 512; zz.rev_s0 = -1; zz.K = 512;
    k_mfma_nt<128><<<dim3(256*4, 1, 1), 256, 0, stream>>>(nt);
  }

  // -------- decoder: one persistent kernel, all 64 steps --------
  {
    DecArgs da;
    da.tgt = tgt; da.Ag = Ag; da.AM = AM; da.KA = KAx; da.CAE = CAE;
    da.dattW = dattW; da.dattv = dattv;
    da.puWhh = puWhh; da.puWih = puWih; da.pubih = pubih; da.pubhh = pubhh;
    da.dWhh = dWhh; da.DBIH2 = DBIH2; da.dbhh = dbhh; da.VKE2 = VKE2; da.OUTB2 = OUTB2;
    da.ENC = ENC; da.EATT = EATT; da.DWF = DWF; da.MKTW = MKTW; da.OWF = OWF;
    da.HIDA = HIDA; da.HIDAB = HIDAB; da.DECH = DECH; da.DECHB = DECHB;
    da.HF0 = HF; da.HFB0 = HFB;
    da.PTRS = PTRS; da.VPRE = VPRE; da.CTX = CTX; da.DPART = DPART;
    da.QCK = QCK; da.CV2P = CV2P; da.GIDEC = GIDEC; da.OUTT = OUTT;
    da.out = (float*)d_out;
    da.BAR = BAR;
    k_dec<<<dim3(256), dim3(256), 0, stream>>>(da);
  }
}

// Round 3
// 25428.622 us; speedup vs baseline: 1.2439x; 1.1355x over previous
//
#include <hip/hip_runtime.h>

typedef unsigned short u16;
typedef unsigned int u32;

#define DEVI __device__ __forceinline__

constexpr float SCALE_ATT = 0.04419417382415922f;  // 1/sqrt(512)

// ---------------- workspace layout (bytes) ----------------
constexpr size_t OFF_GI    = 0;                                  // f32 [2][32][128][1536] per-chunk x@Wih
constexpr size_t OFF_ENC   = OFF_GI    + 4ull*2*32*128*1536;
constexpr size_t OFF_EATT  = OFF_ENC   + 2ull*256*128*512;       // bf16 enc, bf16 enc_att
constexpr size_t OFF_AM    = OFF_EATT  + 2ull*256*128*512;       // f32 [2][256][128][8]
constexpr size_t OFF_HF    = OFF_AM    + 4ull*2*256*128*8;       // ---- zero region start
constexpr size_t OFF_HB    = OFF_HF    + 4ull*2*128*512;
constexpr size_t OFF_HFB   = OFF_HB    + 4ull*2*128*512;
constexpr size_t OFF_HBB   = OFF_HFB   + 2ull*2*128*512;
constexpr size_t OFF_HIDA  = OFF_HBB   + 2ull*2*128*512;
constexpr size_t OFF_HIDAB = OFF_HIDA  + 4ull*2*2*128*512;
constexpr size_t OFF_BAR   = OFF_HIDAB + 2ull*2*2*128*512;       // u32 flag lines (see BAR_* below)
constexpr size_t OFF_ZEND  = OFF_BAR   + 49152;                  // ---- zero region end
constexpr size_t OFF_DECH  = OFF_ZEND;
constexpr size_t OFF_DECHB = OFF_DECH  + 4ull*2*128*512;
constexpr size_t OFF_PTRS  = OFF_DECHB + 2ull*2*128*512;         // f32 [2][128][8]
constexpr size_t OFF_VPRE  = OFF_PTRS  + 4ull*2*128*8;           // f32 [128][1024]  (b-major!)
constexpr size_t OFF_CTX   = OFF_VPRE  + 4ull*128*1024;
constexpr size_t OFF_DPART = OFF_CTX   + 4ull*128*512;
constexpr size_t OFF_QCK   = OFF_DPART + 4ull*128*512;           // f32 [128][520] (513 used)
constexpr size_t OFF_CV2P  = OFF_QCK   + 4ull*128*520;
constexpr size_t OFF_GIDEC = OFF_CV2P  + 4ull*128*512;           // f32 4 K-slabs [128][1536]
constexpr size_t OFF_OUTT  = OFF_GIDEC + 4ull*4*128*1536;        // f32 4 K-slabs [128][512]
constexpr size_t OFF_WOVF  = OFF_OUTT  + 4ull*4*128*512;         // f32 [2][512][512]
constexpr size_t OFF_WOVCF = OFF_WOVF  + 4ull*2*512*512;         // f32 [512][512]
constexpr size_t OFF_MKTF  = OFF_WOVCF + 4ull*512*512;           // f32 [513 rows][1024]
constexpr size_t OFF_DWF   = OFF_MKTF  + 4ull*513*1024;          // bf16 [1536][2048] folded dec Wih
constexpr size_t OFF_MKTW  = OFF_DWF   + 2ull*1536*2048;         // bf16 [513][1024] folded qck W
constexpr size_t OFF_OWF   = OFF_MKTW  + 2ull*513*1024;          // bf16 [512][2560] folded out W
constexpr size_t OFF_BOV   = OFF_OWF   + 2ull*512*2560;          // f32 [2][512]  (contiguous w/ BOVC!)
constexpr size_t OFF_BOVC  = OFF_BOV   + 4ull*2*512;             // f32 [512]
constexpr size_t OFF_KA    = OFF_BOVC  + 4ull*512;               // f32 [2][512][16] (9 used)
constexpr size_t OFF_CAE   = OFF_KA    + 4ull*2*512*16;          // f32 [2][16]
constexpr size_t OFF_RT    = OFF_CAE   + 4ull*2*16;              // f32 [2][512][16]
constexpr size_t OFF_BQC   = OFF_RT    + 4ull*2*512*16;          // f32 [2][512]
constexpr size_t OFF_PMAT  = OFF_BQC   + 4ull*2*512;             // f32 [512][516]
constexpr size_t OFF_CQ    = OFF_PMAT  + 4ull*512*516;
constexpr size_t OFF_VKE2  = OFF_CQ    + 4ull*512;               // f32 [520]
constexpr size_t OFF_DBIH2 = OFF_VKE2  + 4ull*520;               // f32 [1536]
constexpr size_t OFF_OUTB2 = OFF_DBIH2 + 4ull*1536;              // f32 [512]
constexpr size_t WS_NEED   = OFF_OUTB2 + 4ull*512;

// ---------------- helpers ----------------
DEVI float b2f(u16 u){ union{u32 i; float f;} x; x.i = ((u32)u) << 16; return x.f; }
DEVI u16 f2b(float f){ union{float f; u32 i;} x; x.f = f; u32 i = x.i; u32 r = i + 0x7FFFu + ((i >> 16) & 1u); return (u16)(r >> 16); }
DEVI float sigmf_(float x){ return 1.f / (1.f + __expf(-x)); }
DEVI float tanhf_(float x){ x = fminf(15.f, fmaxf(-15.f, x)); float e = __expf(2.f*x); return (e - 1.f) / (e + 1.f); }

typedef __attribute__((ext_vector_type(8))) short bfrag;
typedef __attribute__((ext_vector_type(4))) float ffrag;
typedef __attribute__((ext_vector_type(4))) unsigned int vu4;
typedef __attribute__((ext_vector_type(4))) float vf4;

DEVI uint4 cvt8(float4 a, float4 b){
  union{uint4 u; u16 h[8];} r;
  r.h[0]=f2b(a.x); r.h[1]=f2b(a.y); r.h[2]=f2b(a.z); r.h[3]=f2b(a.w);
  r.h[4]=f2b(b.x); r.h[5]=f2b(b.y); r.h[6]=f2b(b.z); r.h[7]=f2b(b.w);
  return r.u;
}
DEVI vu4 cvt8v(vf4 a, vf4 b){
  union{vu4 u; u16 h[8];} r;
  r.h[0]=f2b(a[0]); r.h[1]=f2b(a[1]); r.h[2]=f2b(a[2]); r.h[3]=f2b(a[3]);
  r.h[4]=f2b(b[0]); r.h[5]=f2b(b[1]); r.h[6]=f2b(b[2]); r.h[7]=f2b(b[3]);
  return r.u;
}

// ---- L2-bypassing (coherence-point) access primitives ----
// Communicated buffers are written with sc0 sc1 (write-through past the
// non-coherent per-XCD L2) and read with sc0 sc1 (read from the coherence
// point). This removes the need for __threadfence (full L2 writeback +
// invalidate) at grid barriers, so read-only data (weights, ENC, EATT, ...)
// stays warm in L2 across all decode steps.
DEVI void ld16_nw(const void* p, vu4& r){
  asm volatile("global_load_dwordx4 %0, %1, off sc0 sc1"
               : "=&v"(r) : "v"(p) : "memory");
}
DEVI void ld32_nw(const float* p, vf4& a, vf4& b){
  asm volatile("global_load_dwordx4 %0, %2, off sc0 sc1\n\t"
               "global_load_dwordx4 %1, %2, off offset:16 sc0 sc1"
               : "=&v"(a), "=&v"(b) : "v"(p) : "memory");
}
DEVI void vm_drain(){
  asm volatile("s_waitcnt vmcnt(0)" ::: "memory");
  __builtin_amdgcn_sched_barrier(0);   // rule #18: keep reg-ops from hoisting above the wait
}
DEVI float ld4f_sys(const float* p){ return __hip_atomic_load(p, __ATOMIC_RELAXED, __HIP_MEMORY_SCOPE_SYSTEM); }
DEVI void st4_sys(float* p, float v){
  asm volatile("global_store_dword %0, %1, off sc0 sc1" :: "v"(p), "v"(v) : "memory");
}
DEVI void st2_sys(u16* p, u16 v){
  u32 w = v;
  asm volatile("global_store_short %0, %1, off sc0 sc1" :: "v"(p), "v"(w) : "memory");
}

// ---- all-store flag grid barrier (no RMW, no threadfence) ----
// arrive: drain own wave's vmem (sys stores committed to coherence point),
//         block-sync, then t0 stores seq to its own 128B flag line.
// gather: designated block polls all flags in parallel, publishes go.
// wait:   others spin on go with system-scope relaxed loads.
constexpr int GB_STRIDE  = 32;     // u32 per flag line (128B)
constexpr int BAR_DECF   = 0;      // 256 flags * 32 u32
constexpr int BAR_DECGO  = 8192;   // 1 line
constexpr int BAR_ENCF   = 8224;   // 64 flags * 32 u32
constexpr int BAR_ENCGO  = 10272;  // 1 line

DEVI u32 ld_sys(u32* p){ return __hip_atomic_load(p, __ATOMIC_RELAXED, __HIP_MEMORY_SCOPE_SYSTEM); }
DEVI void st_sys(u32* p, u32 v){ __hip_atomic_store(p, v, __ATOMIC_RELAXED, __HIP_MEMORY_SCOPE_SYSTEM); }

DEVI void gridbar2(u32* flags, u32* go, u32 seq, int nblk, int blk, int gblk)
{
  asm volatile("s_waitcnt vmcnt(0)" ::: "memory");   // per-wave: all sys stores committed
  __syncthreads();
  int t = threadIdx.x;
  if (blk == gblk){
    if (t == 0) st_sys(&flags[(u32)blk * GB_STRIDE], seq);
    if (t < nblk){
      u32* f = &flags[(u32)t * GB_STRIDE];
      while (ld_sys(f) < seq) __builtin_amdgcn_s_sleep(1);
    }
    __syncthreads();
    if (t == 0) st_sys(go, seq);
  } else {
    if (t == 0){
      st_sys(&flags[(u32)blk * GB_STRIDE], seq);
      while (ld_sys(go) < seq) __builtin_amdgcn_s_sleep(1);
    }
  }
  __syncthreads();
}

// ================ host-launched 3-seg NT GEMM (GI chunks + EATT) ================
struct Seg { const void* p; int ld; int f32; int K; };
struct NTZ {
  Seg sg[3];
  const void* Bp; int ldb; int bf32;
  const void* bias; int biasf32;
  void* Cp; int ldc; int cf32; int cslab;
  int N; int rev_s0; int K;
};
struct NTA { NTZ z[3]; int tilesN; };

template<int BN>
__global__ __launch_bounds__(256) void k_mfma_nt(NTA a)
{
  NTZ z = a.z[blockIdx.z];
  int tn = blockIdx.x % a.tilesN;
  int tm = blockIdx.x / a.tilesN;
  if (tn * BN >= z.N) return;
  int nks = gridDim.y;
  int kb = blockIdx.y * (z.K / nks);
  int ke = kb + z.K / nks;

  __shared__ short Al[128*32];
  __shared__ short Bl[BN*32];

  int t = threadIdx.x;
  int lane = t & 63, w = t >> 6;
  constexpr int FRS = (BN == 128) ? 4 : 2;
  int wn = (BN == 128) ? (w & 1) : 0;
  int rowbase = (BN == 128) ? (w >> 1) * 64 : w * 32;

  ffrag zz4 = {0.f, 0.f, 0.f, 0.f};
  ffrag acc[FRS][4];
  #pragma unroll
  for (int i = 0; i < FRS; i++)
    #pragma unroll
    for (int j = 0; j < 4; j++) acc[i][j] = zz4;

  for (int k0 = kb; k0 < ke; k0 += 32){
    #pragma unroll
    for (int r2 = 0; r2 < 2; r2++){
      int slot = t + r2 * 256;
      int row = slot >> 2, kq = slot & 3;
      int m = tm * 128 + row;
      int arow = (z.rev_s0 >= 0) ? (((z.rev_s0 - (m >> 7)) << 7) | (m & 127)) : m;
      int k = k0 + kq * 8;
      Seg sg;
      if (k < z.sg[0].K) sg = z.sg[0];
      else { k -= z.sg[0].K; if (k < z.sg[1].K) sg = z.sg[1]; else { k -= z.sg[1].K; sg = z.sg[2]; } }
      uint4 v;
      if (sg.f32){
        const float* ap = (const float*)sg.p + (size_t)arow * sg.ld + k;
        v = cvt8(*(const float4*)ap, *(const float4*)(ap + 4));
      } else {
        v = *(const uint4*)((const u16*)sg.p + (size_t)arow * sg.ld + k);
      }
      *(uint4*)&Al[(((row >> 4) << 6) + (kq << 4) + (row & 15)) * 8] = v;
    }
    #pragma unroll
    for (int r2 = 0; r2 < BN/64; r2++){
      int slot = t + r2 * 256;
      int brow = slot >> 2, kq = slot & 3;
      int n = tn * BN + brow;
      uint4 v = make_uint4(0u, 0u, 0u, 0u);
      if (n < z.N){
        int k = k0 + kq * 8;
        if (z.bf32){
          const float* bp = (const float*)z.Bp + (size_t)n * z.ldb + k;
          v = cvt8(*(const float4*)bp, *(const float4*)(bp + 4));
        } else {
          v = *(const uint4*)((const u16*)z.Bp + (size_t)n * z.ldb + k);
        }
      }
      *(uint4*)&Bl[(kq * BN + brow) * 8] = v;
    }
    __syncthreads();
    bfrag af[FRS], bv[4];
    #pragma unroll
    for (int fr = 0; fr < FRS; fr++) af[fr] = *(bfrag*)&Al[(((rowbase >> 4) + fr) * 64 + lane) * 8];
    #pragma unroll
    for (int fc = 0; fc < 4; fc++) bv[fc] = *(bfrag*)&Bl[(((lane >> 4) * BN) + wn * 64 + fc * 16 + (lane & 15)) * 8];
    #pragma unroll
    for (int fr = 0; fr < FRS; fr++)
      #pragma unroll
      for (int fc = 0; fc < 4; fc++)
        acc[fr][fc] = __builtin_amdgcn_mfma_f32_16x16x32_bf16(af[fr], bv[fc], acc[fr][fc], 0, 0, 0);
    __syncthreads();
  }

  float* Cf = (float*)z.Cp + (size_t)blockIdx.y * z.cslab;
  u16*  Cb = (u16*)z.Cp  + (size_t)blockIdx.y * z.cslab;
  #pragma unroll
  for (int fc = 0; fc < 4; fc++){
    int n = tn * BN + wn * 64 + fc * 16 + (lane & 15);
    if (n >= z.N) continue;
    float bs = 0.f;
    if (z.bias) bs = z.biasf32 ? ((const float*)z.bias)[n] : b2f(((const u16*)z.bias)[n]);
    #pragma unroll
    for (int fr = 0; fr < FRS; fr++){
      #pragma unroll
      for (int i = 0; i < 4; i++){
        int m = tm * 128 + rowbase + fr * 16 + ((lane >> 4) << 2) + i;
        float vv = acc[fr][fc][i] + bs;
        size_t idx = (size_t)m * z.ldc + n;
        if (z.cf32) Cf[idx] = vv; else Cb[idx] = f2b(vv);
      }
    }
  }
}

// ================ device-side 4-seg NT GEMM (M=128 fixed) ================
// Segments with nt=1 are cross-block communicated buffers: read via sc0 sc1.
// C-writes always go to communicated buffers: written via sc0 sc1.
struct Seg4 { const void* p; int ld; int f32; int K; int nt; };
struct Z4 {
  Seg4 sg[4];
  const void* Bp; int ldb; int bf32;
  const float* bias;
  float* Cp; int ldc; int cslab;
  int N; int K;
};

template<int BN>
DEVI void dev_mfma4(const Z4& z, int tn, int ks, int nks, short* Al, short* Bl)
{
  int kseg = z.K / nks;
  int kb = ks * kseg, ke = kb + kseg;
  int t = threadIdx.x, lane = t & 63, w = t >> 6;
  constexpr int FRS = (BN == 128) ? 4 : 2;
  int wn = (BN == 128) ? (w & 1) : 0;
  int rowbase = (BN == 128) ? (w >> 1) * 64 : w * 32;
  ffrag zz4 = {0.f, 0.f, 0.f, 0.f};
  ffrag acc[FRS][4];
  #pragma unroll
  for (int i = 0; i < FRS; i++)
    #pragma unroll
    for (int j = 0; j < 4; j++) acc[i][j] = zz4;

  for (int k0 = kb; k0 < ke; k0 += 32){
    // ---- B staging: cached loads (weights; stay warm in L2) ----
    vu4 bvv[BN/64]; int bidx[BN/64];
    #pragma unroll
    for (int r2 = 0; r2 < BN/64; r2++){
      int slot = t + r2 * 256;
      int brow = slot >> 2, kq = slot & 3;
      int n = tn * BN + brow;
      vu4 v = {0u, 0u, 0u, 0u};
      if (n < z.N){
        int k = k0 + kq * 8;
        if (z.bf32){
          const float* bp = (const float*)z.Bp + (size_t)n * z.ldb + k;
          v = cvt8v(*(const vf4*)bp, *(const vf4*)(bp + 4));
        } else {
          v = *(const vu4*)((const u16*)z.Bp + (size_t)n * z.ldb + k);
        }
      }
      bvv[r2] = v; bidx[r2] = (kq * BN + brow) * 8;
    }
    // ---- A staging: issue (possibly sys) loads for both slots, drain once ----
    int rowv[2], kqv2[2], isf[2];
    vf4 fa[2], fb[2]; vu4 ua[2];
    #pragma unroll
    for (int r2 = 0; r2 < 2; r2++){
      int slot = t + r2 * 256;
      int row = slot >> 2, kq = slot & 3;
      int k = k0 + kq * 8;
      Seg4 sg = z.sg[0];
      if (k >= sg.K){ k -= sg.K; sg = z.sg[1];
        if (k >= sg.K){ k -= sg.K; sg = z.sg[2];
          if (k >= sg.K){ k -= sg.K; sg = z.sg[3]; } } }
      rowv[r2] = row; kqv2[r2] = kq; isf[r2] = sg.f32;
      if (sg.f32){
        const float* ap = (const float*)sg.p + (size_t)row * sg.ld + k;
        if (sg.nt) ld32_nw(ap, fa[r2], fb[r2]);
        else { fa[r2] = *(const vf4*)ap; fb[r2] = *(const vf4*)(ap + 4); }
      } else {
        const u16* up = (const u16*)sg.p + (size_t)row * sg.ld + k;
        if (sg.nt) ld16_nw(up, ua[r2]);
        else ua[r2] = *(const vu4*)up;
      }
    }
    vm_drain();
    #pragma unroll
    for (int r2 = 0; r2 < BN/64; r2++) *(vu4*)&Bl[bidx[r2]] = bvv[r2];
    #pragma unroll
    for (int r2 = 0; r2 < 2; r2++){
      vu4 v = isf[r2] ? cvt8v(fa[r2], fb[r2]) : ua[r2];
      *(vu4*)&Al[(((rowv[r2] >> 4) << 6) + (kqv2[r2] << 4) + (rowv[r2] & 15)) * 8] = v;
    }
    __syncthreads();
    bfrag af[FRS], bv[4];
    #pragma unroll
    for (int fr = 0; fr < FRS; fr++) af[fr] = *(bfrag*)&Al[(((rowbase >> 4) + fr) * 64 + lane) * 8];
    #pragma unroll
    for (int fc = 0; fc < 4; fc++) bv[fc] = *(bfrag*)&Bl[(((lane >> 4) * BN) + wn * 64 + fc * 16 + (lane & 15)) * 8];
    #pragma unroll
    for (int fr = 0; fr < FRS; fr++)
      #pragma unroll
      for (int fc = 0; fc < 4; fc++)
        acc[fr][fc] = __builtin_amdgcn_mfma_f32_16x16x32_bf16(af[fr], bv[fc], acc[fr][fc], 0, 0, 0);
    __syncthreads();
  }

  float* Cf = z.Cp + (size_t)ks * z.cslab;
  #pragma unroll
  for (int fc = 0; fc < 4; fc++){
    int n = tn * BN + wn * 64 + fc * 16 + (lane & 15);
    if (n >= z.N) continue;
    float bs = z.bias ? z.bias[n] : 0.f;
    #pragma unroll
    for (int fr = 0; fr < FRS; fr++){
      #pragma unroll
      for (int i = 0; i < 4; i++){
        int m = rowbase + fr * 16 + ((lane >> 4) << 2) + i;
        st4_sys(&Cf[(size_t)m * z.ldc + n], acc[fr][fc][i] + bs);
      }
    }
  }
}

// ================ device-side fused GRU step (h@Whh MFMA + epilogue) ================
// MODE 1 = pointer unit (gi from ptr(B,8)@Wih); MODE 2 = decoder (gi = 4 K-split slabs)
// h state (hb/hf in, hnf/hnb out) is cross-block communicated -> sys access.
template<int MODE>
DEVI void dev_gru3(int g0, const u16* hb, const float* hf, const float* Whh,
                   const float* gi_f, const float* xp, const float* Wih,
                   const float* bih, const float* bhh,
                   float* hnf, u16* hnb, short* Al, short* Bl)
{
  int t = threadIdx.x, lane = t & 63, w = t >> 6;
  int wm = w >> 1, wn = w & 1;
  ffrag zz4 = {0.f, 0.f, 0.f, 0.f};
  ffrag acc[4][3];
  #pragma unroll
  for (int i = 0; i < 4; i++)
    #pragma unroll
    for (int j = 0; j < 3; j++) acc[i][j] = zz4;

  for (int k0 = 0; k0 < 512; k0 += 32){
    // ---- B (Whh, cached) loads issued first ----
    int lb0 = t >> 2, kq0b = t & 3;
    {
      int wn2 = lb0 / 48, rem = lb0 - wn2 * 48, fc = rem >> 4, i16 = rem & 15;
      int grow = fc * 512 + g0 + wn2 * 16 + i16;
      const float* wp = Whh + (size_t)grow * 512 + k0 + kq0b * 8;
      vf4 wa = *(const vf4*)wp, wb = *(const vf4*)(wp + 4);
      // ---- A (h, communicated) sys loads ----
      int rowA0 = t >> 2, kqA0 = t & 3;
      int rowA1 = (t + 256) >> 2, kqA1 = (t + 256) & 3;
      vu4 hv0, hv1;
      ld16_nw(hb + (size_t)rowA0 * 512 + k0 + kqA0 * 8, hv0);
      ld16_nw(hb + (size_t)rowA1 * 512 + k0 + kqA1 * 8, hv1);
      vf4 wa1, wb1; int lb1 = 0, kq1b = 0;
      if (t < 128){
        int slot = t + 256;
        lb1 = slot >> 2; kq1b = slot & 3;
        int wn21 = lb1 / 48, rem1 = lb1 - wn21 * 48, fc1 = rem1 >> 4, i161 = rem1 & 15;
        int grow1 = fc1 * 512 + g0 + wn21 * 16 + i161;
        const float* wp1 = Whh + (size_t)grow1 * 512 + k0 + kq1b * 8;
        wa1 = *(const vf4*)wp1; wb1 = *(const vf4*)(wp1 + 4);
      }
      vm_drain();
      *(vu4*)&Bl[(kq0b * 96 + lb0) * 8] = cvt8v(wa, wb);
      if (t < 128) *(vu4*)&Bl[(kq1b * 96 + lb1) * 8] = cvt8v(wa1, wb1);
      *(vu4*)&Al[(((rowA0 >> 4) << 6) + (kqA0 << 4) + (rowA0 & 15)) * 8] = hv0;
      *(vu4*)&Al[(((rowA1 >> 4) << 6) + (kqA1 << 4) + (rowA1 & 15)) * 8] = hv1;
    }
    __syncthreads();
    bfrag af[4], bv[3];
    #pragma unroll
    for (int fr = 0; fr < 4; fr++) af[fr] = *(bfrag*)&Al[((wm * 4 + fr) * 64 + lane) * 8];
    #pragma unroll
    for (int fc = 0; fc < 3; fc++) bv[fc] = *(bfrag*)&Bl[((lane >> 4) * 96 + (wn * 3 + fc) * 16 + (lane & 15)) * 8];
    #pragma unroll
    for (int fr = 0; fr < 4; fr++)
      #pragma unroll
      for (int fc = 0; fc < 3; fc++)
        acc[fr][fc] = __builtin_amdgcn_mfma_f32_16x16x32_bf16(af[fr], bv[fc], acc[fr][fc], 0, 0, 0);
    __syncthreads();
  }

  // MODE1: stage xp (PTRS slice, communicated) into LDS once
  float* xl = (float*)Al;
  if (MODE == 1){
    for (int i = t; i < 1024; i += 256) xl[i] = ld4f_sys(xp + i);
    __syncthreads();
  }

  int gcol = g0 + wn * 16 + (lane & 15);
  float bir = bih[gcol],        bhr = bhh[gcol];
  float biz = bih[512 + gcol],  bhz = bhh[512 + gcol];
  float bin = bih[1024 + gcol], bhn = bhh[1024 + gcol];
  float wxr[8], wxz[8], wxn[8];
  if (MODE == 1){
    #pragma unroll
    for (int a2 = 0; a2 < 8; a2++){
      wxr[a2] = Wih[(size_t)gcol * 8 + a2];
      wxz[a2] = Wih[(size_t)(512 + gcol) * 8 + a2];
      wxn[a2] = Wih[(size_t)(1024 + gcol) * 8 + a2];
    }
  }
  #pragma unroll
  for (int fr = 0; fr < 4; fr++){
    #pragma unroll
    for (int i = 0; i < 4; i++){
      int brow = wm * 64 + fr * 16 + ((lane >> 4) << 2) + i;
      float gr_, gz_, gn_;
      if (MODE == 2){
        gr_ = gz_ = gn_ = 0.f;
        #pragma unroll
        for (int sl = 0; sl < 4; sl++){
          const float* gp = gi_f + (size_t)sl * 196608 + (size_t)brow * 1536;
          gr_ += ld4f_sys(gp + gcol); gz_ += ld4f_sys(gp + 512 + gcol); gn_ += ld4f_sys(gp + 1024 + gcol);
        }
      } else {
        float4 x0 = *(float4*)&xl[brow * 8];
        float4 x1 = *(float4*)&xl[brow * 8 + 4];
        float xa[8] = {x0.x, x0.y, x0.z, x0.w, x1.x, x1.y, x1.z, x1.w};
        gr_ = gz_ = gn_ = 0.f;
        #pragma unroll
        for (int a2 = 0; a2 < 8; a2++){ gr_ += xa[a2]*wxr[a2]; gz_ += xa[a2]*wxz[a2]; gn_ += xa[a2]*wxn[a2]; }
      }
      float hold = ld4f_sys(hf + (size_t)brow * 512 + gcol);
      float r  = sigmf_(gr_ + acc[fr][0][i] + bir + bhr);
      float zg = sigmf_(gz_ + acc[fr][1][i] + biz + bhz);
      float n  = tanhf_(gn_ + bin + r * (acc[fr][2][i] + bhn));
      float hn = (1.f - zg) * n + zg * hold;
      size_t idx = (size_t)brow * 512 + gcol;
      st4_sys(hnf + idx, hn);
      st2_sys(hnb + idx, f2b(hn));
    }
  }
}

// ================ device-side attention pieces ================
DEVI void dev_puattn(int b, const float* hida2, const float* Ka, const float* cae,
                     const float* Am, const float* Ain, const u16* enc,
                     float* vpre, float* ptrs, float* fs)
{
  int t = threadIdx.x, lane = t & 63, w = t >> 6;
  float* sc0 = fs; float* sc1 = fs + 256; float* smx = fs + 512;
  float* wred = fs + 768; float* qa = fs + 840; float* cd = fs + 860;

  if (t < 16) cd[t] = 0.f;
  for (int u = 0; u < 2; u++){
    const float* hp = hida2 + ((size_t)u * 128 + b) * 512;
    float hv0 = ld4f_sys(hp + t), hv1 = ld4f_sys(hp + t + 256);
    const float* k0p = Ka + u * 8192 + t * 16;
    const float* k1p = Ka + u * 8192 + (t + 256) * 16;
    float p[9];
    #pragma unroll
    for (int j = 0; j < 9; j++) p[j] = hv0 * k0p[j] + hv1 * k1p[j];
    #pragma unroll
    for (int j = 0; j < 9; j++){
      #pragma unroll
      for (int off = 32; off > 0; off >>= 1) p[j] += __shfl_xor(p[j], off);
    }
    if (lane == 0){
      #pragma unroll
      for (int j = 0; j < 9; j++) wred[w * 9 + j] = p[j];
    }
    __syncthreads();
    if (t < 9) qa[u * 10 + t] = wred[t] + wred[9 + t] + wred[18 + t] + wred[27 + t] + cae[u * 16 + t];
    __syncthreads();
  }

  float su[2];
  #pragma unroll
  for (int u = 0; u < 2; u++){
    const float* amp = Am + (((size_t)u * 256 + t) * 128 + b) * 8;
    float4 a0 = *(const float4*)amp;
    float4 a1 = *(const float4*)(amp + 4);
    const float* q = qa + u * 10;
    su[u] = (q[8] + q[0]*a0.x + q[1]*a0.y + q[2]*a0.z + q[3]*a0.w
                  + q[4]*a1.x + q[5]*a1.y + q[6]*a1.z + q[7]*a1.w) * SCALE_ATT;
  }

  const float* ap = Ain + ((size_t)b * 256 + t) * 8;
  float av[8];
  {
    float4 v0 = *(const float4*)ap;
    float4 v1 = *(const float4*)(ap + 4);
    av[0]=v0.x; av[1]=v0.y; av[2]=v0.z; av[3]=v0.w;
    av[4]=v1.x; av[5]=v1.y; av[6]=v1.z; av[7]=v1.w;
  }

  float inv[2];
  for (int u = 0; u < 2; u++){
    float s_ = su[u];
    float* sc = u ? sc1 : sc0;
    smx[t] = s_; __syncthreads();
    for (int o = 128; o > 0; o >>= 1){ if (t < o) smx[t] = fmaxf(smx[t], smx[t + o]); __syncthreads(); }
    float mx = smx[0]; __syncthreads();
    float e = __expf(s_ - mx); sc[t] = e;
    #pragma unroll
    for (int a2 = 0; a2 < 8; a2++) atomicAdd(&cd[u * 8 + a2], e * av[a2]);
    smx[t] = e; __syncthreads();
    for (int o = 128; o > 0; o >>= 1){ if (t < o) smx[t] += smx[t + o]; __syncthreads(); }
    inv[u] = 1.f / smx[0]; __syncthreads();
  }
  if (t < 8){
    st4_sys(&ptrs[((size_t)0 * 128 + b) * 8 + t], cd[t] * inv[0]);
    st4_sys(&ptrs[((size_t)128 + b) * 8 + t],     cd[8 + t] * inv[1]);
  }

  // value pass over ENC: thread t owns cols 2t,2t+1 (one u32 = 2 bf16 per s2)
  float a00 = 0.f, a01 = 0.f, a10 = 0.f, a11 = 0.f;
  const u16* ep = enc + (size_t)b * 512;
  #pragma unroll 8
  for (int s2 = 0; s2 < 256; s2++){
    float w0 = sc0[s2], w1 = sc1[s2];
    u32 pv = *(const u32*)(ep + (size_t)s2 * 65536 + 2 * t);
    float v0 = b2f((u16)pv);
    float v1 = b2f((u16)(pv >> 16));
    a00 += w0 * v0; a01 += w0 * v1; a10 += w1 * v0; a11 += w1 * v1;
  }
  float* vp = vpre + (size_t)b * 1024;
  st4_sys(&vp[2 * t], a00 * inv[0]);           st4_sys(&vp[2 * t + 1], a01 * inv[0]);
  st4_sys(&vp[512 + 2 * t], a10 * inv[1]);     st4_sys(&vp[512 + 2 * t + 1], a11 * inv[1]);
}

DEVI void dev_bahd(int b, const u16* eatt, const float* dpart, const float* vvec,
                   const u16* enc, float* ctx, float* fs)
{
  int t = threadIdx.x, lane = t & 63, w = t >> 6;
  float* dp = fs; float* vv = fs + 512; float* sc = fs + 1024; float* smx = fs + 1280;
  dp[t] = ld4f_sys(dpart + (size_t)b * 512 + t);
  dp[t + 256] = ld4f_sys(dpart + (size_t)b * 512 + t + 256);
  vv[t] = vvec[t]; vv[t + 256] = vvec[t + 256];
  __syncthreads();
  for (int s = w; s < 256; s += 4){
    uint4 v = *(const uint4*)(eatt + ((size_t)s * 128 + b) * 512 + lane * 8);
    const u16* h = (const u16*)&v;
    float4 d0 = *(float4*)&dp[lane * 8], d1 = *(float4*)&dp[lane * 8 + 4];
    float4 v0 = *(float4*)&vv[lane * 8], v1 = *(float4*)&vv[lane * 8 + 4];
    float r = fmaxf(0.f, b2f(h[0]) + d0.x) * v0.x + fmaxf(0.f, b2f(h[1]) + d0.y) * v0.y
            + fmaxf(0.f, b2f(h[2]) + d0.z) * v0.z + fmaxf(0.f, b2f(h[3]) + d0.w) * v0.w
            + fmaxf(0.f, b2f(h[4]) + d1.x) * v1.x + fmaxf(0.f, b2f(h[5]) + d1.y) * v1.y
            + fmaxf(0.f, b2f(h[6]) + d1.z) * v1.z + fmaxf(0.f, b2f(h[7]) + d1.w) * v1.w;
    #pragma unroll
    for (int off = 32; off > 0; off >>= 1) r += __shfl_xor(r, off);
    if (lane == 0) sc[s] = r;
  }
  __syncthreads();
  float s0 = sc[t];
  smx[t] = s0; __syncthreads();
  for (int o = 128; o > 0; o >>= 1){ if (t < o) smx[t] = fmaxf(smx[t], smx[t + o]); __syncthreads(); }
  float mx = smx[0]; __syncthreads();
  float e = __expf(s0 - mx); sc[t] = e; smx[t] = e; __syncthreads();
  for (int o = 128; o > 0; o >>= 1){ if (t < o) smx[t] += smx[t + o]; __syncthreads(); }
  float inv = 1.f / smx[0];
  float a0 = 0.f, a1 = 0.f;
  const u16* ep = enc + (size_t)b * 512;
  #pragma unroll 8
  for (int s2 = 0; s2 < 256; s2++){
    float wgt = sc[s2];
    u32 pv = *(const u32*)(ep + (size_t)s2 * 65536 + 2 * t);
    a0 += wgt * b2f((u16)pv);
    a1 += wgt * b2f((u16)(pv >> 16));
  }
  st4_sys(&ctx[(size_t)b * 512 + 2 * t], a0 * inv);
  st4_sys(&ctx[(size_t)b * 512 + 2 * t + 1], a1 * inv);
}

DEVI void dev_cattn(int b, const float* qck, const u16* enc, float* cv2p, float* fs)
{
  int t = threadIdx.x, lane = t & 63, w = t >> 6;
  float* qv = fs; float* sc = fs + 1024; float* smx = fs + 1280;
  qv[t] = ld4f_sys(qck + (size_t)b * 520 + t);
  qv[t + 256] = ld4f_sys(qck + (size_t)b * 520 + t + 256);
  __syncthreads();
  float qc0 = ld4f_sys(qck + (size_t)b * 520 + 512);
  for (int s = w; s < 256; s += 4){
    uint4 v = *(const uint4*)(enc + ((size_t)s * 128 + b) * 512 + lane * 8);
    const u16* h = (const u16*)&v;
    float4 q0 = *(float4*)&qv[lane * 8], q1 = *(float4*)&qv[lane * 8 + 4];
    float r = b2f(h[0])*q0.x + b2f(h[1])*q0.y + b2f(h[2])*q0.z + b2f(h[3])*q0.w
            + b2f(h[4])*q1.x + b2f(h[5])*q1.y + b2f(h[6])*q1.z + b2f(h[7])*q1.w;
    #pragma unroll
    for (int off = 32; off > 0; off >>= 1) r += __shfl_xor(r, off);
    if (lane == 0) sc[s] = (r + qc0) * SCALE_ATT;
  }
  __syncthreads();
  float s0 = sc[t];
  smx[t] = s0; __syncthreads();
  for (int o = 128; o > 0; o >>= 1){ if (t < o) smx[t] = fmaxf(smx[t], smx[t + o]); __syncthreads(); }
  float mx = smx[0]; __syncthreads();
  float e = __expf(s0 - mx); sc[t] = e; smx[t] = e; __syncthreads();
  for (int o = 128; o > 0; o >>= 1){ if (t < o) smx[t] += smx[t + o]; __syncthreads(); }
  float inv = 1.f / smx[0];
  float a0 = 0.f, a1 = 0.f;
  const u16* ep = enc + (size_t)b * 512;
  #pragma unroll 8
  for (int s2 = 0; s2 < 256; s2++){
    float wgt = sc[s2];
    u32 pv = *(const u32*)(ep + (size_t)s2 * 65536 + 2 * t);
    a0 += wgt * b2f((u16)pv);
    a1 += wgt * b2f((u16)(pv >> 16));
  }
  st4_sys(&cv2p[(size_t)b * 512 + 2 * t], a0 * inv);
  st4_sys(&cv2p[(size_t)b * 512 + 2 * t + 1], a1 * inv);
}

DEVI void dev_outcvt(int b, const float* outt, const float* outb2, float* dst)
{
  int t = threadIdx.x;
  #pragma unroll
  for (int rep = 0; rep < 2; rep++){
    int o = t + rep * 256;
    float s = ld4f_sys(outt + (size_t)b * 512 + o) + ld4f_sys(outt + 65536 + (size_t)b * 512 + o)
            + ld4f_sys(outt + 131072 + (size_t)b * 512 + o) + ld4f_sys(outt + 196608 + (size_t)b * 512 + o);
    dst[(size_t)b * 512 + o] = s + outb2[o];   // final output: flushed at kernel end
  }
}

// ================ persistent encoder (32 steps per launch, manual barrier) ================
struct EncArgs {
  const float *WhhF, *WhhB, *giF, *giB;
  const float *bihF, *bhhF, *bihB, *bhhB;
  float *HF, *HB; u16 *HFB, *HBB, *ENC;
  u32 *BAR; int bar0;
  int s0;
};

__global__ __launch_bounds__(256) void k_enc(EncArgs a)
{
  __shared__ short Bw[24576];   // 48 rows (3 gates x 16 cols) x 512 K, bf16, MFMA layout
  __shared__ short Al[4096];
  int blk = blockIdx.x;
  int d = blk >> 5, gt = blk & 31;
  int t = threadIdx.x, lane = t & 63, w = t >> 6;

  const float* Whh = d ? a.WhhB : a.WhhF;
  for (int c = t; c < 3072; c += 256){
    int brow = c >> 6, kc = c & 63;
    int grow = (brow >> 4) * 512 + gt * 16 + (brow & 15);
    const float* wp = Whh + (size_t)grow * 512 + kc * 8;
    *(uint4*)&Bw[((kc * 48) + brow) * 8] = cvt8(*(const float4*)wp, *(const float4*)(wp + 4));
  }
  const float* bih = d ? a.bihB : a.bihF;
  const float* bhh = d ? a.bhhB : a.bhhF;
  int gcol = gt * 16 + (lane & 15);
  float bir = bih[gcol],        bhr = bhh[gcol];
  float biz = bih[512 + gcol],  bhz = bhh[512 + gcol];
  float bin = bih[1024 + gcol], bhn = bhh[1024 + gcol];
  float* hf_base = d ? a.HB : a.HF;
  u16*   hb_base = d ? a.HBB : a.HFB;
  const float* gi_base = d ? a.giB : a.giF;
  __syncthreads();

  for (int si = 0; si < 32; si++){
    int s = a.s0 + si;
    const u16* hb = hb_base + (size_t)(s & 1) * 65536;
    const float* hf = hf_base + (size_t)(s & 1) * 65536;
    float* hnf = hf_base + (size_t)((s + 1) & 1) * 65536;
    u16* hnb = hb_base + (size_t)((s + 1) & 1) * 65536;
    u16* eacc = a.ENC + (size_t)(d ? 255 - s : s) * 65536;

    ffrag zz4 = {0.f, 0.f, 0.f, 0.f};
    ffrag acc[2][3];
    #pragma unroll
    for (int i = 0; i < 2; i++)
      #pragma unroll
      for (int j = 0; j < 3; j++) acc[i][j] = zz4;

    for (int ki = 0; ki < 16; ki++){
      int k0 = ki * 32;
      // h state is cross-block communicated -> sys loads, one drain
      int row0 = t >> 2, kq0 = t & 3;
      int row1 = (t + 256) >> 2, kq1 = (t + 256) & 3;
      vu4 hv0, hv1;
      ld16_nw(hb + (size_t)row0 * 512 + k0 + kq0 * 8, hv0);
      ld16_nw(hb + (size_t)row1 * 512 + k0 + kq1 * 8, hv1);
      vm_drain();
      *(vu4*)&Al[(((row0 >> 4) << 6) + (kq0 << 4) + (row0 & 15)) * 8] = hv0;
      *(vu4*)&Al[(((row1 >> 4) << 6) + (kq1 << 4) + (row1 & 15)) * 8] = hv1;
      __syncthreads();
      bfrag af[2], bv[3];
      #pragma unroll
      for (int fr = 0; fr < 2; fr++) af[fr] = *(bfrag*)&Al[(((w * 2 + fr) * 64) + lane) * 8];
      #pragma unroll
      for (int fc = 0; fc < 3; fc++) bv[fc] = *(bfrag*)&Bw[(((ki * 4 + (lane >> 4)) * 48) + fc * 16 + (lane & 15)) * 8];
      #pragma unroll
      for (int fr = 0; fr < 2; fr++)
        #pragma unroll
        for (int fc = 0; fc < 3; fc++)
          acc[fr][fc] = __builtin_amdgcn_mfma_f32_16x16x32_bf16(af[fr], bv[fc], acc[fr][fc], 0, 0, 0);
      __syncthreads();
    }

    const float* gp0 = gi_base + (size_t)si * 196608;
    #pragma unroll
    for (int fr = 0; fr < 2; fr++){
      #pragma unroll
      for (int i = 0; i < 4; i++){
        int brow = w * 32 + fr * 16 + ((lane >> 4) << 2) + i;
        const float* gp = gp0 + (size_t)brow * 1536;
        float gr_ = gp[gcol], gz_ = gp[512 + gcol], gn_ = gp[1024 + gcol];
        float hold = ld4f_sys(hf + (size_t)brow * 512 + gcol);
        float r  = sigmf_(gr_ + acc[fr][0][i] + bir + bhr);
        float zg = sigmf_(gz_ + acc[fr][1][i] + biz + bhz);
        float n  = tanhf_(gn_ + bin + r * (acc[fr][2][i] + bhn));
        float hn = (1.f - zg) * n + zg * hold;
        size_t idx = (size_t)brow * 512 + gcol;
        st4_sys(hnf + idx, hn);
        st2_sys(hnb + idx, f2b(hn));
        eacc[idx] = f2b(b2f(eacc[idx]) + hn);   // block-private slice; cross-launch coherence only
      }
    }
    gridbar2(a.BAR + BAR_ENCF, a.BAR + BAR_ENCGO, (u32)(a.s0 + si + 1), 64, blk, 0);
  }
}

// ================ persistent decoder (all 64 steps, manual barrier) ================
struct DecArgs {
  const float *tgt, *Ag, *AM, *KA, *CAE, *dattW, *dattv;
  const float *puWhh, *puWih, *pubih, *pubhh;
  const float *dWhh, *DBIH2, *dbhh, *VKE2, *OUTB2;
  const u16 *ENC, *EATT, *DWF, *MKTW, *OWF;
  float *HIDA; u16 *HIDAB;
  float *DECH; u16 *DECHB;
  float *HF0; u16 *HFB0;
  float *PTRS, *VPRE, *CTX, *DPART, *QCK, *CV2P, *GIDEC, *OUTT, *out;
  u32 *BAR;
};

__global__ __launch_bounds__(256) void k_dec(DecArgs a)
{
  __shared__ short Al[4096];
  __shared__ short Bl[4096];
  __shared__ float fs[1600];
  const int blk = blockIdx.x;
  const Seg4 S4SENT = {nullptr, 0, 0, 1 << 30, 0};
  u32* dF = a.BAR + BAR_DECF;
  u32* dG = a.BAR + BAR_DECGO;
  const int GATHER = 200;   // busy only in phase B -> polls start early in other phases

  for (int st = 0; st < 64; st++){
    const float* hida_c  = a.HIDA  + (size_t)(st & 1) * 131072;
    float*       hida_n  = a.HIDA  + (size_t)((st + 1) & 1) * 131072;
    const u16*   hidab_c = a.HIDAB + (size_t)(st & 1) * 131072;
    u16*         hidab_n = a.HIDAB + (size_t)((st + 1) & 1) * 131072;
    const float* dech_c  = (st == 0) ? a.HF0  : a.DECH  + (size_t)((st + 1) & 1) * 65536;
    const u16*   dechb_c = (st == 0) ? a.HFB0 : a.DECHB + (size_t)((st + 1) & 1) * 65536;
    float*       dech_n  = a.DECH  + (size_t)(st & 1) * 65536;
    u16*         dechb_n = a.DECHB + (size_t)(st & 1) * 65536;
    u32 seq0 = (u32)(st * 5);

    // ---- phase A: pu GRUs | dpart GEMM | outcvt(st-1)
    if (blk < 32){
      int u = blk >> 4, g0 = (blk & 15) * 32;
      dev_gru3<1>(g0, hidab_c + (size_t)u * 65536, hida_c + (size_t)u * 65536,
                  a.puWhh + (size_t)u * 786432, nullptr,
                  a.PTRS + u * 1024, a.puWih + (size_t)u * 12288,
                  a.pubih + u * 1536, a.pubhh + u * 1536,
                  hida_n + (size_t)u * 65536, hidab_n + (size_t)u * 65536, Al, Bl);
    } else if (blk < 40){
      Z4 z;
      z.sg[0] = {dechb_c, 512, 0, 512, 1}; z.sg[1] = S4SENT; z.sg[2] = S4SENT; z.sg[3] = S4SENT;
      z.Bp = a.dattW; z.ldb = 1024; z.bf32 = 1; z.bias = nullptr;
      z.Cp = a.DPART; z.ldc = 512; z.cslab = 0; z.N = 512; z.K = 512;
      dev_mfma4<64>(z, blk - 32, 0, 1, Al, Bl);
    } else if (blk < 168 && st > 0){
      dev_outcvt(blk - 40, a.OUTT, a.OUTB2, a.out + (size_t)(st - 1) * 65536);
    }
    gridbar2(dF, dG, seq0 + 1, 256, blk, GATHER);

    // ---- phase B: pointer attention (both units) | Bahdanau
    if (blk < 128){
      dev_puattn(blk, hida_n, a.KA, a.CAE, a.AM, a.Ag, a.ENC, a.VPRE, a.PTRS, fs);
    } else {
      dev_bahd(blk - 128, a.EATT, a.DPART, a.dattv, a.ENC, a.CTX, fs);
    }
    gridbar2(dF, dG, seq0 + 2, 256, blk, GATHER);

    // ---- phase C: decoder gi GEMM (folded Wih) | qck GEMM (folded)
    if (blk < 48){
      Z4 z;
      z.sg[0] = {a.tgt + (size_t)(st ? st - 1 : 0) * 65536, 512, 1, 512, 0};
      z.sg[1] = {a.VPRE, 1024, 1, 1024, 1};
      z.sg[2] = {a.CTX, 512, 1, 512, 1};
      z.sg[3] = S4SENT;
      z.Bp = a.DWF; z.ldb = 2048; z.bf32 = 0; z.bias = nullptr;
      z.Cp = a.GIDEC; z.ldc = 1536; z.cslab = 196608; z.N = 1536; z.K = 2048;
      dev_mfma4<128>(z, blk % 12, blk / 12, 4, Al, Bl);
    } else if (blk < 57){
      Z4 z;
      z.sg[0] = {a.VPRE, 1024, 1, 1024, 1}; z.sg[1] = S4SENT; z.sg[2] = S4SENT; z.sg[3] = S4SENT;
      z.Bp = a.MKTW; z.ldb = 1024; z.bf32 = 0; z.bias = a.VKE2;
      z.Cp = a.QCK; z.ldc = 520; z.cslab = 0; z.N = 513; z.K = 1024;
      dev_mfma4<64>(z, blk - 48, 0, 1, Al, Bl);
    }
    gridbar2(dF, dG, seq0 + 3, 256, blk, GATHER);

    // ---- phase D: decoder GRU combine | content attention
    if (blk < 16){
      dev_gru3<2>(blk * 32, dechb_c, dech_c, a.dWhh, a.GIDEC, nullptr, nullptr,
                  a.DBIH2, a.dbhh, dech_n, dechb_n, Al, Bl);
    } else if (blk < 144){
      dev_cattn(blk - 16, a.QCK, a.ENC, a.CV2P, fs);
    }
    gridbar2(dF, dG, seq0 + 4, 256, blk, GATHER);

    // ---- phase E: folded output head GEMM (K=2560, split-K 4)
    if (blk < 32){
      Z4 z;
      z.sg[0] = {dechb_n, 512, 0, 512, 1};
      z.sg[1] = {a.CTX, 512, 1, 512, 1};
      z.sg[2] = {a.VPRE, 1024, 1, 1024, 1};
      z.sg[3] = {a.CV2P, 512, 1, 512, 1};
      z.Bp = a.OWF; z.ldb = 2560; z.bf32 = 0; z.bias = nullptr;
      z.Cp = a.OUTT; z.ldc = 512; z.cslab = 65536; z.N = 512; z.K = 2560;
      dev_mfma4<64>(z, blk & 7, blk >> 3, 4, Al, Bl);
    }
    gridbar2(dF, dG, seq0 + 5, 256, blk, GATHER);
  }
  if (blk < 128) dev_outcvt(blk, a.OUTT, a.OUTB2, a.out + 63ull * 65536);
}

// ================ setup: batched fold jobs ================
struct Job {
  const float* A; const float* B; const float* D; void* C;
  int Asm, Ask, Bsk, Bsn, Dsm, Dsn, Csm, Csn;
  int cbf, M, N, K, kind;
};
struct Jobs { Job j[24]; int nj; long long off[25]; };

__global__ __launch_bounds__(256) void k_setup(Jobs J)
{
  long long total = J.off[J.nj];
  for (long long tid = (long long)blockIdx.x * 256 + threadIdx.x; tid < total; tid += (long long)gridDim.x * 256){
    int ji = 0;
    while (tid >= J.off[ji + 1]) ji++;
    Job jb = J.j[ji];
    long long l = tid - J.off[ji];
    if (jb.kind == 0){
      int m = (int)(l / jb.N), n = (int)(l - (long long)m * jb.N);
      float acc = 0.f;
      const float* ap = jb.A + (size_t)m * jb.Asm;
      const float* bp = jb.B + (size_t)n * jb.Bsn;
      for (int k = 0; k < jb.K; k++)
        acc += ap[(size_t)k * jb.Ask] * bp[(size_t)k * jb.Bsk];
      if (jb.D) acc += jb.D[(size_t)m * jb.Dsm + (size_t)n * jb.Dsn];
      if (jb.cbf) ((u16*)jb.C)[(size_t)m * jb.Csm + (size_t)n * jb.Csn] = f2b(acc);
      else ((float*)jb.C)[(size_t)m * jb.Csm + (size_t)n * jb.Csn] = acc;
    } else if (jb.kind == 1){
      int m = (int)(l / jb.N), n = (int)(l - (long long)m * jb.N);
      ((u16*)jb.C)[(size_t)m * jb.Csm + (size_t)n * jb.Csn] = f2b(jb.A[(size_t)m * jb.Asm + (size_t)n * jb.Ask]);
    } else if (jb.kind == 2){
      int u = (int)(l >> 15), sb = (int)(l & 32767);
      float x[8];
      #pragma unroll
      for (int a2 = 0; a2 < 8; a2++) x[a2] = jb.A[(size_t)sb * 8 + a2];
      float* op = (float*)jb.C + ((size_t)u * 32768 + sb) * 8;
      #pragma unroll
      for (int c = 0; c < 8; c++){
        float acc = jb.D[u * 8 + c];
        #pragma unroll
        for (int a2 = 0; a2 < 8; a2++) acc += x[a2] * jb.B[(u * 8 + c) * 8 + a2];
        op[c] = acc;
      }
    } else {
      int u = (int)(l >> 10), r = (int)(l & 1023);
      int bb = r >> 3, aa = r & 7;
      int su = u ? 255 : 0;
      ((float*)jb.C)[l] = jb.A[((size_t)su * 128 + bb) * 8 + aa];
    }
  }
}

// ================ host ================
static inline Seg mkseg(const void* p, int ld, int f32, int K){ Seg s; s.p = p; s.ld = ld; s.f32 = f32; s.K = K; return s; }
static const Seg SENT = {nullptr, 0, 0, 1 << 30};

static inline void addJ(Jobs& JS, Job jb, long long cnt){
  JS.j[JS.nj] = jb;
  JS.off[JS.nj + 1] = JS.off[JS.nj] + cnt;
  JS.nj++;
}
static inline Job JG(const float* A, int Asm, int Ask, const float* B, int Bsk, int Bsn,
                     const float* D, int Dsm, int Dsn, void* C, int Csm, int Csn,
                     int cbf, int M, int N, int K, int kind = 0){
  Job j; j.A=A; j.B=B; j.D=D; j.C=C; j.Asm=Asm; j.Ask=Ask; j.Bsk=Bsk; j.Bsn=Bsn;
  j.Dsm=Dsm; j.Dsn=Dsn; j.Csm=Csm; j.Csn=Csn; j.cbf=cbf; j.M=M; j.N=N; j.K=K; j.kind=kind;
  return j;
}

extern "C" void kernel_launch(void* const* d_in, const int* in_sizes, int n_in,
                              void* d_out, int out_size, void* d_ws, size_t ws_size,
                              hipStream_t stream)
{
  (void)in_sizes; (void)out_size;
  if (n_in < 44 || ws_size < WS_NEED) return;

  const float* src   = (const float*)d_in[0];
  const float* tgt   = (const float*)d_in[1];
  const float* Ag    = (const float*)d_in[2];
  const float* eWihF = (const float*)d_in[3];
  const float* eWhhF = (const float*)d_in[4];
  const float* ebihF = (const float*)d_in[5];
  const float* ebhhF = (const float*)d_in[6];
  const float* eWihB = (const float*)d_in[7];
  const float* eWhhB = (const float*)d_in[8];
  const float* ebihB = (const float*)d_in[9];
  const float* ebhhB = (const float*)d_in[10];
  const float* dattW = (const float*)d_in[11];
  const float* dattb = (const float*)d_in[12];
  const float* dattv = (const float*)d_in[13];
  const float* dWih  = (const float*)d_in[14];
  const float* dWhh  = (const float*)d_in[15];
  const float* dbih  = (const float*)d_in[16];
  const float* dbhh  = (const float*)d_in[17];
  const float* doW   = (const float*)d_in[18];
  const float* dob   = (const float*)d_in[19];
  const float* puWih = (const float*)d_in[20];
  const float* puWhh = (const float*)d_in[21];
  const float* pubih = (const float*)d_in[22];
  const float* pubhh = (const float*)d_in[23];
  const float* puqW  = (const float*)d_in[24];
  const float* puqb  = (const float*)d_in[25];
  const float* puAW  = (const float*)d_in[26];
  const float* puAb  = (const float*)d_in[27];
  const float* puqp  = (const float*)d_in[28];
  const float* pukp  = (const float*)d_in[29];
  const float* puvp  = (const float*)d_in[30];
  const float* puinb = (const float*)d_in[31];
  const float* puop  = (const float*)d_in[32];
  const float* puob  = (const float*)d_in[33];
  const float* aaq   = (const float*)d_in[34];
  const float* aak   = (const float*)d_in[35];
  const float* aav   = (const float*)d_in[36];
  const float* aainb = (const float*)d_in[37];
  const float* aao   = (const float*)d_in[38];
  const float* aaob  = (const float*)d_in[39];
  const float* tohW  = (const float*)d_in[40];
  const float* tohb  = (const float*)d_in[41];
  const float* outW  = (const float*)d_in[42];
  const float* outb  = (const float*)d_in[43];

  char* ws = (char*)d_ws;
  float* GI    = (float*)(ws + OFF_GI);
  u16*   ENC   = (u16*)(ws + OFF_ENC);
  u16*   EATT  = (u16*)(ws + OFF_EATT);
  float* AM    = (float*)(ws + OFF_AM);
  float* HF    = (float*)(ws + OFF_HF);
  float* HB    = (float*)(ws + OFF_HB);
  u16*   HFB   = (u16*)(ws + OFF_HFB);
  u16*   HBB   = (u16*)(ws + OFF_HBB);
  float* HIDA  = (float*)(ws + OFF_HIDA);
  u16*   HIDAB = (u16*)(ws + OFF_HIDAB);
  u32*   BAR   = (u32*)(ws + OFF_BAR);
  float* DECH  = (float*)(ws + OFF_DECH);
  u16*   DECHB = (u16*)(ws + OFF_DECHB);
  float* PTRS  = (float*)(ws + OFF_PTRS);
  float* VPRE  = (float*)(ws + OFF_VPRE);
  float* CTX   = (float*)(ws + OFF_CTX);
  float* DPART = (float*)(ws + OFF_DPART);
  float* QCK   = (float*)(ws + OFF_QCK);
  float* CV2P  = (float*)(ws + OFF_CV2P);
  float* GIDEC = (float*)(ws + OFF_GIDEC);
  float* OUTT  = (float*)(ws + OFF_OUTT);
  float* WOVF  = (float*)(ws + OFF_WOVF);
  float* WOVCF = (float*)(ws + OFF_WOVCF);
  float* MKTF  = (float*)(ws + OFF_MKTF);
  u16*   DWF   = (u16*)(ws + OFF_DWF);
  u16*   MKTW  = (u16*)(ws + OFF_MKTW);
  u16*   OWF   = (u16*)(ws + OFF_OWF);
  float* BOV   = (float*)(ws + OFF_BOV);
  float* BOVC  = (float*)(ws + OFF_BOVC);
  float* KAx   = (float*)(ws + OFF_KA);
  float* CAE   = (float*)(ws + OFF_CAE);
  float* RT    = (float*)(ws + OFF_RT);
  float* BQC   = (float*)(ws + OFF_BQC);
  float* PMAT  = (float*)(ws + OFF_PMAT);
  float* CQ    = (float*)(ws + OFF_CQ);
  float* VKE2  = (float*)(ws + OFF_VKE2);
  float* DBIH2 = (float*)(ws + OFF_DBIH2);
  float* OUTB2 = (float*)(ws + OFF_OUTB2);

  hipMemsetAsync(ENC, 0, 2ull*256*128*512, stream);
  hipMemsetAsync(ws + OFF_HF, 0, OFF_ZEND - OFF_HF, stream);  // states + barrier flags

  // -------- stage 1: independent folds --------
  {
    Jobs S{}; S.nj = 0; S.off[0] = 0;
    for (int u = 0; u < 2; u++){
      const float* qp  = puqp + (size_t)u * 262144;
      const float* kp  = pukp + (size_t)u * 4096;
      float* RTu = RT + u * 8192;
      addJ(S, JG(qp, 1, 512, kp, 8, 1, nullptr, 0, 0, RTu, 16, 1, 0, 512, 8, 512), 4096);
      addJ(S, JG(qp, 1, 512, puinb + u*1536 + 512, 1, 0, nullptr, 0, 0, RTu + 8, 16, 1, 0, 512, 1, 512), 512);
      addJ(S, JG(qp, 512, 1, puqb + u*512, 1, 0, puinb + u*1536, 1, 0, BQC + u*512, 1, 1, 0, 512, 1, 512), 512);
      addJ(S, JG(puop + (size_t)u*262144, 512, 1, puvp + (size_t)u*262144, 512, 1, nullptr, 0, 0, WOVF + (size_t)u*262144, 512, 1, 0, 512, 512, 512), 262144);
      addJ(S, JG(puop + (size_t)u*262144, 512, 1, puinb + u*1536 + 1024, 1, 0, puob + u*512, 1, 0, BOV + u*512, 1, 1, 0, 512, 1, 512), 512);
    }
    addJ(S, JG(aao, 512, 1, aav, 512, 1, nullptr, 0, 0, WOVCF, 512, 1, 0, 512, 512, 512), 262144);
    addJ(S, JG(aao, 512, 1, aainb + 1024, 1, 0, aaob, 1, 0, BOVC, 1, 1, 0, 512, 1, 512), 512);
    addJ(S, JG(aaq, 1, 512, aak, 512, 1, nullptr, 0, 0, PMAT, 516, 1, 0, 512, 512, 512), 262144);
    addJ(S, JG(aaq, 1, 512, aainb + 512, 1, 0, nullptr, 0, 0, PMAT + 512, 516, 1, 0, 512, 1, 512), 512);
    addJ(S, JG(aaq, 512, 1, tohb, 1, 0, aainb, 1, 0, CQ, 1, 1, 0, 512, 1, 512), 512);
    addJ(S, JG(dWih, 2048, 1, nullptr, 0, 0, nullptr, 0, 0, DWF, 2048, 1, 1, 1536, 512, 0, 1), 786432);
    addJ(S, JG(dWih + 1536, 2048, 1, nullptr, 0, 0, nullptr, 0, 0, DWF + 1536, 2048, 1, 1, 1536, 512, 0, 1), 786432);
    addJ(S, JG(outW, 2048, 1, doW, 1024, 1, nullptr, 0, 0, OWF, 2560, 1, 1, 512, 1024, 512), 524288);
    addJ(S, JG(outW, 2048, 1, dob, 1, 0, outb, 1, 0, OUTB2, 1, 1, 0, 512, 1, 512), 512);
    addJ(S, JG(Ag, 0, 0, puAW, 0, 0, puAb, 0, 0, AM, 0, 0, 0, 0, 0, 0, 2), 65536);
    addJ(S, JG(Ag, 0, 0, nullptr, 0, 0, nullptr, 0, 0, PTRS, 0, 0, 0, 0, 0, 0, 3), 2048);
    k_setup<<<2048, 256, 0, stream>>>(S);
  }
  // -------- stage 2 --------
  {
    Jobs S{}; S.nj = 0; S.off[0] = 0;
    for (int u = 0; u < 2; u++){
      const float* kp = pukp + (size_t)u * 4096;
      addJ(S, JG(puqW + (size_t)u*262144, 1, 512, RT + u*8192, 16, 1, nullptr, 0, 0, KAx + u*8192, 16, 1, 0, 512, 9, 512), 4608);
      addJ(S, JG(BQC + u*512, 0, 1, kp, 8, 1, nullptr, 0, 0, CAE + u*16, 0, 1, 0, 1, 8, 512), 8);
      addJ(S, JG(BQC + u*512, 0, 1, puinb + u*1536 + 512, 1, 0, nullptr, 0, 0, CAE + u*16 + 8, 0, 1, 0, 1, 1, 512), 1);
      addJ(S, JG(dWih + 512 + u*512, 2048, 1, WOVF + (size_t)u*262144, 512, 1, nullptr, 0, 0, DWF + 512 + u*512, 2048, 1, 1, 1536, 512, 512), 786432);
      addJ(S, JG(outW + 512 + u*512, 2048, 1, WOVF + (size_t)u*262144, 512, 1, nullptr, 0, 0, OWF + 1024 + u*512, 2560, 1, 1, 512, 512, 512), 262144);
    }
    addJ(S, JG(tohW, 1, 1024, PMAT, 516, 1, nullptr, 0, 0, MKTF, 1, 1024, 0, 1024, 513, 512), 525312);
    addJ(S, JG(CQ, 0, 1, aak, 512, 1, nullptr, 0, 0, VKE2, 0, 1, 0, 1, 512, 512), 512);
    addJ(S, JG(CQ, 0, 1, aainb + 512, 1, 0, nullptr, 0, 0, VKE2 + 512, 0, 1, 0, 1, 1, 512), 1);
    addJ(S, JG(dWih + 512, 2048, 1, BOV, 1, 0, dbih, 1, 0, DBIH2, 1, 1, 0, 1536, 1, 1024), 1536);
    addJ(S, JG(outW + 1536, 2048, 1, WOVCF, 512, 1, nullptr, 0, 0, OWF + 2048, 2560, 1, 1, 512, 512, 512), 262144);
    addJ(S, JG(outW + 512, 2048, 1, BOV, 1, 0, OUTB2, 1, 0, OUTB2, 1, 1, 0, 512, 1, 1536), 512);
    k_setup<<<2048, 256, 0, stream>>>(S);
  }
  // -------- stage 3 --------
  {
    Jobs S{}; S.nj = 0; S.off[0] = 0;
    for (int u = 0; u < 2; u++)
      addJ(S, JG(MKTF + u*512, 1024, 1, WOVF + (size_t)u*262144, 512, 1, nullptr, 0, 0, MKTW + u*512, 1024, 1, 1, 513, 512, 512), 262656);
    addJ(S, JG(MKTF, 1024, 1, BOV, 1, 0, VKE2, 1, 0, VKE2, 1, 1, 0, 513, 1, 1024), 513);
    k_setup<<<1024, 256, 0, stream>>>(S);
  }

  // -------- encoder: 8 chunks of (gi GEMM + persistent 32-step scan) --------
  for (int c = 0; c < 8; c++){
    int c0 = c * 32;
    NTA nt{};
    nt.tilesN = 12;
    for (int d = 0; d < 2; d++){
      NTZ& zz = nt.z[d];
      zz.sg[0] = mkseg(d == 0 ? (const void*)(src + (size_t)c0 * 65536) : (const void*)src, 512, 1, 512);
      zz.sg[1] = SENT; zz.sg[2] = SENT;
      zz.Bp = d ? eWihB : eWihF; zz.ldb = 512; zz.bf32 = 1;
      zz.bias = nullptr; zz.biasf32 = 0;
      zz.Cp = GI + (size_t)d * 6291456; zz.ldc = 1536; zz.cf32 = 1; zz.cslab = 0;
      zz.N = 1536; zz.rev_s0 = (d == 0) ? -1 : (255 - c0); zz.K = 512;
    }
    k_mfma_nt<128><<<dim3(32*12, 1, 2), 256, 0, stream>>>(nt);

    EncArgs ea;
    ea.WhhF = eWhhF; ea.WhhB = eWhhB;
    ea.giF = GI; ea.giB = GI + 6291456;
    ea.bihF = ebihF; ea.bhhF = ebhhF; ea.bihB = ebihB; ea.bhhB = ebhhB;
    ea.HF = HF; ea.HB = HB; ea.HFB = HFB; ea.HBB = HBB; ea.ENC = ENC;
    ea.BAR = BAR; ea.bar0 = c * 32;
    ea.s0 = c0;
    k_enc<<<dim3(64), dim3(256), 0, stream>>>(ea);
  }

  // -------- enc_att = enc @ W2.T + b --------
  {
    NTA nt{};
    nt.tilesN = 4;
    NTZ& zz = nt.z[0];
    zz.sg[0] = mkseg(ENC, 512, 0, 512); zz.sg[1] = SENT; zz.sg[2] = SENT;
    zz.Bp = dattW + 512; zz.ldb = 1024; zz.bf32 = 1;
    zz.bias = dattb; zz.biasf32 = 1;
    zz.Cp = EATT; zz.ldc = 512; zz.cf32 = 0; zz.cslab = 0;
    zz.N = 512; zz.rev_s0 = -1; zz.K = 512;
    k_mfma_nt<128><<<dim3(256*4, 1, 1), 256, 0, stream>>>(nt);
  }

  // -------- decoder: one persistent kernel, all 64 steps --------
  {
    DecArgs da;
    da.tgt = tgt; da.Ag = Ag; da.AM = AM; da.KA = KAx; da.CAE = CAE;
    da.dattW = dattW; da.dattv = dattv;
    da.puWhh = puWhh; da.puWih = puWih; da.pubih = pubih; da.pubhh = pubhh;
    da.dWhh = dWhh; da.DBIH2 = DBIH2; da.dbhh = dbhh; da.VKE2 = VKE2; da.OUTB2 = OUTB2;
    da.ENC = ENC; da.EATT = EATT; da.DWF = DWF; da.MKTW = MKTW; da.OWF = OWF;
    da.HIDA = HIDA; da.HIDAB = HIDAB; da.DECH = DECH; da.DECHB = DECHB;
    da.HF0 = HF; da.HFB0 = HFB;
    da.PTRS = PTRS; da.VPRE = VPRE; da.CTX = CTX; da.DPART = DPART;
    da.QCK = QCK; da.CV2P = CV2P; da.GIDEC = GIDEC; da.OUTT = OUTT;
    da.out = (float*)d_out;
    da.BAR = BAR;
    k_dec<<<dim3(256), dim3(256), 0, stream>>>(da);
  }
}

// Round 5
// 22811.427 us; speedup vs baseline: 1.3866x; 1.1147x over previous
//
#include <hip/hip_runtime.h>

typedef unsigned short u16;
typedef unsigned int u32;

#define DEVI __device__ __forceinline__

constexpr float SCALE_ATT = 0.04419417382415922f;  // 1/sqrt(512)

// ---------------- workspace layout (bytes) ----------------
constexpr size_t OFF_GI    = 0;                                  // f32 [2][32][128][1536] per-chunk x@Wih
constexpr size_t OFF_ENC   = OFF_GI    + 4ull*2*32*128*1536;
constexpr size_t OFF_EATT  = OFF_ENC   + 2ull*256*128*512;       // bf16 enc, bf16 enc_att
constexpr size_t OFF_AM    = OFF_EATT  + 2ull*256*128*512;       // f32 [2][256][128][8]
constexpr size_t OFF_HF    = OFF_AM    + 4ull*2*256*128*8;       // ---- zero region start
constexpr size_t OFF_HB    = OFF_HF    + 4ull*2*128*512;
constexpr size_t OFF_HFB   = OFF_HB    + 4ull*2*128*512;
constexpr size_t OFF_HBB   = OFF_HFB   + 2ull*2*128*512;
constexpr size_t OFF_HIDA  = OFF_HBB   + 2ull*2*128*512;
constexpr size_t OFF_HIDAB = OFF_HIDA  + 4ull*2*2*128*512;
constexpr size_t OFF_BAR   = OFF_HIDAB + 2ull*2*2*128*512;       // u32 flag lines (see BAR_* below)
constexpr size_t OFF_ZEND  = OFF_BAR   + 49152;                  // ---- zero region end
constexpr size_t OFF_DECH  = OFF_ZEND;
constexpr size_t OFF_DECHB = OFF_DECH  + 4ull*2*128*512;
constexpr size_t OFF_PTRS  = OFF_DECHB + 2ull*2*128*512;         // f32 [2][128][8]
constexpr size_t OFF_VPRE  = OFF_PTRS  + 4ull*2*128*8;           // f32 [128][1024]  (b-major!)
constexpr size_t OFF_CTX   = OFF_VPRE  + 4ull*128*1024;
constexpr size_t OFF_DPART = OFF_CTX   + 4ull*128*512;
constexpr size_t OFF_QCK   = OFF_DPART + 4ull*128*512;           // f32 [128][520] (513 used)
constexpr size_t OFF_CV2P  = OFF_QCK   + 4ull*128*520;
constexpr size_t OFF_GIDEC = OFF_CV2P  + 4ull*128*512;           // f32 4 K-slabs [128][1536]
constexpr size_t OFF_OUTT  = OFF_GIDEC + 4ull*4*128*1536;        // f32 4 K-slabs [128][512]
constexpr size_t OFF_WOVF  = OFF_OUTT  + 4ull*4*128*512;         // f32 [2][512][512]
constexpr size_t OFF_WOVCF = OFF_WOVF  + 4ull*2*512*512;         // f32 [512][512]
constexpr size_t OFF_MKTF  = OFF_WOVCF + 4ull*512*512;           // f32 [513 rows][1024]
constexpr size_t OFF_DWF   = OFF_MKTF  + 4ull*513*1024;          // bf16 [1536][2048] folded dec Wih
constexpr size_t OFF_MKTW  = OFF_DWF   + 2ull*1536*2048;         // bf16 [513][1024] folded qck W
constexpr size_t OFF_OWF   = OFF_MKTW  + 2ull*513*1024;          // bf16 [512][2560] folded out W
constexpr size_t OFF_BOV   = OFF_OWF   + 2ull*512*2560;          // f32 [2][512]  (contiguous w/ BOVC!)
constexpr size_t OFF_BOVC  = OFF_BOV   + 4ull*2*512;             // f32 [512]
constexpr size_t OFF_KA    = OFF_BOVC  + 4ull*512;               // f32 [2][512][16] (9 used)
constexpr size_t OFF_CAE   = OFF_KA    + 4ull*2*512*16;          // f32 [2][16]
constexpr size_t OFF_RT    = OFF_CAE   + 4ull*2*16;              // f32 [2][512][16]
constexpr size_t OFF_BQC   = OFF_RT    + 4ull*2*512*16;          // f32 [2][512]
constexpr size_t OFF_PMAT  = OFF_BQC   + 4ull*2*512;             // f32 [512][516]
constexpr size_t OFF_CQ    = OFF_PMAT  + 4ull*512*516;
constexpr size_t OFF_VKE2  = OFF_CQ    + 4ull*512;               // f32 [520]
constexpr size_t OFF_DBIH2 = OFF_VKE2  + 4ull*520;               // f32 [1536]
constexpr size_t OFF_OUTB2 = OFF_DBIH2 + 4ull*1536;              // f32 [512]
constexpr size_t WS_NEED   = OFF_OUTB2 + 4ull*512;

// ---------------- helpers ----------------
DEVI float b2f(u16 u){ union{u32 i; float f;} x; x.i = ((u32)u) << 16; return x.f; }
DEVI u16 f2b(float f){ union{float f; u32 i;} x; x.f = f; u32 i = x.i; u32 r = i + 0x7FFFu + ((i >> 16) & 1u); return (u16)(r >> 16); }
DEVI float sigmf_(float x){ return 1.f / (1.f + __expf(-x)); }
DEVI float tanhf_(float x){ x = fminf(15.f, fmaxf(-15.f, x)); float e = __expf(2.f*x); return (e - 1.f) / (e + 1.f); }

typedef __attribute__((ext_vector_type(8))) short bfrag;
typedef __attribute__((ext_vector_type(4))) float ffrag;
typedef __attribute__((ext_vector_type(4))) unsigned int vu4;
typedef __attribute__((ext_vector_type(4))) float vf4;

DEVI uint4 cvt8(float4 a, float4 b){
  union{uint4 u; u16 h[8];} r;
  r.h[0]=f2b(a.x); r.h[1]=f2b(a.y); r.h[2]=f2b(a.z); r.h[3]=f2b(a.w);
  r.h[4]=f2b(b.x); r.h[5]=f2b(b.y); r.h[6]=f2b(b.z); r.h[7]=f2b(b.w);
  return r.u;
}
DEVI vu4 cvt8v(vf4 a, vf4 b){
  union{vu4 u; u16 h[8];} r;
  r.h[0]=f2b(a[0]); r.h[1]=f2b(a[1]); r.h[2]=f2b(a[2]); r.h[3]=f2b(a[3]);
  r.h[4]=f2b(b[0]); r.h[5]=f2b(b[1]); r.h[6]=f2b(b[2]); r.h[7]=f2b(b[3]);
  return r.u;
}

// ---- L2-bypassing (coherence-point) access primitives ----
DEVI void ld16_nw(const void* p, vu4& r){
  asm volatile("global_load_dwordx4 %0, %1, off sc0 sc1"
               : "=&v"(r) : "v"(p) : "memory");
}
DEVI void ld32_nw(const float* p, vf4& a, vf4& b){
  asm volatile("global_load_dwordx4 %0, %2, off sc0 sc1\n\t"
               "global_load_dwordx4 %1, %2, off offset:16 sc0 sc1"
               : "=&v"(a), "=&v"(b) : "v"(p) : "memory");
}
DEVI void vm_drain(){
  asm volatile("s_waitcnt vmcnt(0)" ::: "memory");
  __builtin_amdgcn_sched_barrier(0);   // rule #18
}
DEVI float ld4f_sys(const float* p){ return __hip_atomic_load(p, __ATOMIC_RELAXED, __HIP_MEMORY_SCOPE_SYSTEM); }
DEVI void st4_sys(float* p, float v){
  asm volatile("global_store_dword %0, %1, off sc0 sc1" :: "v"(p), "v"(v) : "memory");
}
DEVI void st2_sys(u16* p, u16 v){
  u32 w = v;
  asm volatile("global_store_short %0, %1, off sc0 sc1" :: "v"(p), "v"(w) : "memory");
}

// ---- all-store flag grid barrier (no RMW, no threadfence) ----
constexpr int GB_STRIDE  = 32;     // u32 per flag line (128B)
constexpr int BAR_DECF   = 0;      // 256 flags * 32 u32
constexpr int BAR_DECGO  = 8192;   // 1 line
constexpr int BAR_ENCF   = 8224;   // 64 flags * 32 u32
constexpr int BAR_ENCGO  = 10272;  // 1 line

DEVI u32 ld_sys(u32* p){ return __hip_atomic_load(p, __ATOMIC_RELAXED, __HIP_MEMORY_SCOPE_SYSTEM); }
DEVI void st_sys(u32* p, u32 v){ __hip_atomic_store(p, v, __ATOMIC_RELAXED, __HIP_MEMORY_SCOPE_SYSTEM); }

DEVI void gridbar2(u32* flags, u32* go, u32 seq, int nblk, int blk, int gblk)
{
  asm volatile("s_waitcnt vmcnt(0)" ::: "memory");   // per-wave: all sys stores committed
  __syncthreads();
  int t = threadIdx.x;
  if (blk == gblk){
    if (t == 0) st_sys(&flags[(u32)blk * GB_STRIDE], seq);
    if (t < nblk){
      u32* f = &flags[(u32)t * GB_STRIDE];
      while (ld_sys(f) < seq) __builtin_amdgcn_s_sleep(1);
    }
    __syncthreads();
    if (t == 0) st_sys(go, seq);
  } else {
    if (t == 0){
      st_sys(&flags[(u32)blk * GB_STRIDE], seq);
      while (ld_sys(go) < seq) __builtin_amdgcn_s_sleep(1);
    }
  }
  __syncthreads();
}

// ================ host-launched 3-seg NT GEMM (GI chunks + EATT) ================
struct Seg { const void* p; int ld; int f32; int K; };
struct NTZ {
  Seg sg[3];
  const void* Bp; int ldb; int bf32;
  const void* bias; int biasf32;
  void* Cp; int ldc; int cf32; int cslab;
  int N; int rev_s0; int K;
};
struct NTA { NTZ z[3]; int tilesN; };

template<int BN>
__global__ __launch_bounds__(256) void k_mfma_nt(NTA a)
{
  NTZ z = a.z[blockIdx.z];
  int tn = blockIdx.x % a.tilesN;
  int tm = blockIdx.x / a.tilesN;
  if (tn * BN >= z.N) return;
  int nks = gridDim.y;
  int kb = blockIdx.y * (z.K / nks);
  int ke = kb + z.K / nks;

  __shared__ short Al[128*32];
  __shared__ short Bl[BN*32];

  int t = threadIdx.x;
  int lane = t & 63, w = t >> 6;
  constexpr int FRS = (BN == 128) ? 4 : 2;
  int wn = (BN == 128) ? (w & 1) : 0;
  int rowbase = (BN == 128) ? (w >> 1) * 64 : w * 32;

  ffrag zz4 = {0.f, 0.f, 0.f, 0.f};
  ffrag acc[FRS][4];
  #pragma unroll
  for (int i = 0; i < FRS; i++)
    #pragma unroll
    for (int j = 0; j < 4; j++) acc[i][j] = zz4;

  for (int k0 = kb; k0 < ke; k0 += 32){
    #pragma unroll
    for (int r2 = 0; r2 < 2; r2++){
      int slot = t + r2 * 256;
      int row = slot >> 2, kq = slot & 3;
      int m = tm * 128 + row;
      int arow = (z.rev_s0 >= 0) ? (((z.rev_s0 - (m >> 7)) << 7) | (m & 127)) : m;
      int k = k0 + kq * 8;
      Seg sg;
      if (k < z.sg[0].K) sg = z.sg[0];
      else { k -= z.sg[0].K; if (k < z.sg[1].K) sg = z.sg[1]; else { k -= z.sg[1].K; sg = z.sg[2]; } }
      uint4 v;
      if (sg.f32){
        const float* ap = (const float*)sg.p + (size_t)arow * sg.ld + k;
        v = cvt8(*(const float4*)ap, *(const float4*)(ap + 4));
      } else {
        v = *(const uint4*)((const u16*)sg.p + (size_t)arow * sg.ld + k);
      }
      *(uint4*)&Al[(((row >> 4) << 6) + (kq << 4) + (row & 15)) * 8] = v;
    }
    #pragma unroll
    for (int r2 = 0; r2 < BN/64; r2++){
      int slot = t + r2 * 256;
      int brow = slot >> 2, kq = slot & 3;
      int n = tn * BN + brow;
      uint4 v = make_uint4(0u, 0u, 0u, 0u);
      if (n < z.N){
        int k = k0 + kq * 8;
        if (z.bf32){
          const float* bp = (const float*)z.Bp + (size_t)n * z.ldb + k;
          v = cvt8(*(const float4*)bp, *(const float4*)(bp + 4));
        } else {
          v = *(const uint4*)((const u16*)z.Bp + (size_t)n * z.ldb + k);
        }
      }
      *(uint4*)&Bl[(kq * BN + brow) * 8] = v;
    }
    __syncthreads();
    bfrag af[FRS], bv[4];
    #pragma unroll
    for (int fr = 0; fr < FRS; fr++) af[fr] = *(bfrag*)&Al[(((rowbase >> 4) + fr) * 64 + lane) * 8];
    #pragma unroll
    for (int fc = 0; fc < 4; fc++) bv[fc] = *(bfrag*)&Bl[(((lane >> 4) * BN) + wn * 64 + fc * 16 + (lane & 15)) * 8];
    #pragma unroll
    for (int fr = 0; fr < FRS; fr++)
      #pragma unroll
      for (int fc = 0; fc < 4; fc++)
        acc[fr][fc] = __builtin_amdgcn_mfma_f32_16x16x32_bf16(af[fr], bv[fc], acc[fr][fc], 0, 0, 0);
    __syncthreads();
  }

  float* Cf = (float*)z.Cp + (size_t)blockIdx.y * z.cslab;
  u16*  Cb = (u16*)z.Cp  + (size_t)blockIdx.y * z.cslab;
  #pragma unroll
  for (int fc = 0; fc < 4; fc++){
    int n = tn * BN + wn * 64 + fc * 16 + (lane & 15);
    if (n >= z.N) continue;
    float bs = 0.f;
    if (z.bias) bs = z.biasf32 ? ((const float*)z.bias)[n] : b2f(((const u16*)z.bias)[n]);
    #pragma unroll
    for (int fr = 0; fr < FRS; fr++){
      #pragma unroll
      for (int i = 0; i < 4; i++){
        int m = tm * 128 + rowbase + fr * 16 + ((lane >> 4) << 2) + i;
        float vv = acc[fr][fc][i] + bs;
        size_t idx = (size_t)m * z.ldc + n;
        if (z.cf32) Cf[idx] = vv; else Cb[idx] = f2b(vv);
      }
    }
  }
}

// ================ device-side 4-seg NT GEMM (M=128 fixed) ================
// Segments with nt=1 are cross-block communicated buffers: read via sc0 sc1.
// C-writes always go to communicated buffers: written via sc0 sc1.
struct Seg4 { const void* p; int ld; int f32; int K; int nt; };
struct Z4 {
  Seg4 sg[4];
  const void* Bp; int ldb; int bf32;
  const float* bias;
  float* Cp; int ldc; int cslab;
  int N; int K;
};

template<int BN>
DEVI void dev_mfma4(const Z4& z, int tn, int ks, int nks, short* Al, short* Bl)
{
  int kseg = z.K / nks;
  int kb = ks * kseg, ke = kb + kseg;
  int t = threadIdx.x, lane = t & 63, w = t >> 6;
  constexpr int FRS = (BN == 128) ? 4 : 2;
  int wn = (BN == 128) ? (w & 1) : 0;
  int rowbase = (BN == 128) ? (w >> 1) * 64 : w * 32;
  ffrag zz4 = {0.f, 0.f, 0.f, 0.f};
  ffrag acc[FRS][4];
  #pragma unroll
  for (int i = 0; i < FRS; i++)
    #pragma unroll
    for (int j = 0; j < 4; j++) acc[i][j] = zz4;

  for (int k0 = kb; k0 < ke; k0 += 32){
    // ---- B staging: cached loads (weights; stay warm in L2) ----
    vu4 bvv[BN/64]; int bidx[BN/64];
    #pragma unroll
    for (int r2 = 0; r2 < BN/64; r2++){
      int slot = t + r2 * 256;
      int brow = slot >> 2, kq = slot & 3;
      int n = tn * BN + brow;
      vu4 v = {0u, 0u, 0u, 0u};
      if (n < z.N){
        int k = k0 + kq * 8;
        if (z.bf32){
          const float* bp = (const float*)z.Bp + (size_t)n * z.ldb + k;
          v = cvt8v(*(const vf4*)bp, *(const vf4*)(bp + 4));
        } else {
          v = *(const vu4*)((const u16*)z.Bp + (size_t)n * z.ldb + k);
        }
      }
      bvv[r2] = v; bidx[r2] = (kq * BN + brow) * 8;
    }
    // ---- A staging: issue (possibly sys) loads for both slots, drain once ----
    int rowv[2], kqv2[2], isf[2];
    vf4 fa[2], fb[2]; vu4 ua[2];
    #pragma unroll
    for (int r2 = 0; r2 < 2; r2++){
      int slot = t + r2 * 256;
      int row = slot >> 2, kq = slot & 3;
      int k = k0 + kq * 8;
      Seg4 sg = z.sg[0];
      if (k >= sg.K){ k -= sg.K; sg = z.sg[1];
        if (k >= sg.K){ k -= sg.K; sg = z.sg[2];
          if (k >= sg.K){ k -= sg.K; sg = z.sg[3]; } } }
      rowv[r2] = row; kqv2[r2] = kq; isf[r2] = sg.f32;
      if (sg.f32){
        const float* ap = (const float*)sg.p + (size_t)row * sg.ld + k;
        if (sg.nt) ld32_nw(ap, fa[r2], fb[r2]);
        else { fa[r2] = *(const vf4*)ap; fb[r2] = *(const vf4*)(ap + 4); }
      } else {
        const u16* up = (const u16*)sg.p + (size_t)row * sg.ld + k;
        if (sg.nt) ld16_nw(up, ua[r2]);
        else ua[r2] = *(const vu4*)up;
      }
    }
    vm_drain();
    #pragma unroll
    for (int r2 = 0; r2 < BN/64; r2++) *(vu4*)&Bl[bidx[r2]] = bvv[r2];
    #pragma unroll
    for (int r2 = 0; r2 < 2; r2++){
      vu4 v = isf[r2] ? cvt8v(fa[r2], fb[r2]) : ua[r2];
      *(vu4*)&Al[(((rowv[r2] >> 4) << 6) + (kqv2[r2] << 4) + (rowv[r2] & 15)) * 8] = v;
    }
    __syncthreads();
    bfrag af[FRS], bv[4];
    #pragma unroll
    for (int fr = 0; fr < FRS; fr++) af[fr] = *(bfrag*)&Al[(((rowbase >> 4) + fr) * 64 + lane) * 8];
    #pragma unroll
    for (int fc = 0; fc < 4; fc++) bv[fc] = *(bfrag*)&Bl[(((lane >> 4) * BN) + wn * 64 + fc * 16 + (lane & 15)) * 8];
    #pragma unroll
    for (int fr = 0; fr < FRS; fr++)
      #pragma unroll
      for (int fc = 0; fc < 4; fc++)
        acc[fr][fc] = __builtin_amdgcn_mfma_f32_16x16x32_bf16(af[fr], bv[fc], acc[fr][fc], 0, 0, 0);
    __syncthreads();
  }

  float* Cf = z.Cp + (size_t)ks * z.cslab;
  #pragma unroll
  for (int fc = 0; fc < 4; fc++){
    int n = tn * BN + wn * 64 + fc * 16 + (lane & 15);
    if (n >= z.N) continue;
    float bs = z.bias ? z.bias[n] : 0.f;
    #pragma unroll
    for (int fr = 0; fr < FRS; fr++){
      #pragma unroll
      for (int i = 0; i < 4; i++){
        int m = rowbase + fr * 16 + ((lane >> 4) << 2) + i;
        st4_sys(&Cf[(size_t)m * z.ldc + n], acc[fr][fc][i] + bs);
      }
    }
  }
}

// ================ device-side fused GRU step (h@Whh MFMA + epilogue) ================
// MODE 1 = pointer unit (gi from ptr(B,8)@Wih); MODE 2 = decoder (gi = 4 K-split slabs)
// h state (hb/hf in, hnf/hnb out) is cross-block communicated -> sys access.
template<int MODE>
DEVI void dev_gru3(int g0, const u16* hb, const float* hf, const float* Whh,
                   const float* gi_f, const float* xp, const float* Wih,
                   const float* bih, const float* bhh,
                   float* hnf, u16* hnb, short* Al, short* Bl)
{
  int t = threadIdx.x, lane = t & 63, w = t >> 6;
  int wm = w >> 1, wn = w & 1;
  ffrag zz4 = {0.f, 0.f, 0.f, 0.f};
  ffrag acc[4][3];
  #pragma unroll
  for (int i = 0; i < 4; i++)
    #pragma unroll
    for (int j = 0; j < 3; j++) acc[i][j] = zz4;

  for (int k0 = 0; k0 < 512; k0 += 32){
    // ---- B (Whh, cached) loads issued first ----
    int lb0 = t >> 2, kq0b = t & 3;
    {
      int wn2 = lb0 / 48, rem = lb0 - wn2 * 48, fc = rem >> 4, i16 = rem & 15;
      int grow = fc * 512 + g0 + wn2 * 16 + i16;
      const float* wp = Whh + (size_t)grow * 512 + k0 + kq0b * 8;
      vf4 wa = *(const vf4*)wp, wb = *(const vf4*)(wp + 4);
      // ---- A (h, communicated) sys loads ----
      int rowA0 = t >> 2, kqA0 = t & 3;
      int rowA1 = (t + 256) >> 2, kqA1 = (t + 256) & 3;
      vu4 hv0, hv1;
      ld16_nw(hb + (size_t)rowA0 * 512 + k0 + kqA0 * 8, hv0);
      ld16_nw(hb + (size_t)rowA1 * 512 + k0 + kqA1 * 8, hv1);
      vf4 wa1, wb1; int lb1 = 0, kq1b = 0;
      if (t < 128){
        int slot = t + 256;
        lb1 = slot >> 2; kq1b = slot & 3;
        int wn21 = lb1 / 48, rem1 = lb1 - wn21 * 48, fc1 = rem1 >> 4, i161 = rem1 & 15;
        int grow1 = fc1 * 512 + g0 + wn21 * 16 + i161;
        const float* wp1 = Whh + (size_t)grow1 * 512 + k0 + kq1b * 8;
        wa1 = *(const vf4*)wp1; wb1 = *(const vf4*)(wp1 + 4);
      }
      vm_drain();
      *(vu4*)&Bl[(kq0b * 96 + lb0) * 8] = cvt8v(wa, wb);
      if (t < 128) *(vu4*)&Bl[(kq1b * 96 + lb1) * 8] = cvt8v(wa1, wb1);
      *(vu4*)&Al[(((rowA0 >> 4) << 6) + (kqA0 << 4) + (rowA0 & 15)) * 8] = hv0;
      *(vu4*)&Al[(((rowA1 >> 4) << 6) + (kqA1 << 4) + (rowA1 & 15)) * 8] = hv1;
    }
    __syncthreads();
    bfrag af[4], bv[3];
    #pragma unroll
    for (int fr = 0; fr < 4; fr++) af[fr] = *(bfrag*)&Al[((wm * 4 + fr) * 64 + lane) * 8];
    #pragma unroll
    for (int fc = 0; fc < 3; fc++) bv[fc] = *(bfrag*)&Bl[((lane >> 4) * 96 + (wn * 3 + fc) * 16 + (lane & 15)) * 8];
    #pragma unroll
    for (int fr = 0; fr < 4; fr++)
      #pragma unroll
      for (int fc = 0; fc < 3; fc++)
        acc[fr][fc] = __builtin_amdgcn_mfma_f32_16x16x32_bf16(af[fr], bv[fc], acc[fr][fc], 0, 0, 0);
    __syncthreads();
  }

  // MODE1: stage xp (PTRS slice, communicated) into LDS once
  float* xl = (float*)Al;
  if (MODE == 1){
    for (int i = t; i < 1024; i += 256) xl[i] = ld4f_sys(xp + i);
    __syncthreads();
  }

  int gcol = g0 + wn * 16 + (lane & 15);
  float bir = bih[gcol],        bhr = bhh[gcol];
  float biz = bih[512 + gcol],  bhz = bhh[512 + gcol];
  float bin = bih[1024 + gcol], bhn = bhh[1024 + gcol];
  float wxr[8], wxz[8], wxn[8];
  if (MODE == 1){
    #pragma unroll
    for (int a2 = 0; a2 < 8; a2++){
      wxr[a2] = Wih[(size_t)gcol * 8 + a2];
      wxz[a2] = Wih[(size_t)(512 + gcol) * 8 + a2];
      wxn[a2] = Wih[(size_t)(1024 + gcol) * 8 + a2];
    }
  }
  #pragma unroll
  for (int fr = 0; fr < 4; fr++){
    #pragma unroll
    for (int i = 0; i < 4; i++){
      int brow = wm * 64 + fr * 16 + ((lane >> 4) << 2) + i;
      float gr_, gz_, gn_;
      if (MODE == 2){
        gr_ = gz_ = gn_ = 0.f;
        #pragma unroll
        for (int sl = 0; sl < 4; sl++){
          const float* gp = gi_f + (size_t)sl * 196608 + (size_t)brow * 1536;
          gr_ += ld4f_sys(gp + gcol); gz_ += ld4f_sys(gp + 512 + gcol); gn_ += ld4f_sys(gp + 1024 + gcol);
        }
      } else {
        float4 x0 = *(float4*)&xl[brow * 8];
        float4 x1 = *(float4*)&xl[brow * 8 + 4];
        float xa[8] = {x0.x, x0.y, x0.z, x0.w, x1.x, x1.y, x1.z, x1.w};
        gr_ = gz_ = gn_ = 0.f;
        #pragma unroll
        for (int a2 = 0; a2 < 8; a2++){ gr_ += xa[a2]*wxr[a2]; gz_ += xa[a2]*wxz[a2]; gn_ += xa[a2]*wxn[a2]; }
      }
      float hold = ld4f_sys(hf + (size_t)brow * 512 + gcol);
      float r  = sigmf_(gr_ + acc[fr][0][i] + bir + bhr);
      float zg = sigmf_(gz_ + acc[fr][1][i] + biz + bhz);
      float n  = tanhf_(gn_ + bin + r * (acc[fr][2][i] + bhn));
      float hn = (1.f - zg) * n + zg * hold;
      size_t idx = (size_t)brow * 512 + gcol;
      st4_sys(hnf + idx, hn);
      st2_sys(hnb + idx, f2b(hn));
    }
  }
}

// ================ device-side attention pieces ================
DEVI void dev_puattn(int b, const float* hida2, const float* Ka, const float* cae,
                     const float* Am, const float* Ain, const u16* enc,
                     float* vpre, float* ptrs, float* fs)
{
  int t = threadIdx.x, lane = t & 63, w = t >> 6;
  float* sc0 = fs; float* sc1 = fs + 256;
  float* wred = fs + 512;   // 36
  float* qa   = fs + 560;   // 20
  float* cd   = fs + 584;   // 16
  float* red  = fs + 604;   // 8

  for (int u = 0; u < 2; u++){
    const float* hp = hida2 + ((size_t)u * 128 + b) * 512;
    float hv0 = ld4f_sys(hp + t), hv1 = ld4f_sys(hp + t + 256);
    const float* k0p = Ka + u * 8192 + t * 16;
    const float* k1p = Ka + u * 8192 + (t + 256) * 16;
    float p[9];
    #pragma unroll
    for (int j = 0; j < 9; j++) p[j] = hv0 * k0p[j] + hv1 * k1p[j];
    #pragma unroll
    for (int j = 0; j < 9; j++){
      #pragma unroll
      for (int off = 32; off > 0; off >>= 1) p[j] += __shfl_xor(p[j], off);
    }
    if (lane == 0){
      #pragma unroll
      for (int j = 0; j < 9; j++) wred[w * 9 + j] = p[j];
    }
    __syncthreads();
    if (t < 9) qa[u * 10 + t] = wred[t] + wred[9 + t] + wred[18 + t] + wred[27 + t] + cae[u * 16 + t];
    __syncthreads();
  }

  float su[2];
  #pragma unroll
  for (int u = 0; u < 2; u++){
    const float* amp = Am + (((size_t)u * 256 + t) * 128 + b) * 8;
    float4 a0 = *(const float4*)amp;
    float4 a1 = *(const float4*)(amp + 4);
    const float* q = qa + u * 10;
    su[u] = (q[8] + q[0]*a0.x + q[1]*a0.y + q[2]*a0.z + q[3]*a0.w
                  + q[4]*a1.x + q[5]*a1.y + q[6]*a1.z + q[7]*a1.w) * SCALE_ATT;
  }

  const float* ap = Ain + ((size_t)b * 256 + t) * 8;
  float av[8];
  {
    float4 v0 = *(const float4*)ap;
    float4 v1 = *(const float4*)(ap + 4);
    av[0]=v0.x; av[1]=v0.y; av[2]=v0.z; av[3]=v0.w;
    av[4]=v1.x; av[5]=v1.y; av[6]=v1.z; av[7]=v1.w;
  }

  float inv[2];
  for (int u = 0; u < 2; u++){
    float s_ = su[u];
    float* sc = u ? sc1 : sc0;
    // wave-level max + 4-way combine (2 syncs, no LDS tree)
    float m = s_;
    #pragma unroll
    for (int off = 32; off > 0; off >>= 1) m = fmaxf(m, __shfl_xor(m, off));
    if (lane == 0) red[w] = m;
    __syncthreads();
    float mx = fmaxf(fmaxf(red[0], red[1]), fmaxf(red[2], red[3]));
    float e = __expf(s_ - mx); sc[t] = e;
    // joint shuffle reduce: denominator + 8 pointer-address components (no LDS atomics)
    float ca[9];
    ca[8] = e;
    #pragma unroll
    for (int a2 = 0; a2 < 8; a2++) ca[a2] = e * av[a2];
    #pragma unroll
    for (int j = 0; j < 9; j++){
      #pragma unroll
      for (int off = 32; off > 0; off >>= 1) ca[j] += __shfl_xor(ca[j], off);
    }
    if (lane == 0){
      #pragma unroll
      for (int j = 0; j < 9; j++) wred[w * 9 + j] = ca[j];
    }
    __syncthreads();
    if (t < 9){
      float v = wred[t] + wred[9 + t] + wred[18 + t] + wred[27 + t];
      if (t < 8) cd[u * 8 + t] = v;
      else red[4 + u] = v;
    }
    __syncthreads();
    inv[u] = 1.f / red[4 + u];
  }
  if (t < 8){
    st4_sys(&ptrs[((size_t)0 * 128 + b) * 8 + t], cd[t] * inv[0]);
    st4_sys(&ptrs[((size_t)128 + b) * 8 + t],     cd[8 + t] * inv[1]);
  }

  // value pass over ENC: thread t owns cols 2t,2t+1; deep unroll for MLP
  float a00 = 0.f, a01 = 0.f, a10 = 0.f, a11 = 0.f;
  const u16* ep = enc + (size_t)b * 512;
  #pragma unroll 16
  for (int s2 = 0; s2 < 256; s2++){
    float w0 = sc0[s2], w1 = sc1[s2];
    u32 pv = *(const u32*)(ep + (size_t)s2 * 65536 + 2 * t);
    float v0 = b2f((u16)pv);
    float v1 = b2f((u16)(pv >> 16));
    a00 += w0 * v0; a01 += w0 * v1; a10 += w1 * v0; a11 += w1 * v1;
  }
  float* vp = vpre + (size_t)b * 1024;
  st4_sys(&vp[2 * t], a00 * inv[0]);           st4_sys(&vp[2 * t + 1], a01 * inv[0]);
  st4_sys(&vp[512 + 2 * t], a10 * inv[1]);     st4_sys(&vp[512 + 2 * t + 1], a11 * inv[1]);
}

DEVI void dev_bahd(int b, const u16* eatt, const float* dpart, const float* vvec,
                   const u16* enc, float* ctx, float* fs)
{
  int t = threadIdx.x, lane = t & 63, w = t >> 6;
  float* dp = fs; float* vv = fs + 512; float* sc = fs + 1024; float* red = fs + 1280;
  dp[t] = ld4f_sys(dpart + (size_t)b * 512 + t);
  dp[t + 256] = ld4f_sys(dpart + (size_t)b * 512 + t + 256);
  vv[t] = vvec[t]; vv[t + 256] = vvec[t + 256];
  __syncthreads();
  float4 d0 = *(float4*)&dp[lane * 8], d1 = *(float4*)&dp[lane * 8 + 4];
  float4 v0 = *(float4*)&vv[lane * 8], v1 = *(float4*)&vv[lane * 8 + 4];
  // score pass: batch 8 independent row loads per wave (8x MLP)
  for (int sb = 0; sb < 256; sb += 32){
    uint4 vl[8];
    #pragma unroll
    for (int i = 0; i < 8; i++){
      int s = sb + i * 4 + w;
      vl[i] = *(const uint4*)(eatt + ((size_t)s * 128 + b) * 512 + lane * 8);
    }
    #pragma unroll
    for (int i = 0; i < 8; i++){
      const u16* h = (const u16*)&vl[i];
      float r = fmaxf(0.f, b2f(h[0]) + d0.x) * v0.x + fmaxf(0.f, b2f(h[1]) + d0.y) * v0.y
              + fmaxf(0.f, b2f(h[2]) + d0.z) * v0.z + fmaxf(0.f, b2f(h[3]) + d0.w) * v0.w
              + fmaxf(0.f, b2f(h[4]) + d1.x) * v1.x + fmaxf(0.f, b2f(h[5]) + d1.y) * v1.y
              + fmaxf(0.f, b2f(h[6]) + d1.z) * v1.z + fmaxf(0.f, b2f(h[7]) + d1.w) * v1.w;
      #pragma unroll
      for (int off = 32; off > 0; off >>= 1) r += __shfl_xor(r, off);
      if (lane == 0) sc[sb + i * 4 + w] = r;
    }
  }
  __syncthreads();
  float s0 = sc[t];
  float m = s0;
  #pragma unroll
  for (int off = 32; off > 0; off >>= 1) m = fmaxf(m, __shfl_xor(m, off));
  if (lane == 0) red[w] = m;
  __syncthreads();
  float mx = fmaxf(fmaxf(red[0], red[1]), fmaxf(red[2], red[3]));
  float e = __expf(s0 - mx); sc[t] = e;
  float sum = e;
  #pragma unroll
  for (int off = 32; off > 0; off >>= 1) sum += __shfl_xor(sum, off);
  if (lane == 0) red[4 + w] = sum;
  __syncthreads();
  float inv = 1.f / (red[4] + red[5] + red[6] + red[7]);
  float a0 = 0.f, a1 = 0.f;
  const u16* ep = enc + (size_t)b * 512;
  #pragma unroll 16
  for (int s2 = 0; s2 < 256; s2++){
    float wgt = sc[s2];
    u32 pv = *(const u32*)(ep + (size_t)s2 * 65536 + 2 * t);
    a0 += wgt * b2f((u16)pv);
    a1 += wgt * b2f((u16)(pv >> 16));
  }
  st4_sys(&ctx[(size_t)b * 512 + 2 * t], a0 * inv);
  st4_sys(&ctx[(size_t)b * 512 + 2 * t + 1], a1 * inv);
}

DEVI void dev_cattn(int b, const float* qck, const u16* enc, float* cv2p, float* fs)
{
  int t = threadIdx.x, lane = t & 63, w = t >> 6;
  float* qv = fs; float* sc = fs + 1024; float* red = fs + 1280;
  qv[t] = ld4f_sys(qck + (size_t)b * 520 + t);
  qv[t + 256] = ld4f_sys(qck + (size_t)b * 520 + t + 256);
  __syncthreads();
  float qc0 = ld4f_sys(qck + (size_t)b * 520 + 512);
  float4 q0 = *(float4*)&qv[lane * 8], q1 = *(float4*)&qv[lane * 8 + 4];
  for (int sb = 0; sb < 256; sb += 32){
    uint4 vl[8];
    #pragma unroll
    for (int i = 0; i < 8; i++){
      int s = sb + i * 4 + w;
      vl[i] = *(const uint4*)(enc + ((size_t)s * 128 + b) * 512 + lane * 8);
    }
    #pragma unroll
    for (int i = 0; i < 8; i++){
      const u16* h = (const u16*)&vl[i];
      float r = b2f(h[0])*q0.x + b2f(h[1])*q0.y + b2f(h[2])*q0.z + b2f(h[3])*q0.w
              + b2f(h[4])*q1.x + b2f(h[5])*q1.y + b2f(h[6])*q1.z + b2f(h[7])*q1.w;
      #pragma unroll
      for (int off = 32; off > 0; off >>= 1) r += __shfl_xor(r, off);
      if (lane == 0) sc[sb + i * 4 + w] = (r + qc0) * SCALE_ATT;
    }
  }
  __syncthreads();
  float s0 = sc[t];
  float m = s0;
  #pragma unroll
  for (int off = 32; off > 0; off >>= 1) m = fmaxf(m, __shfl_xor(m, off));
  if (lane == 0) red[w] = m;
  __syncthreads();
  float mx = fmaxf(fmaxf(red[0], red[1]), fmaxf(red[2], red[3]));
  float e = __expf(s0 - mx); sc[t] = e;
  float sum = e;
  #pragma unroll
  for (int off = 32; off > 0; off >>= 1) sum += __shfl_xor(sum, off);
  if (lane == 0) red[4 + w] = sum;
  __syncthreads();
  float inv = 1.f / (red[4] + red[5] + red[6] + red[7]);
  float a0 = 0.f, a1 = 0.f;
  const u16* ep = enc + (size_t)b * 512;
  #pragma unroll 16
  for (int s2 = 0; s2 < 256; s2++){
    float wgt = sc[s2];
    u32 pv = *(const u32*)(ep + (size_t)s2 * 65536 + 2 * t);
    a0 += wgt * b2f((u16)pv);
    a1 += wgt * b2f((u16)(pv >> 16));
  }
  st4_sys(&cv2p[(size_t)b * 512 + 2 * t], a0 * inv);
  st4_sys(&cv2p[(size_t)b * 512 + 2 * t + 1], a1 * inv);
}

DEVI void dev_outcvt(int b, const float* outt, const float* outb2, float* dst)
{
  int t = threadIdx.x;
  #pragma unroll
  for (int rep = 0; rep < 2; rep++){
    int o = t + rep * 256;
    float s = ld4f_sys(outt + (size_t)b * 512 + o) + ld4f_sys(outt + 65536 + (size_t)b * 512 + o)
            + ld4f_sys(outt + 131072 + (size_t)b * 512 + o) + ld4f_sys(outt + 196608 + (size_t)b * 512 + o);
    dst[(size_t)b * 512 + o] = s + outb2[o];   // final output: flushed at kernel end
  }
}

// ================ persistent encoder (32 steps per launch, manual barrier) ================
struct EncArgs {
  const float *WhhF, *WhhB, *giF, *giB;
  const float *bihF, *bhhF, *bihB, *bhhB;
  float *HF, *HB; u16 *HFB, *HBB, *ENC;
  u32 *BAR; int bar0;
  int s0;
};

__global__ __launch_bounds__(256) void k_enc(EncArgs a)
{
  __shared__ short Bw[24576];   // 48 rows (3 gates x 16 cols) x 512 K, bf16, MFMA layout
  __shared__ short Al[4096];
  int blk = blockIdx.x;
  int d = blk >> 5, gt = blk & 31;
  int t = threadIdx.x, lane = t & 63, w = t >> 6;

  const float* Whh = d ? a.WhhB : a.WhhF;
  for (int c = t; c < 3072; c += 256){
    int brow = c >> 6, kc = c & 63;
    int grow = (brow >> 4) * 512 + gt * 16 + (brow & 15);
    const float* wp = Whh + (size_t)grow * 512 + kc * 8;
    *(uint4*)&Bw[((kc * 48) + brow) * 8] = cvt8(*(const float4*)wp, *(const float4*)(wp + 4));
  }
  const float* bih = d ? a.bihB : a.bihF;
  const float* bhh = d ? a.bhhB : a.bhhF;
  int gcol = gt * 16 + (lane & 15);
  float bir = bih[gcol],        bhr = bhh[gcol];
  float biz = bih[512 + gcol],  bhz = bhh[512 + gcol];
  float bin = bih[1024 + gcol], bhn = bhh[1024 + gcol];
  float* hf_base = d ? a.HB : a.HF;
  u16*   hb_base = d ? a.HBB : a.HFB;
  const float* gi_base = d ? a.giB : a.giF;
  __syncthreads();

  for (int si = 0; si < 32; si++){
    int s = a.s0 + si;
    const u16* hb = hb_base + (size_t)(s & 1) * 65536;
    const float* hf = hf_base + (size_t)(s & 1) * 65536;
    float* hnf = hf_base + (size_t)((s + 1) & 1) * 65536;
    u16* hnb = hb_base + (size_t)((s + 1) & 1) * 65536;
    u16* eacc = a.ENC + (size_t)(d ? 255 - s : s) * 65536;

    ffrag zz4 = {0.f, 0.f, 0.f, 0.f};
    ffrag acc[2][3];
    #pragma unroll
    for (int i = 0; i < 2; i++)
      #pragma unroll
      for (int j = 0; j < 3; j++) acc[i][j] = zz4;

    for (int ki = 0; ki < 16; ki++){
      int k0 = ki * 32;
      // h state is cross-block communicated -> sys loads, one drain
      int row0 = t >> 2, kq0 = t & 3;
      int row1 = (t + 256) >> 2, kq1 = (t + 256) & 3;
      vu4 hv0, hv1;
      ld16_nw(hb + (size_t)row0 * 512 + k0 + kq0 * 8, hv0);
      ld16_nw(hb + (size_t)row1 * 512 + k0 + kq1 * 8, hv1);
      vm_drain();
      *(vu4*)&Al[(((row0 >> 4) << 6) + (kq0 << 4) + (row0 & 15)) * 8] = hv0;
      *(vu4*)&Al[(((row1 >> 4) << 6) + (kq1 << 4) + (row1 & 15)) * 8] = hv1;
      __syncthreads();
      bfrag af[2], bv[3];
      #pragma unroll
      for (int fr = 0; fr < 2; fr++) af[fr] = *(bfrag*)&Al[(((w * 2 + fr) * 64) + lane) * 8];
      #pragma unroll
      for (int fc = 0; fc < 3; fc++) bv[fc] = *(bfrag*)&Bw[(((ki * 4 + (lane >> 4)) * 48) + fc * 16 + (lane & 15)) * 8];
      #pragma unroll
      for (int fr = 0; fr < 2; fr++)
        #pragma unroll
        for (int fc = 0; fc < 3; fc++)
          acc[fr][fc] = __builtin_amdgcn_mfma_f32_16x16x32_bf16(af[fr], bv[fc], acc[fr][fc], 0, 0, 0);
      __syncthreads();
    }

    const float* gp0 = gi_base + (size_t)si * 196608;
    #pragma unroll
    for (int fr = 0; fr < 2; fr++){
      #pragma unroll
      for (int i = 0; i < 4; i++){
        int brow = w * 32 + fr * 16 + ((lane >> 4) << 2) + i;
        const float* gp = gp0 + (size_t)brow * 1536;
        float gr_ = gp[gcol], gz_ = gp[512 + gcol], gn_ = gp[1024 + gcol];
        float hold = ld4f_sys(hf + (size_t)brow * 512 + gcol);
        float r  = sigmf_(gr_ + acc[fr][0][i] + bir + bhr);
        float zg = sigmf_(gz_ + acc[fr][1][i] + biz + bhz);
        float n  = tanhf_(gn_ + bin + r * (acc[fr][2][i] + bhn));
        float hn = (1.f - zg) * n + zg * hold;
        size_t idx = (size_t)brow * 512 + gcol;
        st4_sys(hnf + idx, hn);
        st2_sys(hnb + idx, f2b(hn));
        eacc[idx] = f2b(b2f(eacc[idx]) + hn);   // block-private slice; cross-launch coherence only
      }
    }
    gridbar2(a.BAR + BAR_ENCF, a.BAR + BAR_ENCGO, (u32)(a.s0 + si + 1), 64, blk, 0);
  }
}

// ================ persistent decoder (all 64 steps, manual barrier) ================
struct DecArgs {
  const float *tgt, *Ag, *AM, *KA, *CAE, *dattW, *dattv;
  const float *puWhh, *puWih, *pubih, *pubhh;
  const float *dWhh, *DBIH2, *dbhh, *VKE2, *OUTB2;
  const u16 *ENC, *EATT, *DWF, *MKTW, *OWF;
  float *HIDA; u16 *HIDAB;
  float *DECH; u16 *DECHB;
  float *HF0; u16 *HFB0;
  float *PTRS, *VPRE, *CTX, *DPART, *QCK, *CV2P, *GIDEC, *OUTT, *out;
  u32 *BAR;
};

__global__ __launch_bounds__(256) void k_dec(DecArgs a)
{
  __shared__ short Al[4096];
  __shared__ short Bl[4096];
  __shared__ float fs[1600];
  const int blk = blockIdx.x;
  const Seg4 S4SENT = {nullptr, 0, 0, 1 << 30, 0};
  u32* dF = a.BAR + BAR_DECF;
  u32* dG = a.BAR + BAR_DECGO;
  const int GATHER = 200;   // busy only in phase B -> polls start early in other phases

  for (int st = 0; st < 64; st++){
    const float* hida_c  = a.HIDA  + (size_t)(st & 1) * 131072;
    float*       hida_n  = a.HIDA  + (size_t)((st + 1) & 1) * 131072;
    const u16*   hidab_c = a.HIDAB + (size_t)(st & 1) * 131072;
    u16*         hidab_n = a.HIDAB + (size_t)((st + 1) & 1) * 131072;
    const float* dech_c  = (st == 0) ? a.HF0  : a.DECH  + (size_t)((st + 1) & 1) * 65536;
    const u16*   dechb_c = (st == 0) ? a.HFB0 : a.DECHB + (size_t)((st + 1) & 1) * 65536;
    float*       dech_n  = a.DECH  + (size_t)(st & 1) * 65536;
    u16*         dechb_n = a.DECHB + (size_t)(st & 1) * 65536;
    u32 seq0 = (u32)(st * 5);

    // ---- phase A: pu GRUs | dpart GEMM | outcvt(st-1)
    if (blk < 32){
      int u = blk >> 4, g0 = (blk & 15) * 32;
      dev_gru3<1>(g0, hidab_c + (size_t)u * 65536, hida_c + (size_t)u * 65536,
                  a.puWhh + (size_t)u * 786432, nullptr,
                  a.PTRS + u * 1024, a.puWih + (size_t)u * 12288,
                  a.pubih + u * 1536, a.pubhh + u * 1536,
                  hida_n + (size_t)u * 65536, hidab_n + (size_t)u * 65536, Al, Bl);
    } else if (blk < 40){
      Z4 z;
      z.sg[0] = {dechb_c, 512, 0, 512, 1}; z.sg[1] = S4SENT; z.sg[2] = S4SENT; z.sg[3] = S4SENT;
      z.Bp = a.dattW; z.ldb = 1024; z.bf32 = 1; z.bias = nullptr;
      z.Cp = a.DPART; z.ldc = 512; z.cslab = 0; z.N = 512; z.K = 512;
      dev_mfma4<64>(z, blk - 32, 0, 1, Al, Bl);
    } else if (blk < 168 && st > 0){
      dev_outcvt(blk - 40, a.OUTT, a.OUTB2, a.out + (size_t)(st - 1) * 65536);
    }
    gridbar2(dF, dG, seq0 + 1, 256, blk, GATHER);

    // ---- phase B: pointer attention (both units) | Bahdanau
    if (blk < 128){
      dev_puattn(blk, hida_n, a.KA, a.CAE, a.AM, a.Ag, a.ENC, a.VPRE, a.PTRS, fs);
    } else {
      dev_bahd(blk - 128, a.EATT, a.DPART, a.dattv, a.ENC, a.CTX, fs);
    }
    gridbar2(dF, dG, seq0 + 2, 256, blk, GATHER);

    // ---- phase C: decoder gi GEMM (folded Wih) | qck GEMM (folded)
    if (blk < 48){
      Z4 z;
      z.sg[0] = {a.tgt + (size_t)(st ? st - 1 : 0) * 65536, 512, 1, 512, 0};
      z.sg[1] = {a.VPRE, 1024, 1, 1024, 1};
      z.sg[2] = {a.CTX, 512, 1, 512, 1};
      z.sg[3] = S4SENT;
      z.Bp = a.DWF; z.ldb = 2048; z.bf32 = 0; z.bias = nullptr;
      z.Cp = a.GIDEC; z.ldc = 1536; z.cslab = 196608; z.N = 1536; z.K = 2048;
      dev_mfma4<128>(z, blk % 12, blk / 12, 4, Al, Bl);
    } else if (blk < 57){
      Z4 z;
      z.sg[0] = {a.VPRE, 1024, 1, 1024, 1}; z.sg[1] = S4SENT; z.sg[2] = S4SENT; z.sg[3] = S4SENT;
      z.Bp = a.MKTW; z.ldb = 1024; z.bf32 = 0; z.bias = a.VKE2;
      z.Cp = a.QCK; z.ldc = 520; z.cslab = 0; z.N = 513; z.K = 1024;
      dev_mfma4<64>(z, blk - 48, 0, 1, Al, Bl);
    }
    gridbar2(dF, dG, seq0 + 3, 256, blk, GATHER);

    // ---- phase D: decoder GRU combine | content attention
    if (blk < 16){
      dev_gru3<2>(blk * 32, dechb_c, dech_c, a.dWhh, a.GIDEC, nullptr, nullptr,
                  a.DBIH2, a.dbhh, dech_n, dechb_n, Al, Bl);
    } else if (blk < 144){
      dev_cattn(blk - 16, a.QCK, a.ENC, a.CV2P, fs);
    }
    gridbar2(dF, dG, seq0 + 4, 256, blk, GATHER);

    // ---- phase E: folded output head GEMM (K=2560, split-K 4)
    if (blk < 32){
      Z4 z;
      z.sg[0] = {dechb_n, 512, 0, 512, 1};
      z.sg[1] = {a.CTX, 512, 1, 512, 1};
      z.sg[2] = {a.VPRE, 1024, 1, 1024, 1};
      z.sg[3] = {a.CV2P, 512, 1, 512, 1};
      z.Bp = a.OWF; z.ldb = 2560; z.bf32 = 0; z.bias = nullptr;
      z.Cp = a.OUTT; z.ldc = 512; z.cslab = 65536; z.N = 512; z.K = 2560;
      dev_mfma4<64>(z, blk & 7, blk >> 3, 4, Al, Bl);
    }
    gridbar2(dF, dG, seq0 + 5, 256, blk, GATHER);
  }
  if (blk < 128) dev_outcvt(blk, a.OUTT, a.OUTB2, a.out + 63ull * 65536);
}

// ================ setup: batched fold jobs ================
struct Job {
  const float* A; const float* B; const float* D; void* C;
  int Asm, Ask, Bsk, Bsn, Dsm, Dsn, Csm, Csn;
  int cbf, M, N, K, kind;
};
struct Jobs { Job j[24]; int nj; long long off[25]; };

__global__ __launch_bounds__(256) void k_setup(Jobs J)
{
  long long total = J.off[J.nj];
  for (long long tid = (long long)blockIdx.x * 256 + threadIdx.x; tid < total; tid += (long long)gridDim.x * 256){
    int ji = 0;
    while (tid >= J.off[ji + 1]) ji++;
    Job jb = J.j[ji];
    long long l = tid - J.off[ji];
    if (jb.kind == 0){
      int m = (int)(l / jb.N), n = (int)(l - (long long)m * jb.N);
      float acc = 0.f;
      const float* ap = jb.A + (size_t)m * jb.Asm;
      const float* bp = jb.B + (size_t)n * jb.Bsn;
      for (int k = 0; k < jb.K; k++)
        acc += ap[(size_t)k * jb.Ask] * bp[(size_t)k * jb.Bsk];
      if (jb.D) acc += jb.D[(size_t)m * jb.Dsm + (size_t)n * jb.Dsn];
      if (jb.cbf) ((u16*)jb.C)[(size_t)m * jb.Csm + (size_t)n * jb.Csn] = f2b(acc);
      else ((float*)jb.C)[(size_t)m * jb.Csm + (size_t)n * jb.Csn] = acc;
    } else if (jb.kind == 1){
      int m = (int)(l / jb.N), n = (int)(l - (long long)m * jb.N);
      ((u16*)jb.C)[(size_t)m * jb.Csm + (size_t)n * jb.Csn] = f2b(jb.A[(size_t)m * jb.Asm + (size_t)n * jb.Ask]);
    } else if (jb.kind == 2){
      int u = (int)(l >> 15), sb = (int)(l & 32767);
      float x[8];
      #pragma unroll
      for (int a2 = 0; a2 < 8; a2++) x[a2] = jb.A[(size_t)sb * 8 + a2];
      float* op = (float*)jb.C + ((size_t)u * 32768 + sb) * 8;
      #pragma unroll
      for (int c = 0; c < 8; c++){
        float acc = jb.D[u * 8 + c];
        #pragma unroll
        for (int a2 = 0; a2 < 8; a2++) acc += x[a2] * jb.B[(u * 8 + c) * 8 + a2];
        op[c] = acc;
      }
    } else {
      int u = (int)(l >> 10), r = (int)(l & 1023);
      int bb = r >> 3, aa = r & 7;
      int su = u ? 255 : 0;
      ((float*)jb.C)[l] = jb.A[((size_t)su * 128 + bb) * 8 + aa];
    }
  }
}

// ================ host ================
static inline Seg mkseg(const void* p, int ld, int f32, int K){ Seg s; s.p = p; s.ld = ld; s.f32 = f32; s.K = K; return s; }
static const Seg SENT = {nullptr, 0, 0, 1 << 30};

static inline void addJ(Jobs& JS, Job jb, long long cnt){
  JS.j[JS.nj] = jb;
  JS.off[JS.nj + 1] = JS.off[JS.nj] + cnt;
  JS.nj++;
}
static inline Job JG(const float* A, int Asm, int Ask, const float* B, int Bsk, int Bsn,
                     const float* D, int Dsm, int Dsn, void* C, int Csm, int Csn,
                     int cbf, int M, int N, int K, int kind = 0){
  Job j; j.A=A; j.B=B; j.D=D; j.C=C; j.Asm=Asm; j.Ask=Ask; j.Bsk=Bsk; j.Bsn=Bsn;
  j.Dsm=Dsm; j.Dsn=Dsn; j.Csm=Csm; j.Csn=Csn; j.cbf=cbf; j.M=M; j.N=N; j.K=K; j.kind=kind;
  return j;
}

extern "C" void kernel_launch(void* const* d_in, const int* in_sizes, int n_in,
                              void* d_out, int out_size, void* d_ws, size_t ws_size,
                              hipStream_t stream)
{
  (void)in_sizes; (void)out_size;
  if (n_in < 44 || ws_size < WS_NEED) return;

  const float* src   = (const float*)d_in[0];
  const float* tgt   = (const float*)d_in[1];
  const float* Ag    = (const float*)d_in[2];
  const float* eWihF = (const float*)d_in[3];
  const float* eWhhF = (const float*)d_in[4];
  const float* ebihF = (const float*)d_in[5];
  const float* ebhhF = (const float*)d_in[6];
  const float* eWihB = (const float*)d_in[7];
  const float* eWhhB = (const float*)d_in[8];
  const float* ebihB = (const float*)d_in[9];
  const float* ebhhB = (const float*)d_in[10];
  const float* dattW = (const float*)d_in[11];
  const float* dattb = (const float*)d_in[12];
  const float* dattv = (const float*)d_in[13];
  const float* dWih  = (const float*)d_in[14];
  const float* dWhh  = (const float*)d_in[15];
  const float* dbih  = (const float*)d_in[16];
  const float* dbhh  = (const float*)d_in[17];
  const float* doW   = (const float*)d_in[18];
  const float* dob   = (const float*)d_in[19];
  const float* puWih = (const float*)d_in[20];
  const float* puWhh = (const float*)d_in[21];
  const float* pubih = (const float*)d_in[22];
  const float* pubhh = (const float*)d_in[23];
  const float* puqW  = (const float*)d_in[24];
  const float* puqb  = (const float*)d_in[25];
  const float* puAW  = (const float*)d_in[26];
  const float* puAb  = (const float*)d_in[27];
  const float* puqp  = (const float*)d_in[28];
  const float* pukp  = (const float*)d_in[29];
  const float* puvp  = (const float*)d_in[30];
  const float* puinb = (const float*)d_in[31];
  const float* puop  = (const float*)d_in[32];
  const float* puob  = (const float*)d_in[33];
  const float* aaq   = (const float*)d_in[34];
  const float* aak   = (const float*)d_in[35];
  const float* aav   = (const float*)d_in[36];
  const float* aainb = (const float*)d_in[37];
  const float* aao   = (const float*)d_in[38];
  const float* aaob  = (const float*)d_in[39];
  const float* tohW  = (const float*)d_in[40];
  const float* tohb  = (const float*)d_in[41];
  const float* outW  = (const float*)d_in[42];
  const float* outb  = (const float*)d_in[43];

  char* ws = (char*)d_ws;
  float* GI    = (float*)(ws + OFF_GI);
  u16*   ENC   = (u16*)(ws + OFF_ENC);
  u16*   EATT  = (u16*)(ws + OFF_EATT);
  float* AM    = (float*)(ws + OFF_AM);
  float* HF    = (float*)(ws + OFF_HF);
  float* HB    = (float*)(ws + OFF_HB);
  u16*   HFB   = (u16*)(ws + OFF_HFB);
  u16*   HBB   = (u16*)(ws + OFF_HBB);
  float* HIDA  = (float*)(ws + OFF_HIDA);
  u16*   HIDAB = (u16*)(ws + OFF_HIDAB);
  u32*   BAR   = (u32*)(ws + OFF_BAR);
  float* DECH  = (float*)(ws + OFF_DECH);
  u16*   DECHB = (u16*)(ws + OFF_DECHB);
  float* PTRS  = (float*)(ws + OFF_PTRS);
  float* VPRE  = (float*)(ws + OFF_VPRE);
  float* CTX   = (float*)(ws + OFF_CTX);
  float* DPART = (float*)(ws + OFF_DPART);
  float* QCK   = (float*)(ws + OFF_QCK);
  float* CV2P  = (float*)(ws + OFF_CV2P);
  float* GIDEC = (float*)(ws + OFF_GIDEC);
  float* OUTT  = (float*)(ws + OFF_OUTT);
  float* WOVF  = (float*)(ws + OFF_WOVF);
  float* WOVCF = (float*)(ws + OFF_WOVCF);
  float* MKTF  = (float*)(ws + OFF_MKTF);
  u16*   DWF   = (u16*)(ws + OFF_DWF);
  u16*   MKTW  = (u16*)(ws + OFF_MKTW);
  u16*   OWF   = (u16*)(ws + OFF_OWF);
  float* BOV   = (float*)(ws + OFF_BOV);
  float* BOVC  = (float*)(ws + OFF_BOVC);
  float* KAx   = (float*)(ws + OFF_KA);
  float* CAE   = (float*)(ws + OFF_CAE);
  float* RT    = (float*)(ws + OFF_RT);
  float* BQC   = (float*)(ws + OFF_BQC);
  float* PMAT  = (float*)(ws + OFF_PMAT);
  float* CQ    = (float*)(ws + OFF_CQ);
  float* VKE2  = (float*)(ws + OFF_VKE2);
  float* DBIH2 = (float*)(ws + OFF_DBIH2);
  float* OUTB2 = (float*)(ws + OFF_OUTB2);

  hipMemsetAsync(ENC, 0, 2ull*256*128*512, stream);
  hipMemsetAsync(ws + OFF_HF, 0, OFF_ZEND - OFF_HF, stream);  // states + barrier flags

  // -------- stage 1: independent folds --------
  {
    Jobs S{}; S.nj = 0; S.off[0] = 0;
    for (int u = 0; u < 2; u++){
      const float* qp  = puqp + (size_t)u * 262144;
      const float* kp  = pukp + (size_t)u * 4096;
      float* RTu = RT + u * 8192;
      addJ(S, JG(qp, 1, 512, kp, 8, 1, nullptr, 0, 0, RTu, 16, 1, 0, 512, 8, 512), 4096);
      addJ(S, JG(qp, 1, 512, puinb + u*1536 + 512, 1, 0, nullptr, 0, 0, RTu + 8, 16, 1, 0, 512, 1, 512), 512);
      addJ(S, JG(qp, 512, 1, puqb + u*512, 1, 0, puinb + u*1536, 1, 0, BQC + u*512, 1, 1, 0, 512, 1, 512), 512);
      addJ(S, JG(puop + (size_t)u*262144, 512, 1, puvp + (size_t)u*262144, 512, 1, nullptr, 0, 0, WOVF + (size_t)u*262144, 512, 1, 0, 512, 512, 512), 262144);
      addJ(S, JG(puop + (size_t)u*262144, 512, 1, puinb + u*1536 + 1024, 1, 0, puob + u*512, 1, 0, BOV + u*512, 1, 1, 0, 512, 1, 512), 512);
    }
    addJ(S, JG(aao, 512, 1, aav, 512, 1, nullptr, 0, 0, WOVCF, 512, 1, 0, 512, 512, 512), 262144);
    addJ(S, JG(aao, 512, 1, aainb + 1024, 1, 0, aaob, 1, 0, BOVC, 1, 1, 0, 512, 1, 512), 512);
    addJ(S, JG(aaq, 1, 512, aak, 512, 1, nullptr, 0, 0, PMAT, 516, 1, 0, 512, 512, 512), 262144);
    addJ(S, JG(aaq, 1, 512, aainb + 512, 1, 0, nullptr, 0, 0, PMAT + 512, 516, 1, 0, 512, 1, 512), 512);
    addJ(S, JG(aaq, 512, 1, tohb, 1, 0, aainb, 1, 0, CQ, 1, 1, 0, 512, 1, 512), 512);
    addJ(S, JG(dWih, 2048, 1, nullptr, 0, 0, nullptr, 0, 0, DWF, 2048, 1, 1, 1536, 512, 0, 1), 786432);
    addJ(S, JG(dWih + 1536, 2048, 1, nullptr, 0, 0, nullptr, 0, 0, DWF + 1536, 2048, 1, 1, 1536, 512, 0, 1), 786432);
    addJ(S, JG(outW, 2048, 1, doW, 1024, 1, nullptr, 0, 0, OWF, 2560, 1, 1, 512, 1024, 512), 524288);
    addJ(S, JG(outW, 2048, 1, dob, 1, 0, outb, 1, 0, OUTB2, 1, 1, 0, 512, 1, 512), 512);
    addJ(S, JG(Ag, 0, 0, puAW, 0, 0, puAb, 0, 0, AM, 0, 0, 0, 0, 0, 0, 2), 65536);
    addJ(S, JG(Ag, 0, 0, nullptr, 0, 0, nullptr, 0, 0, PTRS, 0, 0, 0, 0, 0, 0, 3), 2048);
    k_setup<<<2048, 256, 0, stream>>>(S);
  }
  // -------- stage 2 --------
  {
    Jobs S{}; S.nj = 0; S.off[0] = 0;
    for (int u = 0; u < 2; u++){
      const float* kp = pukp + (size_t)u * 4096;
      addJ(S, JG(puqW + (size_t)u*262144, 1, 512, RT + u*8192, 16, 1, nullptr, 0, 0, KAx + u*8192, 16, 1, 0, 512, 9, 512), 4608);
      addJ(S, JG(BQC + u*512, 0, 1, kp, 8, 1, nullptr, 0, 0, CAE + u*16, 0, 1, 0, 1, 8, 512), 8);
      addJ(S, JG(BQC + u*512, 0, 1, puinb + u*1536 + 512, 1, 0, nullptr, 0, 0, CAE + u*16 + 8, 0, 1, 0, 1, 1, 512), 1);
      addJ(S, JG(dWih + 512 + u*512, 2048, 1, WOVF + (size_t)u*262144, 512, 1, nullptr, 0, 0, DWF + 512 + u*512, 2048, 1, 1, 1536, 512, 512), 786432);
      addJ(S, JG(outW + 512 + u*512, 2048, 1, WOVF + (size_t)u*262144, 512, 1, nullptr, 0, 0, OWF + 1024 + u*512, 2560, 1, 1, 512, 512, 512), 262144);
    }
    addJ(S, JG(tohW, 1, 1024, PMAT, 516, 1, nullptr, 0, 0, MKTF, 1, 1024, 0, 1024, 513, 512), 525312);
    addJ(S, JG(CQ, 0, 1, aak, 512, 1, nullptr, 0, 0, VKE2, 0, 1, 0, 1, 512, 512), 512);
    addJ(S, JG(CQ, 0, 1, aainb + 512, 1, 0, nullptr, 0, 0, VKE2 + 512, 0, 1, 0, 1, 1, 512), 1);
    addJ(S, JG(dWih + 512, 2048, 1, BOV, 1, 0, dbih, 1, 0, DBIH2, 1, 1, 0, 1536, 1, 1024), 1536);
    addJ(S, JG(outW + 1536, 2048, 1, WOVCF, 512, 1, nullptr, 0, 0, OWF + 2048, 2560, 1, 1, 512, 512, 512), 262144);
    addJ(S, JG(outW + 512, 2048, 1, BOV, 1, 0, OUTB2, 1, 0, OUTB2, 1, 1, 0, 512, 1, 1536), 512);
    k_setup<<<2048, 256, 0, stream>>>(S);
  }
  // -------- stage 3 --------
  {
    Jobs S{}; S.nj = 0; S.off[0] = 0;
    for (int u = 0; u < 2; u++)
      addJ(S, JG(MKTF + u*512, 1024, 1, WOVF + (size_t)u*262144, 512, 1, nullptr, 0, 0, MKTW + u*512, 1024, 1, 1, 513, 512, 512), 262656);
    addJ(S, JG(MKTF, 1024, 1, BOV, 1, 0, VKE2, 1, 0, VKE2, 1, 1, 0, 513, 1, 1024), 513);
    k_setup<<<1024, 256, 0, stream>>>(S);
  }

  // -------- encoder: 8 chunks of (gi GEMM + persistent 32-step scan) --------
  for (int c = 0; c < 8; c++){
    int c0 = c * 32;
    NTA nt{};
    nt.tilesN = 12;
    for (int d = 0; d < 2; d++){
      NTZ& zz = nt.z[d];
      zz.sg[0] = mkseg(d == 0 ? (const void*)(src + (size_t)c0 * 65536) : (const void*)src, 512, 1, 512);
      zz.sg[1] = SENT; zz.sg[2] = SENT;
      zz.Bp = d ? eWihB : eWihF; zz.ldb = 512; zz.bf32 = 1;
      zz.bias = nullptr; zz.biasf32 = 0;
      zz.Cp = GI + (size_t)d * 6291456; zz.ldc = 1536; zz.cf32 = 1; zz.cslab = 0;
      zz.N = 1536; zz.rev_s0 = (d == 0) ? -1 : (255 - c0); zz.K = 512;
    }
    k_mfma_nt<128><<<dim3(32*12, 1, 2), 256, 0, stream>>>(nt);

    EncArgs ea;
    ea.WhhF = eWhhF; ea.WhhB = eWhhB;
    ea.giF = GI; ea.giB = GI + 6291456;
    ea.bihF = ebihF; ea.bhhF = ebhhF; ea.bihB = ebihB; ea.bhhB = ebhhB;
    ea.HF = HF; ea.HB = HB; ea.HFB = HFB; ea.HBB = HBB; ea.ENC = ENC;
    ea.BAR = BAR; ea.bar0 = c * 32;
    ea.s0 = c0;
    k_enc<<<dim3(64), dim3(256), 0, stream>>>(ea);
  }

  // -------- enc_att = enc @ W2.T + b --------
  {
    NTA nt{};
    nt.tilesN = 4;
    NTZ& zz = nt.z[0];
    zz.sg[0] = mkseg(ENC, 512, 0, 512); zz.sg[1] = SENT; zz.sg[2] = SENT;
    zz.Bp = dattW + 512; zz.ldb = 1024; zz.bf32 = 1;
    zz.bias = dattb; zz.biasf32 = 1;
    zz.Cp = EATT; zz.ldc = 512; zz.cf32 = 0; zz.cslab = 0;
    zz.N = 512; zz.rev_s0 = -1; zz.K = 512;
    k_mfma_nt<128><<<dim3(256*4, 1, 1), 256, 0, stream>>>(nt);
  }

  // -------- decoder: one persistent kernel, all 64 steps --------
  {
    DecArgs da;
    da.tgt = tgt; da.Ag = Ag; da.AM = AM; da.KA = KAx; da.CAE = CAE;
    da.dattW = dattW; da.dattv = dattv;
    da.puWhh = puWhh; da.puWih = puWih; da.pubih = pubih; da.pubhh = pubhh;
    da.dWhh = dWhh; da.DBIH2 = DBIH2; da.dbhh = dbhh; da.VKE2 = VKE2; da.OUTB2 = OUTB2;
    da.ENC = ENC; da.EATT = EATT; da.DWF = DWF; da.MKTW = MKTW; da.OWF = OWF;
    da.HIDA = HIDA; da.HIDAB = HIDAB; da.DECH = DECH; da.DECHB = DECHB;
    da.HF0 = HF; da.HFB0 = HFB;
    da.PTRS = PTRS; da.VPRE = VPRE; da.CTX = CTX; da.DPART = DPART;
    da.QCK = QCK; da.CV2P = CV2P; da.GIDEC = GIDEC; da.OUTT = OUTT;
    da.out = (float*)d_out;
    da.BAR = BAR;
    k_dec<<<dim3(256), dim3(256), 0, stream>>>(da);
  }
}

// Round 6
// 20730.690 us; speedup vs baseline: 1.5258x; 1.1004x over previous
//
#include <hip/hip_runtime.h>

typedef unsigned short u16;
typedef unsigned int u32;

#define DEVI __device__ __forceinline__

constexpr float SCALE_ATT = 0.04419417382415922f;  // 1/sqrt(512)

// ---------------- workspace layout (bytes) ----------------
constexpr size_t OFF_GI    = 0;                                  // f32 [2][32][128][1536] per-chunk x@Wih
constexpr size_t OFF_ENC   = OFF_GI    + 4ull*2*32*128*1536;
constexpr size_t OFF_EATT  = OFF_ENC   + 2ull*256*128*512;       // bf16 enc, bf16 enc_att
constexpr size_t OFF_AM    = OFF_EATT  + 2ull*256*128*512;       // f32 [2][256][128][8]
constexpr size_t OFF_HF    = OFF_AM    + 4ull*2*256*128*8;       // ---- zero region start
constexpr size_t OFF_HB    = OFF_HF    + 4ull*2*128*512;
constexpr size_t OFF_HFB   = OFF_HB    + 4ull*2*128*512;
constexpr size_t OFF_HBB   = OFF_HFB   + 2ull*2*128*512;
constexpr size_t OFF_HIDA  = OFF_HBB   + 2ull*2*128*512;
constexpr size_t OFF_HIDAB = OFF_HIDA  + 4ull*2*2*128*512;
constexpr size_t OFF_BAR   = OFF_HIDAB + 2ull*2*2*128*512;       // u32 flag lines (see BAR_* below)
constexpr size_t OFF_ZEND  = OFF_BAR   + 49152;                  // ---- zero region end
constexpr size_t OFF_DECH  = OFF_ZEND;
constexpr size_t OFF_DECHB = OFF_DECH  + 4ull*2*128*512;
constexpr size_t OFF_PTRS  = OFF_DECHB + 2ull*2*128*512;         // f32 [2][128][8]
constexpr size_t OFF_VPRE  = OFF_PTRS  + 4ull*2*128*8;           // f32 [128][1024]  (b-major!)
constexpr size_t OFF_CTX   = OFF_VPRE  + 4ull*128*1024;
constexpr size_t OFF_DPART = OFF_CTX   + 4ull*128*512;
constexpr size_t OFF_QCK   = OFF_DPART + 4ull*128*512;           // f32 [128][520] (513 used)
constexpr size_t OFF_CV2P  = OFF_QCK   + 4ull*128*520;
constexpr size_t OFF_GIDEC = OFF_CV2P  + 4ull*128*512;           // f32 4 K-slabs [128][1536]
constexpr size_t OFF_OUTT  = OFF_GIDEC + 4ull*4*128*1536;        // f32 4 K-slabs [128][512]
constexpr size_t OFF_WOVF  = OFF_OUTT  + 4ull*4*128*512;         // f32 [2][512][512]
constexpr size_t OFF_WOVCF = OFF_WOVF  + 4ull*2*512*512;         // f32 [512][512]
constexpr size_t OFF_MKTF  = OFF_WOVCF + 4ull*512*512;           // f32 [513 rows][1024]
constexpr size_t OFF_DWF   = OFF_MKTF  + 4ull*513*1024;          // bf16 [1536][2048] folded dec Wih
constexpr size_t OFF_MKTW  = OFF_DWF   + 2ull*1536*2048;         // bf16 [513][1024] folded qck W
constexpr size_t OFF_OWF   = OFF_MKTW  + 2ull*513*1024;          // bf16 [512][2560] folded out W
constexpr size_t OFF_BOV   = OFF_OWF   + 2ull*512*2560;          // f32 [2][512]  (contiguous w/ BOVC!)
constexpr size_t OFF_BOVC  = OFF_BOV   + 4ull*2*512;             // f32 [512]
constexpr size_t OFF_KA    = OFF_BOVC  + 4ull*512;               // f32 [2][512][16] (9 used)
constexpr size_t OFF_CAE   = OFF_KA    + 4ull*2*512*16;          // f32 [2][16]
constexpr size_t OFF_RT    = OFF_CAE   + 4ull*2*16;              // f32 [2][512][16]
constexpr size_t OFF_BQC   = OFF_RT    + 4ull*2*512*16;          // f32 [2][512]
constexpr size_t OFF_PMAT  = OFF_BQC   + 4ull*2*512;             // f32 [512][516]
constexpr size_t OFF_CQ    = OFF_PMAT  + 4ull*512*516;
constexpr size_t OFF_VKE2  = OFF_CQ    + 4ull*512;               // f32 [520]
constexpr size_t OFF_DBIH2 = OFF_VKE2  + 4ull*520;               // f32 [1536]
constexpr size_t OFF_OUTB2 = OFF_DBIH2 + 4ull*1536;              // f32 [512]
constexpr size_t WS_NEED   = OFF_OUTB2 + 4ull*512;

// ---------------- helpers ----------------
DEVI float b2f(u16 u){ union{u32 i; float f;} x; x.i = ((u32)u) << 16; return x.f; }
DEVI u16 f2b(float f){ union{float f; u32 i;} x; x.f = f; u32 i = x.i; u32 r = i + 0x7FFFu + ((i >> 16) & 1u); return (u16)(r >> 16); }
DEVI float sigmf_(float x){ return 1.f / (1.f + __expf(-x)); }
DEVI float tanhf_(float x){ x = fminf(15.f, fmaxf(-15.f, x)); float e = __expf(2.f*x); return (e - 1.f) / (e + 1.f); }

typedef __attribute__((ext_vector_type(8))) short bfrag;
typedef __attribute__((ext_vector_type(4))) float ffrag;
typedef __attribute__((ext_vector_type(4))) unsigned int vu4;
typedef __attribute__((ext_vector_type(4))) float vf4;

DEVI uint4 cvt8(float4 a, float4 b){
  union{uint4 u; u16 h[8];} r;
  r.h[0]=f2b(a.x); r.h[1]=f2b(a.y); r.h[2]=f2b(a.z); r.h[3]=f2b(a.w);
  r.h[4]=f2b(b.x); r.h[5]=f2b(b.y); r.h[6]=f2b(b.z); r.h[7]=f2b(b.w);
  return r.u;
}
DEVI vu4 cvt8v(vf4 a, vf4 b){
  union{vu4 u; u16 h[8];} r;
  r.h[0]=f2b(a[0]); r.h[1]=f2b(a[1]); r.h[2]=f2b(a[2]); r.h[3]=f2b(a[3]);
  r.h[4]=f2b(b[0]); r.h[5]=f2b(b[1]); r.h[6]=f2b(b[2]); r.h[7]=f2b(b[3]);
  return r.u;
}

// ---- L2-bypassing (coherence-point) access primitives ----
DEVI void ld16_nw(const void* p, vu4& r){
  asm volatile("global_load_dwordx4 %0, %1, off sc0 sc1"
               : "=&v"(r) : "v"(p) : "memory");
}
DEVI void ld32_nw(const float* p, vf4& a, vf4& b){
  asm volatile("global_load_dwordx4 %0, %2, off sc0 sc1\n\t"
               "global_load_dwordx4 %1, %2, off offset:16 sc0 sc1"
               : "=&v"(a), "=&v"(b) : "v"(p) : "memory");
}
DEVI void vm_drain(){
  asm volatile("s_waitcnt vmcnt(0)" ::: "memory");
  __builtin_amdgcn_sched_barrier(0);   // rule #18
}
DEVI float ld4f_sys(const float* p){ return __hip_atomic_load(p, __ATOMIC_RELAXED, __HIP_MEMORY_SCOPE_SYSTEM); }
DEVI void st4_sys(float* p, float v){
  asm volatile("global_store_dword %0, %1, off sc0 sc1" :: "v"(p), "v"(v) : "memory");
}
DEVI void st2_sys(u16* p, u16 v){
  u32 w = v;
  asm volatile("global_store_short %0, %1, off sc0 sc1" :: "v"(p), "v"(w) : "memory");
}

// ---- all-store flag grid barrier (no RMW, no threadfence) ----
constexpr int GB_STRIDE  = 32;     // u32 per flag line (128B)
constexpr int BAR_DECF   = 0;      // 256 flags * 32 u32
constexpr int BAR_DECGO  = 8192;   // 1 line
constexpr int BAR_ENCF   = 8224;   // 64 flags * 32 u32
constexpr int BAR_ENCGO  = 10272;  // 1 line

DEVI u32 ld_sys(u32* p){ return __hip_atomic_load(p, __ATOMIC_RELAXED, __HIP_MEMORY_SCOPE_SYSTEM); }
DEVI void st_sys(u32* p, u32 v){ __hip_atomic_store(p, v, __ATOMIC_RELAXED, __HIP_MEMORY_SCOPE_SYSTEM); }

DEVI void gridbar2(u32* flags, u32* go, u32 seq, int nblk, int blk, int gblk)
{
  asm volatile("s_waitcnt vmcnt(0)" ::: "memory");   // per-wave: all sys stores committed
  __syncthreads();
  int t = threadIdx.x;
  if (blk == gblk){
    if (t == 0) st_sys(&flags[(u32)blk * GB_STRIDE], seq);
    if (t < nblk){
      u32* f = &flags[(u32)t * GB_STRIDE];
      while (ld_sys(f) < seq) __builtin_amdgcn_s_sleep(1);
    }
    __syncthreads();
    if (t == 0) st_sys(go, seq);
  } else {
    if (t == 0){
      st_sys(&flags[(u32)blk * GB_STRIDE], seq);
      while (ld_sys(go) < seq) __builtin_amdgcn_s_sleep(1);
    }
  }
  __syncthreads();
}

// ================ host-launched 3-seg NT GEMM (GI chunks + EATT) ================
struct Seg { const void* p; int ld; int f32; int K; };
struct NTZ {
  Seg sg[3];
  const void* Bp; int ldb; int bf32;
  const void* bias; int biasf32;
  void* Cp; int ldc; int cf32; int cslab;
  int N; int rev_s0; int K;
};
struct NTA { NTZ z[3]; int tilesN; };

template<int BN>
__global__ __launch_bounds__(256) void k_mfma_nt(NTA a)
{
  NTZ z = a.z[blockIdx.z];
  int tn = blockIdx.x % a.tilesN;
  int tm = blockIdx.x / a.tilesN;
  if (tn * BN >= z.N) return;
  int nks = gridDim.y;
  int kb = blockIdx.y * (z.K / nks);
  int ke = kb + z.K / nks;

  __shared__ short Al[128*32];
  __shared__ short Bl[BN*32];

  int t = threadIdx.x;
  int lane = t & 63, w = t >> 6;
  constexpr int FRS = (BN == 128) ? 4 : 2;
  int wn = (BN == 128) ? (w & 1) : 0;
  int rowbase = (BN == 128) ? (w >> 1) * 64 : w * 32;

  ffrag zz4 = {0.f, 0.f, 0.f, 0.f};
  ffrag acc[FRS][4];
  #pragma unroll
  for (int i = 0; i < FRS; i++)
    #pragma unroll
    for (int j = 0; j < 4; j++) acc[i][j] = zz4;

  for (int k0 = kb; k0 < ke; k0 += 32){
    #pragma unroll
    for (int r2 = 0; r2 < 2; r2++){
      int slot = t + r2 * 256;
      int row = slot >> 2, kq = slot & 3;
      int m = tm * 128 + row;
      int arow = (z.rev_s0 >= 0) ? (((z.rev_s0 - (m >> 7)) << 7) | (m & 127)) : m;
      int k = k0 + kq * 8;
      Seg sg;
      if (k < z.sg[0].K) sg = z.sg[0];
      else { k -= z.sg[0].K; if (k < z.sg[1].K) sg = z.sg[1]; else { k -= z.sg[1].K; sg = z.sg[2]; } }
      uint4 v;
      if (sg.f32){
        const float* ap = (const float*)sg.p + (size_t)arow * sg.ld + k;
        v = cvt8(*(const float4*)ap, *(const float4*)(ap + 4));
      } else {
        v = *(const uint4*)((const u16*)sg.p + (size_t)arow * sg.ld + k);
      }
      *(uint4*)&Al[(((row >> 4) << 6) + (kq << 4) + (row & 15)) * 8] = v;
    }
    #pragma unroll
    for (int r2 = 0; r2 < BN/64; r2++){
      int slot = t + r2 * 256;
      int brow = slot >> 2, kq = slot & 3;
      int n = tn * BN + brow;
      uint4 v = make_uint4(0u, 0u, 0u, 0u);
      if (n < z.N){
        int k = k0 + kq * 8;
        if (z.bf32){
          const float* bp = (const float*)z.Bp + (size_t)n * z.ldb + k;
          v = cvt8(*(const float4*)bp, *(const float4*)(bp + 4));
        } else {
          v = *(const uint4*)((const u16*)z.Bp + (size_t)n * z.ldb + k);
        }
      }
      *(uint4*)&Bl[(kq * BN + brow) * 8] = v;
    }
    __syncthreads();
    bfrag af[FRS], bv[4];
    #pragma unroll
    for (int fr = 0; fr < FRS; fr++) af[fr] = *(bfrag*)&Al[(((rowbase >> 4) + fr) * 64 + lane) * 8];
    #pragma unroll
    for (int fc = 0; fc < 4; fc++) bv[fc] = *(bfrag*)&Bl[(((lane >> 4) * BN) + wn * 64 + fc * 16 + (lane & 15)) * 8];
    #pragma unroll
    for (int fr = 0; fr < FRS; fr++)
      #pragma unroll
      for (int fc = 0; fc < 4; fc++)
        acc[fr][fc] = __builtin_amdgcn_mfma_f32_16x16x32_bf16(af[fr], bv[fc], acc[fr][fc], 0, 0, 0);
    __syncthreads();
  }

  float* Cf = (float*)z.Cp + (size_t)blockIdx.y * z.cslab;
  u16*  Cb = (u16*)z.Cp  + (size_t)blockIdx.y * z.cslab;
  #pragma unroll
  for (int fc = 0; fc < 4; fc++){
    int n = tn * BN + wn * 64 + fc * 16 + (lane & 15);
    if (n >= z.N) continue;
    float bs = 0.f;
    if (z.bias) bs = z.biasf32 ? ((const float*)z.bias)[n] : b2f(((const u16*)z.bias)[n]);
    #pragma unroll
    for (int fr = 0; fr < FRS; fr++){
      #pragma unroll
      for (int i = 0; i < 4; i++){
        int m = tm * 128 + rowbase + fr * 16 + ((lane >> 4) << 2) + i;
        float vv = acc[fr][fc][i] + bs;
        size_t idx = (size_t)m * z.ldc + n;
        if (z.cf32) Cf[idx] = vv; else Cb[idx] = f2b(vv);
      }
    }
  }
}

// ================ device-side 4-seg NT GEMM (M=128 fixed) ================
// Segments with nt=1 are cross-block communicated buffers: read via sc0 sc1.
// C-writes always go to communicated buffers: written via sc0 sc1.
struct Seg4 { const void* p; int ld; int f32; int K; int nt; };
struct Z4 {
  Seg4 sg[4];
  const void* Bp; int ldb; int bf32;
  const float* bias;
  float* Cp; int ldc; int cslab;
  int N; int K;
};

template<int BN>
DEVI void dev_mfma4(const Z4& z, int tn, int ks, int nks, short* Al, short* Bl)
{
  int kseg = z.K / nks;
  int kb = ks * kseg, ke = kb + kseg;
  int t = threadIdx.x, lane = t & 63, w = t >> 6;
  constexpr int FRS = (BN == 128) ? 4 : 2;
  int wn = (BN == 128) ? (w & 1) : 0;
  int rowbase = (BN == 128) ? (w >> 1) * 64 : w * 32;
  ffrag zz4 = {0.f, 0.f, 0.f, 0.f};
  ffrag acc[FRS][4];
  #pragma unroll
  for (int i = 0; i < FRS; i++)
    #pragma unroll
    for (int j = 0; j < 4; j++) acc[i][j] = zz4;

  for (int k0 = kb; k0 < ke; k0 += 32){
    // ---- B staging: cached loads (weights; stay warm in L2) ----
    vu4 bvv[BN/64]; int bidx[BN/64];
    #pragma unroll
    for (int r2 = 0; r2 < BN/64; r2++){
      int slot = t + r2 * 256;
      int brow = slot >> 2, kq = slot & 3;
      int n = tn * BN + brow;
      vu4 v = {0u, 0u, 0u, 0u};
      if (n < z.N){
        int k = k0 + kq * 8;
        if (z.bf32){
          const float* bp = (const float*)z.Bp + (size_t)n * z.ldb + k;
          v = cvt8v(*(const vf4*)bp, *(const vf4*)(bp + 4));
        } else {
          v = *(const vu4*)((const u16*)z.Bp + (size_t)n * z.ldb + k);
        }
      }
      bvv[r2] = v; bidx[r2] = (kq * BN + brow) * 8;
    }
    // ---- A staging: issue (possibly sys) loads for both slots, drain once ----
    int rowv[2], kqv2[2], isf[2];
    vf4 fa[2], fb[2]; vu4 ua[2];
    #pragma unroll
    for (int r2 = 0; r2 < 2; r2++){
      int slot = t + r2 * 256;
      int row = slot >> 2, kq = slot & 3;
      int k = k0 + kq * 8;
      Seg4 sg = z.sg[0];
      if (k >= sg.K){ k -= sg.K; sg = z.sg[1];
        if (k >= sg.K){ k -= sg.K; sg = z.sg[2];
          if (k >= sg.K){ k -= sg.K; sg = z.sg[3]; } } }
      rowv[r2] = row; kqv2[r2] = kq; isf[r2] = sg.f32;
      if (sg.f32){
        const float* ap = (const float*)sg.p + (size_t)row * sg.ld + k;
        if (sg.nt) ld32_nw(ap, fa[r2], fb[r2]);
        else { fa[r2] = *(const vf4*)ap; fb[r2] = *(const vf4*)(ap + 4); }
      } else {
        const u16* up = (const u16*)sg.p + (size_t)row * sg.ld + k;
        if (sg.nt) ld16_nw(up, ua[r2]);
        else ua[r2] = *(const vu4*)up;
      }
    }
    vm_drain();
    #pragma unroll
    for (int r2 = 0; r2 < BN/64; r2++) *(vu4*)&Bl[bidx[r2]] = bvv[r2];
    #pragma unroll
    for (int r2 = 0; r2 < 2; r2++){
      vu4 v = isf[r2] ? cvt8v(fa[r2], fb[r2]) : ua[r2];
      *(vu4*)&Al[(((rowv[r2] >> 4) << 6) + (kqv2[r2] << 4) + (rowv[r2] & 15)) * 8] = v;
    }
    __syncthreads();
    bfrag af[FRS], bv[4];
    #pragma unroll
    for (int fr = 0; fr < FRS; fr++) af[fr] = *(bfrag*)&Al[(((rowbase >> 4) + fr) * 64 + lane) * 8];
    #pragma unroll
    for (int fc = 0; fc < 4; fc++) bv[fc] = *(bfrag*)&Bl[(((lane >> 4) * BN) + wn * 64 + fc * 16 + (lane & 15)) * 8];
    #pragma unroll
    for (int fr = 0; fr < FRS; fr++)
      #pragma unroll
      for (int fc = 0; fc < 4; fc++)
        acc[fr][fc] = __builtin_amdgcn_mfma_f32_16x16x32_bf16(af[fr], bv[fc], acc[fr][fc], 0, 0, 0);
    __syncthreads();
  }

  float* Cf = z.Cp + (size_t)ks * z.cslab;
  #pragma unroll
  for (int fc = 0; fc < 4; fc++){
    int n = tn * BN + wn * 64 + fc * 16 + (lane & 15);
    if (n >= z.N) continue;
    float bs = z.bias ? z.bias[n] : 0.f;
    #pragma unroll
    for (int fr = 0; fr < FRS; fr++){
      #pragma unroll
      for (int i = 0; i < 4; i++){
        int m = rowbase + fr * 16 + ((lane >> 4) << 2) + i;
        st4_sys(&Cf[(size_t)m * z.ldc + n], acc[fr][fc][i] + bs);
      }
    }
  }
}

// ================ device-side fused GRU step (h@Whh MFMA + epilogue) ================
// MODE 1 = pointer unit (gi from ptr(B,8)@Wih); MODE 2 = decoder (gi = 4 K-split slabs)
// h state (hb/hf in, hnf/hnb out) is cross-block communicated -> sys access.
template<int MODE>
DEVI void dev_gru3(int g0, const u16* hb, const float* hf, const float* Whh,
                   const float* gi_f, const float* xp, const float* Wih,
                   const float* bih, const float* bhh,
                   float* hnf, u16* hnb, short* Al, short* Bl)
{
  int t = threadIdx.x, lane = t & 63, w = t >> 6;
  int wm = w >> 1, wn = w & 1;
  ffrag zz4 = {0.f, 0.f, 0.f, 0.f};
  ffrag acc[4][3];
  #pragma unroll
  for (int i = 0; i < 4; i++)
    #pragma unroll
    for (int j = 0; j < 3; j++) acc[i][j] = zz4;

  for (int k0 = 0; k0 < 512; k0 += 32){
    // ---- B (Whh, cached) loads issued first ----
    int lb0 = t >> 2, kq0b = t & 3;
    {
      int wn2 = lb0 / 48, rem = lb0 - wn2 * 48, fc = rem >> 4, i16 = rem & 15;
      int grow = fc * 512 + g0 + wn2 * 16 + i16;
      const float* wp = Whh + (size_t)grow * 512 + k0 + kq0b * 8;
      vf4 wa = *(const vf4*)wp, wb = *(const vf4*)(wp + 4);
      // ---- A (h, communicated) sys loads ----
      int rowA0 = t >> 2, kqA0 = t & 3;
      int rowA1 = (t + 256) >> 2, kqA1 = (t + 256) & 3;
      vu4 hv0, hv1;
      ld16_nw(hb + (size_t)rowA0 * 512 + k0 + kqA0 * 8, hv0);
      ld16_nw(hb + (size_t)rowA1 * 512 + k0 + kqA1 * 8, hv1);
      vf4 wa1, wb1; int lb1 = 0, kq1b = 0;
      if (t < 128){
        int slot = t + 256;
        lb1 = slot >> 2; kq1b = slot & 3;
        int wn21 = lb1 / 48, rem1 = lb1 - wn21 * 48, fc1 = rem1 >> 4, i161 = rem1 & 15;
        int grow1 = fc1 * 512 + g0 + wn21 * 16 + i161;
        const float* wp1 = Whh + (size_t)grow1 * 512 + k0 + kq1b * 8;
        wa1 = *(const vf4*)wp1; wb1 = *(const vf4*)(wp1 + 4);
      }
      vm_drain();
      *(vu4*)&Bl[(kq0b * 96 + lb0) * 8] = cvt8v(wa, wb);
      if (t < 128) *(vu4*)&Bl[(kq1b * 96 + lb1) * 8] = cvt8v(wa1, wb1);
      *(vu4*)&Al[(((rowA0 >> 4) << 6) + (kqA0 << 4) + (rowA0 & 15)) * 8] = hv0;
      *(vu4*)&Al[(((rowA1 >> 4) << 6) + (kqA1 << 4) + (rowA1 & 15)) * 8] = hv1;
    }
    __syncthreads();
    bfrag af[4], bv[3];
    #pragma unroll
    for (int fr = 0; fr < 4; fr++) af[fr] = *(bfrag*)&Al[((wm * 4 + fr) * 64 + lane) * 8];
    #pragma unroll
    for (int fc = 0; fc < 3; fc++) bv[fc] = *(bfrag*)&Bl[((lane >> 4) * 96 + (wn * 3 + fc) * 16 + (lane & 15)) * 8];
    #pragma unroll
    for (int fr = 0; fr < 4; fr++)
      #pragma unroll
      for (int fc = 0; fc < 3; fc++)
        acc[fr][fc] = __builtin_amdgcn_mfma_f32_16x16x32_bf16(af[fr], bv[fc], acc[fr][fc], 0, 0, 0);
    __syncthreads();
  }

  // MODE1: stage xp (PTRS slice, communicated) into LDS once
  float* xl = (float*)Al;
  if (MODE == 1){
    for (int i = t; i < 1024; i += 256) xl[i] = ld4f_sys(xp + i);
    __syncthreads();
  }

  int gcol = g0 + wn * 16 + (lane & 15);
  float bir = bih[gcol],        bhr = bhh[gcol];
  float biz = bih[512 + gcol],  bhz = bhh[512 + gcol];
  float bin = bih[1024 + gcol], bhn = bhh[1024 + gcol];
  float wxr[8], wxz[8], wxn[8];
  if (MODE == 1){
    #pragma unroll
    for (int a2 = 0; a2 < 8; a2++){
      wxr[a2] = Wih[(size_t)gcol * 8 + a2];
      wxz[a2] = Wih[(size_t)(512 + gcol) * 8 + a2];
      wxn[a2] = Wih[(size_t)(1024 + gcol) * 8 + a2];
    }
  }
  #pragma unroll
  for (int fr = 0; fr < 4; fr++){
    #pragma unroll
    for (int i = 0; i < 4; i++){
      int brow = wm * 64 + fr * 16 + ((lane >> 4) << 2) + i;
      float gr_, gz_, gn_;
      if (MODE == 2){
        gr_ = gz_ = gn_ = 0.f;
        #pragma unroll
        for (int sl = 0; sl < 4; sl++){
          const float* gp = gi_f + (size_t)sl * 196608 + (size_t)brow * 1536;
          gr_ += ld4f_sys(gp + gcol); gz_ += ld4f_sys(gp + 512 + gcol); gn_ += ld4f_sys(gp + 1024 + gcol);
        }
      } else {
        float4 x0 = *(float4*)&xl[brow * 8];
        float4 x1 = *(float4*)&xl[brow * 8 + 4];
        float xa[8] = {x0.x, x0.y, x0.z, x0.w, x1.x, x1.y, x1.z, x1.w};
        gr_ = gz_ = gn_ = 0.f;
        #pragma unroll
        for (int a2 = 0; a2 < 8; a2++){ gr_ += xa[a2]*wxr[a2]; gz_ += xa[a2]*wxz[a2]; gn_ += xa[a2]*wxn[a2]; }
      }
      float hold = ld4f_sys(hf + (size_t)brow * 512 + gcol);
      float r  = sigmf_(gr_ + acc[fr][0][i] + bir + bhr);
      float zg = sigmf_(gz_ + acc[fr][1][i] + biz + bhz);
      float n  = tanhf_(gn_ + bin + r * (acc[fr][2][i] + bhn));
      float hn = (1.f - zg) * n + zg * hold;
      size_t idx = (size_t)brow * 512 + gcol;
      st4_sys(hnf + idx, hn);
      st2_sys(hnb + idx, f2b(hn));
    }
  }
}

// ================ device-side attention pieces ================
DEVI void dev_puattn(int b, const float* hida2, const float* Ka, const float* cae,
                     const float* Am, const float* Ain, const u16* enc,
                     float* vpre, float* ptrs, float* fs)
{
  int t = threadIdx.x, lane = t & 63, w = t >> 6;
  float* sc0 = fs; float* sc1 = fs + 256;
  float* wred = fs + 512;   // 36
  float* qa   = fs + 560;   // 20
  float* cd   = fs + 584;   // 16
  float* red  = fs + 604;   // 8

  for (int u = 0; u < 2; u++){
    const float* hp = hida2 + ((size_t)u * 128 + b) * 512;
    float hv0 = ld4f_sys(hp + t), hv1 = ld4f_sys(hp + t + 256);
    const float* k0p = Ka + u * 8192 + t * 16;
    const float* k1p = Ka + u * 8192 + (t + 256) * 16;
    float p[9];
    #pragma unroll
    for (int j = 0; j < 9; j++) p[j] = hv0 * k0p[j] + hv1 * k1p[j];
    #pragma unroll
    for (int j = 0; j < 9; j++){
      #pragma unroll
      for (int off = 32; off > 0; off >>= 1) p[j] += __shfl_xor(p[j], off);
    }
    if (lane == 0){
      #pragma unroll
      for (int j = 0; j < 9; j++) wred[w * 9 + j] = p[j];
    }
    __syncthreads();
    if (t < 9) qa[u * 10 + t] = wred[t] + wred[9 + t] + wred[18 + t] + wred[27 + t] + cae[u * 16 + t];
    __syncthreads();
  }

  float su[2];
  #pragma unroll
  for (int u = 0; u < 2; u++){
    const float* amp = Am + (((size_t)u * 256 + t) * 128 + b) * 8;
    float4 a0 = *(const float4*)amp;
    float4 a1 = *(const float4*)(amp + 4);
    const float* q = qa + u * 10;
    su[u] = (q[8] + q[0]*a0.x + q[1]*a0.y + q[2]*a0.z + q[3]*a0.w
                  + q[4]*a1.x + q[5]*a1.y + q[6]*a1.z + q[7]*a1.w) * SCALE_ATT;
  }

  const float* ap = Ain + ((size_t)b * 256 + t) * 8;
  float av[8];
  {
    float4 v0 = *(const float4*)ap;
    float4 v1 = *(const float4*)(ap + 4);
    av[0]=v0.x; av[1]=v0.y; av[2]=v0.z; av[3]=v0.w;
    av[4]=v1.x; av[5]=v1.y; av[6]=v1.z; av[7]=v1.w;
  }

  float inv[2];
  for (int u = 0; u < 2; u++){
    float s_ = su[u];
    float* sc = u ? sc1 : sc0;
    // wave-level max + 4-way combine (2 syncs, no LDS tree)
    float m = s_;
    #pragma unroll
    for (int off = 32; off > 0; off >>= 1) m = fmaxf(m, __shfl_xor(m, off));
    if (lane == 0) red[w] = m;
    __syncthreads();
    float mx = fmaxf(fmaxf(red[0], red[1]), fmaxf(red[2], red[3]));
    float e = __expf(s_ - mx); sc[t] = e;
    // joint shuffle reduce: denominator + 8 pointer-address components (no LDS atomics)
    float ca[9];
    ca[8] = e;
    #pragma unroll
    for (int a2 = 0; a2 < 8; a2++) ca[a2] = e * av[a2];
    #pragma unroll
    for (int j = 0; j < 9; j++){
      #pragma unroll
      for (int off = 32; off > 0; off >>= 1) ca[j] += __shfl_xor(ca[j], off);
    }
    if (lane == 0){
      #pragma unroll
      for (int j = 0; j < 9; j++) wred[w * 9 + j] = ca[j];
    }
    __syncthreads();
    if (t < 9){
      float v = wred[t] + wred[9 + t] + wred[18 + t] + wred[27 + t];
      if (t < 8) cd[u * 8 + t] = v;
      else red[4 + u] = v;
    }
    __syncthreads();
    inv[u] = 1.f / red[4 + u];
  }
  if (t < 8){
    st4_sys(&ptrs[((size_t)0 * 128 + b) * 8 + t], cd[t] * inv[0]);
    st4_sys(&ptrs[((size_t)128 + b) * 8 + t],     cd[8 + t] * inv[1]);
  }

  // value pass over ENC: thread t owns cols 2t,2t+1; deep unroll for MLP
  float a00 = 0.f, a01 = 0.f, a10 = 0.f, a11 = 0.f;
  const u16* ep = enc + (size_t)b * 512;
  #pragma unroll 16
  for (int s2 = 0; s2 < 256; s2++){
    float w0 = sc0[s2], w1 = sc1[s2];
    u32 pv = *(const u32*)(ep + (size_t)s2 * 65536 + 2 * t);
    float v0 = b2f((u16)pv);
    float v1 = b2f((u16)(pv >> 16));
    a00 += w0 * v0; a01 += w0 * v1; a10 += w1 * v0; a11 += w1 * v1;
  }
  float* vp = vpre + (size_t)b * 1024;
  st4_sys(&vp[2 * t], a00 * inv[0]);           st4_sys(&vp[2 * t + 1], a01 * inv[0]);
  st4_sys(&vp[512 + 2 * t], a10 * inv[1]);     st4_sys(&vp[512 + 2 * t + 1], a11 * inv[1]);
}

DEVI void dev_bahd(int b, const u16* eatt, const float* dpart, const float* vvec,
                   const u16* enc, float* ctx, float* fs)
{
  int t = threadIdx.x, lane = t & 63, w = t >> 6;
  float* dp = fs; float* vv = fs + 512; float* sc = fs + 1024; float* red = fs + 1280;
  dp[t] = ld4f_sys(dpart + (size_t)b * 512 + t);
  dp[t + 256] = ld4f_sys(dpart + (size_t)b * 512 + t + 256);
  vv[t] = vvec[t]; vv[t + 256] = vvec[t + 256];
  __syncthreads();
  float4 d0 = *(float4*)&dp[lane * 8], d1 = *(float4*)&dp[lane * 8 + 4];
  float4 v0 = *(float4*)&vv[lane * 8], v1 = *(float4*)&vv[lane * 8 + 4];
  // score pass: batch 8 independent row loads per wave (8x MLP)
  for (int sb = 0; sb < 256; sb += 32){
    uint4 vl[8];
    #pragma unroll
    for (int i = 0; i < 8; i++){
      int s = sb + i * 4 + w;
      vl[i] = *(const uint4*)(eatt + ((size_t)s * 128 + b) * 512 + lane * 8);
    }
    #pragma unroll
    for (int i = 0; i < 8; i++){
      const u16* h = (const u16*)&vl[i];
      float r = fmaxf(0.f, b2f(h[0]) + d0.x) * v0.x + fmaxf(0.f, b2f(h[1]) + d0.y) * v0.y
              + fmaxf(0.f, b2f(h[2]) + d0.z) * v0.z + fmaxf(0.f, b2f(h[3]) + d0.w) * v0.w
              + fmaxf(0.f, b2f(h[4]) + d1.x) * v1.x + fmaxf(0.f, b2f(h[5]) + d1.y) * v1.y
              + fmaxf(0.f, b2f(h[6]) + d1.z) * v1.z + fmaxf(0.f, b2f(h[7]) + d1.w) * v1.w;
      #pragma unroll
      for (int off = 32; off > 0; off >>= 1) r += __shfl_xor(r, off);
      if (lane == 0) sc[sb + i * 4 + w] = r;
    }
  }
  __syncthreads();
  float s0 = sc[t];
  float m = s0;
  #pragma unroll
  for (int off = 32; off > 0; off >>= 1) m = fmaxf(m, __shfl_xor(m, off));
  if (lane == 0) red[w] = m;
  __syncthreads();
  float mx = fmaxf(fmaxf(red[0], red[1]), fmaxf(red[2], red[3]));
  float e = __expf(s0 - mx); sc[t] = e;
  float sum = e;
  #pragma unroll
  for (int off = 32; off > 0; off >>= 1) sum += __shfl_xor(sum, off);
  if (lane == 0) red[4 + w] = sum;
  __syncthreads();
  float inv = 1.f / (red[4] + red[5] + red[6] + red[7]);
  float a0 = 0.f, a1 = 0.f;
  const u16* ep = enc + (size_t)b * 512;
  #pragma unroll 16
  for (int s2 = 0; s2 < 256; s2++){
    float wgt = sc[s2];
    u32 pv = *(const u32*)(ep + (size_t)s2 * 65536 + 2 * t);
    a0 += wgt * b2f((u16)pv);
    a1 += wgt * b2f((u16)(pv >> 16));
  }
  st4_sys(&ctx[(size_t)b * 512 + 2 * t], a0 * inv);
  st4_sys(&ctx[(size_t)b * 512 + 2 * t + 1], a1 * inv);
}

DEVI void dev_cattn(int b, const float* qck, const u16* enc, float* cv2p, float* fs)
{
  int t = threadIdx.x, lane = t & 63, w = t >> 6;
  float* qv = fs; float* sc = fs + 1024; float* red = fs + 1280;
  qv[t] = ld4f_sys(qck + (size_t)b * 520 + t);
  qv[t + 256] = ld4f_sys(qck + (size_t)b * 520 + t + 256);
  __syncthreads();
  float qc0 = ld4f_sys(qck + (size_t)b * 520 + 512);
  float4 q0 = *(float4*)&qv[lane * 8], q1 = *(float4*)&qv[lane * 8 + 4];
  for (int sb = 0; sb < 256; sb += 32){
    uint4 vl[8];
    #pragma unroll
    for (int i = 0; i < 8; i++){
      int s = sb + i * 4 + w;
      vl[i] = *(const uint4*)(enc + ((size_t)s * 128 + b) * 512 + lane * 8);
    }
    #pragma unroll
    for (int i = 0; i < 8; i++){
      const u16* h = (const u16*)&vl[i];
      float r = b2f(h[0])*q0.x + b2f(h[1])*q0.y + b2f(h[2])*q0.z + b2f(h[3])*q0.w
              + b2f(h[4])*q1.x + b2f(h[5])*q1.y + b2f(h[6])*q1.z + b2f(h[7])*q1.w;
      #pragma unroll
      for (int off = 32; off > 0; off >>= 1) r += __shfl_xor(r, off);
      if (lane == 0) sc[sb + i * 4 + w] = (r + qc0) * SCALE_ATT;
    }
  }
  __syncthreads();
  float s0 = sc[t];
  float m = s0;
  #pragma unroll
  for (int off = 32; off > 0; off >>= 1) m = fmaxf(m, __shfl_xor(m, off));
  if (lane == 0) red[w] = m;
  __syncthreads();
  float mx = fmaxf(fmaxf(red[0], red[1]), fmaxf(red[2], red[3]));
  float e = __expf(s0 - mx); sc[t] = e;
  float sum = e;
  #pragma unroll
  for (int off = 32; off > 0; off >>= 1) sum += __shfl_xor(sum, off);
  if (lane == 0) red[4 + w] = sum;
  __syncthreads();
  float inv = 1.f / (red[4] + red[5] + red[6] + red[7]);
  float a0 = 0.f, a1 = 0.f;
  const u16* ep = enc + (size_t)b * 512;
  #pragma unroll 16
  for (int s2 = 0; s2 < 256; s2++){
    float wgt = sc[s2];
    u32 pv = *(const u32*)(ep + (size_t)s2 * 65536 + 2 * t);
    a0 += wgt * b2f((u16)pv);
    a1 += wgt * b2f((u16)(pv >> 16));
  }
  st4_sys(&cv2p[(size_t)b * 512 + 2 * t], a0 * inv);
  st4_sys(&cv2p[(size_t)b * 512 + 2 * t + 1], a1 * inv);
}

DEVI void dev_outcvt(int b, const float* outt, const float* outb2, float* dst)
{
  int t = threadIdx.x;
  #pragma unroll
  for (int rep = 0; rep < 2; rep++){
    int o = t + rep * 256;
    float s = ld4f_sys(outt + (size_t)b * 512 + o) + ld4f_sys(outt + 65536 + (size_t)b * 512 + o)
            + ld4f_sys(outt + 131072 + (size_t)b * 512 + o) + ld4f_sys(outt + 196608 + (size_t)b * 512 + o);
    dst[(size_t)b * 512 + o] = s + outb2[o];   // final output: flushed at kernel end
  }
}

// ================ persistent encoder (32 steps per launch, manual barrier) ================
struct EncArgs {
  const float *WhhF, *WhhB, *giF, *giB;
  const float *bihF, *bhhF, *bihB, *bhhB;
  float *HF, *HB; u16 *HFB, *HBB, *ENC;
  u32 *BAR; int bar0;
  int s0;
};

__global__ __launch_bounds__(256) void k_enc(EncArgs a)
{
  __shared__ short Bw[24576];   // 48 rows (3 gates x 16 cols) x 512 K, bf16, MFMA layout
  __shared__ short Al[4096];
  int blk = blockIdx.x;
  int d = blk >> 5, gt = blk & 31;
  int t = threadIdx.x, lane = t & 63, w = t >> 6;

  const float* Whh = d ? a.WhhB : a.WhhF;
  for (int c = t; c < 3072; c += 256){
    int brow = c >> 6, kc = c & 63;
    int grow = (brow >> 4) * 512 + gt * 16 + (brow & 15);
    const float* wp = Whh + (size_t)grow * 512 + kc * 8;
    *(uint4*)&Bw[((kc * 48) + brow) * 8] = cvt8(*(const float4*)wp, *(const float4*)(wp + 4));
  }
  const float* bih = d ? a.bihB : a.bihF;
  const float* bhh = d ? a.bhhB : a.bhhF;
  int gcol = gt * 16 + (lane & 15);
  float bir = bih[gcol],        bhr = bhh[gcol];
  float biz = bih[512 + gcol],  bhz = bhh[512 + gcol];
  float bin = bih[1024 + gcol], bhn = bhh[1024 + gcol];
  float* hf_base = d ? a.HB : a.HF;
  u16*   hb_base = d ? a.HBB : a.HFB;
  const float* gi_base = d ? a.giB : a.giF;
  __syncthreads();

  for (int si = 0; si < 32; si++){
    int s = a.s0 + si;
    const u16* hb = hb_base + (size_t)(s & 1) * 65536;
    const float* hf = hf_base + (size_t)(s & 1) * 65536;
    float* hnf = hf_base + (size_t)((s + 1) & 1) * 65536;
    u16* hnb = hb_base + (size_t)((s + 1) & 1) * 65536;
    u16* eacc = a.ENC + (size_t)(d ? 255 - s : s) * 65536;

    ffrag zz4 = {0.f, 0.f, 0.f, 0.f};
    ffrag acc[2][3];
    #pragma unroll
    for (int i = 0; i < 2; i++)
      #pragma unroll
      for (int j = 0; j < 3; j++) acc[i][j] = zz4;

    for (int ki = 0; ki < 16; ki++){
      int k0 = ki * 32;
      // h state is cross-block communicated -> sys loads, one drain
      int row0 = t >> 2, kq0 = t & 3;
      int row1 = (t + 256) >> 2, kq1 = (t + 256) & 3;
      vu4 hv0, hv1;
      ld16_nw(hb + (size_t)row0 * 512 + k0 + kq0 * 8, hv0);
      ld16_nw(hb + (size_t)row1 * 512 + k0 + kq1 * 8, hv1);
      vm_drain();
      *(vu4*)&Al[(((row0 >> 4) << 6) + (kq0 << 4) + (row0 & 15)) * 8] = hv0;
      *(vu4*)&Al[(((row1 >> 4) << 6) + (kq1 << 4) + (row1 & 15)) * 8] = hv1;
      __syncthreads();
      bfrag af[2], bv[3];
      #pragma unroll
      for (int fr = 0; fr < 2; fr++) af[fr] = *(bfrag*)&Al[(((w * 2 + fr) * 64) + lane) * 8];
      #pragma unroll
      for (int fc = 0; fc < 3; fc++) bv[fc] = *(bfrag*)&Bw[(((ki * 4 + (lane >> 4)) * 48) + fc * 16 + (lane & 15)) * 8];
      #pragma unroll
      for (int fr = 0; fr < 2; fr++)
        #pragma unroll
        for (int fc = 0; fc < 3; fc++)
          acc[fr][fc] = __builtin_amdgcn_mfma_f32_16x16x32_bf16(af[fr], bv[fc], acc[fr][fc], 0, 0, 0);
      __syncthreads();
    }

    const float* gp0 = gi_base + (size_t)si * 196608;
    #pragma unroll
    for (int fr = 0; fr < 2; fr++){
      #pragma unroll
      for (int i = 0; i < 4; i++){
        int brow = w * 32 + fr * 16 + ((lane >> 4) << 2) + i;
        const float* gp = gp0 + (size_t)brow * 1536;
        float gr_ = gp[gcol], gz_ = gp[512 + gcol], gn_ = gp[1024 + gcol];
        float hold = ld4f_sys(hf + (size_t)brow * 512 + gcol);
        float r  = sigmf_(gr_ + acc[fr][0][i] + bir + bhr);
        float zg = sigmf_(gz_ + acc[fr][1][i] + biz + bhz);
        float n  = tanhf_(gn_ + bin + r * (acc[fr][2][i] + bhn));
        float hn = (1.f - zg) * n + zg * hold;
        size_t idx = (size_t)brow * 512 + gcol;
        st4_sys(hnf + idx, hn);
        st2_sys(hnb + idx, f2b(hn));
        eacc[idx] = f2b(b2f(eacc[idx]) + hn);   // block-private slice; cross-launch coherence only
      }
    }
    gridbar2(a.BAR + BAR_ENCF, a.BAR + BAR_ENCGO, (u32)(a.s0 + si + 1), 64, blk, 0);
  }
}

// ================ persistent decoder (all 64 steps, 4 barriers/step) ================
// Phase A is dissolved: puGRU(st+1) runs in phase C(st) (needs PTRS from B(st)),
// dpart GEMM(st+1) runs in phase E(st) (needs dechb from D(st)), outcvt(st-1)
// runs in phase C(st). One-time prologue handles puGRU(0)/dpart(0).
struct DecArgs {
  const float *tgt, *Ag, *AM, *KA, *CAE, *dattW, *dattv;
  const float *puWhh, *puWih, *pubih, *pubhh;
  const float *dWhh, *DBIH2, *dbhh, *VKE2, *OUTB2;
  const u16 *ENC, *EATT, *DWF, *MKTW, *OWF;
  float *HIDA; u16 *HIDAB;
  float *DECH; u16 *DECHB;
  float *HF0; u16 *HFB0;
  float *PTRS, *VPRE, *CTX, *DPART, *QCK, *CV2P, *GIDEC, *OUTT, *out;
  u32 *BAR;
};

__global__ __launch_bounds__(256) void k_dec(DecArgs a)
{
  __shared__ short Al[4096];
  __shared__ short Bl[4096];
  __shared__ float fs[1600];
  const int blk = blockIdx.x;
  const Seg4 S4SENT = {nullptr, 0, 0, 1 << 30, 0};
  u32* dF = a.BAR + BAR_DECF;
  u32* dG = a.BAR + BAR_DECGO;
  const int GATHER = 230;   // busy only in phase B (bahd) -> polls start early elsewhere

  // helper lambda-free: puGRU for step s on unit u, gate block g0
  // reads HIDA[s&1], writes HIDA[(s+1)&1]
  #define PU_GRU(s_, u_, g0_) do { \
    int s__ = (s_); int u__ = (u_); \
    const u16*  pc_ = a.HIDAB + (size_t)(s__ & 1) * 131072 + (size_t)u__ * 65536; \
    const float* pf_ = a.HIDA  + (size_t)(s__ & 1) * 131072 + (size_t)u__ * 65536; \
    float* pn_  = a.HIDA  + (size_t)((s__ + 1) & 1) * 131072 + (size_t)u__ * 65536; \
    u16*   pnb_ = a.HIDAB + (size_t)((s__ + 1) & 1) * 131072 + (size_t)u__ * 65536; \
    dev_gru3<1>((g0_), pc_, pf_, a.puWhh + (size_t)u__ * 786432, nullptr, \
                a.PTRS + u__ * 1024, a.puWih + (size_t)u__ * 12288, \
                a.pubih + u__ * 1536, a.pubhh + u__ * 1536, pn_, pnb_, Al, Bl); \
  } while(0)

  #define DPART_GEMM(srcb_, tn_) do { \
    Z4 z_; \
    z_.sg[0] = {(srcb_), 512, 0, 512, 1}; z_.sg[1] = S4SENT; z_.sg[2] = S4SENT; z_.sg[3] = S4SENT; \
    z_.Bp = a.dattW; z_.ldb = 1024; z_.bf32 = 1; z_.bias = nullptr; \
    z_.Cp = a.DPART; z_.ldc = 512; z_.cslab = 0; z_.N = 512; z_.K = 512; \
    dev_mfma4<64>(z_, (tn_), 0, 1, Al, Bl); \
  } while(0)

  // ---- prologue: puGRU(0) | dpart(0)  (one extra barrier, once) ----
  if (blk < 32){
    int u = blk >> 4, g0 = (blk & 15) * 32;
    PU_GRU(0, u, g0);
  } else if (blk < 40){
    DPART_GEMM(a.HFB0, blk - 32);
  }
  gridbar2(dF, dG, 1u, 256, blk, GATHER);

  for (int st = 0; st < 64; st++){
    const float* dech_c  = (st == 0) ? a.HF0  : a.DECH  + (size_t)((st + 1) & 1) * 65536;
    const u16*   dechb_c = (st == 0) ? a.HFB0 : a.DECHB + (size_t)((st + 1) & 1) * 65536;
    float*       dech_n  = a.DECH  + (size_t)(st & 1) * 65536;
    u16*         dechb_n = a.DECHB + (size_t)(st & 1) * 65536;
    const float* hida_n  = a.HIDA  + (size_t)((st + 1) & 1) * 131072;  // written by puGRU(st)
    u32 seq0 = 2u + (u32)(st * 4);

    // ---- phase B: pointer attention (both units) | Bahdanau
    if (blk < 128){
      dev_puattn(blk, hida_n, a.KA, a.CAE, a.AM, a.Ag, a.ENC, a.VPRE, a.PTRS, fs);
    } else {
      dev_bahd(blk - 128, a.EATT, a.DPART, a.dattv, a.ENC, a.CTX, fs);
    }
    gridbar2(dF, dG, seq0 + 0, 256, blk, GATHER);

    // ---- phase C: gidec GEMM | qck GEMM | puGRU(st+1) | outcvt(st-1)
    if (blk < 48){
      Z4 z;
      z.sg[0] = {a.tgt + (size_t)(st ? st - 1 : 0) * 65536, 512, 1, 512, 0};
      z.sg[1] = {a.VPRE, 1024, 1, 1024, 1};
      z.sg[2] = {a.CTX, 512, 1, 512, 1};
      z.sg[3] = S4SENT;
      z.Bp = a.DWF; z.ldb = 2048; z.bf32 = 0; z.bias = nullptr;
      z.Cp = a.GIDEC; z.ldc = 1536; z.cslab = 196608; z.N = 1536; z.K = 2048;
      dev_mfma4<128>(z, blk % 12, blk / 12, 4, Al, Bl);
    } else if (blk < 57){
      Z4 z;
      z.sg[0] = {a.VPRE, 1024, 1, 1024, 1}; z.sg[1] = S4SENT; z.sg[2] = S4SENT; z.sg[3] = S4SENT;
      z.Bp = a.MKTW; z.ldb = 1024; z.bf32 = 0; z.bias = a.VKE2;
      z.Cp = a.QCK; z.ldc = 520; z.cslab = 0; z.N = 513; z.K = 1024;
      dev_mfma4<64>(z, blk - 48, 0, 1, Al, Bl);
    } else if (blk < 89){
      if (st < 63){
        int u = (blk - 57) >> 4, g0 = ((blk - 57) & 15) * 32;
        PU_GRU(st + 1, u, g0);
      }
    } else if (blk < 217 && st > 0){
      dev_outcvt(blk - 89, a.OUTT, a.OUTB2, a.out + (size_t)(st - 1) * 65536);
    }
    gridbar2(dF, dG, seq0 + 1, 256, blk, GATHER);

    // ---- phase D: decoder GRU combine | content attention
    if (blk < 16){
      dev_gru3<2>(blk * 32, dechb_c, dech_c, a.dWhh, a.GIDEC, nullptr, nullptr,
                  a.DBIH2, a.dbhh, dech_n, dechb_n, Al, Bl);
    } else if (blk < 144){
      dev_cattn(blk - 16, a.QCK, a.ENC, a.CV2P, fs);
    }
    gridbar2(dF, dG, seq0 + 2, 256, blk, GATHER);

    // ---- phase E: folded output head GEMM (K=2560, split-K 4) | dpart(st+1)
    if (blk < 32){
      Z4 z;
      z.sg[0] = {dechb_n, 512, 0, 512, 1};
      z.sg[1] = {a.CTX, 512, 1, 512, 1};
      z.sg[2] = {a.VPRE, 1024, 1, 1024, 1};
      z.sg[3] = {a.CV2P, 512, 1, 512, 1};
      z.Bp = a.OWF; z.ldb = 2560; z.bf32 = 0; z.bias = nullptr;
      z.Cp = a.OUTT; z.ldc = 512; z.cslab = 65536; z.N = 512; z.K = 2560;
      dev_mfma4<64>(z, blk & 7, blk >> 3, 4, Al, Bl);
    } else if (blk < 40){
      if (st < 63) DPART_GEMM(dechb_n, blk - 32);
    }
    gridbar2(dF, dG, seq0 + 3, 256, blk, GATHER);
  }
  if (blk < 128) dev_outcvt(blk, a.OUTT, a.OUTB2, a.out + 63ull * 65536);
  #undef PU_GRU
  #undef DPART_GEMM
}

// ================ setup: batched fold jobs ================
struct Job {
  const float* A; const float* B; const float* D; void* C;
  int Asm, Ask, Bsk, Bsn, Dsm, Dsn, Csm, Csn;
  int cbf, M, N, K, kind;
};
struct Jobs { Job j[24]; int nj; long long off[25]; };

__global__ __launch_bounds__(256) void k_setup(Jobs J)
{
  long long total = J.off[J.nj];
  for (long long tid = (long long)blockIdx.x * 256 + threadIdx.x; tid < total; tid += (long long)gridDim.x * 256){
    int ji = 0;
    while (tid >= J.off[ji + 1]) ji++;
    Job jb = J.j[ji];
    long long l = tid - J.off[ji];
    if (jb.kind == 0){
      int m = (int)(l / jb.N), n = (int)(l - (long long)m * jb.N);
      float acc = 0.f;
      const float* ap = jb.A + (size_t)m * jb.Asm;
      const float* bp = jb.B + (size_t)n * jb.Bsn;
      for (int k = 0; k < jb.K; k++)
        acc += ap[(size_t)k * jb.Ask] * bp[(size_t)k * jb.Bsk];
      if (jb.D) acc += jb.D[(size_t)m * jb.Dsm + (size_t)n * jb.Dsn];
      if (jb.cbf) ((u16*)jb.C)[(size_t)m * jb.Csm + (size_t)n * jb.Csn] = f2b(acc);
      else ((float*)jb.C)[(size_t)m * jb.Csm + (size_t)n * jb.Csn] = acc;
    } else if (jb.kind == 1){
      int m = (int)(l / jb.N), n = (int)(l - (long long)m * jb.N);
      ((u16*)jb.C)[(size_t)m * jb.Csm + (size_t)n * jb.Csn] = f2b(jb.A[(size_t)m * jb.Asm + (size_t)n * jb.Ask]);
    } else if (jb.kind == 2){
      int u = (int)(l >> 15), sb = (int)(l & 32767);
      float x[8];
      #pragma unroll
      for (int a2 = 0; a2 < 8; a2++) x[a2] = jb.A[(size_t)sb * 8 + a2];
      float* op = (float*)jb.C + ((size_t)u * 32768 + sb) * 8;
      #pragma unroll
      for (int c = 0; c < 8; c++){
        float acc = jb.D[u * 8 + c];
        #pragma unroll
        for (int a2 = 0; a2 < 8; a2++) acc += x[a2] * jb.B[(u * 8 + c) * 8 + a2];
        op[c] = acc;
      }
    } else {
      int u = (int)(l >> 10), r = (int)(l & 1023);
      int bb = r >> 3, aa = r & 7;
      int su = u ? 255 : 0;
      ((float*)jb.C)[l] = jb.A[((size_t)su * 128 + bb) * 8 + aa];
    }
  }
}

// ================ host ================
static inline Seg mkseg(const void* p, int ld, int f32, int K){ Seg s; s.p = p; s.ld = ld; s.f32 = f32; s.K = K; return s; }
static const Seg SENT = {nullptr, 0, 0, 1 << 30};

static inline void addJ(Jobs& JS, Job jb, long long cnt){
  JS.j[JS.nj] = jb;
  JS.off[JS.nj + 1] = JS.off[JS.nj] + cnt;
  JS.nj++;
}
static inline Job JG(const float* A, int Asm, int Ask, const float* B, int Bsk, int Bsn,
                     const float* D, int Dsm, int Dsn, void* C, int Csm, int Csn,
                     int cbf, int M, int N, int K, int kind = 0){
  Job j; j.A=A; j.B=B; j.D=D; j.C=C; j.Asm=Asm; j.Ask=Ask; j.Bsk=Bsk; j.Bsn=Bsn;
  j.Dsm=Dsm; j.Dsn=Dsn; j.Csm=Csm; j.Csn=Csn; j.cbf=cbf; j.M=M; j.N=N; j.K=K; j.kind=kind;
  return j;
}

extern "C" void kernel_launch(void* const* d_in, const int* in_sizes, int n_in,
                              void* d_out, int out_size, void* d_ws, size_t ws_size,
                              hipStream_t stream)
{
  (void)in_sizes; (void)out_size;
  if (n_in < 44 || ws_size < WS_NEED) return;

  const float* src   = (const float*)d_in[0];
  const float* tgt   = (const float*)d_in[1];
  const float* Ag    = (const float*)d_in[2];
  const float* eWihF = (const float*)d_in[3];
  const float* eWhhF = (const float*)d_in[4];
  const float* ebihF = (const float*)d_in[5];
  const float* ebhhF = (const float*)d_in[6];
  const float* eWihB = (const float*)d_in[7];
  const float* eWhhB = (const float*)d_in[8];
  const float* ebihB = (const float*)d_in[9];
  const float* ebhhB = (const float*)d_in[10];
  const float* dattW = (const float*)d_in[11];
  const float* dattb = (const float*)d_in[12];
  const float* dattv = (const float*)d_in[13];
  const float* dWih  = (const float*)d_in[14];
  const float* dWhh  = (const float*)d_in[15];
  const float* dbih  = (const float*)d_in[16];
  const float* dbhh  = (const float*)d_in[17];
  const float* doW   = (const float*)d_in[18];
  const float* dob   = (const float*)d_in[19];
  const float* puWih = (const float*)d_in[20];
  const float* puWhh = (const float*)d_in[21];
  const float* pubih = (const float*)d_in[22];
  const float* pubhh = (const float*)d_in[23];
  const float* puqW  = (const float*)d_in[24];
  const float* puqb  = (const float*)d_in[25];
  const float* puAW  = (const float*)d_in[26];
  const float* puAb  = (const float*)d_in[27];
  const float* puqp  = (const float*)d_in[28];
  const float* pukp  = (const float*)d_in[29];
  const float* puvp  = (const float*)d_in[30];
  const float* puinb = (const float*)d_in[31];
  const float* puop  = (const float*)d_in[32];
  const float* puob  = (const float*)d_in[33];
  const float* aaq   = (const float*)d_in[34];
  const float* aak   = (const float*)d_in[35];
  const float* aav   = (const float*)d_in[36];
  const float* aainb = (const float*)d_in[37];
  const float* aao   = (const float*)d_in[38];
  const float* aaob  = (const float*)d_in[39];
  const float* tohW  = (const float*)d_in[40];
  const float* tohb  = (const float*)d_in[41];
  const float* outW  = (const float*)d_in[42];
  const float* outb  = (const float*)d_in[43];

  char* ws = (char*)d_ws;
  float* GI    = (float*)(ws + OFF_GI);
  u16*   ENC   = (u16*)(ws + OFF_ENC);
  u16*   EATT  = (u16*)(ws + OFF_EATT);
  float* AM    = (float*)(ws + OFF_AM);
  float* HF    = (float*)(ws + OFF_HF);
  float* HB    = (float*)(ws + OFF_HB);
  u16*   HFB   = (u16*)(ws + OFF_HFB);
  u16*   HBB   = (u16*)(ws + OFF_HBB);
  float* HIDA  = (float*)(ws + OFF_HIDA);
  u16*   HIDAB = (u16*)(ws + OFF_HIDAB);
  u32*   BAR   = (u32*)(ws + OFF_BAR);
  float* DECH  = (float*)(ws + OFF_DECH);
  u16*   DECHB = (u16*)(ws + OFF_DECHB);
  float* PTRS  = (float*)(ws + OFF_PTRS);
  float* VPRE  = (float*)(ws + OFF_VPRE);
  float* CTX   = (float*)(ws + OFF_CTX);
  float* DPART = (float*)(ws + OFF_DPART);
  float* QCK   = (float*)(ws + OFF_QCK);
  float* CV2P  = (float*)(ws + OFF_CV2P);
  float* GIDEC = (float*)(ws + OFF_GIDEC);
  float* OUTT  = (float*)(ws + OFF_OUTT);
  float* WOVF  = (float*)(ws + OFF_WOVF);
  float* WOVCF = (float*)(ws + OFF_WOVCF);
  float* MKTF  = (float*)(ws + OFF_MKTF);
  u16*   DWF   = (u16*)(ws + OFF_DWF);
  u16*   MKTW  = (u16*)(ws + OFF_MKTW);
  u16*   OWF   = (u16*)(ws + OFF_OWF);
  float* BOV   = (float*)(ws + OFF_BOV);
  float* BOVC  = (float*)(ws + OFF_BOVC);
  float* KAx   = (float*)(ws + OFF_KA);
  float* CAE   = (float*)(ws + OFF_CAE);
  float* RT    = (float*)(ws + OFF_RT);
  float* BQC   = (float*)(ws + OFF_BQC);
  float* PMAT  = (float*)(ws + OFF_PMAT);
  float* CQ    = (float*)(ws + OFF_CQ);
  float* VKE2  = (float*)(ws + OFF_VKE2);
  float* DBIH2 = (float*)(ws + OFF_DBIH2);
  float* OUTB2 = (float*)(ws + OFF_OUTB2);

  hipMemsetAsync(ENC, 0, 2ull*256*128*512, stream);
  hipMemsetAsync(ws + OFF_HF, 0, OFF_ZEND - OFF_HF, stream);  // states + barrier flags

  // -------- stage 1: independent folds --------
  {
    Jobs S{}; S.nj = 0; S.off[0] = 0;
    for (int u = 0; u < 2; u++){
      const float* qp  = puqp + (size_t)u * 262144;
      const float* kp  = pukp + (size_t)u * 4096;
      float* RTu = RT + u * 8192;
      addJ(S, JG(qp, 1, 512, kp, 8, 1, nullptr, 0, 0, RTu, 16, 1, 0, 512, 8, 512), 4096);
      addJ(S, JG(qp, 1, 512, puinb + u*1536 + 512, 1, 0, nullptr, 0, 0, RTu + 8, 16, 1, 0, 512, 1, 512), 512);
      addJ(S, JG(qp, 512, 1, puqb + u*512, 1, 0, puinb + u*1536, 1, 0, BQC + u*512, 1, 1, 0, 512, 1, 512), 512);
      addJ(S, JG(puop + (size_t)u*262144, 512, 1, puvp + (size_t)u*262144, 512, 1, nullptr, 0, 0, WOVF + (size_t)u*262144, 512, 1, 0, 512, 512, 512), 262144);
      addJ(S, JG(puop + (size_t)u*262144, 512, 1, puinb + u*1536 + 1024, 1, 0, puob + u*512, 1, 0, BOV + u*512, 1, 1, 0, 512, 1, 512), 512);
    }
    addJ(S, JG(aao, 512, 1, aav, 512, 1, nullptr, 0, 0, WOVCF, 512, 1, 0, 512, 512, 512), 262144);
    addJ(S, JG(aao, 512, 1, aainb + 1024, 1, 0, aaob, 1, 0, BOVC, 1, 1, 0, 512, 1, 512), 512);
    addJ(S, JG(aaq, 1, 512, aak, 512, 1, nullptr, 0, 0, PMAT, 516, 1, 0, 512, 512, 512), 262144);
    addJ(S, JG(aaq, 1, 512, aainb + 512, 1, 0, nullptr, 0, 0, PMAT + 512, 516, 1, 0, 512, 1, 512), 512);
    addJ(S, JG(aaq, 512, 1, tohb, 1, 0, aainb, 1, 0, CQ, 1, 1, 0, 512, 1, 512), 512);
    addJ(S, JG(dWih, 2048, 1, nullptr, 0, 0, nullptr, 0, 0, DWF, 2048, 1, 1, 1536, 512, 0, 1), 786432);
    addJ(S, JG(dWih + 1536, 2048, 1, nullptr, 0, 0, nullptr, 0, 0, DWF + 1536, 2048, 1, 1, 1536, 512, 0, 1), 786432);
    addJ(S, JG(outW, 2048, 1, doW, 1024, 1, nullptr, 0, 0, OWF, 2560, 1, 1, 512, 1024, 512), 524288);
    addJ(S, JG(outW, 2048, 1, dob, 1, 0, outb, 1, 0, OUTB2, 1, 1, 0, 512, 1, 512), 512);
    addJ(S, JG(Ag, 0, 0, puAW, 0, 0, puAb, 0, 0, AM, 0, 0, 0, 0, 0, 0, 2), 65536);
    addJ(S, JG(Ag, 0, 0, nullptr, 0, 0, nullptr, 0, 0, PTRS, 0, 0, 0, 0, 0, 0, 3), 2048);
    k_setup<<<2048, 256, 0, stream>>>(S);
  }
  // -------- stage 2 --------
  {
    Jobs S{}; S.nj = 0; S.off[0] = 0;
    for (int u = 0; u < 2; u++){
      const float* kp = pukp + (size_t)u * 4096;
      addJ(S, JG(puqW + (size_t)u*262144, 1, 512, RT + u*8192, 16, 1, nullptr, 0, 0, KAx + u*8192, 16, 1, 0, 512, 9, 512), 4608);
      addJ(S, JG(BQC + u*512, 0, 1, kp, 8, 1, nullptr, 0, 0, CAE + u*16, 0, 1, 0, 1, 8, 512), 8);
      addJ(S, JG(BQC + u*512, 0, 1, puinb + u*1536 + 512, 1, 0, nullptr, 0, 0, CAE + u*16 + 8, 0, 1, 0, 1, 1, 512), 1);
      addJ(S, JG(dWih + 512 + u*512, 2048, 1, WOVF + (size_t)u*262144, 512, 1, nullptr, 0, 0, DWF + 512 + u*512, 2048, 1, 1, 1536, 512, 512), 786432);
      addJ(S, JG(outW + 512 + u*512, 2048, 1, WOVF + (size_t)u*262144, 512, 1, nullptr, 0, 0, OWF + 1024 + u*512, 2560, 1, 1, 512, 512, 512), 262144);
    }
    addJ(S, JG(tohW, 1, 1024, PMAT, 516, 1, nullptr, 0, 0, MKTF, 1, 1024, 0, 1024, 513, 512), 525312);
    addJ(S, JG(CQ, 0, 1, aak, 512, 1, nullptr, 0, 0, VKE2, 0, 1, 0, 1, 512, 512), 512);
    addJ(S, JG(CQ, 0, 1, aainb + 512, 1, 0, nullptr, 0, 0, VKE2 + 512, 0, 1, 0, 1, 1, 512), 1);
    addJ(S, JG(dWih + 512, 2048, 1, BOV, 1, 0, dbih, 1, 0, DBIH2, 1, 1, 0, 1536, 1, 1024), 1536);
    addJ(S, JG(outW + 1536, 2048, 1, WOVCF, 512, 1, nullptr, 0, 0, OWF + 2048, 2560, 1, 1, 512, 512, 512), 262144);
    addJ(S, JG(outW + 512, 2048, 1, BOV, 1, 0, OUTB2, 1, 0, OUTB2, 1, 1, 0, 512, 1, 1536), 512);
    k_setup<<<2048, 256, 0, stream>>>(S);
  }
  // -------- stage 3 --------
  {
    Jobs S{}; S.nj = 0; S.off[0] = 0;
    for (int u = 0; u < 2; u++)
      addJ(S, JG(MKTF + u*512, 1024, 1, WOVF + (size_t)u*262144, 512, 1, nullptr, 0, 0, MKTW + u*512, 1024, 1, 1, 513, 512, 512), 262656);
    addJ(S, JG(MKTF, 1024, 1, BOV, 1, 0, VKE2, 1, 0, VKE2, 1, 1, 0, 513, 1, 1024), 513);
    k_setup<<<1024, 256, 0, stream>>>(S);
  }

  // -------- encoder: 8 chunks of (gi GEMM + persistent 32-step scan) --------
  for (int c = 0; c < 8; c++){
    int c0 = c * 32;
    NTA nt{};
    nt.tilesN = 12;
    for (int d = 0; d < 2; d++){
      NTZ& zz = nt.z[d];
      zz.sg[0] = mkseg(d == 0 ? (const void*)(src + (size_t)c0 * 65536) : (const void*)src, 512, 1, 512);
      zz.sg[1] = SENT; zz.sg[2] = SENT;
      zz.Bp = d ? eWihB : eWihF; zz.ldb = 512; zz.bf32 = 1;
      zz.bias = nullptr; zz.biasf32 = 0;
      zz.Cp = GI + (size_t)d * 6291456; zz.ldc = 1536; zz.cf32 = 1; zz.cslab = 0;
      zz.N = 1536; zz.rev_s0 = (d == 0) ? -1 : (255 - c0); zz.K = 512;
    }
    k_mfma_nt<128><<<dim3(32*12, 1, 2), 256, 0, stream>>>(nt);

    EncArgs ea;
    ea.WhhF = eWhhF; ea.WhhB = eWhhB;
    ea.giF = GI; ea.giB = GI + 6291456;
    ea.bihF = ebihF; ea.bhhF = ebhhF; ea.bihB = ebihB; ea.bhhB = ebhhB;
    ea.HF = HF; ea.HB = HB; ea.HFB = HFB; ea.HBB = HBB; ea.ENC = ENC;
    ea.BAR = BAR; ea.bar0 = c * 32;
    ea.s0 = c0;
    k_enc<<<dim3(64), dim3(256), 0, stream>>>(ea);
  }

  // -------- enc_att = enc @ W2.T + b --------
  {
    NTA nt{};
    nt.tilesN = 4;
    NTZ& zz = nt.z[0];
    zz.sg[0] = mkseg(ENC, 512, 0, 512); zz.sg[1] = SENT; zz.sg[2] = SENT;
    zz.Bp = dattW + 512; zz.ldb = 1024; zz.bf32 = 1;
    zz.bias = dattb; zz.biasf32 = 1;
    zz.Cp = EATT; zz.ldc = 512; zz.cf32 = 0; zz.cslab = 0;
    zz.N = 512; zz.rev_s0 = -1; zz.K = 512;
    k_mfma_nt<128><<<dim3(256*4, 1, 1), 256, 0, stream>>>(nt);
  }

  // -------- decoder: one persistent kernel, all 64 steps --------
  {
    DecArgs da;
    da.tgt = tgt; da.Ag = Ag; da.AM = AM; da.KA = KAx; da.CAE = CAE;
    da.dattW = dattW; da.dattv = dattv;
    da.puWhh = puWhh; da.puWih = puWih; da.pubih = pubih; da.pubhh = pubhh;
    da.dWhh = dWhh; da.DBIH2 = DBIH2; da.dbhh = dbhh; da.VKE2 = VKE2; da.OUTB2 = OUTB2;
    da.ENC = ENC; da.EATT = EATT; da.DWF = DWF; da.MKTW = MKTW; da.OWF = OWF;
    da.HIDA = HIDA; da.HIDAB = HIDAB; da.DECH = DECH; da.DECHB = DECHB;
    da.HF0 = HF; da.HFB0 = HFB;
    da.PTRS = PTRS; da.VPRE = VPRE; da.CTX = CTX; da.DPART = DPART;
    da.QCK = QCK; da.CV2P = CV2P; da.GIDEC = GIDEC; da.OUTT = OUTT;
    da.out = (float*)d_out;
    da.BAR = BAR;
    k_dec<<<dim3(256), dim3(256), 0, stream>>>(da);
  }
}

// Round 7
// 20719.144 us; speedup vs baseline: 1.5266x; 1.0006x over previous
//
#include <hip/hip_runtime.h>

typedef unsigned short u16;
typedef unsigned int u32;

#define DEVI __device__ __forceinline__

constexpr float SCALE_ATT = 0.04419417382415922f;  // 1/sqrt(512)

// ---------------- workspace layout (bytes) ----------------
constexpr size_t OFF_GI    = 0;                                  // f32 [2][32][128][1536] per-chunk x@Wih
constexpr size_t OFF_ENC   = OFF_GI    + 4ull*2*32*128*1536;
constexpr size_t OFF_EATT  = OFF_ENC   + 2ull*256*128*512;       // bf16 enc, bf16 enc_att
constexpr size_t OFF_AM    = OFF_EATT  + 2ull*256*128*512;       // f32 [2][256][128][8]
constexpr size_t OFF_HF    = OFF_AM    + 4ull*2*256*128*8;       // ---- zero region start
constexpr size_t OFF_HB    = OFF_HF    + 4ull*2*128*512;
constexpr size_t OFF_HFB   = OFF_HB    + 4ull*2*128*512;
constexpr size_t OFF_HBB   = OFF_HFB   + 2ull*2*128*512;
constexpr size_t OFF_HIDA  = OFF_HBB   + 2ull*2*128*512;
constexpr size_t OFF_HIDAB = OFF_HIDA  + 4ull*2*2*128*512;
constexpr size_t OFF_BAR   = OFF_HIDAB + 2ull*2*2*128*512;       // u32 flag lines (see BAR_* below)
constexpr size_t OFF_ZEND  = OFF_BAR   + 98304;                  // ---- zero region end
constexpr size_t OFF_DECH  = OFF_ZEND;
constexpr size_t OFF_DECHB = OFF_DECH  + 4ull*2*128*512;
constexpr size_t OFF_PTRS  = OFF_DECHB + 2ull*2*128*512;         // f32 [2][128][8]
constexpr size_t OFF_VPRE  = OFF_PTRS  + 4ull*2*128*8;           // f32 [128][1024]  (b-major!)
constexpr size_t OFF_CTX   = OFF_VPRE  + 4ull*128*1024;
constexpr size_t OFF_DPART = OFF_CTX   + 4ull*128*512;
constexpr size_t OFF_QCK   = OFF_DPART + 4ull*128*512;           // f32 [128][520] (513 used)
constexpr size_t OFF_CV2P  = OFF_QCK   + 4ull*128*520;
constexpr size_t OFF_GIDEC = OFF_CV2P  + 4ull*128*512;           // f32 4 K-slabs [128][1536]
constexpr size_t OFF_OUTT  = OFF_GIDEC + 4ull*4*128*1536;        // f32 4 K-slabs [128][512]
constexpr size_t OFF_WOVF  = OFF_OUTT  + 4ull*4*128*512;         // f32 [2][512][512]
constexpr size_t OFF_WOVCF = OFF_WOVF  + 4ull*2*512*512;         // f32 [512][512]
constexpr size_t OFF_MKTF  = OFF_WOVCF + 4ull*512*512;           // f32 [513 rows][1024]
constexpr size_t OFF_DWF   = OFF_MKTF  + 4ull*513*1024;          // bf16 [1536][2048] folded dec Wih
constexpr size_t OFF_MKTW  = OFF_DWF   + 2ull*1536*2048;         // bf16 [513][1024] folded qck W
constexpr size_t OFF_OWF   = OFF_MKTW  + 2ull*513*1024;          // bf16 [512][2560] folded out W
constexpr size_t OFF_BOV   = OFF_OWF   + 2ull*512*2560;          // f32 [2][512]  (contiguous w/ BOVC!)
constexpr size_t OFF_BOVC  = OFF_BOV   + 4ull*2*512;             // f32 [512]
constexpr size_t OFF_KA    = OFF_BOVC  + 4ull*512;               // f32 [2][512][16] (9 used)
constexpr size_t OFF_CAE   = OFF_KA    + 4ull*2*512*16;          // f32 [2][16]
constexpr size_t OFF_RT    = OFF_CAE   + 4ull*2*16;              // f32 [2][512][16]
constexpr size_t OFF_BQC   = OFF_RT    + 4ull*2*512*16;          // f32 [2][512]
constexpr size_t OFF_PMAT  = OFF_BQC   + 4ull*2*512;             // f32 [512][516]
constexpr size_t OFF_CQ    = OFF_PMAT  + 4ull*512*516;
constexpr size_t OFF_VKE2  = OFF_CQ    + 4ull*512;               // f32 [520]
constexpr size_t OFF_DBIH2 = OFF_VKE2  + 4ull*520;               // f32 [1536]
constexpr size_t OFF_OUTB2 = OFF_DBIH2 + 4ull*1536;              // f32 [512]
constexpr size_t WS_NEED   = OFF_OUTB2 + 4ull*512;

// ---------------- helpers ----------------
DEVI float b2f(u16 u){ union{u32 i; float f;} x; x.i = ((u32)u) << 16; return x.f; }
DEVI u16 f2b(float f){ union{float f; u32 i;} x; x.f = f; u32 i = x.i; u32 r = i + 0x7FFFu + ((i >> 16) & 1u); return (u16)(r >> 16); }
DEVI float sigmf_(float x){ return 1.f / (1.f + __expf(-x)); }
DEVI float tanhf_(float x){ x = fminf(15.f, fmaxf(-15.f, x)); float e = __expf(2.f*x); return (e - 1.f) / (e + 1.f); }

typedef __attribute__((ext_vector_type(8))) short bfrag;
typedef __attribute__((ext_vector_type(4))) float ffrag;
typedef __attribute__((ext_vector_type(4))) unsigned int vu4;
typedef __attribute__((ext_vector_type(4))) float vf4;

DEVI uint4 cvt8(float4 a, float4 b){
  union{uint4 u; u16 h[8];} r;
  r.h[0]=f2b(a.x); r.h[1]=f2b(a.y); r.h[2]=f2b(a.z); r.h[3]=f2b(a.w);
  r.h[4]=f2b(b.x); r.h[5]=f2b(b.y); r.h[6]=f2b(b.z); r.h[7]=f2b(b.w);
  return r.u;
}
DEVI vu4 cvt8v(vf4 a, vf4 b){
  union{vu4 u; u16 h[8];} r;
  r.h[0]=f2b(a[0]); r.h[1]=f2b(a[1]); r.h[2]=f2b(a[2]); r.h[3]=f2b(a[3]);
  r.h[4]=f2b(b[0]); r.h[5]=f2b(b[1]); r.h[6]=f2b(b[2]); r.h[7]=f2b(b[3]);
  return r.u;
}

// ---- L2-bypassing (coherence-point) access primitives ----
DEVI void ld16_nw(const void* p, vu4& r){
  asm volatile("global_load_dwordx4 %0, %1, off sc0 sc1"
               : "=&v"(r) : "v"(p) : "memory");
}
DEVI void ld32_nw(const float* p, vf4& a, vf4& b){
  asm volatile("global_load_dwordx4 %0, %2, off sc0 sc1\n\t"
               "global_load_dwordx4 %1, %2, off offset:16 sc0 sc1"
               : "=&v"(a), "=&v"(b) : "v"(p) : "memory");
}
DEVI void vm_drain(){
  asm volatile("s_waitcnt vmcnt(0)" ::: "memory");
  __builtin_amdgcn_sched_barrier(0);   // rule #18
}
DEVI float ld4f_sys(const float* p){ return __hip_atomic_load(p, __ATOMIC_RELAXED, __HIP_MEMORY_SCOPE_SYSTEM); }
DEVI void st4_sys(float* p, float v){
  asm volatile("global_store_dword %0, %1, off sc0 sc1" :: "v"(p), "v"(v) : "memory");
}
DEVI void st2_sys(u16* p, u16 v){
  u32 w = v;
  asm volatile("global_store_short %0, %1, off sc0 sc1" :: "v"(p), "v"(w) : "memory");
}

// ---- all-store flag grid barrier, FULL FAN-OUT (no shared-line reads) ----
// Round-6 calibration: barrier ~20-23us. Cause: 255 blocks read-spinning ONE
// `go` line -> same-address reads serialize at the coherence point (~100ns
// each, no read combining). Fix: per-block go lines. Gather's nblk threads
// each store seq to go[t] (parallel, private lines); each waiter spins on
// go[blk] only (1 reader + 1 writer per line). Expected ~1.5-2us/barrier.
constexpr int GB_STRIDE  = 32;      // u32 per flag line (128B)
constexpr int BAR_DECF   = 0;       // 256 flag lines
constexpr int BAR_DECGO  = 8192;    // 256 go lines
constexpr int BAR_ENCF   = 16384;   // 64 flag lines
constexpr int BAR_ENCGO  = 18432;   // 64 go lines

DEVI u32 ld_sys(u32* p){ return __hip_atomic_load(p, __ATOMIC_RELAXED, __HIP_MEMORY_SCOPE_SYSTEM); }
DEVI void st_sys(u32* p, u32 v){ __hip_atomic_store(p, v, __ATOMIC_RELAXED, __HIP_MEMORY_SCOPE_SYSTEM); }

DEVI void gridbar2(u32* flags, u32* go, u32 seq, int nblk, int blk, int gblk)
{
  asm volatile("s_waitcnt vmcnt(0)" ::: "memory");   // per-wave: all sys stores committed
  __syncthreads();
  int t = threadIdx.x;
  if (blk == gblk){
    if (t == 0) st_sys(&flags[(u32)blk * GB_STRIDE], seq);
    if (t < nblk){
      u32* f = &flags[(u32)t * GB_STRIDE];
      while (ld_sys(f) < seq) __builtin_amdgcn_s_sleep(1);
    }
    __syncthreads();
    if (t < nblk) st_sys(&go[(u32)t * GB_STRIDE], seq);   // fan-out release
  } else {
    if (t == 0){
      st_sys(&flags[(u32)blk * GB_STRIDE], seq);
      u32* g = &go[(u32)blk * GB_STRIDE];                 // private go line
      while (ld_sys(g) < seq) __builtin_amdgcn_s_sleep(1);
    }
  }
  __syncthreads();
}

// ================ host-launched 3-seg NT GEMM (GI chunks + EATT) ================
struct Seg { const void* p; int ld; int f32; int K; };
struct NTZ {
  Seg sg[3];
  const void* Bp; int ldb; int bf32;
  const void* bias; int biasf32;
  void* Cp; int ldc; int cf32; int cslab;
  int N; int rev_s0; int K;
};
struct NTA { NTZ z[3]; int tilesN; };

template<int BN>
__global__ __launch_bounds__(256) void k_mfma_nt(NTA a)
{
  NTZ z = a.z[blockIdx.z];
  int tn = blockIdx.x % a.tilesN;
  int tm = blockIdx.x / a.tilesN;
  if (tn * BN >= z.N) return;
  int nks = gridDim.y;
  int kb = blockIdx.y * (z.K / nks);
  int ke = kb + z.K / nks;

  __shared__ short Al[128*32];
  __shared__ short Bl[BN*32];

  int t = threadIdx.x;
  int lane = t & 63, w = t >> 6;
  constexpr int FRS = (BN == 128) ? 4 : 2;
  int wn = (BN == 128) ? (w & 1) : 0;
  int rowbase = (BN == 128) ? (w >> 1) * 64 : w * 32;

  ffrag zz4 = {0.f, 0.f, 0.f, 0.f};
  ffrag acc[FRS][4];
  #pragma unroll
  for (int i = 0; i < FRS; i++)
    #pragma unroll
    for (int j = 0; j < 4; j++) acc[i][j] = zz4;

  for (int k0 = kb; k0 < ke; k0 += 32){
    #pragma unroll
    for (int r2 = 0; r2 < 2; r2++){
      int slot = t + r2 * 256;
      int row = slot >> 2, kq = slot & 3;
      int m = tm * 128 + row;
      int arow = (z.rev_s0 >= 0) ? (((z.rev_s0 - (m >> 7)) << 7) | (m & 127)) : m;
      int k = k0 + kq * 8;
      Seg sg;
      if (k < z.sg[0].K) sg = z.sg[0];
      else { k -= z.sg[0].K; if (k < z.sg[1].K) sg = z.sg[1]; else { k -= z.sg[1].K; sg = z.sg[2]; } }
      uint4 v;
      if (sg.f32){
        const float* ap = (const float*)sg.p + (size_t)arow * sg.ld + k;
        v = cvt8(*(const float4*)ap, *(const float4*)(ap + 4));
      } else {
        v = *(const uint4*)((const u16*)sg.p + (size_t)arow * sg.ld + k);
      }
      *(uint4*)&Al[(((row >> 4) << 6) + (kq << 4) + (row & 15)) * 8] = v;
    }
    #pragma unroll
    for (int r2 = 0; r2 < BN/64; r2++){
      int slot = t + r2 * 256;
      int brow = slot >> 2, kq = slot & 3;
      int n = tn * BN + brow;
      uint4 v = make_uint4(0u, 0u, 0u, 0u);
      if (n < z.N){
        int k = k0 + kq * 8;
        if (z.bf32){
          const float* bp = (const float*)z.Bp + (size_t)n * z.ldb + k;
          v = cvt8(*(const float4*)bp, *(const float4*)(bp + 4));
        } else {
          v = *(const uint4*)((const u16*)z.Bp + (size_t)n * z.ldb + k);
        }
      }
      *(uint4*)&Bl[(kq * BN + brow) * 8] = v;
    }
    __syncthreads();
    bfrag af[FRS], bv[4];
    #pragma unroll
    for (int fr = 0; fr < FRS; fr++) af[fr] = *(bfrag*)&Al[(((rowbase >> 4) + fr) * 64 + lane) * 8];
    #pragma unroll
    for (int fc = 0; fc < 4; fc++) bv[fc] = *(bfrag*)&Bl[(((lane >> 4) * BN) + wn * 64 + fc * 16 + (lane & 15)) * 8];
    #pragma unroll
    for (int fr = 0; fr < FRS; fr++)
      #pragma unroll
      for (int fc = 0; fc < 4; fc++)
        acc[fr][fc] = __builtin_amdgcn_mfma_f32_16x16x32_bf16(af[fr], bv[fc], acc[fr][fc], 0, 0, 0);
    __syncthreads();
  }

  float* Cf = (float*)z.Cp + (size_t)blockIdx.y * z.cslab;
  u16*  Cb = (u16*)z.Cp  + (size_t)blockIdx.y * z.cslab;
  #pragma unroll
  for (int fc = 0; fc < 4; fc++){
    int n = tn * BN + wn * 64 + fc * 16 + (lane & 15);
    if (n >= z.N) continue;
    float bs = 0.f;
    if (z.bias) bs = z.biasf32 ? ((const float*)z.bias)[n] : b2f(((const u16*)z.bias)[n]);
    #pragma unroll
    for (int fr = 0; fr < FRS; fr++){
      #pragma unroll
      for (int i = 0; i < 4; i++){
        int m = tm * 128 + rowbase + fr * 16 + ((lane >> 4) << 2) + i;
        float vv = acc[fr][fc][i] + bs;
        size_t idx = (size_t)m * z.ldc + n;
        if (z.cf32) Cf[idx] = vv; else Cb[idx] = f2b(vv);
      }
    }
  }
}

// ================ device-side 4-seg NT GEMM (M=128 fixed) ================
// Segments with nt=1 are cross-block communicated buffers: read via sc0 sc1.
// C-writes always go to communicated buffers: written via sc0 sc1.
struct Seg4 { const void* p; int ld; int f32; int K; int nt; };
struct Z4 {
  Seg4 sg[4];
  const void* Bp; int ldb; int bf32;
  const float* bias;
  float* Cp; int ldc; int cslab;
  int N; int K;
};

template<int BN>
DEVI void dev_mfma4(const Z4& z, int tn, int ks, int nks, short* Al, short* Bl)
{
  int kseg = z.K / nks;
  int kb = ks * kseg, ke = kb + kseg;
  int t = threadIdx.x, lane = t & 63, w = t >> 6;
  constexpr int FRS = (BN == 128) ? 4 : 2;
  int wn = (BN == 128) ? (w & 1) : 0;
  int rowbase = (BN == 128) ? (w >> 1) * 64 : w * 32;
  ffrag zz4 = {0.f, 0.f, 0.f, 0.f};
  ffrag acc[FRS][4];
  #pragma unroll
  for (int i = 0; i < FRS; i++)
    #pragma unroll
    for (int j = 0; j < 4; j++) acc[i][j] = zz4;

  for (int k0 = kb; k0 < ke; k0 += 32){
    // ---- B staging: cached loads (weights; stay warm in L2) ----
    vu4 bvv[BN/64]; int bidx[BN/64];
    #pragma unroll
    for (int r2 = 0; r2 < BN/64; r2++){
      int slot = t + r2 * 256;
      int brow = slot >> 2, kq = slot & 3;
      int n = tn * BN + brow;
      vu4 v = {0u, 0u, 0u, 0u};
      if (n < z.N){
        int k = k0 + kq * 8;
        if (z.bf32){
          const float* bp = (const float*)z.Bp + (size_t)n * z.ldb + k;
          v = cvt8v(*(const vf4*)bp, *(const vf4*)(bp + 4));
        } else {
          v = *(const vu4*)((const u16*)z.Bp + (size_t)n * z.ldb + k);
        }
      }
      bvv[r2] = v; bidx[r2] = (kq * BN + brow) * 8;
    }
    // ---- A staging: issue (possibly sys) loads for both slots, drain once ----
    int rowv[2], kqv2[2], isf[2];
    vf4 fa[2], fb[2]; vu4 ua[2];
    #pragma unroll
    for (int r2 = 0; r2 < 2; r2++){
      int slot = t + r2 * 256;
      int row = slot >> 2, kq = slot & 3;
      int k = k0 + kq * 8;
      Seg4 sg = z.sg[0];
      if (k >= sg.K){ k -= sg.K; sg = z.sg[1];
        if (k >= sg.K){ k -= sg.K; sg = z.sg[2];
          if (k >= sg.K){ k -= sg.K; sg = z.sg[3]; } } }
      rowv[r2] = row; kqv2[r2] = kq; isf[r2] = sg.f32;
      if (sg.f32){
        const float* ap = (const float*)sg.p + (size_t)row * sg.ld + k;
        if (sg.nt) ld32_nw(ap, fa[r2], fb[r2]);
        else { fa[r2] = *(const vf4*)ap; fb[r2] = *(const vf4*)(ap + 4); }
      } else {
        const u16* up = (const u16*)sg.p + (size_t)row * sg.ld + k;
        if (sg.nt) ld16_nw(up, ua[r2]);
        else ua[r2] = *(const vu4*)up;
      }
    }
    vm_drain();
    #pragma unroll
    for (int r2 = 0; r2 < BN/64; r2++) *(vu4*)&Bl[bidx[r2]] = bvv[r2];
    #pragma unroll
    for (int r2 = 0; r2 < 2; r2++){
      vu4 v = isf[r2] ? cvt8v(fa[r2], fb[r2]) : ua[r2];
      *(vu4*)&Al[(((rowv[r2] >> 4) << 6) + (kqv2[r2] << 4) + (rowv[r2] & 15)) * 8] = v;
    }
    __syncthreads();
    bfrag af[FRS], bv[4];
    #pragma unroll
    for (int fr = 0; fr < FRS; fr++) af[fr] = *(bfrag*)&Al[(((rowbase >> 4) + fr) * 64 + lane) * 8];
    #pragma unroll
    for (int fc = 0; fc < 4; fc++) bv[fc] = *(bfrag*)&Bl[(((lane >> 4) * BN) + wn * 64 + fc * 16 + (lane & 15)) * 8];
    #pragma unroll
    for (int fr = 0; fr < FRS; fr++)
      #pragma unroll
      for (int fc = 0; fc < 4; fc++)
        acc[fr][fc] = __builtin_amdgcn_mfma_f32_16x16x32_bf16(af[fr], bv[fc], acc[fr][fc], 0, 0, 0);
    __syncthreads();
  }

  float* Cf = z.Cp + (size_t)ks * z.cslab;
  #pragma unroll
  for (int fc = 0; fc < 4; fc++){
    int n = tn * BN + wn * 64 + fc * 16 + (lane & 15);
    if (n >= z.N) continue;
    float bs = z.bias ? z.bias[n] : 0.f;
    #pragma unroll
    for (int fr = 0; fr < FRS; fr++){
      #pragma unroll
      for (int i = 0; i < 4; i++){
        int m = rowbase + fr * 16 + ((lane >> 4) << 2) + i;
        st4_sys(&Cf[(size_t)m * z.ldc + n], acc[fr][fc][i] + bs);
      }
    }
  }
}

// ================ device-side fused GRU step (h@Whh MFMA + epilogue) ================
// MODE 1 = pointer unit (gi from ptr(B,8)@Wih); MODE 2 = decoder (gi = 4 K-split slabs)
// h state (hb/hf in, hnf/hnb out) is cross-block communicated -> sys access.
template<int MODE>
DEVI void dev_gru3(int g0, const u16* hb, const float* hf, const float* Whh,
                   const float* gi_f, const float* xp, const float* Wih,
                   const float* bih, const float* bhh,
                   float* hnf, u16* hnb, short* Al, short* Bl)
{
  int t = threadIdx.x, lane = t & 63, w = t >> 6;
  int wm = w >> 1, wn = w & 1;
  ffrag zz4 = {0.f, 0.f, 0.f, 0.f};
  ffrag acc[4][3];
  #pragma unroll
  for (int i = 0; i < 4; i++)
    #pragma unroll
    for (int j = 0; j < 3; j++) acc[i][j] = zz4;

  for (int k0 = 0; k0 < 512; k0 += 32){
    // ---- B (Whh, cached) loads issued first ----
    int lb0 = t >> 2, kq0b = t & 3;
    {
      int wn2 = lb0 / 48, rem = lb0 - wn2 * 48, fc = rem >> 4, i16 = rem & 15;
      int grow = fc * 512 + g0 + wn2 * 16 + i16;
      const float* wp = Whh + (size_t)grow * 512 + k0 + kq0b * 8;
      vf4 wa = *(const vf4*)wp, wb = *(const vf4*)(wp + 4);
      // ---- A (h, communicated) sys loads ----
      int rowA0 = t >> 2, kqA0 = t & 3;
      int rowA1 = (t + 256) >> 2, kqA1 = (t + 256) & 3;
      vu4 hv0, hv1;
      ld16_nw(hb + (size_t)rowA0 * 512 + k0 + kqA0 * 8, hv0);
      ld16_nw(hb + (size_t)rowA1 * 512 + k0 + kqA1 * 8, hv1);
      vf4 wa1, wb1; int lb1 = 0, kq1b = 0;
      if (t < 128){
        int slot = t + 256;
        lb1 = slot >> 2; kq1b = slot & 3;
        int wn21 = lb1 / 48, rem1 = lb1 - wn21 * 48, fc1 = rem1 >> 4, i161 = rem1 & 15;
        int grow1 = fc1 * 512 + g0 + wn21 * 16 + i161;
        const float* wp1 = Whh + (size_t)grow1 * 512 + k0 + kq1b * 8;
        wa1 = *(const vf4*)wp1; wb1 = *(const vf4*)(wp1 + 4);
      }
      vm_drain();
      *(vu4*)&Bl[(kq0b * 96 + lb0) * 8] = cvt8v(wa, wb);
      if (t < 128) *(vu4*)&Bl[(kq1b * 96 + lb1) * 8] = cvt8v(wa1, wb1);
      *(vu4*)&Al[(((rowA0 >> 4) << 6) + (kqA0 << 4) + (rowA0 & 15)) * 8] = hv0;
      *(vu4*)&Al[(((rowA1 >> 4) << 6) + (kqA1 << 4) + (rowA1 & 15)) * 8] = hv1;
    }
    __syncthreads();
    bfrag af[4], bv[3];
    #pragma unroll
    for (int fr = 0; fr < 4; fr++) af[fr] = *(bfrag*)&Al[((wm * 4 + fr) * 64 + lane) * 8];
    #pragma unroll
    for (int fc = 0; fc < 3; fc++) bv[fc] = *(bfrag*)&Bl[((lane >> 4) * 96 + (wn * 3 + fc) * 16 + (lane & 15)) * 8];
    #pragma unroll
    for (int fr = 0; fr < 4; fr++)
      #pragma unroll
      for (int fc = 0; fc < 3; fc++)
        acc[fr][fc] = __builtin_amdgcn_mfma_f32_16x16x32_bf16(af[fr], bv[fc], acc[fr][fc], 0, 0, 0);
    __syncthreads();
  }

  // MODE1: stage xp (PTRS slice, communicated) into LDS once
  float* xl = (float*)Al;
  if (MODE == 1){
    for (int i = t; i < 1024; i += 256) xl[i] = ld4f_sys(xp + i);
    __syncthreads();
  }

  int gcol = g0 + wn * 16 + (lane & 15);
  float bir = bih[gcol],        bhr = bhh[gcol];
  float biz = bih[512 + gcol],  bhz = bhh[512 + gcol];
  float bin = bih[1024 + gcol], bhn = bhh[1024 + gcol];
  float wxr[8], wxz[8], wxn[8];
  if (MODE == 1){
    #pragma unroll
    for (int a2 = 0; a2 < 8; a2++){
      wxr[a2] = Wih[(size_t)gcol * 8 + a2];
      wxz[a2] = Wih[(size_t)(512 + gcol) * 8 + a2];
      wxn[a2] = Wih[(size_t)(1024 + gcol) * 8 + a2];
    }
  }
  #pragma unroll
  for (int fr = 0; fr < 4; fr++){
    #pragma unroll
    for (int i = 0; i < 4; i++){
      int brow = wm * 64 + fr * 16 + ((lane >> 4) << 2) + i;
      float gr_, gz_, gn_;
      if (MODE == 2){
        gr_ = gz_ = gn_ = 0.f;
        #pragma unroll
        for (int sl = 0; sl < 4; sl++){
          const float* gp = gi_f + (size_t)sl * 196608 + (size_t)brow * 1536;
          gr_ += ld4f_sys(gp + gcol); gz_ += ld4f_sys(gp + 512 + gcol); gn_ += ld4f_sys(gp + 1024 + gcol);
        }
      } else {
        float4 x0 = *(float4*)&xl[brow * 8];
        float4 x1 = *(float4*)&xl[brow * 8 + 4];
        float xa[8] = {x0.x, x0.y, x0.z, x0.w, x1.x, x1.y, x1.z, x1.w};
        gr_ = gz_ = gn_ = 0.f;
        #pragma unroll
        for (int a2 = 0; a2 < 8; a2++){ gr_ += xa[a2]*wxr[a2]; gz_ += xa[a2]*wxz[a2]; gn_ += xa[a2]*wxn[a2]; }
      }
      float hold = ld4f_sys(hf + (size_t)brow * 512 + gcol);
      float r  = sigmf_(gr_ + acc[fr][0][i] + bir + bhr);
      float zg = sigmf_(gz_ + acc[fr][1][i] + biz + bhz);
      float n  = tanhf_(gn_ + bin + r * (acc[fr][2][i] + bhn));
      float hn = (1.f - zg) * n + zg * hold;
      size_t idx = (size_t)brow * 512 + gcol;
      st4_sys(hnf + idx, hn);
      st2_sys(hnb + idx, f2b(hn));
    }
  }
}

// ================ device-side attention pieces ================
DEVI void dev_puattn(int b, const float* hida2, const float* Ka, const float* cae,
                     const float* Am, const float* Ain, const u16* enc,
                     float* vpre, float* ptrs, float* fs)
{
  int t = threadIdx.x, lane = t & 63, w = t >> 6;
  float* sc0 = fs; float* sc1 = fs + 256;
  float* wred = fs + 512;   // 36
  float* qa   = fs + 560;   // 20
  float* cd   = fs + 584;   // 16
  float* red  = fs + 604;   // 8

  for (int u = 0; u < 2; u++){
    const float* hp = hida2 + ((size_t)u * 128 + b) * 512;
    float hv0 = ld4f_sys(hp + t), hv1 = ld4f_sys(hp + t + 256);
    const float* k0p = Ka + u * 8192 + t * 16;
    const float* k1p = Ka + u * 8192 + (t + 256) * 16;
    float p[9];
    #pragma unroll
    for (int j = 0; j < 9; j++) p[j] = hv0 * k0p[j] + hv1 * k1p[j];
    #pragma unroll
    for (int j = 0; j < 9; j++){
      #pragma unroll
      for (int off = 32; off > 0; off >>= 1) p[j] += __shfl_xor(p[j], off);
    }
    if (lane == 0){
      #pragma unroll
      for (int j = 0; j < 9; j++) wred[w * 9 + j] = p[j];
    }
    __syncthreads();
    if (t < 9) qa[u * 10 + t] = wred[t] + wred[9 + t] + wred[18 + t] + wred[27 + t] + cae[u * 16 + t];
    __syncthreads();
  }

  float su[2];
  #pragma unroll
  for (int u = 0; u < 2; u++){
    const float* amp = Am + (((size_t)u * 256 + t) * 128 + b) * 8;
    float4 a0 = *(const float4*)amp;
    float4 a1 = *(const float4*)(amp + 4);
    const float* q = qa + u * 10;
    su[u] = (q[8] + q[0]*a0.x + q[1]*a0.y + q[2]*a0.z + q[3]*a0.w
                  + q[4]*a1.x + q[5]*a1.y + q[6]*a1.z + q[7]*a1.w) * SCALE_ATT;
  }

  const float* ap = Ain + ((size_t)b * 256 + t) * 8;
  float av[8];
  {
    float4 v0 = *(const float4*)ap;
    float4 v1 = *(const float4*)(ap + 4);
    av[0]=v0.x; av[1]=v0.y; av[2]=v0.z; av[3]=v0.w;
    av[4]=v1.x; av[5]=v1.y; av[6]=v1.z; av[7]=v1.w;
  }

  float inv[2];
  for (int u = 0; u < 2; u++){
    float s_ = su[u];
    float* sc = u ? sc1 : sc0;
    // wave-level max + 4-way combine (2 syncs, no LDS tree)
    float m = s_;
    #pragma unroll
    for (int off = 32; off > 0; off >>= 1) m = fmaxf(m, __shfl_xor(m, off));
    if (lane == 0) red[w] = m;
    __syncthreads();
    float mx = fmaxf(fmaxf(red[0], red[1]), fmaxf(red[2], red[3]));
    float e = __expf(s_ - mx); sc[t] = e;
    // joint shuffle reduce: denominator + 8 pointer-address components (no LDS atomics)
    float ca[9];
    ca[8] = e;
    #pragma unroll
    for (int a2 = 0; a2 < 8; a2++) ca[a2] = e * av[a2];
    #pragma unroll
    for (int j = 0; j < 9; j++){
      #pragma unroll
      for (int off = 32; off > 0; off >>= 1) ca[j] += __shfl_xor(ca[j], off);
    }
    if (lane == 0){
      #pragma unroll
      for (int j = 0; j < 9; j++) wred[w * 9 + j] = ca[j];
    }
    __syncthreads();
    if (t < 9){
      float v = wred[t] + wred[9 + t] + wred[18 + t] + wred[27 + t];
      if (t < 8) cd[u * 8 + t] = v;
      else red[4 + u] = v;
    }
    __syncthreads();
    inv[u] = 1.f / red[4 + u];
  }
  if (t < 8){
    st4_sys(&ptrs[((size_t)0 * 128 + b) * 8 + t], cd[t] * inv[0]);
    st4_sys(&ptrs[((size_t)128 + b) * 8 + t],     cd[8 + t] * inv[1]);
  }

  // value pass over ENC: thread t owns cols 2t,2t+1; deep unroll for MLP
  float a00 = 0.f, a01 = 0.f, a10 = 0.f, a11 = 0.f;
  const u16* ep = enc + (size_t)b * 512;
  #pragma unroll 16
  for (int s2 = 0; s2 < 256; s2++){
    float w0 = sc0[s2], w1 = sc1[s2];
    u32 pv = *(const u32*)(ep + (size_t)s2 * 65536 + 2 * t);
    float v0 = b2f((u16)pv);
    float v1 = b2f((u16)(pv >> 16));
    a00 += w0 * v0; a01 += w0 * v1; a10 += w1 * v0; a11 += w1 * v1;
  }
  float* vp = vpre + (size_t)b * 1024;
  st4_sys(&vp[2 * t], a00 * inv[0]);           st4_sys(&vp[2 * t + 1], a01 * inv[0]);
  st4_sys(&vp[512 + 2 * t], a10 * inv[1]);     st4_sys(&vp[512 + 2 * t + 1], a11 * inv[1]);
}

DEVI void dev_bahd(int b, const u16* eatt, const float* dpart, const float* vvec,
                   const u16* enc, float* ctx, float* fs)
{
  int t = threadIdx.x, lane = t & 63, w = t >> 6;
  float* dp = fs; float* vv = fs + 512; float* sc = fs + 1024; float* red = fs + 1280;
  dp[t] = ld4f_sys(dpart + (size_t)b * 512 + t);
  dp[t + 256] = ld4f_sys(dpart + (size_t)b * 512 + t + 256);
  vv[t] = vvec[t]; vv[t + 256] = vvec[t + 256];
  __syncthreads();
  float4 d0 = *(float4*)&dp[lane * 8], d1 = *(float4*)&dp[lane * 8 + 4];
  float4 v0 = *(float4*)&vv[lane * 8], v1 = *(float4*)&vv[lane * 8 + 4];
  // score pass: batch 8 independent row loads per wave (8x MLP)
  for (int sb = 0; sb < 256; sb += 32){
    uint4 vl[8];
    #pragma unroll
    for (int i = 0; i < 8; i++){
      int s = sb + i * 4 + w;
      vl[i] = *(const uint4*)(eatt + ((size_t)s * 128 + b) * 512 + lane * 8);
    }
    #pragma unroll
    for (int i = 0; i < 8; i++){
      const u16* h = (const u16*)&vl[i];
      float r = fmaxf(0.f, b2f(h[0]) + d0.x) * v0.x + fmaxf(0.f, b2f(h[1]) + d0.y) * v0.y
              + fmaxf(0.f, b2f(h[2]) + d0.z) * v0.z + fmaxf(0.f, b2f(h[3]) + d0.w) * v0.w
              + fmaxf(0.f, b2f(h[4]) + d1.x) * v1.x + fmaxf(0.f, b2f(h[5]) + d1.y) * v1.y
              + fmaxf(0.f, b2f(h[6]) + d1.z) * v1.z + fmaxf(0.f, b2f(h[7]) + d1.w) * v1.w;
      #pragma unroll
      for (int off = 32; off > 0; off >>= 1) r += __shfl_xor(r, off);
      if (lane == 0) sc[sb + i * 4 + w] = r;
    }
  }
  __syncthreads();
  float s0 = sc[t];
  float m = s0;
  #pragma unroll
  for (int off = 32; off > 0; off >>= 1) m = fmaxf(m, __shfl_xor(m, off));
  if (lane == 0) red[w] = m;
  __syncthreads();
  float mx = fmaxf(fmaxf(red[0], red[1]), fmaxf(red[2], red[3]));
  float e = __expf(s0 - mx); sc[t] = e;
  float sum = e;
  #pragma unroll
  for (int off = 32; off > 0; off >>= 1) sum += __shfl_xor(sum, off);
  if (lane == 0) red[4 + w] = sum;
  __syncthreads();
  float inv = 1.f / (red[4] + red[5] + red[6] + red[7]);
  float a0 = 0.f, a1 = 0.f;
  const u16* ep = enc + (size_t)b * 512;
  #pragma unroll 16
  for (int s2 = 0; s2 < 256; s2++){
    float wgt = sc[s2];
    u32 pv = *(const u32*)(ep + (size_t)s2 * 65536 + 2 * t);
    a0 += wgt * b2f((u16)pv);
    a1 += wgt * b2f((u16)(pv >> 16));
  }
  st4_sys(&ctx[(size_t)b * 512 + 2 * t], a0 * inv);
  st4_sys(&ctx[(size_t)b * 512 + 2 * t + 1], a1 * inv);
}

DEVI void dev_cattn(int b, const float* qck, const u16* enc, float* cv2p, float* fs)
{
  int t = threadIdx.x, lane = t & 63, w = t >> 6;
  float* qv = fs; float* sc = fs + 1024; float* red = fs + 1280;
  qv[t] = ld4f_sys(qck + (size_t)b * 520 + t);
  qv[t + 256] = ld4f_sys(qck + (size_t)b * 520 + t + 256);
  __syncthreads();
  float qc0 = ld4f_sys(qck + (size_t)b * 520 + 512);
  float4 q0 = *(float4*)&qv[lane * 8], q1 = *(float4*)&qv[lane * 8 + 4];
  for (int sb = 0; sb < 256; sb += 32){
    uint4 vl[8];
    #pragma unroll
    for (int i = 0; i < 8; i++){
      int s = sb + i * 4 + w;
      vl[i] = *(const uint4*)(enc + ((size_t)s * 128 + b) * 512 + lane * 8);
    }
    #pragma unroll
    for (int i = 0; i < 8; i++){
      const u16* h = (const u16*)&vl[i];
      float r = b2f(h[0])*q0.x + b2f(h[1])*q0.y + b2f(h[2])*q0.z + b2f(h[3])*q0.w
              + b2f(h[4])*q1.x + b2f(h[5])*q1.y + b2f(h[6])*q1.z + b2f(h[7])*q1.w;
      #pragma unroll
      for (int off = 32; off > 0; off >>= 1) r += __shfl_xor(r, off);
      if (lane == 0) sc[sb + i * 4 + w] = (r + qc0) * SCALE_ATT;
    }
  }
  __syncthreads();
  float s0 = sc[t];
  float m = s0;
  #pragma unroll
  for (int off = 32; off > 0; off >>= 1) m = fmaxf(m, __shfl_xor(m, off));
  if (lane == 0) red[w] = m;
  __syncthreads();
  float mx = fmaxf(fmaxf(red[0], red[1]), fmaxf(red[2], red[3]));
  float e = __expf(s0 - mx); sc[t] = e;
  float sum = e;
  #pragma unroll
  for (int off = 32; off > 0; off >>= 1) sum += __shfl_xor(sum, off);
  if (lane == 0) red[4 + w] = sum;
  __syncthreads();
  float inv = 1.f / (red[4] + red[5] + red[6] + red[7]);
  float a0 = 0.f, a1 = 0.f;
  const u16* ep = enc + (size_t)b * 512;
  #pragma unroll 16
  for (int s2 = 0; s2 < 256; s2++){
    float wgt = sc[s2];
    u32 pv = *(const u32*)(ep + (size_t)s2 * 65536 + 2 * t);
    a0 += wgt * b2f((u16)pv);
    a1 += wgt * b2f((u16)(pv >> 16));
  }
  st4_sys(&cv2p[(size_t)b * 512 + 2 * t], a0 * inv);
  st4_sys(&cv2p[(size_t)b * 512 + 2 * t + 1], a1 * inv);
}

DEVI void dev_outcvt(int b, const float* outt, const float* outb2, float* dst)
{
  int t = threadIdx.x;
  #pragma unroll
  for (int rep = 0; rep < 2; rep++){
    int o = t + rep * 256;
    float s = ld4f_sys(outt + (size_t)b * 512 + o) + ld4f_sys(outt + 65536 + (size_t)b * 512 + o)
            + ld4f_sys(outt + 131072 + (size_t)b * 512 + o) + ld4f_sys(outt + 196608 + (size_t)b * 512 + o);
    dst[(size_t)b * 512 + o] = s + outb2[o];   // final output: flushed at kernel end
  }
}

// ================ persistent encoder (32 steps per launch, manual barrier) ================
struct EncArgs {
  const float *WhhF, *WhhB, *giF, *giB;
  const float *bihF, *bhhF, *bihB, *bhhB;
  float *HF, *HB; u16 *HFB, *HBB, *ENC;
  u32 *BAR; int bar0;
  int s0;
};

__global__ __launch_bounds__(256) void k_enc(EncArgs a)
{
  __shared__ short Bw[24576];   // 48 rows (3 gates x 16 cols) x 512 K, bf16, MFMA layout
  __shared__ short Al[4096];
  int blk = blockIdx.x;
  int d = blk >> 5, gt = blk & 31;
  int t = threadIdx.x, lane = t & 63, w = t >> 6;

  const float* Whh = d ? a.WhhB : a.WhhF;
  for (int c = t; c < 3072; c += 256){
    int brow = c >> 6, kc = c & 63;
    int grow = (brow >> 4) * 512 + gt * 16 + (brow & 15);
    const float* wp = Whh + (size_t)grow * 512 + kc * 8;
    *(uint4*)&Bw[((kc * 48) + brow) * 8] = cvt8(*(const float4*)wp, *(const float4*)(wp + 4));
  }
  const float* bih = d ? a.bihB : a.bihF;
  const float* bhh = d ? a.bhhB : a.bhhF;
  int gcol = gt * 16 + (lane & 15);
  float bir = bih[gcol],        bhr = bhh[gcol];
  float biz = bih[512 + gcol],  bhz = bhh[512 + gcol];
  float bin = bih[1024 + gcol], bhn = bhh[1024 + gcol];
  float* hf_base = d ? a.HB : a.HF;
  u16*   hb_base = d ? a.HBB : a.HFB;
  const float* gi_base = d ? a.giB : a.giF;
  __syncthreads();

  for (int si = 0; si < 32; si++){
    int s = a.s0 + si;
    const u16* hb = hb_base + (size_t)(s & 1) * 65536;
    const float* hf = hf_base + (size_t)(s & 1) * 65536;
    float* hnf = hf_base + (size_t)((s + 1) & 1) * 65536;
    u16* hnb = hb_base + (size_t)((s + 1) & 1) * 65536;
    u16* eacc = a.ENC + (size_t)(d ? 255 - s : s) * 65536;

    ffrag zz4 = {0.f, 0.f, 0.f, 0.f};
    ffrag acc[2][3];
    #pragma unroll
    for (int i = 0; i < 2; i++)
      #pragma unroll
      for (int j = 0; j < 3; j++) acc[i][j] = zz4;

    for (int ki = 0; ki < 16; ki++){
      int k0 = ki * 32;
      // h state is cross-block communicated -> sys loads, one drain
      int row0 = t >> 2, kq0 = t & 3;
      int row1 = (t + 256) >> 2, kq1 = (t + 256) & 3;
      vu4 hv0, hv1;
      ld16_nw(hb + (size_t)row0 * 512 + k0 + kq0 * 8, hv0);
      ld16_nw(hb + (size_t)row1 * 512 + k0 + kq1 * 8, hv1);
      vm_drain();
      *(vu4*)&Al[(((row0 >> 4) << 6) + (kq0 << 4) + (row0 & 15)) * 8] = hv0;
      *(vu4*)&Al[(((row1 >> 4) << 6) + (kq1 << 4) + (row1 & 15)) * 8] = hv1;
      __syncthreads();
      bfrag af[2], bv[3];
      #pragma unroll
      for (int fr = 0; fr < 2; fr++) af[fr] = *(bfrag*)&Al[(((w * 2 + fr) * 64) + lane) * 8];
      #pragma unroll
      for (int fc = 0; fc < 3; fc++) bv[fc] = *(bfrag*)&Bw[(((ki * 4 + (lane >> 4)) * 48) + fc * 16 + (lane & 15)) * 8];
      #pragma unroll
      for (int fr = 0; fr < 2; fr++)
        #pragma unroll
        for (int fc = 0; fc < 3; fc++)
          acc[fr][fc] = __builtin_amdgcn_mfma_f32_16x16x32_bf16(af[fr], bv[fc], acc[fr][fc], 0, 0, 0);
      __syncthreads();
    }

    const float* gp0 = gi_base + (size_t)si * 196608;
    #pragma unroll
    for (int fr = 0; fr < 2; fr++){
      #pragma unroll
      for (int i = 0; i < 4; i++){
        int brow = w * 32 + fr * 16 + ((lane >> 4) << 2) + i;
        const float* gp = gp0 + (size_t)brow * 1536;
        float gr_ = gp[gcol], gz_ = gp[512 + gcol], gn_ = gp[1024 + gcol];
        float hold = ld4f_sys(hf + (size_t)brow * 512 + gcol);
        float r  = sigmf_(gr_ + acc[fr][0][i] + bir + bhr);
        float zg = sigmf_(gz_ + acc[fr][1][i] + biz + bhz);
        float n  = tanhf_(gn_ + bin + r * (acc[fr][2][i] + bhn));
        float hn = (1.f - zg) * n + zg * hold;
        size_t idx = (size_t)brow * 512 + gcol;
        st4_sys(hnf + idx, hn);
        st2_sys(hnb + idx, f2b(hn));
        eacc[idx] = f2b(b2f(eacc[idx]) + hn);   // block-private slice; cross-launch coherence only
      }
    }
    gridbar2(a.BAR + BAR_ENCF, a.BAR + BAR_ENCGO, (u32)(a.s0 + si + 1), 64, blk, 0);
  }
}

// ================ persistent decoder (all 64 steps, 4 barriers/step) ================
// Phase A is dissolved: puGRU(st+1) runs in phase C(st) (needs PTRS from B(st)),
// dpart GEMM(st+1) runs in phase E(st) (needs dechb from D(st)), outcvt(st-1)
// runs in phase C(st). One-time prologue handles puGRU(0)/dpart(0).
struct DecArgs {
  const float *tgt, *Ag, *AM, *KA, *CAE, *dattW, *dattv;
  const float *puWhh, *puWih, *pubih, *pubhh;
  const float *dWhh, *DBIH2, *dbhh, *VKE2, *OUTB2;
  const u16 *ENC, *EATT, *DWF, *MKTW, *OWF;
  float *HIDA; u16 *HIDAB;
  float *DECH; u16 *DECHB;
  float *HF0; u16 *HFB0;
  float *PTRS, *VPRE, *CTX, *DPART, *QCK, *CV2P, *GIDEC, *OUTT, *out;
  u32 *BAR;
};

__global__ __launch_bounds__(256) void k_dec(DecArgs a)
{
  __shared__ short Al[4096];
  __shared__ short Bl[4096];
  __shared__ float fs[1600];
  const int blk = blockIdx.x;
  const Seg4 S4SENT = {nullptr, 0, 0, 1 << 30, 0};
  u32* dF = a.BAR + BAR_DECF;
  u32* dG = a.BAR + BAR_DECGO;
  const int GATHER = 230;   // busy only in phase B (bahd) -> polls start early elsewhere

  // helper lambda-free: puGRU for step s on unit u, gate block g0
  // reads HIDA[s&1], writes HIDA[(s+1)&1]
  #define PU_GRU(s_, u_, g0_) do { \
    int s__ = (s_); int u__ = (u_); \
    const u16*  pc_ = a.HIDAB + (size_t)(s__ & 1) * 131072 + (size_t)u__ * 65536; \
    const float* pf_ = a.HIDA  + (size_t)(s__ & 1) * 131072 + (size_t)u__ * 65536; \
    float* pn_  = a.HIDA  + (size_t)((s__ + 1) & 1) * 131072 + (size_t)u__ * 65536; \
    u16*   pnb_ = a.HIDAB + (size_t)((s__ + 1) & 1) * 131072 + (size_t)u__ * 65536; \
    dev_gru3<1>((g0_), pc_, pf_, a.puWhh + (size_t)u__ * 786432, nullptr, \
                a.PTRS + u__ * 1024, a.puWih + (size_t)u__ * 12288, \
                a.pubih + u__ * 1536, a.pubhh + u__ * 1536, pn_, pnb_, Al, Bl); \
  } while(0)

  #define DPART_GEMM(srcb_, tn_) do { \
    Z4 z_; \
    z_.sg[0] = {(srcb_), 512, 0, 512, 1}; z_.sg[1] = S4SENT; z_.sg[2] = S4SENT; z_.sg[3] = S4SENT; \
    z_.Bp = a.dattW; z_.ldb = 1024; z_.bf32 = 1; z_.bias = nullptr; \
    z_.Cp = a.DPART; z_.ldc = 512; z_.cslab = 0; z_.N = 512; z_.K = 512; \
    dev_mfma4<64>(z_, (tn_), 0, 1, Al, Bl); \
  } while(0)

  // ---- prologue: puGRU(0) | dpart(0)  (one extra barrier, once) ----
  if (blk < 32){
    int u = blk >> 4, g0 = (blk & 15) * 32;
    PU_GRU(0, u, g0);
  } else if (blk < 40){
    DPART_GEMM(a.HFB0, blk - 32);
  }
  gridbar2(dF, dG, 1u, 256, blk, GATHER);

  for (int st = 0; st < 64; st++){
    const float* dech_c  = (st == 0) ? a.HF0  : a.DECH  + (size_t)((st + 1) & 1) * 65536;
    const u16*   dechb_c = (st == 0) ? a.HFB0 : a.DECHB + (size_t)((st + 1) & 1) * 65536;
    float*       dech_n  = a.DECH  + (size_t)(st & 1) * 65536;
    u16*         dechb_n = a.DECHB + (size_t)(st & 1) * 65536;
    const float* hida_n  = a.HIDA  + (size_t)((st + 1) & 1) * 131072;  // written by puGRU(st)
    u32 seq0 = 2u + (u32)(st * 4);

    // ---- phase B: pointer attention (both units) | Bahdanau
    if (blk < 128){
      dev_puattn(blk, hida_n, a.KA, a.CAE, a.AM, a.Ag, a.ENC, a.VPRE, a.PTRS, fs);
    } else {
      dev_bahd(blk - 128, a.EATT, a.DPART, a.dattv, a.ENC, a.CTX, fs);
    }
    gridbar2(dF, dG, seq0 + 0, 256, blk, GATHER);

    // ---- phase C: gidec GEMM | qck GEMM | puGRU(st+1) | outcvt(st-1)
    if (blk < 48){
      Z4 z;
      z.sg[0] = {a.tgt + (size_t)(st ? st - 1 : 0) * 65536, 512, 1, 512, 0};
      z.sg[1] = {a.VPRE, 1024, 1, 1024, 1};
      z.sg[2] = {a.CTX, 512, 1, 512, 1};
      z.sg[3] = S4SENT;
      z.Bp = a.DWF; z.ldb = 2048; z.bf32 = 0; z.bias = nullptr;
      z.Cp = a.GIDEC; z.ldc = 1536; z.cslab = 196608; z.N = 1536; z.K = 2048;
      dev_mfma4<128>(z, blk % 12, blk / 12, 4, Al, Bl);
    } else if (blk < 57){
      Z4 z;
      z.sg[0] = {a.VPRE, 1024, 1, 1024, 1}; z.sg[1] = S4SENT; z.sg[2] = S4SENT; z.sg[3] = S4SENT;
      z.Bp = a.MKTW; z.ldb = 1024; z.bf32 = 0; z.bias = a.VKE2;
      z.Cp = a.QCK; z.ldc = 520; z.cslab = 0; z.N = 513; z.K = 1024;
      dev_mfma4<64>(z, blk - 48, 0, 1, Al, Bl);
    } else if (blk < 89){
      if (st < 63){
        int u = (blk - 57) >> 4, g0 = ((blk - 57) & 15) * 32;
        PU_GRU(st + 1, u, g0);
      }
    } else if (blk < 217 && st > 0){
      dev_outcvt(blk - 89, a.OUTT, a.OUTB2, a.out + (size_t)(st - 1) * 65536);
    }
    gridbar2(dF, dG, seq0 + 1, 256, blk, GATHER);

    // ---- phase D: decoder GRU combine | content attention
    if (blk < 16){
      dev_gru3<2>(blk * 32, dechb_c, dech_c, a.dWhh, a.GIDEC, nullptr, nullptr,
                  a.DBIH2, a.dbhh, dech_n, dechb_n, Al, Bl);
    } else if (blk < 144){
      dev_cattn(blk - 16, a.QCK, a.ENC, a.CV2P, fs);
    }
    gridbar2(dF, dG, seq0 + 2, 256, blk, GATHER);

    // ---- phase E: folded output head GEMM (K=2560, split-K 4) | dpart(st+1)
    if (blk < 32){
      Z4 z;
      z.sg[0] = {dechb_n, 512, 0, 512, 1};
      z.sg[1] = {a.CTX, 512, 1, 512, 1};
      z.sg[2] = {a.VPRE, 1024, 1, 1024, 1};
      z.sg[3] = {a.CV2P, 512, 1, 512, 1};
      z.Bp = a.OWF; z.ldb = 2560; z.bf32 = 0; z.bias = nullptr;
      z.Cp = a.OUTT; z.ldc = 512; z.cslab = 65536; z.N = 512; z.K = 2560;
      dev_mfma4<64>(z, blk & 7, blk >> 3, 4, Al, Bl);
    } else if (blk < 40){
      if (st < 63) DPART_GEMM(dechb_n, blk - 32);
    }
    gridbar2(dF, dG, seq0 + 3, 256, blk, GATHER);
  }
  if (blk < 128) dev_outcvt(blk, a.OUTT, a.OUTB2, a.out + 63ull * 65536);
  #undef PU_GRU
  #undef DPART_GEMM
}

// ================ setup: batched fold jobs ================
struct Job {
  const float* A; const float* B; const float* D; void* C;
  int Asm, Ask, Bsk, Bsn, Dsm, Dsn, Csm, Csn;
  int cbf, M, N, K, kind;
};
struct Jobs { Job j[24]; int nj; long long off[25]; };

__global__ __launch_bounds__(256) void k_setup(Jobs J)
{
  long long total = J.off[J.nj];
  for (long long tid = (long long)blockIdx.x * 256 + threadIdx.x; tid < total; tid += (long long)gridDim.x * 256){
    int ji = 0;
    while (tid >= J.off[ji + 1]) ji++;
    Job jb = J.j[ji];
    long long l = tid - J.off[ji];
    if (jb.kind == 0){
      int m = (int)(l / jb.N), n = (int)(l - (long long)m * jb.N);
      float acc = 0.f;
      const float* ap = jb.A + (size_t)m * jb.Asm;
      const float* bp = jb.B + (size_t)n * jb.Bsn;
      for (int k = 0; k < jb.K; k++)
        acc += ap[(size_t)k * jb.Ask] * bp[(size_t)k * jb.Bsk];
      if (jb.D) acc += jb.D[(size_t)m * jb.Dsm + (size_t)n * jb.Dsn];
      if (jb.cbf) ((u16*)jb.C)[(size_t)m * jb.Csm + (size_t)n * jb.Csn] = f2b(acc);
      else ((float*)jb.C)[(size_t)m * jb.Csm + (size_t)n * jb.Csn] = acc;
    } else if (jb.kind == 1){
      int m = (int)(l / jb.N), n = (int)(l - (long long)m * jb.N);
      ((u16*)jb.C)[(size_t)m * jb.Csm + (size_t)n * jb.Csn] = f2b(jb.A[(size_t)m * jb.Asm + (size_t)n * jb.Ask]);
    } else if (jb.kind == 2){
      int u = (int)(l >> 15), sb = (int)(l & 32767);
      float x[8];
      #pragma unroll
      for (int a2 = 0; a2 < 8; a2++) x[a2] = jb.A[(size_t)sb * 8 + a2];
      float* op = (float*)jb.C + ((size_t)u * 32768 + sb) * 8;
      #pragma unroll
      for (int c = 0; c < 8; c++){
        float acc = jb.D[u * 8 + c];
        #pragma unroll
        for (int a2 = 0; a2 < 8; a2++) acc += x[a2] * jb.B[(u * 8 + c) * 8 + a2];
        op[c] = acc;
      }
    } else {
      int u = (int)(l >> 10), r = (int)(l & 1023);
      int bb = r >> 3, aa = r & 7;
      int su = u ? 255 : 0;
      ((float*)jb.C)[l] = jb.A[((size_t)su * 128 + bb) * 8 + aa];
    }
  }
}

// ================ host ================
static inline Seg mkseg(const void* p, int ld, int f32, int K){ Seg s; s.p = p; s.ld = ld; s.f32 = f32; s.K = K; return s; }
static const Seg SENT = {nullptr, 0, 0, 1 << 30};

static inline void addJ(Jobs& JS, Job jb, long long cnt){
  JS.j[JS.nj] = jb;
  JS.off[JS.nj + 1] = JS.off[JS.nj] + cnt;
  JS.nj++;
}
static inline Job JG(const float* A, int Asm, int Ask, const float* B, int Bsk, int Bsn,
                     const float* D, int Dsm, int Dsn, void* C, int Csm, int Csn,
                     int cbf, int M, int N, int K, int kind = 0){
  Job j; j.A=A; j.B=B; j.D=D; j.C=C; j.Asm=Asm; j.Ask=Ask; j.Bsk=Bsk; j.Bsn=Bsn;
  j.Dsm=Dsm; j.Dsn=Dsn; j.Csm=Csm; j.Csn=Csn; j.cbf=cbf; j.M=M; j.N=N; j.K=K; j.kind=kind;
  return j;
}

extern "C" void kernel_launch(void* const* d_in, const int* in_sizes, int n_in,
                              void* d_out, int out_size, void* d_ws, size_t ws_size,
                              hipStream_t stream)
{
  (void)in_sizes; (void)out_size;
  if (n_in < 44 || ws_size < WS_NEED) return;

  const float* src   = (const float*)d_in[0];
  const float* tgt   = (const float*)d_in[1];
  const float* Ag    = (const float*)d_in[2];
  const float* eWihF = (const float*)d_in[3];
  const float* eWhhF = (const float*)d_in[4];
  const float* ebihF = (const float*)d_in[5];
  const float* ebhhF = (const float*)d_in[6];
  const float* eWihB = (const float*)d_in[7];
  const float* eWhhB = (const float*)d_in[8];
  const float* ebihB = (const float*)d_in[9];
  const float* ebhhB = (const float*)d_in[10];
  const float* dattW = (const float*)d_in[11];
  const float* dattb = (const float*)d_in[12];
  const float* dattv = (const float*)d_in[13];
  const float* dWih  = (const float*)d_in[14];
  const float* dWhh  = (const float*)d_in[15];
  const float* dbih  = (const float*)d_in[16];
  const float* dbhh  = (const float*)d_in[17];
  const float* doW   = (const float*)d_in[18];
  const float* dob   = (const float*)d_in[19];
  const float* puWih = (const float*)d_in[20];
  const float* puWhh = (const float*)d_in[21];
  const float* pubih = (const float*)d_in[22];
  const float* pubhh = (const float*)d_in[23];
  const float* puqW  = (const float*)d_in[24];
  const float* puqb  = (const float*)d_in[25];
  const float* puAW  = (const float*)d_in[26];
  const float* puAb  = (const float*)d_in[27];
  const float* puqp  = (const float*)d_in[28];
  const float* pukp  = (const float*)d_in[29];
  const float* puvp  = (const float*)d_in[30];
  const float* puinb = (const float*)d_in[31];
  const float* puop  = (const float*)d_in[32];
  const float* puob  = (const float*)d_in[33];
  const float* aaq   = (const float*)d_in[34];
  const float* aak   = (const float*)d_in[35];
  const float* aav   = (const float*)d_in[36];
  const float* aainb = (const float*)d_in[37];
  const float* aao   = (const float*)d_in[38];
  const float* aaob  = (const float*)d_in[39];
  const float* tohW  = (const float*)d_in[40];
  const float* tohb  = (const float*)d_in[41];
  const float* outW  = (const float*)d_in[42];
  const float* outb  = (const float*)d_in[43];

  char* ws = (char*)d_ws;
  float* GI    = (float*)(ws + OFF_GI);
  u16*   ENC   = (u16*)(ws + OFF_ENC);
  u16*   EATT  = (u16*)(ws + OFF_EATT);
  float* AM    = (float*)(ws + OFF_AM);
  float* HF    = (float*)(ws + OFF_HF);
  float* HB    = (float*)(ws + OFF_HB);
  u16*   HFB   = (u16*)(ws + OFF_HFB);
  u16*   HBB   = (u16*)(ws + OFF_HBB);
  float* HIDA  = (float*)(ws + OFF_HIDA);
  u16*   HIDAB = (u16*)(ws + OFF_HIDAB);
  u32*   BAR   = (u32*)(ws + OFF_BAR);
  float* DECH  = (float*)(ws + OFF_DECH);
  u16*   DECHB = (u16*)(ws + OFF_DECHB);
  float* PTRS  = (float*)(ws + OFF_PTRS);
  float* VPRE  = (float*)(ws + OFF_VPRE);
  float* CTX   = (float*)(ws + OFF_CTX);
  float* DPART = (float*)(ws + OFF_DPART);
  float* QCK   = (float*)(ws + OFF_QCK);
  float* CV2P  = (float*)(ws + OFF_CV2P);
  float* GIDEC = (float*)(ws + OFF_GIDEC);
  float* OUTT  = (float*)(ws + OFF_OUTT);
  float* WOVF  = (float*)(ws + OFF_WOVF);
  float* WOVCF = (float*)(ws + OFF_WOVCF);
  float* MKTF  = (float*)(ws + OFF_MKTF);
  u16*   DWF   = (u16*)(ws + OFF_DWF);
  u16*   MKTW  = (u16*)(ws + OFF_MKTW);
  u16*   OWF   = (u16*)(ws + OFF_OWF);
  float* BOV   = (float*)(ws + OFF_BOV);
  float* BOVC  = (float*)(ws + OFF_BOVC);
  float* KAx   = (float*)(ws + OFF_KA);
  float* CAE   = (float*)(ws + OFF_CAE);
  float* RT    = (float*)(ws + OFF_RT);
  float* BQC   = (float*)(ws + OFF_BQC);
  float* PMAT  = (float*)(ws + OFF_PMAT);
  float* CQ    = (float*)(ws + OFF_CQ);
  float* VKE2  = (float*)(ws + OFF_VKE2);
  float* DBIH2 = (float*)(ws + OFF_DBIH2);
  float* OUTB2 = (float*)(ws + OFF_OUTB2);

  hipMemsetAsync(ENC, 0, 2ull*256*128*512, stream);
  hipMemsetAsync(ws + OFF_HF, 0, OFF_ZEND - OFF_HF, stream);  // states + barrier flags

  // -------- stage 1: independent folds --------
  {
    Jobs S{}; S.nj = 0; S.off[0] = 0;
    for (int u = 0; u < 2; u++){
      const float* qp  = puqp + (size_t)u * 262144;
      const float* kp  = pukp + (size_t)u * 4096;
      float* RTu = RT + u * 8192;
      addJ(S, JG(qp, 1, 512, kp, 8, 1, nullptr, 0, 0, RTu, 16, 1, 0, 512, 8, 512), 4096);
      addJ(S, JG(qp, 1, 512, puinb + u*1536 + 512, 1, 0, nullptr, 0, 0, RTu + 8, 16, 1, 0, 512, 1, 512), 512);
      addJ(S, JG(qp, 512, 1, puqb + u*512, 1, 0, puinb + u*1536, 1, 0, BQC + u*512, 1, 1, 0, 512, 1, 512), 512);
      addJ(S, JG(puop + (size_t)u*262144, 512, 1, puvp + (size_t)u*262144, 512, 1, nullptr, 0, 0, WOVF + (size_t)u*262144, 512, 1, 0, 512, 512, 512), 262144);
      addJ(S, JG(puop + (size_t)u*262144, 512, 1, puinb + u*1536 + 1024, 1, 0, puob + u*512, 1, 0, BOV + u*512, 1, 1, 0, 512, 1, 512), 512);
    }
    addJ(S, JG(aao, 512, 1, aav, 512, 1, nullptr, 0, 0, WOVCF, 512, 1, 0, 512, 512, 512), 262144);
    addJ(S, JG(aao, 512, 1, aainb + 1024, 1, 0, aaob, 1, 0, BOVC, 1, 1, 0, 512, 1, 512), 512);
    addJ(S, JG(aaq, 1, 512, aak, 512, 1, nullptr, 0, 0, PMAT, 516, 1, 0, 512, 512, 512), 262144);
    addJ(S, JG(aaq, 1, 512, aainb + 512, 1, 0, nullptr, 0, 0, PMAT + 512, 516, 1, 0, 512, 1, 512), 512);
    addJ(S, JG(aaq, 512, 1, tohb, 1, 0, aainb, 1, 0, CQ, 1, 1, 0, 512, 1, 512), 512);
    addJ(S, JG(dWih, 2048, 1, nullptr, 0, 0, nullptr, 0, 0, DWF, 2048, 1, 1, 1536, 512, 0, 1), 786432);
    addJ(S, JG(dWih + 1536, 2048, 1, nullptr, 0, 0, nullptr, 0, 0, DWF + 1536, 2048, 1, 1, 1536, 512, 0, 1), 786432);
    addJ(S, JG(outW, 2048, 1, doW, 1024, 1, nullptr, 0, 0, OWF, 2560, 1, 1, 512, 1024, 512), 524288);
    addJ(S, JG(outW, 2048, 1, dob, 1, 0, outb, 1, 0, OUTB2, 1, 1, 0, 512, 1, 512), 512);
    addJ(S, JG(Ag, 0, 0, puAW, 0, 0, puAb, 0, 0, AM, 0, 0, 0, 0, 0, 0, 2), 65536);
    addJ(S, JG(Ag, 0, 0, nullptr, 0, 0, nullptr, 0, 0, PTRS, 0, 0, 0, 0, 0, 0, 3), 2048);
    k_setup<<<2048, 256, 0, stream>>>(S);
  }
  // -------- stage 2 --------
  {
    Jobs S{}; S.nj = 0; S.off[0] = 0;
    for (int u = 0; u < 2; u++){
      const float* kp = pukp + (size_t)u * 4096;
      addJ(S, JG(puqW + (size_t)u*262144, 1, 512, RT + u*8192, 16, 1, nullptr, 0, 0, KAx + u*8192, 16, 1, 0, 512, 9, 512), 4608);
      addJ(S, JG(BQC + u*512, 0, 1, kp, 8, 1, nullptr, 0, 0, CAE + u*16, 0, 1, 0, 1, 8, 512), 8);
      addJ(S, JG(BQC + u*512, 0, 1, puinb + u*1536 + 512, 1, 0, nullptr, 0, 0, CAE + u*16 + 8, 0, 1, 0, 1, 1, 512), 1);
      addJ(S, JG(dWih + 512 + u*512, 2048, 1, WOVF + (size_t)u*262144, 512, 1, nullptr, 0, 0, DWF + 512 + u*512, 2048, 1, 1, 1536, 512, 512), 786432);
      addJ(S, JG(outW + 512 + u*512, 2048, 1, WOVF + (size_t)u*262144, 512, 1, nullptr, 0, 0, OWF + 1024 + u*512, 2560, 1, 1, 512, 512, 512), 262144);
    }
    addJ(S, JG(tohW, 1, 1024, PMAT, 516, 1, nullptr, 0, 0, MKTF, 1, 1024, 0, 1024, 513, 512), 525312);
    addJ(S, JG(CQ, 0, 1, aak, 512, 1, nullptr, 0, 0, VKE2, 0, 1, 0, 1, 512, 512), 512);
    addJ(S, JG(CQ, 0, 1, aainb + 512, 1, 0, nullptr, 0, 0, VKE2 + 512, 0, 1, 0, 1, 1, 512), 1);
    addJ(S, JG(dWih + 512, 2048, 1, BOV, 1, 0, dbih, 1, 0, DBIH2, 1, 1, 0, 1536, 1, 1024), 1536);
    addJ(S, JG(outW + 1536, 2048, 1, WOVCF, 512, 1, nullptr, 0, 0, OWF + 2048, 2560, 1, 1, 512, 512, 512), 262144);
    addJ(S, JG(outW + 512, 2048, 1, BOV, 1, 0, OUTB2, 1, 0, OUTB2, 1, 1, 0, 512, 1, 1536), 512);
    k_setup<<<2048, 256, 0, stream>>>(S);
  }
  // -------- stage 3 --------
  {
    Jobs S{}; S.nj = 0; S.off[0] = 0;
    for (int u = 0; u < 2; u++)
      addJ(S, JG(MKTF + u*512, 1024, 1, WOVF + (size_t)u*262144, 512, 1, nullptr, 0, 0, MKTW + u*512, 1024, 1, 1, 513, 512, 512), 262656);
    addJ(S, JG(MKTF, 1024, 1, BOV, 1, 0, VKE2, 1, 0, VKE2, 1, 1, 0, 513, 1, 1024), 513);
    k_setup<<<1024, 256, 0, stream>>>(S);
  }

  // -------- encoder: 8 chunks of (gi GEMM + persistent 32-step scan) --------
  for (int c = 0; c < 8; c++){
    int c0 = c * 32;
    NTA nt{};
    nt.tilesN = 12;
    for (int d = 0; d < 2; d++){
      NTZ& zz = nt.z[d];
      zz.sg[0] = mkseg(d == 0 ? (const void*)(src + (size_t)c0 * 65536) : (const void*)src, 512, 1, 512);
      zz.sg[1] = SENT; zz.sg[2] = SENT;
      zz.Bp = d ? eWihB : eWihF; zz.ldb = 512; zz.bf32 = 1;
      zz.bias = nullptr; zz.biasf32 = 0;
      zz.Cp = GI + (size_t)d * 6291456; zz.ldc = 1536; zz.cf32 = 1; zz.cslab = 0;
      zz.N = 1536; zz.rev_s0 = (d == 0) ? -1 : (255 - c0); zz.K = 512;
    }
    k_mfma_nt<128><<<dim3(32*12, 1, 2), 256, 0, stream>>>(nt);

    EncArgs ea;
    ea.WhhF = eWhhF; ea.WhhB = eWhhB;
    ea.giF = GI; ea.giB = GI + 6291456;
    ea.bihF = ebihF; ea.bhhF = ebhhF; ea.bihB = ebihB; ea.bhhB = ebhhB;
    ea.HF = HF; ea.HB = HB; ea.HFB = HFB; ea.HBB = HBB; ea.ENC = ENC;
    ea.BAR = BAR; ea.bar0 = c * 32;
    ea.s0 = c0;
    k_enc<<<dim3(64), dim3(256), 0, stream>>>(ea);
  }

  // -------- enc_att = enc @ W2.T + b --------
  {
    NTA nt{};
    nt.tilesN = 4;
    NTZ& zz = nt.z[0];
    zz.sg[0] = mkseg(ENC, 512, 0, 512); zz.sg[1] = SENT; zz.sg[2] = SENT;
    zz.Bp = dattW + 512; zz.ldb = 1024; zz.bf32 = 1;
    zz.bias = dattb; zz.biasf32 = 1;
    zz.Cp = EATT; zz.ldc = 512; zz.cf32 = 0; zz.cslab = 0;
    zz.N = 512; zz.rev_s0 = -1; zz.K = 512;
    k_mfma_nt<128><<<dim3(256*4, 1, 1), 256, 0, stream>>>(nt);
  }

  // -------- decoder: one persistent kernel, all 64 steps --------
  {
    DecArgs da;
    da.tgt = tgt; da.Ag = Ag; da.AM = AM; da.KA = KAx; da.CAE = CAE;
    da.dattW = dattW; da.dattv = dattv;
    da.puWhh = puWhh; da.puWih = puWih; da.pubih = pubih; da.pubhh = pubhh;
    da.dWhh = dWhh; da.DBIH2 = DBIH2; da.dbhh = dbhh; da.VKE2 = VKE2; da.OUTB2 = OUTB2;
    da.ENC = ENC; da.EATT = EATT; da.DWF = DWF; da.MKTW = MKTW; da.OWF = OWF;
    da.HIDA = HIDA; da.HIDAB = HIDAB; da.DECH = DECH; da.DECHB = DECHB;
    da.HF0 = HF; da.HFB0 = HFB;
    da.PTRS = PTRS; da.VPRE = VPRE; da.CTX = CTX; da.DPART = DPART;
    da.QCK = QCK; da.CV2P = CV2P; da.GIDEC = GIDEC; da.OUTT = OUTT;
    da.out = (float*)d_out;
    da.BAR = BAR;
    k_dec<<<dim3(256), dim3(256), 0, stream>>>(da);
  }
}

// Round 8
// 20310.573 us; speedup vs baseline: 1.5573x; 1.0201x over previous
//
#include <hip/hip_runtime.h>

typedef unsigned short u16;
typedef unsigned int u32;

#define DEVI __device__ __forceinline__

constexpr float SCALE_ATT = 0.04419417382415922f;  // 1/sqrt(512)

// ---------------- workspace layout (bytes) ----------------
constexpr size_t OFF_GI    = 0;                                  // f32 [2][32][128][1536] per-chunk x@Wih
constexpr size_t OFF_ENC   = OFF_GI    + 4ull*2*32*128*1536;
constexpr size_t OFF_EATT  = OFF_ENC   + 2ull*256*128*512;       // bf16 enc, bf16 enc_att
constexpr size_t OFF_AM    = OFF_EATT  + 2ull*256*128*512;       // f32 [2][256][128][8]
constexpr size_t OFF_HF    = OFF_AM    + 4ull*2*256*128*8;       // ---- zero region start
constexpr size_t OFF_HB    = OFF_HF    + 4ull*2*128*512;
constexpr size_t OFF_HFB   = OFF_HB    + 4ull*2*128*512;
constexpr size_t OFF_HBB   = OFF_HFB   + 2ull*2*128*512;
constexpr size_t OFF_HIDA  = OFF_HBB   + 2ull*2*128*512;
constexpr size_t OFF_HIDAB = OFF_HIDA  + 4ull*2*2*128*512;
constexpr size_t OFF_BAR   = OFF_HIDAB + 2ull*2*2*128*512;       // u32 flag lines (see BAR_* below)
constexpr size_t OFF_ZEND  = OFF_BAR   + 98304;                  // ---- zero region end
constexpr size_t OFF_DECH  = OFF_ZEND;
constexpr size_t OFF_DECHB = OFF_DECH  + 4ull*2*128*512;
constexpr size_t OFF_PTRS  = OFF_DECHB + 2ull*2*128*512;         // f32 [2][128][8]
constexpr size_t OFF_VPRE  = OFF_PTRS  + 4ull*2*128*8;           // f32 [128][1024]  (b-major!)
constexpr size_t OFF_CTX   = OFF_VPRE  + 4ull*128*1024;
constexpr size_t OFF_DPART = OFF_CTX   + 4ull*128*512;
constexpr size_t OFF_QCK   = OFF_DPART + 4ull*128*512;           // f32 [128][520] (513 used)
constexpr size_t OFF_CV2P  = OFF_QCK   + 4ull*128*520;
constexpr size_t OFF_GIDEC = OFF_CV2P  + 4ull*128*512;           // f32 4 K-slabs [128][1536]
constexpr size_t OFF_OUTT  = OFF_GIDEC + 4ull*4*128*1536;        // f32 4 K-slabs [128][512]
constexpr size_t OFF_WOVF  = OFF_OUTT  + 4ull*4*128*512;         // f32 [2][512][512]
constexpr size_t OFF_WOVCF = OFF_WOVF  + 4ull*2*512*512;         // f32 [512][512]
constexpr size_t OFF_MKTF  = OFF_WOVCF + 4ull*512*512;           // f32 [513 rows][1024]
constexpr size_t OFF_DWF   = OFF_MKTF  + 4ull*513*1024;          // bf16 [1536][2048] folded dec Wih
constexpr size_t OFF_MKTW  = OFF_DWF   + 2ull*1536*2048;         // bf16 [513][1024] folded qck W
constexpr size_t OFF_OWF   = OFF_MKTW  + 2ull*513*1024;          // bf16 [512][2560] folded out W
constexpr size_t OFF_BOV   = OFF_OWF   + 2ull*512*2560;          // f32 [2][512]  (contiguous w/ BOVC!)
constexpr size_t OFF_BOVC  = OFF_BOV   + 4ull*2*512;             // f32 [512]
constexpr size_t OFF_KA    = OFF_BOVC  + 4ull*512;               // f32 [2][512][16] (9 used)
constexpr size_t OFF_CAE   = OFF_KA    + 4ull*2*512*16;          // f32 [2][16]
constexpr size_t OFF_RT    = OFF_CAE   + 4ull*2*16;              // f32 [2][512][16]
constexpr size_t OFF_BQC   = OFF_RT    + 4ull*2*512*16;          // f32 [2][512]
constexpr size_t OFF_PMAT  = OFF_BQC   + 4ull*2*512;             // f32 [512][516]
constexpr size_t OFF_CQ    = OFF_PMAT  + 4ull*512*516;
constexpr size_t OFF_VKE2  = OFF_CQ    + 4ull*512;               // f32 [520]
constexpr size_t OFF_DBIH2 = OFF_VKE2  + 4ull*520;               // f32 [1536]
constexpr size_t OFF_OUTB2 = OFF_DBIH2 + 4ull*1536;              // f32 [512]
constexpr size_t WS_NEED   = OFF_OUTB2 + 4ull*512;

// ---------------- helpers ----------------
DEVI float b2f(u16 u){ union{u32 i; float f;} x; x.i = ((u32)u) << 16; return x.f; }
DEVI u16 f2b(float f){ union{float f; u32 i;} x; x.f = f; u32 i = x.i; u32 r = i + 0x7FFFu + ((i >> 16) & 1u); return (u16)(r >> 16); }
DEVI float sigmf_(float x){ return 1.f / (1.f + __expf(-x)); }
DEVI float tanhf_(float x){ x = fminf(15.f, fmaxf(-15.f, x)); float e = __expf(2.f*x); return (e - 1.f) / (e + 1.f); }

typedef __attribute__((ext_vector_type(8))) short bfrag;
typedef __attribute__((ext_vector_type(4))) float ffrag;
typedef __attribute__((ext_vector_type(4))) unsigned int vu4;
typedef __attribute__((ext_vector_type(4))) float vf4;

DEVI uint4 cvt8(float4 a, float4 b){
  union{uint4 u; u16 h[8];} r;
  r.h[0]=f2b(a.x); r.h[1]=f2b(a.y); r.h[2]=f2b(a.z); r.h[3]=f2b(a.w);
  r.h[4]=f2b(b.x); r.h[5]=f2b(b.y); r.h[6]=f2b(b.z); r.h[7]=f2b(b.w);
  return r.u;
}
DEVI vu4 cvt8v(vf4 a, vf4 b){
  union{vu4 u; u16 h[8];} r;
  r.h[0]=f2b(a[0]); r.h[1]=f2b(a[1]); r.h[2]=f2b(a[2]); r.h[3]=f2b(a[3]);
  r.h[4]=f2b(b[0]); r.h[5]=f2b(b[1]); r.h[6]=f2b(b[2]); r.h[7]=f2b(b[3]);
  return r.u;
}

// ---- L2-bypassing (coherence-point) access primitives ----
DEVI void ld16_nw(const void* p, vu4& r){
  asm volatile("global_load_dwordx4 %0, %1, off sc0 sc1"
               : "=&v"(r) : "v"(p) : "memory");
}
DEVI void ld32_nw(const float* p, vf4& a, vf4& b){
  asm volatile("global_load_dwordx4 %0, %2, off sc0 sc1\n\t"
               "global_load_dwordx4 %1, %2, off offset:16 sc0 sc1"
               : "=&v"(a), "=&v"(b) : "v"(p) : "memory");
}
DEVI void vm_drain(){
  asm volatile("s_waitcnt vmcnt(0)" ::: "memory");
  __builtin_amdgcn_sched_barrier(0);   // rule #18
}
DEVI float ld4f_sys(const float* p){ return __hip_atomic_load(p, __ATOMIC_RELAXED, __HIP_MEMORY_SCOPE_SYSTEM); }
DEVI void st4_sys(float* p, float v){
  asm volatile("global_store_dword %0, %1, off sc0 sc1" :: "v"(p), "v"(v) : "memory");
}
DEVI void st2_sys(u16* p, u16 v){
  u32 w = v;
  asm volatile("global_store_short %0, %1, off sc0 sc1" :: "v"(p), "v"(w) : "memory");
}

// ---- all-store flag grid barrier, full fan-out (measured ~3us) ----
constexpr int GB_STRIDE  = 32;      // u32 per flag line (128B)
constexpr int BAR_DECF   = 0;       // 256 flag lines
constexpr int BAR_DECGO  = 8192;    // 256 go lines
constexpr int BAR_ENCF   = 16384;   // 64 flag lines
constexpr int BAR_ENCGO  = 18432;   // 64 go lines

DEVI u32 ld_sys(u32* p){ return __hip_atomic_load(p, __ATOMIC_RELAXED, __HIP_MEMORY_SCOPE_SYSTEM); }
DEVI void st_sys(u32* p, u32 v){ __hip_atomic_store(p, v, __ATOMIC_RELAXED, __HIP_MEMORY_SCOPE_SYSTEM); }

DEVI void gridbar2(u32* flags, u32* go, u32 seq, int nblk, int blk, int gblk)
{
  asm volatile("s_waitcnt vmcnt(0)" ::: "memory");   // per-wave: all sys stores committed
  __syncthreads();
  int t = threadIdx.x;
  if (blk == gblk){
    if (t == 0) st_sys(&flags[(u32)blk * GB_STRIDE], seq);
    if (t < nblk){
      u32* f = &flags[(u32)t * GB_STRIDE];
      while (ld_sys(f) < seq) __builtin_amdgcn_s_sleep(1);
    }
    __syncthreads();
    if (t < nblk) st_sys(&go[(u32)t * GB_STRIDE], seq);   // fan-out release
  } else {
    if (t == 0){
      st_sys(&flags[(u32)blk * GB_STRIDE], seq);
      u32* g = &go[(u32)blk * GB_STRIDE];                 // private go line
      while (ld_sys(g) < seq) __builtin_amdgcn_s_sleep(1);
    }
  }
  __syncthreads();
}

// ================ host-launched 3-seg NT GEMM (GI chunks + EATT) ================
struct Seg { const void* p; int ld; int f32; int K; };
struct NTZ {
  Seg sg[3];
  const void* Bp; int ldb; int bf32;
  const void* bias; int biasf32;
  void* Cp; int ldc; int cf32; int cslab;
  int N; int rev_s0; int K;
};
struct NTA { NTZ z[3]; int tilesN; };

template<int BN>
__global__ __launch_bounds__(256) void k_mfma_nt(NTA a)
{
  NTZ z = a.z[blockIdx.z];
  int tn = blockIdx.x % a.tilesN;
  int tm = blockIdx.x / a.tilesN;
  if (tn * BN >= z.N) return;
  int nks = gridDim.y;
  int kb = blockIdx.y * (z.K / nks);
  int ke = kb + z.K / nks;

  __shared__ short Al[128*32];
  __shared__ short Bl[BN*32];

  int t = threadIdx.x;
  int lane = t & 63, w = t >> 6;
  constexpr int FRS = (BN == 128) ? 4 : 2;
  int wn = (BN == 128) ? (w & 1) : 0;
  int rowbase = (BN == 128) ? (w >> 1) * 64 : w * 32;

  ffrag zz4 = {0.f, 0.f, 0.f, 0.f};
  ffrag acc[FRS][4];
  #pragma unroll
  for (int i = 0; i < FRS; i++)
    #pragma unroll
    for (int j = 0; j < 4; j++) acc[i][j] = zz4;

  for (int k0 = kb; k0 < ke; k0 += 32){
    #pragma unroll
    for (int r2 = 0; r2 < 2; r2++){
      int slot = t + r2 * 256;
      int row = slot >> 2, kq = slot & 3;
      int m = tm * 128 + row;
      int arow = (z.rev_s0 >= 0) ? (((z.rev_s0 - (m >> 7)) << 7) | (m & 127)) : m;
      int k = k0 + kq * 8;
      Seg sg;
      if (k < z.sg[0].K) sg = z.sg[0];
      else { k -= z.sg[0].K; if (k < z.sg[1].K) sg = z.sg[1]; else { k -= z.sg[1].K; sg = z.sg[2]; } }
      uint4 v;
      if (sg.f32){
        const float* ap = (const float*)sg.p + (size_t)arow * sg.ld + k;
        v = cvt8(*(const float4*)ap, *(const float4*)(ap + 4));
      } else {
        v = *(const uint4*)((const u16*)sg.p + (size_t)arow * sg.ld + k);
      }
      *(uint4*)&Al[(((row >> 4) << 6) + (kq << 4) + (row & 15)) * 8] = v;
    }
    #pragma unroll
    for (int r2 = 0; r2 < BN/64; r2++){
      int slot = t + r2 * 256;
      int brow = slot >> 2, kq = slot & 3;
      int n = tn * BN + brow;
      uint4 v = make_uint4(0u, 0u, 0u, 0u);
      if (n < z.N){
        int k = k0 + kq * 8;
        if (z.bf32){
          const float* bp = (const float*)z.Bp + (size_t)n * z.ldb + k;
          v = cvt8(*(const float4*)bp, *(const float4*)(bp + 4));
        } else {
          v = *(const uint4*)((const u16*)z.Bp + (size_t)n * z.ldb + k);
        }
      }
      *(uint4*)&Bl[(kq * BN + brow) * 8] = v;
    }
    __syncthreads();
    bfrag af[FRS], bv[4];
    #pragma unroll
    for (int fr = 0; fr < FRS; fr++) af[fr] = *(bfrag*)&Al[(((rowbase >> 4) + fr) * 64 + lane) * 8];
    #pragma unroll
    for (int fc = 0; fc < 4; fc++) bv[fc] = *(bfrag*)&Bl[(((lane >> 4) * BN) + wn * 64 + fc * 16 + (lane & 15)) * 8];
    #pragma unroll
    for (int fr = 0; fr < FRS; fr++)
      #pragma unroll
      for (int fc = 0; fc < 4; fc++)
        acc[fr][fc] = __builtin_amdgcn_mfma_f32_16x16x32_bf16(af[fr], bv[fc], acc[fr][fc], 0, 0, 0);
    __syncthreads();
  }

  float* Cf = (float*)z.Cp + (size_t)blockIdx.y * z.cslab;
  u16*  Cb = (u16*)z.Cp  + (size_t)blockIdx.y * z.cslab;
  #pragma unroll
  for (int fc = 0; fc < 4; fc++){
    int n = tn * BN + wn * 64 + fc * 16 + (lane & 15);
    if (n >= z.N) continue;
    float bs = 0.f;
    if (z.bias) bs = z.biasf32 ? ((const float*)z.bias)[n] : b2f(((const u16*)z.bias)[n]);
    #pragma unroll
    for (int fr = 0; fr < FRS; fr++){
      #pragma unroll
      for (int i = 0; i < 4; i++){
        int m = tm * 128 + rowbase + fr * 16 + ((lane >> 4) << 2) + i;
        float vv = acc[fr][fc][i] + bs;
        size_t idx = (size_t)m * z.ldc + n;
        if (z.cf32) Cf[idx] = vv; else Cb[idx] = f2b(vv);
      }
    }
  }
}

// ================ device-side 4-seg NT GEMM (M=128 fixed, 64-wide K chunks) ================
// Segments with nt=1 are cross-block communicated buffers: read via sc0 sc1.
// C-writes always go to communicated buffers: written via sc0 sc1.
// 64-wide chunks: 2x 32-sub-chunks staged per single vm_drain -> halves the
// number of exposed latency epochs (16 -> 8 for K-slab 512).
struct Seg4 { const void* p; int ld; int f32; int K; int nt; };
struct Z4 {
  Seg4 sg[4];
  const void* Bp; int ldb; int bf32;
  const float* bias;
  float* Cp; int ldc; int cslab;
  int N; int K;
};

template<int BN>
DEVI void dev_mfma4(const Z4& z, int tn, int ks, int nks, short* Al, short* Bl)
{
  constexpr int BSTR = BN * 32;          // shorts per B chunk
  int kseg = z.K / nks;
  int kb = ks * kseg, ke = kb + kseg;
  int t = threadIdx.x, lane = t & 63, w = t >> 6;
  constexpr int FRS = (BN == 128) ? 4 : 2;
  int wn = (BN == 128) ? (w & 1) : 0;
  int rowbase = (BN == 128) ? (w >> 1) * 64 : w * 32;
  ffrag zz4 = {0.f, 0.f, 0.f, 0.f};
  ffrag acc[FRS][4];
  #pragma unroll
  for (int i = 0; i < FRS; i++)
    #pragma unroll
    for (int j = 0; j < 4; j++) acc[i][j] = zz4;

  for (int k0 = kb; k0 < ke; k0 += 64){
    // ---- A staging: 2 chunks x 2 slots; issue all loads, drain ONCE ----
    int rowv[4], kqv2[4], isf[4];
    vf4 fa[4], fb[4]; vu4 ua[4];
    #pragma unroll
    for (int cc = 0; cc < 2; cc++){
      #pragma unroll
      for (int r2 = 0; r2 < 2; r2++){
        int id = cc * 2 + r2;
        int slot = t + r2 * 256;
        int row = slot >> 2, kq = slot & 3;
        int k = k0 + cc * 32 + kq * 8;
        Seg4 sg = z.sg[0];
        if (k >= sg.K){ k -= sg.K; sg = z.sg[1];
          if (k >= sg.K){ k -= sg.K; sg = z.sg[2];
            if (k >= sg.K){ k -= sg.K; sg = z.sg[3]; } } }
        rowv[id] = row; kqv2[id] = kq; isf[id] = sg.f32;
        if (sg.f32){
          const float* ap = (const float*)sg.p + (size_t)row * sg.ld + k;
          if (sg.nt) ld32_nw(ap, fa[id], fb[id]);
          else { fa[id] = *(const vf4*)ap; fb[id] = *(const vf4*)(ap + 4); }
        } else {
          const u16* up = (const u16*)sg.p + (size_t)row * sg.ld + k;
          if (sg.nt) ld16_nw(up, ua[id]);
          else ua[id] = *(const vu4*)up;
        }
      }
    }
    // ---- B staging: cached weight loads for both chunks ----
    vu4 bvv[2][BN/64]; int bidx[BN/64];
    #pragma unroll
    for (int r2 = 0; r2 < BN/64; r2++){
      int slot = t + r2 * 256;
      int brow = slot >> 2, kq = slot & 3;
      bidx[r2] = (kq * BN + brow) * 8;
      int n = tn * BN + brow;
      #pragma unroll
      for (int cc = 0; cc < 2; cc++){
        vu4 v = {0u, 0u, 0u, 0u};
        if (n < z.N){
          int k = k0 + cc * 32 + kq * 8;
          if (z.bf32){
            const float* bp = (const float*)z.Bp + (size_t)n * z.ldb + k;
            v = cvt8v(*(const vf4*)bp, *(const vf4*)(bp + 4));
          } else {
            v = *(const vu4*)((const u16*)z.Bp + (size_t)n * z.ldb + k);
          }
        }
        bvv[cc][r2] = v;
      }
    }
    vm_drain();
    #pragma unroll
    for (int cc = 0; cc < 2; cc++){
      #pragma unroll
      for (int r2 = 0; r2 < BN/64; r2++) *(vu4*)&Bl[cc * BSTR + bidx[r2]] = bvv[cc][r2];
      #pragma unroll
      for (int r2 = 0; r2 < 2; r2++){
        int id = cc * 2 + r2;
        vu4 v = isf[id] ? cvt8v(fa[id], fb[id]) : ua[id];
        *(vu4*)&Al[cc * 4096 + (((rowv[id] >> 4) << 6) + (kqv2[id] << 4) + (rowv[id] & 15)) * 8] = v;
      }
    }
    __syncthreads();
    #pragma unroll
    for (int cc = 0; cc < 2; cc++){
      bfrag af[FRS], bv[4];
      #pragma unroll
      for (int fr = 0; fr < FRS; fr++) af[fr] = *(bfrag*)&Al[cc * 4096 + (((rowbase >> 4) + fr) * 64 + lane) * 8];
      #pragma unroll
      for (int fc = 0; fc < 4; fc++) bv[fc] = *(bfrag*)&Bl[cc * BSTR + (((lane >> 4) * BN) + wn * 64 + fc * 16 + (lane & 15)) * 8];
      #pragma unroll
      for (int fr = 0; fr < FRS; fr++)
        #pragma unroll
        for (int fc = 0; fc < 4; fc++)
          acc[fr][fc] = __builtin_amdgcn_mfma_f32_16x16x32_bf16(af[fr], bv[fc], acc[fr][fc], 0, 0, 0);
    }
    __syncthreads();
  }

  float* Cf = z.Cp + (size_t)ks * z.cslab;
  #pragma unroll
  for (int fc = 0; fc < 4; fc++){
    int n = tn * BN + wn * 64 + fc * 16 + (lane & 15);
    if (n >= z.N) continue;
    float bs = z.bias ? z.bias[n] : 0.f;
    #pragma unroll
    for (int fr = 0; fr < FRS; fr++){
      #pragma unroll
      for (int i = 0; i < 4; i++){
        int m = rowbase + fr * 16 + ((lane >> 4) << 2) + i;
        st4_sys(&Cf[(size_t)m * z.ldc + n], acc[fr][fc][i] + bs);
      }
    }
  }
}

// ================ device-side fused GRU step (64-wide K chunks) ================
// MODE 1 = pointer unit (gi from ptr(B,8)@Wih); MODE 2 = decoder (gi = 4 K-split slabs)
// h state (hb/hf in, hnf/hnb out) is cross-block communicated -> sys access.
template<int MODE>
DEVI void dev_gru3(int g0, const u16* hb, const float* hf, const float* Whh,
                   const float* gi_f, const float* xp, const float* Wih,
                   const float* bih, const float* bhh,
                   float* hnf, u16* hnb, short* Al, short* Bl)
{
  int t = threadIdx.x, lane = t & 63, w = t >> 6;
  int wm = w >> 1, wn = w & 1;
  ffrag zz4 = {0.f, 0.f, 0.f, 0.f};
  ffrag acc[4][3];
  #pragma unroll
  for (int i = 0; i < 4; i++)
    #pragma unroll
    for (int j = 0; j < 3; j++) acc[i][j] = zz4;

  int rowA0 = t >> 2, kqA0 = t & 3;
  int rowA1 = (t + 256) >> 2, kqA1 = (t + 256) & 3;
  int lb0 = t >> 2, kq0b = t & 3;
  int wn2 = lb0 / 48, rem = lb0 - wn2 * 48, fcx = rem >> 4, i16 = rem & 15;
  int grow0 = fcx * 512 + g0 + wn2 * 16 + i16;
  int lb1 = 0, kq1b = 0, grow1 = 0;
  if (t < 128){
    int slot = t + 256;
    lb1 = slot >> 2; kq1b = slot & 3;
    int wn21 = lb1 / 48, rem1 = lb1 - wn21 * 48, fc1 = rem1 >> 4, i161 = rem1 & 15;
    grow1 = fc1 * 512 + g0 + wn21 * 16 + i161;
  }

  for (int k0 = 0; k0 < 512; k0 += 64){
    // A (h state, communicated): 4 sys loads, both chunks
    vu4 hv[4];
    #pragma unroll
    for (int cc = 0; cc < 2; cc++){
      ld16_nw(hb + (size_t)rowA0 * 512 + (k0 + cc * 32) + kqA0 * 8, hv[cc * 2]);
      ld16_nw(hb + (size_t)rowA1 * 512 + (k0 + cc * 32) + kqA1 * 8, hv[cc * 2 + 1]);
    }
    // B (Whh, cached): both chunks -> LDS
    #pragma unroll
    for (int cc = 0; cc < 2; cc++){
      const float* wp = Whh + (size_t)grow0 * 512 + (k0 + cc * 32) + kq0b * 8;
      *(vu4*)&Bl[cc * 3072 + (kq0b * 96 + lb0) * 8] = cvt8v(*(const vf4*)wp, *(const vf4*)(wp + 4));
    }
    if (t < 128){
      #pragma unroll
      for (int cc = 0; cc < 2; cc++){
        const float* wp1 = Whh + (size_t)grow1 * 512 + (k0 + cc * 32) + kq1b * 8;
        *(vu4*)&Bl[cc * 3072 + (kq1b * 96 + lb1) * 8] = cvt8v(*(const vf4*)wp1, *(const vf4*)(wp1 + 4));
      }
    }
    vm_drain();
    #pragma unroll
    for (int cc = 0; cc < 2; cc++){
      *(vu4*)&Al[cc * 4096 + (((rowA0 >> 4) << 6) + (kqA0 << 4) + (rowA0 & 15)) * 8] = hv[cc * 2];
      *(vu4*)&Al[cc * 4096 + (((rowA1 >> 4) << 6) + (kqA1 << 4) + (rowA1 & 15)) * 8] = hv[cc * 2 + 1];
    }
    __syncthreads();
    #pragma unroll
    for (int cc = 0; cc < 2; cc++){
      bfrag af[4], bv[3];
      #pragma unroll
      for (int fr = 0; fr < 4; fr++) af[fr] = *(bfrag*)&Al[cc * 4096 + ((wm * 4 + fr) * 64 + lane) * 8];
      #pragma unroll
      for (int fc = 0; fc < 3; fc++) bv[fc] = *(bfrag*)&Bl[cc * 3072 + ((lane >> 4) * 96 + (wn * 3 + fc) * 16 + (lane & 15)) * 8];
      #pragma unroll
      for (int fr = 0; fr < 4; fr++)
        #pragma unroll
        for (int fc = 0; fc < 3; fc++)
          acc[fr][fc] = __builtin_amdgcn_mfma_f32_16x16x32_bf16(af[fr], bv[fc], acc[fr][fc], 0, 0, 0);
    }
    __syncthreads();
  }

  // MODE1: stage xp (PTRS slice, communicated) into LDS once
  float* xl = (float*)Al;
  if (MODE == 1){
    for (int i = t; i < 1024; i += 256) xl[i] = ld4f_sys(xp + i);
    __syncthreads();
  }

  int gcol = g0 + wn * 16 + (lane & 15);
  float bir = bih[gcol],        bhr = bhh[gcol];
  float biz = bih[512 + gcol],  bhz = bhh[512 + gcol];
  float bin = bih[1024 + gcol], bhn = bhh[1024 + gcol];
  float wxr[8], wxz[8], wxn[8];
  if (MODE == 1){
    #pragma unroll
    for (int a2 = 0; a2 < 8; a2++){
      wxr[a2] = Wih[(size_t)gcol * 8 + a2];
      wxz[a2] = Wih[(size_t)(512 + gcol) * 8 + a2];
      wxn[a2] = Wih[(size_t)(1024 + gcol) * 8 + a2];
    }
  }
  #pragma unroll
  for (int fr = 0; fr < 4; fr++){
    #pragma unroll
    for (int i = 0; i < 4; i++){
      int brow = wm * 64 + fr * 16 + ((lane >> 4) << 2) + i;
      float gr_, gz_, gn_;
      if (MODE == 2){
        gr_ = gz_ = gn_ = 0.f;
        #pragma unroll
        for (int sl = 0; sl < 4; sl++){
          const float* gp = gi_f + (size_t)sl * 196608 + (size_t)brow * 1536;
          gr_ += ld4f_sys(gp + gcol); gz_ += ld4f_sys(gp + 512 + gcol); gn_ += ld4f_sys(gp + 1024 + gcol);
        }
      } else {
        float4 x0 = *(float4*)&xl[brow * 8];
        float4 x1 = *(float4*)&xl[brow * 8 + 4];
        float xa[8] = {x0.x, x0.y, x0.z, x0.w, x1.x, x1.y, x1.z, x1.w};
        gr_ = gz_ = gn_ = 0.f;
        #pragma unroll
        for (int a2 = 0; a2 < 8; a2++){ gr_ += xa[a2]*wxr[a2]; gz_ += xa[a2]*wxz[a2]; gn_ += xa[a2]*wxn[a2]; }
      }
      float hold = ld4f_sys(hf + (size_t)brow * 512 + gcol);
      float r  = sigmf_(gr_ + acc[fr][0][i] + bir + bhr);
      float zg = sigmf_(gz_ + acc[fr][1][i] + biz + bhz);
      float n  = tanhf_(gn_ + bin + r * (acc[fr][2][i] + bhn));
      float hn = (1.f - zg) * n + zg * hold;
      size_t idx = (size_t)brow * 512 + gcol;
      st4_sys(hnf + idx, hn);
      st2_sys(hnb + idx, f2b(hn));
    }
  }
}

// ================ device-side attention pieces ================
DEVI void dev_puattn(int b, const float* hida2, const float* Ka, const float* cae,
                     const float* Am, const float* Ain, const u16* enc,
                     float* vpre, float* ptrs, float* fs)
{
  int t = threadIdx.x, lane = t & 63, w = t >> 6;
  float* sc0 = fs; float* sc1 = fs + 256;
  float* wred = fs + 512;   // 36
  float* qa   = fs + 560;   // 20
  float* cd   = fs + 584;   // 16
  float* red  = fs + 604;   // 8

  for (int u = 0; u < 2; u++){
    const float* hp = hida2 + ((size_t)u * 128 + b) * 512;
    float hv0 = ld4f_sys(hp + t), hv1 = ld4f_sys(hp + t + 256);
    const float* k0p = Ka + u * 8192 + t * 16;
    const float* k1p = Ka + u * 8192 + (t + 256) * 16;
    float p[9];
    #pragma unroll
    for (int j = 0; j < 9; j++) p[j] = hv0 * k0p[j] + hv1 * k1p[j];
    #pragma unroll
    for (int j = 0; j < 9; j++){
      #pragma unroll
      for (int off = 32; off > 0; off >>= 1) p[j] += __shfl_xor(p[j], off);
    }
    if (lane == 0){
      #pragma unroll
      for (int j = 0; j < 9; j++) wred[w * 9 + j] = p[j];
    }
    __syncthreads();
    if (t < 9) qa[u * 10 + t] = wred[t] + wred[9 + t] + wred[18 + t] + wred[27 + t] + cae[u * 16 + t];
    __syncthreads();
  }

  float su[2];
  #pragma unroll
  for (int u = 0; u < 2; u++){
    const float* amp = Am + (((size_t)u * 256 + t) * 128 + b) * 8;
    float4 a0 = *(const float4*)amp;
    float4 a1 = *(const float4*)(amp + 4);
    const float* q = qa + u * 10;
    su[u] = (q[8] + q[0]*a0.x + q[1]*a0.y + q[2]*a0.z + q[3]*a0.w
                  + q[4]*a1.x + q[5]*a1.y + q[6]*a1.z + q[7]*a1.w) * SCALE_ATT;
  }

  const float* ap = Ain + ((size_t)b * 256 + t) * 8;
  float av[8];
  {
    float4 v0 = *(const float4*)ap;
    float4 v1 = *(const float4*)(ap + 4);
    av[0]=v0.x; av[1]=v0.y; av[2]=v0.z; av[3]=v0.w;
    av[4]=v1.x; av[5]=v1.y; av[6]=v1.z; av[7]=v1.w;
  }

  float inv[2];
  for (int u = 0; u < 2; u++){
    float s_ = su[u];
    float* sc = u ? sc1 : sc0;
    // wave-level max + 4-way combine (2 syncs, no LDS tree)
    float m = s_;
    #pragma unroll
    for (int off = 32; off > 0; off >>= 1) m = fmaxf(m, __shfl_xor(m, off));
    if (lane == 0) red[w] = m;
    __syncthreads();
    float mx = fmaxf(fmaxf(red[0], red[1]), fmaxf(red[2], red[3]));
    float e = __expf(s_ - mx); sc[t] = e;
    // joint shuffle reduce: denominator + 8 pointer-address components (no LDS atomics)
    float ca[9];
    ca[8] = e;
    #pragma unroll
    for (int a2 = 0; a2 < 8; a2++) ca[a2] = e * av[a2];
    #pragma unroll
    for (int j = 0; j < 9; j++){
      #pragma unroll
      for (int off = 32; off > 0; off >>= 1) ca[j] += __shfl_xor(ca[j], off);
    }
    if (lane == 0){
      #pragma unroll
      for (int j = 0; j < 9; j++) wred[w * 9 + j] = ca[j];
    }
    __syncthreads();
    if (t < 9){
      float v = wred[t] + wred[9 + t] + wred[18 + t] + wred[27 + t];
      if (t < 8) cd[u * 8 + t] = v;
      else red[4 + u] = v;
    }
    __syncthreads();
    inv[u] = 1.f / red[4 + u];
  }
  if (t < 8){
    st4_sys(&ptrs[((size_t)0 * 128 + b) * 8 + t], cd[t] * inv[0]);
    st4_sys(&ptrs[((size_t)128 + b) * 8 + t],     cd[8 + t] * inv[1]);
  }

  // value pass over ENC: thread t owns cols 2t,2t+1; deep unroll for MLP
  float a00 = 0.f, a01 = 0.f, a10 = 0.f, a11 = 0.f;
  const u16* ep = enc + (size_t)b * 512;
  #pragma unroll 32
  for (int s2 = 0; s2 < 256; s2++){
    float w0 = sc0[s2], w1 = sc1[s2];
    u32 pv = *(const u32*)(ep + (size_t)s2 * 65536 + 2 * t);
    float v0 = b2f((u16)pv);
    float v1 = b2f((u16)(pv >> 16));
    a00 += w0 * v0; a01 += w0 * v1; a10 += w1 * v0; a11 += w1 * v1;
  }
  float* vp = vpre + (size_t)b * 1024;
  st4_sys(&vp[2 * t], a00 * inv[0]);           st4_sys(&vp[2 * t + 1], a01 * inv[0]);
  st4_sys(&vp[512 + 2 * t], a10 * inv[1]);     st4_sys(&vp[512 + 2 * t + 1], a11 * inv[1]);
}

DEVI void dev_bahd(int b, const u16* eatt, const float* dpart, const float* vvec,
                   const u16* enc, float* ctx, float* fs)
{
  int t = threadIdx.x, lane = t & 63, w = t >> 6;
  float* dp = fs; float* vv = fs + 512; float* sc = fs + 1024; float* red = fs + 1280;
  dp[t] = ld4f_sys(dpart + (size_t)b * 512 + t);
  dp[t + 256] = ld4f_sys(dpart + (size_t)b * 512 + t + 256);
  vv[t] = vvec[t]; vv[t + 256] = vvec[t + 256];
  __syncthreads();
  float4 d0 = *(float4*)&dp[lane * 8], d1 = *(float4*)&dp[lane * 8 + 4];
  float4 v0 = *(float4*)&vv[lane * 8], v1 = *(float4*)&vv[lane * 8 + 4];
  // score pass: batch 8 independent row loads per wave (8x MLP)
  for (int sb = 0; sb < 256; sb += 32){
    uint4 vl[8];
    #pragma unroll
    for (int i = 0; i < 8; i++){
      int s = sb + i * 4 + w;
      vl[i] = *(const uint4*)(eatt + ((size_t)s * 128 + b) * 512 + lane * 8);
    }
    #pragma unroll
    for (int i = 0; i < 8; i++){
      const u16* h = (const u16*)&vl[i];
      float r = fmaxf(0.f, b2f(h[0]) + d0.x) * v0.x + fmaxf(0.f, b2f(h[1]) + d0.y) * v0.y
              + fmaxf(0.f, b2f(h[2]) + d0.z) * v0.z + fmaxf(0.f, b2f(h[3]) + d0.w) * v0.w
              + fmaxf(0.f, b2f(h[4]) + d1.x) * v1.x + fmaxf(0.f, b2f(h[5]) + d1.y) * v1.y
              + fmaxf(0.f, b2f(h[6]) + d1.z) * v1.z + fmaxf(0.f, b2f(h[7]) + d1.w) * v1.w;
      #pragma unroll
      for (int off = 32; off > 0; off >>= 1) r += __shfl_xor(r, off);
      if (lane == 0) sc[sb + i * 4 + w] = r;
    }
  }
  __syncthreads();
  float s0 = sc[t];
  float m = s0;
  #pragma unroll
  for (int off = 32; off > 0; off >>= 1) m = fmaxf(m, __shfl_xor(m, off));
  if (lane == 0) red[w] = m;
  __syncthreads();
  float mx = fmaxf(fmaxf(red[0], red[1]), fmaxf(red[2], red[3]));
  float e = __expf(s0 - mx); sc[t] = e;
  float sum = e;
  #pragma unroll
  for (int off = 32; off > 0; off >>= 1) sum += __shfl_xor(sum, off);
  if (lane == 0) red[4 + w] = sum;
  __syncthreads();
  float inv = 1.f / (red[4] + red[5] + red[6] + red[7]);
  float a0 = 0.f, a1 = 0.f;
  const u16* ep = enc + (size_t)b * 512;
  #pragma unroll 32
  for (int s2 = 0; s2 < 256; s2++){
    float wgt = sc[s2];
    u32 pv = *(const u32*)(ep + (size_t)s2 * 65536 + 2 * t);
    a0 += wgt * b2f((u16)pv);
    a1 += wgt * b2f((u16)(pv >> 16));
  }
  st4_sys(&ctx[(size_t)b * 512 + 2 * t], a0 * inv);
  st4_sys(&ctx[(size_t)b * 512 + 2 * t + 1], a1 * inv);
}

DEVI void dev_cattn(int b, const float* qck, const u16* enc, float* cv2p, float* fs)
{
  int t = threadIdx.x, lane = t & 63, w = t >> 6;
  float* qv = fs; float* sc = fs + 1024; float* red = fs + 1280;
  qv[t] = ld4f_sys(qck + (size_t)b * 520 + t);
  qv[t + 256] = ld4f_sys(qck + (size_t)b * 520 + t + 256);
  __syncthreads();
  float qc0 = ld4f_sys(qck + (size_t)b * 520 + 512);
  float4 q0 = *(float4*)&qv[lane * 8], q1 = *(float4*)&qv[lane * 8 + 4];
  for (int sb = 0; sb < 256; sb += 32){
    uint4 vl[8];
    #pragma unroll
    for (int i = 0; i < 8; i++){
      int s = sb + i * 4 + w;
      vl[i] = *(const uint4*)(enc + ((size_t)s * 128 + b) * 512 + lane * 8);
    }
    #pragma unroll
    for (int i = 0; i < 8; i++){
      const u16* h = (const u16*)&vl[i];
      float r = b2f(h[0])*q0.x + b2f(h[1])*q0.y + b2f(h[2])*q0.z + b2f(h[3])*q0.w
              + b2f(h[4])*q1.x + b2f(h[5])*q1.y + b2f(h[6])*q1.z + b2f(h[7])*q1.w;
      #pragma unroll
      for (int off = 32; off > 0; off >>= 1) r += __shfl_xor(r, off);
      if (lane == 0) sc[sb + i * 4 + w] = (r + qc0) * SCALE_ATT;
    }
  }
  __syncthreads();
  float s0 = sc[t];
  float m = s0;
  #pragma unroll
  for (int off = 32; off > 0; off >>= 1) m = fmaxf(m, __shfl_xor(m, off));
  if (lane == 0) red[w] = m;
  __syncthreads();
  float mx = fmaxf(fmaxf(red[0], red[1]), fmaxf(red[2], red[3]));
  float e = __expf(s0 - mx); sc[t] = e;
  float sum = e;
  #pragma unroll
  for (int off = 32; off > 0; off >>= 1) sum += __shfl_xor(sum, off);
  if (lane == 0) red[4 + w] = sum;
  __syncthreads();
  float inv = 1.f / (red[4] + red[5] + red[6] + red[7]);
  float a0 = 0.f, a1 = 0.f;
  const u16* ep = enc + (size_t)b * 512;
  #pragma unroll 32
  for (int s2 = 0; s2 < 256; s2++){
    float wgt = sc[s2];
    u32 pv = *(const u32*)(ep + (size_t)s2 * 65536 + 2 * t);
    a0 += wgt * b2f((u16)pv);
    a1 += wgt * b2f((u16)(pv >> 16));
  }
  st4_sys(&cv2p[(size_t)b * 512 + 2 * t], a0 * inv);
  st4_sys(&cv2p[(size_t)b * 512 + 2 * t + 1], a1 * inv);
}

DEVI void dev_outcvt(int b, const float* outt, const float* outb2, float* dst)
{
  int t = threadIdx.x;
  #pragma unroll
  for (int rep = 0; rep < 2; rep++){
    int o = t + rep * 256;
    float s = ld4f_sys(outt + (size_t)b * 512 + o) + ld4f_sys(outt + 65536 + (size_t)b * 512 + o)
            + ld4f_sys(outt + 131072 + (size_t)b * 512 + o) + ld4f_sys(outt + 196608 + (size_t)b * 512 + o);
    dst[(size_t)b * 512 + o] = s + outb2[o];   // final output: flushed at kernel end
  }
}

// ================ persistent encoder (32 steps per launch, manual barrier) ================
struct EncArgs {
  const float *WhhF, *WhhB, *giF, *giB;
  const float *bihF, *bhhF, *bihB, *bhhB;
  float *HF, *HB; u16 *HFB, *HBB, *ENC;
  u32 *BAR; int bar0;
  int s0;
};

__global__ __launch_bounds__(256) void k_enc(EncArgs a)
{
  __shared__ short Bw[24576];   // 48 rows (3 gates x 16 cols) x 512 K, bf16, MFMA layout
  __shared__ short Al[4096];
  int blk = blockIdx.x;
  int d = blk >> 5, gt = blk & 31;
  int t = threadIdx.x, lane = t & 63, w = t >> 6;

  const float* Whh = d ? a.WhhB : a.WhhF;
  for (int c = t; c < 3072; c += 256){
    int brow = c >> 6, kc = c & 63;
    int grow = (brow >> 4) * 512 + gt * 16 + (brow & 15);
    const float* wp = Whh + (size_t)grow * 512 + kc * 8;
    *(uint4*)&Bw[((kc * 48) + brow) * 8] = cvt8(*(const float4*)wp, *(const float4*)(wp + 4));
  }
  const float* bih = d ? a.bihB : a.bihF;
  const float* bhh = d ? a.bhhB : a.bhhF;
  int gcol = gt * 16 + (lane & 15);
  float bir = bih[gcol],        bhr = bhh[gcol];
  float biz = bih[512 + gcol],  bhz = bhh[512 + gcol];
  float bin = bih[1024 + gcol], bhn = bhh[1024 + gcol];
  float* hf_base = d ? a.HB : a.HF;
  u16*   hb_base = d ? a.HBB : a.HFB;
  const float* gi_base = d ? a.giB : a.giF;
  __syncthreads();

  for (int si = 0; si < 32; si++){
    int s = a.s0 + si;
    const u16* hb = hb_base + (size_t)(s & 1) * 65536;
    const float* hf = hf_base + (size_t)(s & 1) * 65536;
    float* hnf = hf_base + (size_t)((s + 1) & 1) * 65536;
    u16* hnb = hb_base + (size_t)((s + 1) & 1) * 65536;
    u16* eacc = a.ENC + (size_t)(d ? 255 - s : s) * 65536;

    ffrag zz4 = {0.f, 0.f, 0.f, 0.f};
    ffrag acc[2][3];
    #pragma unroll
    for (int i = 0; i < 2; i++)
      #pragma unroll
      for (int j = 0; j < 3; j++) acc[i][j] = zz4;

    for (int ki = 0; ki < 16; ki++){
      int k0 = ki * 32;
      // h state is cross-block communicated -> sys loads, one drain
      int row0 = t >> 2, kq0 = t & 3;
      int row1 = (t + 256) >> 2, kq1 = (t + 256) & 3;
      vu4 hv0, hv1;
      ld16_nw(hb + (size_t)row0 * 512 + k0 + kq0 * 8, hv0);
      ld16_nw(hb + (size_t)row1 * 512 + k0 + kq1 * 8, hv1);
      vm_drain();
      *(vu4*)&Al[(((row0 >> 4) << 6) + (kq0 << 4) + (row0 & 15)) * 8] = hv0;
      *(vu4*)&Al[(((row1 >> 4) << 6) + (kq1 << 4) + (row1 & 15)) * 8] = hv1;
      __syncthreads();
      bfrag af[2], bv[3];
      #pragma unroll
      for (int fr = 0; fr < 2; fr++) af[fr] = *(bfrag*)&Al[(((w * 2 + fr) * 64) + lane) * 8];
      #pragma unroll
      for (int fc = 0; fc < 3; fc++) bv[fc] = *(bfrag*)&Bw[(((ki * 4 + (lane >> 4)) * 48) + fc * 16 + (lane & 15)) * 8];
      #pragma unroll
      for (int fr = 0; fr < 2; fr++)
        #pragma unroll
        for (int fc = 0; fc < 3; fc++)
          acc[fr][fc] = __builtin_amdgcn_mfma_f32_16x16x32_bf16(af[fr], bv[fc], acc[fr][fc], 0, 0, 0);
      __syncthreads();
    }

    const float* gp0 = gi_base + (size_t)si * 196608;
    #pragma unroll
    for (int fr = 0; fr < 2; fr++){
      #pragma unroll
      for (int i = 0; i < 4; i++){
        int brow = w * 32 + fr * 16 + ((lane >> 4) << 2) + i;
        const float* gp = gp0 + (size_t)brow * 1536;
        float gr_ = gp[gcol], gz_ = gp[512 + gcol], gn_ = gp[1024 + gcol];
        float hold = ld4f_sys(hf + (size_t)brow * 512 + gcol);
        float r  = sigmf_(gr_ + acc[fr][0][i] + bir + bhr);
        float zg = sigmf_(gz_ + acc[fr][1][i] + biz + bhz);
        float n  = tanhf_(gn_ + bin + r * (acc[fr][2][i] + bhn));
        float hn = (1.f - zg) * n + zg * hold;
        size_t idx = (size_t)brow * 512 + gcol;
        st4_sys(hnf + idx, hn);
        st2_sys(hnb + idx, f2b(hn));
        eacc[idx] = f2b(b2f(eacc[idx]) + hn);   // block-private slice; cross-launch coherence only
      }
    }
    gridbar2(a.BAR + BAR_ENCF, a.BAR + BAR_ENCGO, (u32)(a.s0 + si + 1), 64, blk, 0);
  }
}

// ================ persistent decoder (all 64 steps, 4 barriers/step) ================
// Phase A is dissolved: puGRU(st+1) runs in phase C(st) (needs PTRS from B(st)),
// dpart GEMM(st+1) runs in phase E(st) (needs dechb from D(st)), outcvt(st-1)
// runs in phase C(st). One-time prologue handles puGRU(0)/dpart(0).
struct DecArgs {
  const float *tgt, *Ag, *AM, *KA, *CAE, *dattW, *dattv;
  const float *puWhh, *puWih, *pubih, *pubhh;
  const float *dWhh, *DBIH2, *dbhh, *VKE2, *OUTB2;
  const u16 *ENC, *EATT, *DWF, *MKTW, *OWF;
  float *HIDA; u16 *HIDAB;
  float *DECH; u16 *DECHB;
  float *HF0; u16 *HFB0;
  float *PTRS, *VPRE, *CTX, *DPART, *QCK, *CV2P, *GIDEC, *OUTT, *out;
  u32 *BAR;
};

__global__ __launch_bounds__(256) void k_dec(DecArgs a)
{
  __shared__ short Al[8192];
  __shared__ short Bl[8192];
  __shared__ float fs[1600];
  const int blk = blockIdx.x;
  const Seg4 S4SENT = {nullptr, 0, 0, 1 << 30, 0};
  u32* dF = a.BAR + BAR_DECF;
  u32* dG = a.BAR + BAR_DECGO;
  const int GATHER = 230;   // busy only in phase B (bahd) -> polls start early elsewhere

  // helper lambda-free: puGRU for step s on unit u, gate block g0
  // reads HIDA[s&1], writes HIDA[(s+1)&1]
  #define PU_GRU(s_, u_, g0_) do { \
    int s__ = (s_); int u__ = (u_); \
    const u16*  pc_ = a.HIDAB + (size_t)(s__ & 1) * 131072 + (size_t)u__ * 65536; \
    const float* pf_ = a.HIDA  + (size_t)(s__ & 1) * 131072 + (size_t)u__ * 65536; \
    float* pn_  = a.HIDA  + (size_t)((s__ + 1) & 1) * 131072 + (size_t)u__ * 65536; \
    u16*   pnb_ = a.HIDAB + (size_t)((s__ + 1) & 1) * 131072 + (size_t)u__ * 65536; \
    dev_gru3<1>((g0_), pc_, pf_, a.puWhh + (size_t)u__ * 786432, nullptr, \
                a.PTRS + u__ * 1024, a.puWih + (size_t)u__ * 12288, \
                a.pubih + u__ * 1536, a.pubhh + u__ * 1536, pn_, pnb_, Al, Bl); \
  } while(0)

  #define DPART_GEMM(srcb_, tn_) do { \
    Z4 z_; \
    z_.sg[0] = {(srcb_), 512, 0, 512, 1}; z_.sg[1] = S4SENT; z_.sg[2] = S4SENT; z_.sg[3] = S4SENT; \
    z_.Bp = a.dattW; z_.ldb = 1024; z_.bf32 = 1; z_.bias = nullptr; \
    z_.Cp = a.DPART; z_.ldc = 512; z_.cslab = 0; z_.N = 512; z_.K = 512; \
    dev_mfma4<64>(z_, (tn_), 0, 1, Al, Bl); \
  } while(0)

  // ---- prologue: puGRU(0) | dpart(0)  (one extra barrier, once) ----
  if (blk < 32){
    int u = blk >> 4, g0 = (blk & 15) * 32;
    PU_GRU(0, u, g0);
  } else if (blk < 40){
    DPART_GEMM(a.HFB0, blk - 32);
  }
  gridbar2(dF, dG, 1u, 256, blk, GATHER);

  for (int st = 0; st < 64; st++){
    const float* dech_c  = (st == 0) ? a.HF0  : a.DECH  + (size_t)((st + 1) & 1) * 65536;
    const u16*   dechb_c = (st == 0) ? a.HFB0 : a.DECHB + (size_t)((st + 1) & 1) * 65536;
    float*       dech_n  = a.DECH  + (size_t)(st & 1) * 65536;
    u16*         dechb_n = a.DECHB + (size_t)(st & 1) * 65536;
    const float* hida_n  = a.HIDA  + (size_t)((st + 1) & 1) * 131072;  // written by puGRU(st)
    u32 seq0 = 2u + (u32)(st * 4);

    // ---- phase B: pointer attention (both units) | Bahdanau
    if (blk < 128){
      dev_puattn(blk, hida_n, a.KA, a.CAE, a.AM, a.Ag, a.ENC, a.VPRE, a.PTRS, fs);
    } else {
      dev_bahd(blk - 128, a.EATT, a.DPART, a.dattv, a.ENC, a.CTX, fs);
    }
    gridbar2(dF, dG, seq0 + 0, 256, blk, GATHER);

    // ---- phase C: gidec GEMM | qck GEMM | puGRU(st+1) | outcvt(st-1)
    if (blk < 48){
      Z4 z;
      z.sg[0] = {a.tgt + (size_t)(st ? st - 1 : 0) * 65536, 512, 1, 512, 0};
      z.sg[1] = {a.VPRE, 1024, 1, 1024, 1};
      z.sg[2] = {a.CTX, 512, 1, 512, 1};
      z.sg[3] = S4SENT;
      z.Bp = a.DWF; z.ldb = 2048; z.bf32 = 0; z.bias = nullptr;
      z.Cp = a.GIDEC; z.ldc = 1536; z.cslab = 196608; z.N = 1536; z.K = 2048;
      dev_mfma4<128>(z, blk % 12, blk / 12, 4, Al, Bl);
    } else if (blk < 57){
      Z4 z;
      z.sg[0] = {a.VPRE, 1024, 1, 1024, 1}; z.sg[1] = S4SENT; z.sg[2] = S4SENT; z.sg[3] = S4SENT;
      z.Bp = a.MKTW; z.ldb = 1024; z.bf32 = 0; z.bias = a.VKE2;
      z.Cp = a.QCK; z.ldc = 520; z.cslab = 0; z.N = 513; z.K = 1024;
      dev_mfma4<64>(z, blk - 48, 0, 1, Al, Bl);
    } else if (blk < 89){
      if (st < 63){
        int u = (blk - 57) >> 4, g0 = ((blk - 57) & 15) * 32;
        PU_GRU(st + 1, u, g0);
      }
    } else if (blk < 217 && st > 0){
      dev_outcvt(blk - 89, a.OUTT, a.OUTB2, a.out + (size_t)(st - 1) * 65536);
    }
    gridbar2(dF, dG, seq0 + 1, 256, blk, GATHER);

    // ---- phase D: decoder GRU combine | content attention
    if (blk < 16){
      dev_gru3<2>(blk * 32, dechb_c, dech_c, a.dWhh, a.GIDEC, nullptr, nullptr,
                  a.DBIH2, a.dbhh, dech_n, dechb_n, Al, Bl);
    } else if (blk < 144){
      dev_cattn(blk - 16, a.QCK, a.ENC, a.CV2P, fs);
    }
    gridbar2(dF, dG, seq0 + 2, 256, blk, GATHER);

    // ---- phase E: folded output head GEMM (K=2560, split-K 4) | dpart(st+1)
    if (blk < 32){
      Z4 z;
      z.sg[0] = {dechb_n, 512, 0, 512, 1};
      z.sg[1] = {a.CTX, 512, 1, 512, 1};
      z.sg[2] = {a.VPRE, 1024, 1, 1024, 1};
      z.sg[3] = {a.CV2P, 512, 1, 512, 1};
      z.Bp = a.OWF; z.ldb = 2560; z.bf32 = 0; z.bias = nullptr;
      z.Cp = a.OUTT; z.ldc = 512; z.cslab = 65536; z.N = 512; z.K = 2560;
      dev_mfma4<64>(z, blk & 7, blk >> 3, 4, Al, Bl);
    } else if (blk < 40){
      if (st < 63) DPART_GEMM(dechb_n, blk - 32);
    }
    gridbar2(dF, dG, seq0 + 3, 256, blk, GATHER);
  }
  if (blk < 128) dev_outcvt(blk, a.OUTT, a.OUTB2, a.out + 63ull * 65536);
  #undef PU_GRU
  #undef DPART_GEMM
}

// ================ setup: batched fold jobs ================
struct Job {
  const float* A; const float* B; const float* D; void* C;
  int Asm, Ask, Bsk, Bsn, Dsm, Dsn, Csm, Csn;
  int cbf, M, N, K, kind;
};
struct Jobs { Job j[24]; int nj; long long off[25]; };

__global__ __launch_bounds__(256) void k_setup(Jobs J)
{
  long long total = J.off[J.nj];
  for (long long tid = (long long)blockIdx.x * 256 + threadIdx.x; tid < total; tid += (long long)gridDim.x * 256){
    int ji = 0;
    while (tid >= J.off[ji + 1]) ji++;
    Job jb = J.j[ji];
    long long l = tid - J.off[ji];
    if (jb.kind == 0){
      int m = (int)(l / jb.N), n = (int)(l - (long long)m * jb.N);
      float acc = 0.f;
      const float* ap = jb.A + (size_t)m * jb.Asm;
      const float* bp = jb.B + (size_t)n * jb.Bsn;
      for (int k = 0; k < jb.K; k++)
        acc += ap[(size_t)k * jb.Ask] * bp[(size_t)k * jb.Bsk];
      if (jb.D) acc += jb.D[(size_t)m * jb.Dsm + (size_t)n * jb.Dsn];
      if (jb.cbf) ((u16*)jb.C)[(size_t)m * jb.Csm + (size_t)n * jb.Csn] = f2b(acc);
      else ((float*)jb.C)[(size_t)m * jb.Csm + (size_t)n * jb.Csn] = acc;
    } else if (jb.kind == 1){
      int m = (int)(l / jb.N), n = (int)(l - (long long)m * jb.N);
      ((u16*)jb.C)[(size_t)m * jb.Csm + (size_t)n * jb.Csn] = f2b(jb.A[(size_t)m * jb.Asm + (size_t)n * jb.Ask]);
    } else if (jb.kind == 2){
      int u = (int)(l >> 15), sb = (int)(l & 32767);
      float x[8];
      #pragma unroll
      for (int a2 = 0; a2 < 8; a2++) x[a2] = jb.A[(size_t)sb * 8 + a2];
      float* op = (float*)jb.C + ((size_t)u * 32768 + sb) * 8;
      #pragma unroll
      for (int c = 0; c < 8; c++){
        float acc = jb.D[u * 8 + c];
        #pragma unroll
        for (int a2 = 0; a2 < 8; a2++) acc += x[a2] * jb.B[(u * 8 + c) * 8 + a2];
        op[c] = acc;
      }
    } else {
      int u = (int)(l >> 10), r = (int)(l & 1023);
      int bb = r >> 3, aa = r & 7;
      int su = u ? 255 : 0;
      ((float*)jb.C)[l] = jb.A[((size_t)su * 128 + bb) * 8 + aa];
    }
  }
}

// ================ host ================
static inline Seg mkseg(const void* p, int ld, int f32, int K){ Seg s; s.p = p; s.ld = ld; s.f32 = f32; s.K = K; return s; }
static const Seg SENT = {nullptr, 0, 0, 1 << 30};

static inline void addJ(Jobs& JS, Job jb, long long cnt){
  JS.j[JS.nj] = jb;
  JS.off[JS.nj + 1] = JS.off[JS.nj] + cnt;
  JS.nj++;
}
static inline Job JG(const float* A, int Asm, int Ask, const float* B, int Bsk, int Bsn,
                     const float* D, int Dsm, int Dsn, void* C, int Csm, int Csn,
                     int cbf, int M, int N, int K, int kind = 0){
  Job j; j.A=A; j.B=B; j.D=D; j.C=C; j.Asm=Asm; j.Ask=Ask; j.Bsk=Bsk; j.Bsn=Bsn;
  j.Dsm=Dsm; j.Dsn=Dsn; j.Csm=Csm; j.Csn=Csn; j.cbf=cbf; j.M=M; j.N=N; j.K=K; j.kind=kind;
  return j;
}

extern "C" void kernel_launch(void* const* d_in, const int* in_sizes, int n_in,
                              void* d_out, int out_size, void* d_ws, size_t ws_size,
                              hipStream_t stream)
{
  (void)in_sizes; (void)out_size;
  if (n_in < 44 || ws_size < WS_NEED) return;

  const float* src   = (const float*)d_in[0];
  const float* tgt   = (const float*)d_in[1];
  const float* Ag    = (const float*)d_in[2];
  const float* eWihF = (const float*)d_in[3];
  const float* eWhhF = (const float*)d_in[4];
  const float* ebihF = (const float*)d_in[5];
  const float* ebhhF = (const float*)d_in[6];
  const float* eWihB = (const float*)d_in[7];
  const float* eWhhB = (const float*)d_in[8];
  const float* ebihB = (const float*)d_in[9];
  const float* ebhhB = (const float*)d_in[10];
  const float* dattW = (const float*)d_in[11];
  const float* dattb = (const float*)d_in[12];
  const float* dattv = (const float*)d_in[13];
  const float* dWih  = (const float*)d_in[14];
  const float* dWhh  = (const float*)d_in[15];
  const float* dbih  = (const float*)d_in[16];
  const float* dbhh  = (const float*)d_in[17];
  const float* doW   = (const float*)d_in[18];
  const float* dob   = (const float*)d_in[19];
  const float* puWih = (const float*)d_in[20];
  const float* puWhh = (const float*)d_in[21];
  const float* pubih = (const float*)d_in[22];
  const float* pubhh = (const float*)d_in[23];
  const float* puqW  = (const float*)d_in[24];
  const float* puqb  = (const float*)d_in[25];
  const float* puAW  = (const float*)d_in[26];
  const float* puAb  = (const float*)d_in[27];
  const float* puqp  = (const float*)d_in[28];
  const float* pukp  = (const float*)d_in[29];
  const float* puvp  = (const float*)d_in[30];
  const float* puinb = (const float*)d_in[31];
  const float* puop  = (const float*)d_in[32];
  const float* puob  = (const float*)d_in[33];
  const float* aaq   = (const float*)d_in[34];
  const float* aak   = (const float*)d_in[35];
  const float* aav   = (const float*)d_in[36];
  const float* aainb = (const float*)d_in[37];
  const float* aao   = (const float*)d_in[38];
  const float* aaob  = (const float*)d_in[39];
  const float* tohW  = (const float*)d_in[40];
  const float* tohb  = (const float*)d_in[41];
  const float* outW  = (const float*)d_in[42];
  const float* outb  = (const float*)d_in[43];

  char* ws = (char*)d_ws;
  float* GI    = (float*)(ws + OFF_GI);
  u16*   ENC   = (u16*)(ws + OFF_ENC);
  u16*   EATT  = (u16*)(ws + OFF_EATT);
  float* AM    = (float*)(ws + OFF_AM);
  float* HF    = (float*)(ws + OFF_HF);
  float* HB    = (float*)(ws + OFF_HB);
  u16*   HFB   = (u16*)(ws + OFF_HFB);
  u16*   HBB   = (u16*)(ws + OFF_HBB);
  float* HIDA  = (float*)(ws + OFF_HIDA);
  u16*   HIDAB = (u16*)(ws + OFF_HIDAB);
  u32*   BAR   = (u32*)(ws + OFF_BAR);
  float* DECH  = (float*)(ws + OFF_DECH);
  u16*   DECHB = (u16*)(ws + OFF_DECHB);
  float* PTRS  = (float*)(ws + OFF_PTRS);
  float* VPRE  = (float*)(ws + OFF_VPRE);
  float* CTX   = (float*)(ws + OFF_CTX);
  float* DPART = (float*)(ws + OFF_DPART);
  float* QCK   = (float*)(ws + OFF_QCK);
  float* CV2P  = (float*)(ws + OFF_CV2P);
  float* GIDEC = (float*)(ws + OFF_GIDEC);
  float* OUTT  = (float*)(ws + OFF_OUTT);
  float* WOVF  = (float*)(ws + OFF_WOVF);
  float* WOVCF = (float*)(ws + OFF_WOVCF);
  float* MKTF  = (float*)(ws + OFF_MKTF);
  u16*   DWF   = (u16*)(ws + OFF_DWF);
  u16*   MKTW  = (u16*)(ws + OFF_MKTW);
  u16*   OWF   = (u16*)(ws + OFF_OWF);
  float* BOV   = (float*)(ws + OFF_BOV);
  float* BOVC  = (float*)(ws + OFF_BOVC);
  float* KAx   = (float*)(ws + OFF_KA);
  float* CAE   = (float*)(ws + OFF_CAE);
  float* RT    = (float*)(ws + OFF_RT);
  float* BQC   = (float*)(ws + OFF_BQC);
  float* PMAT  = (float*)(ws + OFF_PMAT);
  float* CQ    = (float*)(ws + OFF_CQ);
  float* VKE2  = (float*)(ws + OFF_VKE2);
  float* DBIH2 = (float*)(ws + OFF_DBIH2);
  float* OUTB2 = (float*)(ws + OFF_OUTB2);

  hipMemsetAsync(ENC, 0, 2ull*256*128*512, stream);
  hipMemsetAsync(ws + OFF_HF, 0, OFF_ZEND - OFF_HF, stream);  // states + barrier flags

  // -------- stage 1: independent folds --------
  {
    Jobs S{}; S.nj = 0; S.off[0] = 0;
    for (int u = 0; u < 2; u++){
      const float* qp  = puqp + (size_t)u * 262144;
      const float* kp  = pukp + (size_t)u * 4096;
      float* RTu = RT + u * 8192;
      addJ(S, JG(qp, 1, 512, kp, 8, 1, nullptr, 0, 0, RTu, 16, 1, 0, 512, 8, 512), 4096);
      addJ(S, JG(qp, 1, 512, puinb + u*1536 + 512, 1, 0, nullptr, 0, 0, RTu + 8, 16, 1, 0, 512, 1, 512), 512);
      addJ(S, JG(qp, 512, 1, puqb + u*512, 1, 0, puinb + u*1536, 1, 0, BQC + u*512, 1, 1, 0, 512, 1, 512), 512);
      addJ(S, JG(puop + (size_t)u*262144, 512, 1, puvp + (size_t)u*262144, 512, 1, nullptr, 0, 0, WOVF + (size_t)u*262144, 512, 1, 0, 512, 512, 512), 262144);
      addJ(S, JG(puop + (size_t)u*262144, 512, 1, puinb + u*1536 + 1024, 1, 0, puob + u*512, 1, 0, BOV + u*512, 1, 1, 0, 512, 1, 512), 512);
    }
    addJ(S, JG(aao, 512, 1, aav, 512, 1, nullptr, 0, 0, WOVCF, 512, 1, 0, 512, 512, 512), 262144);
    addJ(S, JG(aao, 512, 1, aainb + 1024, 1, 0, aaob, 1, 0, BOVC, 1, 1, 0, 512, 1, 512), 512);
    addJ(S, JG(aaq, 1, 512, aak, 512, 1, nullptr, 0, 0, PMAT, 516, 1, 0, 512, 512, 512), 262144);
    addJ(S, JG(aaq, 1, 512, aainb + 512, 1, 0, nullptr, 0, 0, PMAT + 512, 516, 1, 0, 512, 1, 512), 512);
    addJ(S, JG(aaq, 512, 1, tohb, 1, 0, aainb, 1, 0, CQ, 1, 1, 0, 512, 1, 512), 512);
    addJ(S, JG(dWih, 2048, 1, nullptr, 0, 0, nullptr, 0, 0, DWF, 2048, 1, 1, 1536, 512, 0, 1), 786432);
    addJ(S, JG(dWih + 1536, 2048, 1, nullptr, 0, 0, nullptr, 0, 0, DWF + 1536, 2048, 1, 1, 1536, 512, 0, 1), 786432);
    addJ(S, JG(outW, 2048, 1, doW, 1024, 1, nullptr, 0, 0, OWF, 2560, 1, 1, 512, 1024, 512), 524288);
    addJ(S, JG(outW, 2048, 1, dob, 1, 0, outb, 1, 0, OUTB2, 1, 1, 0, 512, 1, 512), 512);
    addJ(S, JG(Ag, 0, 0, puAW, 0, 0, puAb, 0, 0, AM, 0, 0, 0, 0, 0, 0, 2), 65536);
    addJ(S, JG(Ag, 0, 0, nullptr, 0, 0, nullptr, 0, 0, PTRS, 0, 0, 0, 0, 0, 0, 3), 2048);
    k_setup<<<2048, 256, 0, stream>>>(S);
  }
  // -------- stage 2 --------
  {
    Jobs S{}; S.nj = 0; S.off[0] = 0;
    for (int u = 0; u < 2; u++){
      const float* kp = pukp + (size_t)u * 4096;
      addJ(S, JG(puqW + (size_t)u*262144, 1, 512, RT + u*8192, 16, 1, nullptr, 0, 0, KAx + u*8192, 16, 1, 0, 512, 9, 512), 4608);
      addJ(S, JG(BQC + u*512, 0, 1, kp, 8, 1, nullptr, 0, 0, CAE + u*16, 0, 1, 0, 1, 8, 512), 8);
      addJ(S, JG(BQC + u*512, 0, 1, puinb + u*1536 + 512, 1, 0, nullptr, 0, 0, CAE + u*16 + 8, 0, 1, 0, 1, 1, 512), 1);
      addJ(S, JG(dWih + 512 + u*512, 2048, 1, WOVF + (size_t)u*262144, 512, 1, nullptr, 0, 0, DWF + 512 + u*512, 2048, 1, 1, 1536, 512, 512), 786432);
      addJ(S, JG(outW + 512 + u*512, 2048, 1, WOVF + (size_t)u*262144, 512, 1, nullptr, 0, 0, OWF + 1024 + u*512, 2560, 1, 1, 512, 512, 512), 262144);
    }
    addJ(S, JG(tohW, 1, 1024, PMAT, 516, 1, nullptr, 0, 0, MKTF, 1, 1024, 0, 1024, 513, 512), 525312);
    addJ(S, JG(CQ, 0, 1, aak, 512, 1, nullptr, 0, 0, VKE2, 0, 1, 0, 1, 512, 512), 512);
    addJ(S, JG(CQ, 0, 1, aainb + 512, 1, 0, nullptr, 0, 0, VKE2 + 512, 0, 1, 0, 1, 1, 512), 1);
    addJ(S, JG(dWih + 512, 2048, 1, BOV, 1, 0, dbih, 1, 0, DBIH2, 1, 1, 0, 1536, 1, 1024), 1536);
    addJ(S, JG(outW + 1536, 2048, 1, WOVCF, 512, 1, nullptr, 0, 0, OWF + 2048, 2560, 1, 1, 512, 512, 512), 262144);
    addJ(S, JG(outW + 512, 2048, 1, BOV, 1, 0, OUTB2, 1, 0, OUTB2, 1, 1, 0, 512, 1, 1536), 512);
    k_setup<<<2048, 256, 0, stream>>>(S);
  }
  // -------- stage 3 --------
  {
    Jobs S{}; S.nj = 0; S.off[0] = 0;
    for (int u = 0; u < 2; u++)
      addJ(S, JG(MKTF + u*512, 1024, 1, WOVF + (size_t)u*262144, 512, 1, nullptr, 0, 0, MKTW + u*512, 1024, 1, 1, 513, 512, 512), 262656);
    addJ(S, JG(MKTF, 1024, 1, BOV, 1, 0, VKE2, 1, 0, VKE2, 1, 1, 0, 513, 1, 1024), 513);
    k_setup<<<1024, 256, 0, stream>>>(S);
  }

  // -------- encoder: 8 chunks of (gi GEMM + persistent 32-step scan) --------
  for (int c = 0; c < 8; c++){
    int c0 = c * 32;
    NTA nt{};
    nt.tilesN = 12;
    for (int d = 0; d < 2; d++){
      NTZ& zz = nt.z[d];
      zz.sg[0] = mkseg(d == 0 ? (const void*)(src + (size_t)c0 * 65536) : (const void*)src, 512, 1, 512);
      zz.sg[1] = SENT; zz.sg[2] = SENT;
      zz.Bp = d ? eWihB : eWihF; zz.ldb = 512; zz.bf32 = 1;
      zz.bias = nullptr; zz.biasf32 = 0;
      zz.Cp = GI + (size_t)d * 6291456; zz.ldc = 1536; zz.cf32 = 1; zz.cslab = 0;
      zz.N = 1536; zz.rev_s0 = (d == 0) ? -1 : (255 - c0); zz.K = 512;
    }
    k_mfma_nt<128><<<dim3(32*12, 1, 2), 256, 0, stream>>>(nt);

    EncArgs ea;
    ea.WhhF = eWhhF; ea.WhhB = eWhhB;
    ea.giF = GI; ea.giB = GI + 6291456;
    ea.bihF = ebihF; ea.bhhF = ebhhF; ea.bihB = ebihB; ea.bhhB = ebhhB;
    ea.HF = HF; ea.HB = HB; ea.HFB = HFB; ea.HBB = HBB; ea.ENC = ENC;
    ea.BAR = BAR; ea.bar0 = c * 32;
    ea.s0 = c0;
    k_enc<<<dim3(64), dim3(256), 0, stream>>>(ea);
  }

  // -------- enc_att = enc @ W2.T + b --------
  {
    NTA nt{};
    nt.tilesN = 4;
    NTZ& zz = nt.z[0];
    zz.sg[0] = mkseg(ENC, 512, 0, 512); zz.sg[1] = SENT; zz.sg[2] = SENT;
    zz.Bp = dattW + 512; zz.ldb = 1024; zz.bf32 = 1;
    zz.bias = dattb; zz.biasf32 = 1;
    zz.Cp = EATT; zz.ldc = 512; zz.cf32 = 0; zz.cslab = 0;
    zz.N = 512; zz.rev_s0 = -1; zz.K = 512;
    k_mfma_nt<128><<<dim3(256*4, 1, 1), 256, 0, stream>>>(nt);
  }

  // -------- decoder: one persistent kernel, all 64 steps --------
  {
    DecArgs da;
    da.tgt = tgt; da.Ag = Ag; da.AM = AM; da.KA = KAx; da.CAE = CAE;
    da.dattW = dattW; da.dattv = dattv;
    da.puWhh = puWhh; da.puWih = puWih; da.pubih = pubih; da.pubhh = pubhh;
    da.dWhh = dWhh; da.DBIH2 = DBIH2; da.dbhh = dbhh; da.VKE2 = VKE2; da.OUTB2 = OUTB2;
    da.ENC = ENC; da.EATT = EATT; da.DWF = DWF; da.MKTW = MKTW; da.OWF = OWF;
    da.HIDA = HIDA; da.HIDAB = HIDAB; da.DECH = DECH; da.DECHB = DECHB;
    da.HF0 = HF; da.HFB0 = HFB;
    da.PTRS = PTRS; da.VPRE = VPRE; da.CTX = CTX; da.DPART = DPART;
    da.QCK = QCK; da.CV2P = CV2P; da.GIDEC = GIDEC; da.OUTT = OUTT;
    da.out = (float*)d_out;
    da.BAR = BAR;
    k_dec<<<dim3(256), dim3(256), 0, stream>>>(da);
  }
}